// Round 1
// baseline (1391.498 us; speedup 1.0000x reference)
//
#include <hip/hip_runtime.h>
#include <math.h>

// ---------------------------------------------------------------------------
// LDSTNet forward, fp32 correctness-first implementation.
// B=64, C=64, T=64, N=25, Ci=32. Pools: R1=19, R2=15.
//
// Workspace layout (floats):
//   xcd1   @ 0          : 6,553,600   (B,C,T,25)
//   Pperm  @ 6,553,600  : 6,553,600   (B,4096,25) raw-reshape pre-act pool input; reused as xcd3
//   xcd2   @ 13,107,200 : 6,553,600   (B,C,T,25)
//   x2buf  @ 19,660,800 : 4,980,736   (B,C,T,19) / (B,C,T,15)
//   prebuf @ 24,641,536 : 4,980,736   (B,C,T,19) / (B,C,T,15)
//   F3buf  @ 29,622,272 : 30,400
//   uvbuf  @ 29,652,672 : 320         wu2,wv2,wu3,wv3 (64 each), cu2,cv2,cu3,cv3
// Total ≈ 29,652,992 floats ≈ 118.6 MB.
// ---------------------------------------------------------------------------

#define BN_SCALE_F 0.9999950000374997f

// ---- precompute wu = wcat[:Ci]@Wt, wv = wcat[Ci:]@Wph, cu, cv for both tags
__global__ void prep_uv(const float* __restrict__ Wt2, const float* __restrict__ bt2,
                        const float* __restrict__ Wph2, const float* __restrict__ bph2,
                        const float* __restrict__ wcat2,
                        const float* __restrict__ Wt3, const float* __restrict__ bt3,
                        const float* __restrict__ Wph3, const float* __restrict__ bph3,
                        const float* __restrict__ wcat3,
                        float* __restrict__ uv) {
  int c = threadIdx.x;
  if (c < 64) {
    float s1 = 0.f, s2 = 0.f, s3 = 0.f, s4 = 0.f;
    for (int i = 0; i < 32; ++i) {
      s1 += wcat2[i]      * Wt2[i * 64 + c];
      s2 += wcat2[32 + i] * Wph2[i * 64 + c];
      s3 += wcat3[i]      * Wt3[i * 64 + c];
      s4 += wcat3[32 + i] * Wph3[i * 64 + c];
    }
    uv[c] = s1; uv[64 + c] = s2; uv[128 + c] = s3; uv[192 + c] = s4;
  }
  if (c == 0) {
    float c1 = 0.f, c2 = 0.f, c3 = 0.f, c4 = 0.f;
    for (int i = 0; i < 32; ++i) {
      c1 += wcat2[i] * bt2[i];       c2 += wcat2[32 + i] * bph2[i];
      c3 += wcat3[i] * bt3[i];       c4 += wcat3[32 + i] * bph3[i];
    }
    uv[256] = c1; uv[257] = c2; uv[258] = c3; uv[259] = c4;
  }
}

// ---- ldnet1 fused: FA1 (in LDS only), x_cd1 = x@FA1, P = (x@FA1)@FA1 written
// ---- directly in the pool's raw-reshape permuted layout (pre-activation).
__global__ void ldnet1_fused(const float* __restrict__ x, const float* __restrict__ A,
                             float* __restrict__ xcd1, float* __restrict__ Pperm) {
  const int b = blockIdx.x >> 6;
  const int t = blockIdx.x & 63;
  const int tid = threadIdx.x;
  __shared__ float xt[64][25];
  __shared__ float fa[25][25];
  __shared__ float ot[64][25];
  for (int idx = tid; idx < 1600; idx += 256) {
    int c = idx / 25, n = idx % 25;
    xt[c][n] = x[((b * 64 + c) * 64 + t) * 25 + n];
  }
  __syncthreads();
  for (int idx = tid; idx < 625; idx += 256) {
    int n = idx / 25, m = idx % 25;
    float s = 0.f;
    #pragma unroll
    for (int c = 0; c < 64; ++c) s += xt[c][n] * xt[c][m];
    fa[n][m] = s * 0.125f;
  }
  __syncthreads();
  if (tid < 25) {
    int n = tid;
    float mx = -1e30f;
    for (int m = 0; m < 25; ++m) mx = fmaxf(mx, fa[n][m]);
    float sum = 0.f;
    for (int m = 0; m < 25; ++m) sum += __expf(fa[n][m] - mx);
    float inv = 1.f / sum;
    for (int m = 0; m < 25; ++m) fa[n][m] = __expf(fa[n][m] - mx) * inv + A[n * 25 + m];
  }
  __syncthreads();
  for (int idx = tid; idx < 1600; idx += 256) {
    int c = idx / 25, m = idx % 25;
    float s = 0.f;
    #pragma unroll
    for (int n = 0; n < 25; ++n) s += xt[c][n] * fa[n][m];
    ot[c][m] = s;
    xcd1[((b * 64 + c) * 64 + t) * 25 + m] = s;
  }
  __syncthreads();
  for (int idx = tid; idx < 1600; idx += 256) {
    int c = idx / 25, l = idx % 25;
    float s = 0.f;
    #pragma unroll
    for (int n = 0; n < 25; ++n) s += ot[c][n] * fa[n][l];
    // raw-reshape flat = c*1600 + l*64 + t ; Pperm addr = b*102400 + flat
    Pperm[b * 102400 + c * 1600 + l * 64 + t] = s;
  }
}

// ---- generic ldnet (no P, FA in LDS only)
template<int M>
__global__ void ldnet_g(const float* __restrict__ in, const float* __restrict__ A,
                        float* __restrict__ outp) {
  const int b = blockIdx.x >> 6;
  const int t = blockIdx.x & 63;
  const int tid = threadIdx.x;
  __shared__ float xt[64][M];
  __shared__ float fa[M][M];
  for (int idx = tid; idx < 64 * M; idx += 256) {
    int c = idx / M, n = idx % M;
    xt[c][n] = in[((b * 64 + c) * 64 + t) * M + n];
  }
  __syncthreads();
  for (int idx = tid; idx < M * M; idx += 256) {
    int n = idx / M, m = idx % M;
    float s = 0.f;
    #pragma unroll
    for (int c = 0; c < 64; ++c) s += xt[c][n] * xt[c][m];
    fa[n][m] = s * 0.125f;
  }
  __syncthreads();
  if (tid < M) {
    int n = tid;
    float mx = -1e30f;
    for (int m = 0; m < M; ++m) mx = fmaxf(mx, fa[n][m]);
    float sum = 0.f;
    for (int m = 0; m < M; ++m) sum += __expf(fa[n][m] - mx);
    float inv = 1.f / sum;
    for (int m = 0; m < M; ++m) fa[n][m] = __expf(fa[n][m] - mx) * inv + A[n * M + m];
  }
  __syncthreads();
  for (int idx = tid; idx < 64 * M; idx += 256) {
    int c = idx / M, m = idx % M;
    float s = 0.f;
    #pragma unroll
    for (int n = 0; n < M; ++n) s += xt[c][n] * fa[n][m];
    outp[((b * 64 + c) * 64 + t) * M + m] = s;
  }
}

// ---- pool linear + softmax: logits[b,j,r] = sum_i prelu(Pperm[b,i,j]) * Wp[r,i]
template<int R>
__global__ void pool_linear(const float* __restrict__ Pperm, const float* __restrict__ Wp,
                            const float* __restrict__ ap_, float* __restrict__ F3) {
  const int b = blockIdx.x;
  const int tid = threadIdx.x;
  const float ap = ap_[0];
  __shared__ float pg[128][25];
  __shared__ float wc[R][128];
  __shared__ float lg[25][R];
  const int NP = 25 * R;
  float acc0 = 0.f, acc1 = 0.f;
  const int p0 = tid, p1 = tid + 256;
  const int j0 = p0 / R, r0 = p0 % R;
  const int j1 = p1 / R, r1 = p1 % R;
  for (int i0 = 0; i0 < 4096; i0 += 128) {
    for (int idx = tid; idx < 128 * 25; idx += 256) {
      int ii = idx / 25, j = idx % 25;
      float v = Pperm[b * 102400 + (i0 + ii) * 25 + j];
      pg[ii][j] = v >= 0.f ? v : ap * v;
    }
    for (int idx = tid; idx < R * 128; idx += 256) {
      int r = idx >> 7, ii = idx & 127;
      wc[r][ii] = Wp[r * 4096 + i0 + ii];
    }
    __syncthreads();
    if (p0 < NP) {
      #pragma unroll 8
      for (int ii = 0; ii < 128; ++ii) acc0 += pg[ii][j0] * wc[r0][ii];
    }
    if (p1 < NP) {
      #pragma unroll 8
      for (int ii = 0; ii < 128; ++ii) acc1 += pg[ii][j1] * wc[r1][ii];
    }
    __syncthreads();
  }
  if (p0 < NP) lg[j0][r0] = acc0;
  if (p1 < NP) lg[j1][r1] = acc1;
  __syncthreads();
  if (tid < 25) {
    float mx = -1e30f;
    for (int r = 0; r < R; ++r) mx = fmaxf(mx, lg[tid][r]);
    float sum = 0.f;
    for (int r = 0; r < R; ++r) sum += __expf(lg[tid][r] - mx);
    float inv = 1.f / sum;
    for (int r = 0; r < R; ++r) F3[(b * 25 + tid) * R + r] = __expf(lg[tid][r] - mx) * inv;
  }
}

// ---- x2[b,c,t,r] = sum_n xcd1[b,c,t,n] * F3[b,n,r]
template<int R>
__global__ void x2_einsum(const float* __restrict__ xcd1, const float* __restrict__ F3,
                          float* __restrict__ x2) {
  const int row = blockIdx.x * 256 + threadIdx.x;  // row = b*4096 + c*64 + t
  const int b = row >> 12;
  __shared__ float f3[25 * R];
  for (int idx = threadIdx.x; idx < 25 * R; idx += 256) f3[idx] = F3[b * 25 * R + idx];
  __syncthreads();
  float xr[25];
  #pragma unroll
  for (int n = 0; n < 25; ++n) xr[n] = xcd1[row * 25 + n];
  float acc[R];
  #pragma unroll
  for (int r = 0; r < R; ++r) acc[r] = 0.f;
  #pragma unroll
  for (int n = 0; n < 25; ++n) {
    float v = xr[n];
    #pragma unroll
    for (int r = 0; r < R; ++r) acc[r] += v * f3[n * R + r];
  }
  #pragma unroll
  for (int r = 0; r < R; ++r) x2[row * R + r] = acc[r];
}

// ---- restore: g_x + rank-1 attention + apply + BN(eval)+ReLU, all in one block per (b,t)
template<int M>
__global__ void restore_k(const float* __restrict__ xcd1, const float* __restrict__ pre,
                          const float* __restrict__ Wg, const float* __restrict__ bg,
                          const float* __restrict__ Ck, const float* __restrict__ wu,
                          const float* __restrict__ wv, const float* __restrict__ cuv,
                          float* __restrict__ outk) {
  const int b = blockIdx.x >> 6;
  const int t = blockIdx.x & 63;
  const int tid = threadIdx.x;
  __shared__ float xt[64][25];
  __shared__ float yt[64][M];
  __shared__ float wg[64][64];
  __shared__ float gx[M][64];
  __shared__ float att[25][M];
  __shared__ float uu[25];
  __shared__ float vv[M];
  for (int idx = tid; idx < 1600; idx += 256) {
    int c = idx / 25, n = idx % 25;
    xt[c][n] = xcd1[((b * 64 + c) * 64 + t) * 25 + n];
  }
  for (int idx = tid; idx < 64 * M; idx += 256) {
    int c = idx / M, m = idx % M;
    yt[c][m] = pre[((b * 64 + c) * 64 + t) * M + m];
  }
  for (int idx = tid; idx < 4096; idx += 256) wg[idx >> 6][idx & 63] = Wg[idx];
  __syncthreads();
  for (int idx = tid; idx < M * 64; idx += 256) {
    int m = idx >> 6, g = idx & 63;
    float s = bg[g];
    #pragma unroll
    for (int c = 0; c < 64; ++c) s += wg[g][c] * yt[c][m];
    gx[m][g] = s;
  }
  if (tid < 25) {
    float s = cuv[0];
    #pragma unroll
    for (int c = 0; c < 64; ++c) s += wu[c] * xt[c][tid];
    uu[tid] = s;
  }
  if (tid >= 64 && tid < 64 + M) {
    int m = tid - 64;
    float s = cuv[1];
    #pragma unroll
    for (int c = 0; c < 64; ++c) s += wv[c] * yt[c][m];
    vv[m] = s;
  }
  __syncthreads();
  if (tid < 25) {
    int n = tid;
    float f[M];
    float mx = -1e30f;
    #pragma unroll
    for (int m = 0; m < M; ++m) {
      float v = uu[n] + vv[m];
      v = v >= 0.f ? v : 0.2f * v;      // leaky_relu 0.2
      f[m] = v;
      mx = fmaxf(mx, v);
    }
    float sum = 0.f;
    #pragma unroll
    for (int m = 0; m < M; ++m) { f[m] = __expf(f[m] - mx); sum += f[m]; }
    float inv = 1.f / sum;
    #pragma unroll
    for (int m = 0; m < M; ++m) att[n][m] = f[m] * inv + Ck[n * M + m];
  }
  __syncthreads();
  for (int idx = tid; idx < 1600; idx += 256) {
    int g = idx / 25, n = idx % 25;
    float s = 0.f;
    #pragma unroll
    for (int m = 0; m < M; ++m) s += att[n][m] * gx[m][g];
    outk[((b * 64 + g) * 64 + t) * 25 + n] = fmaxf(s * BN_SCALE_F, 0.f);
  }
}

// ---- final: 3x1 temporal conv over concat(x,xcd1,xcd2,xcd3) + bias, BN, residual, PReLU
// Block: (b, t-tile of 6). 240 active compute threads: 6 t x 8 og x 5 ng.
// Thread register tile: 8 o x 5 n. LDS: one 64-channel chunk of h, 8 t-slots.
__global__ void conv_out(const float* __restrict__ x, const float* __restrict__ xcd1,
                         const float* __restrict__ xcd2, const float* __restrict__ xcd3,
                         const float* __restrict__ Wtcn, const float* __restrict__ btcn,
                         const float* __restrict__ aout_, float* __restrict__ out) {
  const int b = blockIdx.x / 11;
  const int tile = blockIdx.x % 11;
  const int t0 = tile * 6;
  const int tcount = (64 - t0) < 6 ? (64 - t0) : 6;
  const int tid = threadIdx.x;
  __shared__ float hs[64][8][25];   // [ci][tt][n], tt spans t0-1 .. t0+6  (51.2 KB)

  const int tl = tid / 40;          // 0..5 (tid<240)
  const int r  = tid % 40;
  const int og = r / 5;             // 0..7  -> o = og*8+oo
  const int ng = r % 5;             // 0..4  -> n = ng*5+nn
  const bool active = (tid < 240) && (tl < tcount);

  float acc[8][5];
  #pragma unroll
  for (int oo = 0; oo < 8; ++oo)
    #pragma unroll
    for (int nn = 0; nn < 5; ++nn) acc[oo][nn] = 0.f;

  const float* srcs[4] = {x, xcd1, xcd2, xcd3};

  for (int cc = 0; cc < 4; ++cc) {
    __syncthreads();
    const float* s = srcs[cc];
    for (int idx = tid; idx < 64 * 8 * 25; idx += 256) {
      int ci = idx / 200;
      int rem = idx % 200;
      int tt = rem / 25, n = rem % 25;
      int tg = t0 - 1 + tt;
      float v = 0.f;
      if (tg >= 0 && tg < 64) v = s[((b * 64 + ci) * 64 + tg) * 25 + n];
      hs[ci][tt][n] = v;
    }
    __syncthreads();
    if (active) {
      for (int i = 0; i < 64; ++i) {
        #pragma unroll
        for (int kt = 0; kt < 3; ++kt) {
          float w[8];
          #pragma unroll
          for (int oo = 0; oo < 8; ++oo)
            w[oo] = Wtcn[((og * 8 + oo) * 256 + cc * 64 + i) * 3 + kt];
          float h[5];
          #pragma unroll
          for (int nn = 0; nn < 5; ++nn) h[nn] = hs[i][tl + kt][ng * 5 + nn];
          #pragma unroll
          for (int oo = 0; oo < 8; ++oo)
            #pragma unroll
            for (int nn = 0; nn < 5; ++nn) acc[oo][nn] += w[oo] * h[nn];
        }
      }
    }
  }
  if (active) {
    const float aout = aout_[0];
    const int t = t0 + tl;
    #pragma unroll
    for (int oo = 0; oo < 8; ++oo) {
      const int o = og * 8 + oo;
      const float bo = btcn[o];
      #pragma unroll
      for (int nn = 0; nn < 5; ++nn) {
        const int n = ng * 5 + nn;
        float v = (acc[oo][nn] + bo) * BN_SCALE_F + x[((b * 64 + o) * 64 + t) * 25 + n];
        out[((b * 64 + o) * 64 + t) * 25 + n] = v >= 0.f ? v : aout * v;
      }
    }
  }
}

extern "C" void kernel_launch(void* const* d_in, const int* in_sizes, int n_in,
                              void* d_out, int out_size, void* d_ws, size_t ws_size,
                              hipStream_t stream) {
  const float* x     = (const float*)d_in[0];
  const float* A1    = (const float*)d_in[1];
  const float* A2    = (const float*)d_in[2];
  const float* A3    = (const float*)d_in[3];
  const float* Wp1   = (const float*)d_in[4];
  const float* ap1   = (const float*)d_in[5];
  const float* Wp2   = (const float*)d_in[6];
  const float* ap2   = (const float*)d_in[7];
  const float* Wg2   = (const float*)d_in[8];
  const float* bg2   = (const float*)d_in[9];
  const float* Wt2   = (const float*)d_in[10];
  const float* bt2   = (const float*)d_in[11];
  const float* Wph2  = (const float*)d_in[12];
  const float* bph2  = (const float*)d_in[13];
  const float* wcat2 = (const float*)d_in[14];
  const float* Ck2   = (const float*)d_in[15];
  const float* Wg3   = (const float*)d_in[16];
  const float* bg3   = (const float*)d_in[17];
  const float* Wt3   = (const float*)d_in[18];
  const float* bt3   = (const float*)d_in[19];
  const float* Wph3  = (const float*)d_in[20];
  const float* bph3  = (const float*)d_in[21];
  const float* wcat3 = (const float*)d_in[22];
  const float* Ck3   = (const float*)d_in[23];
  const float* Wtcn  = (const float*)d_in[24];
  const float* btcn  = (const float*)d_in[25];
  const float* aout  = (const float*)d_in[26];
  float* out = (float*)d_out;
  float* ws  = (float*)d_ws;

  float* xcd1 = ws;
  float* Pp   = ws + 6553600;      // Pperm; reused as xcd3 after pool2 consumes it
  float* xcd2 = ws + 13107200;
  float* x2b  = ws + 19660800;     // x_2 (R=19) then x_3 (R=15)
  float* preb = ws + 24641536;     // x_cd2_pre then x_cd3_pre
  float* F3b  = ws + 29622272;
  float* uv   = ws + 29652672;

  prep_uv<<<1, 64, 0, stream>>>(Wt2, bt2, Wph2, bph2, wcat2,
                                Wt3, bt3, Wph3, bph3, wcat3, uv);
  ldnet1_fused<<<4096, 256, 0, stream>>>(x, A1, xcd1, Pp);

  // branch 2 (R=19)
  pool_linear<19><<<64, 256, 0, stream>>>(Pp, Wp1, ap1, F3b);
  x2_einsum<19><<<1024, 256, 0, stream>>>(xcd1, F3b, x2b);
  ldnet_g<19><<<4096, 256, 0, stream>>>(x2b, A2, preb);
  restore_k<19><<<4096, 256, 0, stream>>>(xcd1, preb, Wg2, bg2, Ck2,
                                          uv, uv + 64, uv + 256, xcd2);

  // branch 3 (R=15)
  pool_linear<15><<<64, 256, 0, stream>>>(Pp, Wp2, ap2, F3b);
  x2_einsum<15><<<1024, 256, 0, stream>>>(xcd1, F3b, x2b);
  ldnet_g<15><<<4096, 256, 0, stream>>>(x2b, A3, preb);
  restore_k<15><<<4096, 256, 0, stream>>>(xcd1, preb, Wg3, bg3, Ck3,
                                          uv + 128, uv + 192, uv + 258, Pp /* xcd3 */);

  // final conv + bias + BN + residual + PReLU
  conv_out<<<64 * 11, 256, 0, stream>>>(x, xcd1, xcd2, Pp, Wtcn, btcn, aout, out);
}

// Round 3
// 630.472 us; speedup vs baseline: 2.2071x; 2.2071x over previous
//
#include <hip/hip_runtime.h>
#include <math.h>

// ---------------------------------------------------------------------------
// LDSTNet forward. B=64, C=64, T=64, N=25, Ci=32. Pools: R1=19, R2=15.
//
// Workspace layout (floats):
//   xcd1   @ 0          : 6,553,600   (B,C,T,25)
//   Pperm  @ 6,553,600  : 6,553,600   (B,4096,25) raw-reshape pre-act pool input; reused as xcd3
//   xcd2   @ 13,107,200 : 6,553,600   (B,C,T,25)
//   x2buf  @ 19,660,800 : 4,980,736   partials (64x32x850) -> x_2/x_3 -> wT (49,152)
//   prebuf @ 24,641,536 : 4,980,736   (B,C,T,19) / (B,C,T,15)
//   F19    @ 29,622,272 : 30,400
//   F15    @ 29,652,672 : 24,000
//   uvbuf  @ 29,676,672 : 320
// ---------------------------------------------------------------------------

#define BN_SCALE_F 0.9999950000374997f

// ---- precompute wu = wcat[:Ci]@Wt, wv = wcat[Ci:]@Wph, cu, cv for both tags
__global__ void prep_uv(const float* __restrict__ Wt2, const float* __restrict__ bt2,
                        const float* __restrict__ Wph2, const float* __restrict__ bph2,
                        const float* __restrict__ wcat2,
                        const float* __restrict__ Wt3, const float* __restrict__ bt3,
                        const float* __restrict__ Wph3, const float* __restrict__ bph3,
                        const float* __restrict__ wcat3,
                        float* __restrict__ uv) {
  int c = threadIdx.x;
  if (c < 64) {
    float s1 = 0.f, s2 = 0.f, s3 = 0.f, s4 = 0.f;
    for (int i = 0; i < 32; ++i) {
      s1 += wcat2[i]      * Wt2[i * 64 + c];
      s2 += wcat2[32 + i] * Wph2[i * 64 + c];
      s3 += wcat3[i]      * Wt3[i * 64 + c];
      s4 += wcat3[32 + i] * Wph3[i * 64 + c];
    }
    uv[c] = s1; uv[64 + c] = s2; uv[128 + c] = s3; uv[192 + c] = s4;
  }
  if (c == 0) {
    float c1 = 0.f, c2 = 0.f, c3 = 0.f, c4 = 0.f;
    for (int i = 0; i < 32; ++i) {
      c1 += wcat2[i] * bt2[i];       c2 += wcat2[32 + i] * bph2[i];
      c3 += wcat3[i] * bt3[i];       c4 += wcat3[32 + i] * bph3[i];
    }
    uv[256] = c1; uv[257] = c2; uv[258] = c3; uv[259] = c4;
  }
}

// ---- ldnet1 fused: FA1 (LDS only), x_cd1 = x@FA1, P = (x@FA1)@FA1 in pool layout
__global__ void ldnet1_fused(const float* __restrict__ x, const float* __restrict__ A,
                             float* __restrict__ xcd1, float* __restrict__ Pperm) {
  const int b = blockIdx.x >> 6;
  const int t = blockIdx.x & 63;
  const int tid = threadIdx.x;
  __shared__ float xt[64][25];
  __shared__ float fa[25][25];
  __shared__ float ot[64][25];
  for (int idx = tid; idx < 1600; idx += 256) {
    int c = idx / 25, n = idx % 25;
    xt[c][n] = x[((b * 64 + c) * 64 + t) * 25 + n];
  }
  __syncthreads();
  for (int idx = tid; idx < 625; idx += 256) {
    int n = idx / 25, m = idx % 25;
    float s = 0.f;
    #pragma unroll
    for (int c = 0; c < 64; ++c) s += xt[c][n] * xt[c][m];
    fa[n][m] = s * 0.125f;
  }
  __syncthreads();
  if (tid < 25) {
    int n = tid;
    float mx = -1e30f;
    for (int m = 0; m < 25; ++m) mx = fmaxf(mx, fa[n][m]);
    float sum = 0.f;
    for (int m = 0; m < 25; ++m) sum += __expf(fa[n][m] - mx);
    float inv = 1.f / sum;
    for (int m = 0; m < 25; ++m) fa[n][m] = __expf(fa[n][m] - mx) * inv + A[n * 25 + m];
  }
  __syncthreads();
  for (int idx = tid; idx < 1600; idx += 256) {
    int c = idx / 25, m = idx % 25;
    float s = 0.f;
    #pragma unroll
    for (int n = 0; n < 25; ++n) s += xt[c][n] * fa[n][m];
    ot[c][m] = s;
    xcd1[((b * 64 + c) * 64 + t) * 25 + m] = s;
  }
  __syncthreads();
  for (int idx = tid; idx < 1600; idx += 256) {
    int c = idx / 25, l = idx % 25;
    float s = 0.f;
    #pragma unroll
    for (int n = 0; n < 25; ++n) s += ot[c][n] * fa[n][l];
    Pperm[b * 102400 + c * 1600 + l * 64 + t] = s;
  }
}

// ---- generic ldnet
template<int M>
__global__ void ldnet_g(const float* __restrict__ in, const float* __restrict__ A,
                        float* __restrict__ outp) {
  const int b = blockIdx.x >> 6;
  const int t = blockIdx.x & 63;
  const int tid = threadIdx.x;
  __shared__ float xt[64][M];
  __shared__ float fa[M][M];
  for (int idx = tid; idx < 64 * M; idx += 256) {
    int c = idx / M, n = idx % M;
    xt[c][n] = in[((b * 64 + c) * 64 + t) * M + n];
  }
  __syncthreads();
  for (int idx = tid; idx < M * M; idx += 256) {
    int n = idx / M, m = idx % M;
    float s = 0.f;
    #pragma unroll
    for (int c = 0; c < 64; ++c) s += xt[c][n] * xt[c][m];
    fa[n][m] = s * 0.125f;
  }
  __syncthreads();
  if (tid < M) {
    int n = tid;
    float mx = -1e30f;
    for (int m = 0; m < M; ++m) mx = fmaxf(mx, fa[n][m]);
    float sum = 0.f;
    for (int m = 0; m < M; ++m) sum += __expf(fa[n][m] - mx);
    float inv = 1.f / sum;
    for (int m = 0; m < M; ++m) fa[n][m] = __expf(fa[n][m] - mx) * inv + A[n * M + m];
  }
  __syncthreads();
  for (int idx = tid; idx < 64 * M; idx += 256) {
    int c = idx / M, m = idx % M;
    float s = 0.f;
    #pragma unroll
    for (int n = 0; n < M; ++n) s += xt[c][n] * fa[n][m];
    outp[((b * 64 + c) * 64 + t) * M + m] = s;
  }
}

// ---- fused pool partials for BOTH branches (single pass over Pperm).
// grid: 64 b x 32 chunks (128 i each). Item group per thread: (j, aligned r-quad).
// r slots in wct: 0..18 = branch1 (R=19), 20..34 = branch2 (R=15).
__global__ void pool_partial(const float* __restrict__ Pperm,
                             const float* __restrict__ Wp1, const float* __restrict__ Wp2,
                             const float* __restrict__ ap1_, const float* __restrict__ ap2_,
                             float* __restrict__ partials) {
  const int b = blockIdx.x >> 5;
  const int ch = blockIdx.x & 31;
  const int i0 = ch << 7;
  const int tid = threadIdx.x;
  const float a1 = ap1_[0], a2 = ap2_[0];
  __shared__ float pg1[128][25];
  __shared__ float pg2[128][25];
  __shared__ float wct[128][36];
  for (int idx = tid; idx < 3200; idx += 256) {
    float v = Pperm[b * 102400 + i0 * 25 + idx];
    int ii = idx / 25, j = idx - ii * 25;
    pg1[ii][j] = v >= 0.f ? v : a1 * v;
    pg2[ii][j] = v >= 0.f ? v : a2 * v;
  }
  for (int idx = tid; idx < 19 * 128; idx += 256) {
    int r = idx >> 7, ii = idx & 127;
    wct[ii][r] = Wp1[r * 4096 + i0 + ii];
  }
  for (int idx = tid; idx < 15 * 128; idx += 256) {
    int r = idx >> 7, ii = idx & 127;
    wct[ii][20 + r] = Wp2[r * 4096 + i0 + ii];
  }
  __syncthreads();
  if (tid < 225) {
    const int j = tid / 9;
    const int g = tid - j * 9;
    const bool br1 = (g < 5);
    const int r0 = br1 ? g * 4 : 20 + (g - 5) * 4;
    const float* pgc = br1 ? &pg1[0][0] : &pg2[0][0];
    float acc0 = 0.f, acc1 = 0.f, acc2 = 0.f, acc3 = 0.f;
    #pragma unroll 4
    for (int ii = 0; ii < 128; ++ii) {
      float p = pgc[ii * 25 + j];
      const float4 wv = *(const float4*)&wct[ii][r0];
      acc0 += p * wv.x; acc1 += p * wv.y; acc2 += p * wv.z; acc3 += p * wv.w;
    }
    const int base = (b * 32 + ch) * 850;
    if (br1) {
      const int m = base + j * 19 + r0;
      partials[m] = acc0; partials[m + 1] = acc1; partials[m + 2] = acc2;
      if (g != 4) partials[m + 3] = acc3;
    } else {
      const int m = base + 475 + j * 15 + (r0 - 20);
      partials[m] = acc0; partials[m + 1] = acc1; partials[m + 2] = acc2;
      if (g != 8) partials[m + 3] = acc3;
    }
  }
}

// ---- reduce partials over 32 chunks + per-branch softmax
__global__ void pool_reduce(const float* __restrict__ partials,
                            float* __restrict__ F19, float* __restrict__ F15) {
  const int b = blockIdx.x;
  const int tid = threadIdx.x;
  __shared__ float lg[850];
  for (int m = tid; m < 850; m += 256) {
    float s = 0.f;
    for (int ch = 0; ch < 32; ++ch) s += partials[(b * 32 + ch) * 850 + m];
    lg[m] = s;
  }
  __syncthreads();
  if (tid < 25) {
    const float* row = lg + tid * 19;
    float mx = -1e30f;
    for (int r = 0; r < 19; ++r) mx = fmaxf(mx, row[r]);
    float sum = 0.f;
    for (int r = 0; r < 19; ++r) sum += __expf(row[r] - mx);
    float inv = 1.f / sum;
    for (int r = 0; r < 19; ++r)
      F19[(b * 25 + tid) * 19 + r] = __expf(row[r] - mx) * inv;
  } else if (tid >= 32 && tid < 57) {
    const int j = tid - 32;
    const float* row = lg + 475 + j * 15;
    float mx = -1e30f;
    for (int r = 0; r < 15; ++r) mx = fmaxf(mx, row[r]);
    float sum = 0.f;
    for (int r = 0; r < 15; ++r) sum += __expf(row[r] - mx);
    float inv = 1.f / sum;
    for (int r = 0; r < 15; ++r)
      F15[(b * 25 + j) * 15 + r] = __expf(row[r] - mx) * inv;
  }
}

// ---- x2[b,c,t,r] = sum_n xcd1[b,c,t,n] * F3[b,n,r]
template<int R>
__global__ void x2_einsum(const float* __restrict__ xcd1, const float* __restrict__ F3,
                          float* __restrict__ x2) {
  const int row = blockIdx.x * 256 + threadIdx.x;
  const int b = row >> 12;
  __shared__ float f3[25 * R];
  for (int idx = threadIdx.x; idx < 25 * R; idx += 256) f3[idx] = F3[b * 25 * R + idx];
  __syncthreads();
  float xr[25];
  #pragma unroll
  for (int n = 0; n < 25; ++n) xr[n] = xcd1[row * 25 + n];
  float acc[R];
  #pragma unroll
  for (int r = 0; r < R; ++r) acc[r] = 0.f;
  #pragma unroll
  for (int n = 0; n < 25; ++n) {
    float v = xr[n];
    #pragma unroll
    for (int r = 0; r < R; ++r) acc[r] += v * f3[n * R + r];
  }
  #pragma unroll
  for (int r = 0; r < R; ++r) x2[row * R + r] = acc[r];
}

// ---- restore: g_x + rank-1 attention + apply + BN(eval)+ReLU per (b,t)
template<int M>
__global__ void restore_k(const float* __restrict__ xcd1, const float* __restrict__ pre,
                          const float* __restrict__ Wg, const float* __restrict__ bg,
                          const float* __restrict__ Ck, const float* __restrict__ wu,
                          const float* __restrict__ wv, const float* __restrict__ cuv,
                          float* __restrict__ outk) {
  const int b = blockIdx.x >> 6;
  const int t = blockIdx.x & 63;
  const int tid = threadIdx.x;
  __shared__ float xt[64][25];
  __shared__ float yt[64][M];
  __shared__ float wg[64][64];
  __shared__ float gx[M][64];
  __shared__ float att[25][M];
  __shared__ float uu[25];
  __shared__ float vv[M];
  for (int idx = tid; idx < 1600; idx += 256) {
    int c = idx / 25, n = idx % 25;
    xt[c][n] = xcd1[((b * 64 + c) * 64 + t) * 25 + n];
  }
  for (int idx = tid; idx < 64 * M; idx += 256) {
    int c = idx / M, m = idx % M;
    yt[c][m] = pre[((b * 64 + c) * 64 + t) * M + m];
  }
  for (int idx = tid; idx < 4096; idx += 256) wg[idx >> 6][idx & 63] = Wg[idx];
  __syncthreads();
  for (int idx = tid; idx < M * 64; idx += 256) {
    int m = idx >> 6, g = idx & 63;
    float s = bg[g];
    #pragma unroll
    for (int c = 0; c < 64; ++c) s += wg[g][c] * yt[c][m];
    gx[m][g] = s;
  }
  if (tid < 25) {
    float s = cuv[0];
    #pragma unroll
    for (int c = 0; c < 64; ++c) s += wu[c] * xt[c][tid];
    uu[tid] = s;
  }
  if (tid >= 64 && tid < 64 + M) {
    int m = tid - 64;
    float s = cuv[1];
    #pragma unroll
    for (int c = 0; c < 64; ++c) s += wv[c] * yt[c][m];
    vv[m] = s;
  }
  __syncthreads();
  if (tid < 25) {
    int n = tid;
    float f[M];
    float mx = -1e30f;
    #pragma unroll
    for (int m = 0; m < M; ++m) {
      float v = uu[n] + vv[m];
      v = v >= 0.f ? v : 0.2f * v;
      f[m] = v;
      mx = fmaxf(mx, v);
    }
    float sum = 0.f;
    #pragma unroll
    for (int m = 0; m < M; ++m) { f[m] = __expf(f[m] - mx); sum += f[m]; }
    float inv = 1.f / sum;
    #pragma unroll
    for (int m = 0; m < M; ++m) att[n][m] = f[m] * inv + Ck[n * M + m];
  }
  __syncthreads();
  for (int idx = tid; idx < 1600; idx += 256) {
    int g = idx / 25, n = idx % 25;
    float s = 0.f;
    #pragma unroll
    for (int m = 0; m < M; ++m) s += att[n][m] * gx[m][g];
    outk[((b * 64 + g) * 64 + t) * 25 + n] = fmaxf(s * BN_SCALE_F, 0.f);
  }
}

// ---- transpose conv weights: wT[(ci*3+kt)*64 + o] = Wtcn[(o*256+ci)*3 + kt]
__global__ void transpose_w(const float* __restrict__ Wtcn, float* __restrict__ wT) {
  int idx = blockIdx.x * 256 + threadIdx.x;
  if (idx < 49152) {
    int o = idx & 63;
    int k = idx >> 6;
    int ci_g = k / 3, kt = k - ci_g * 3;
    wT[idx] = Wtcn[(o * 256 + ci_g) * 3 + kt];
  }
}

// ---- final conv: lane = output col (64 consec cols), wave = 16-o-channel group.
// Weights via wave-uniform (s_load) reads of wT; h via small zero-padded LDS window.
// grid: 64 b x 25 col-blocks = 1600 blocks, 256 threads.
__global__ __launch_bounds__(256) void conv_fast(
    const float* __restrict__ x, const float* __restrict__ xcd1,
    const float* __restrict__ xcd2, const float* __restrict__ xcd3,
    const float* __restrict__ wT, const float* __restrict__ btcn,
    const float* __restrict__ aout_, float* __restrict__ out) {
  const int blk = blockIdx.x;
  const int b = blk / 25;
  const int c0 = (blk - b * 25) * 64;
  const int tid = threadIdx.x;
  const int lane = tid & 63;
  const int og = __builtin_amdgcn_readfirstlane(tid >> 6);  // 0..3, wave-uniform
  const int c = c0 + lane;                                  // col in [0,1600)
  const int t_lo = c0 / 25 - 1;                             // may be -1
  const int off0 = c - 25 - t_lo * 25;                      // [0,87]

  __shared__ float hs[16][152];

  float acc[16];
  #pragma unroll
  for (int oo = 0; oo < 16; ++oo) acc[oo] = 0.f;

  for (int cs = 0; cs < 16; ++cs) {
    const float* sb = (cs < 8) ? ((cs < 4) ? x : xcd1) : ((cs < 12) ? xcd2 : xcd3);
    const float* sp = sb + (b * 64 + (cs & 3) * 16) * 1600;
    __syncthreads();
    for (int idx = tid; idx < 2400; idx += 256) {
      int ii = idx / 150, j = idx - ii * 150;
      int gg = t_lo * 25 + j;
      hs[ii][j] = (gg >= 0 && gg < 1600) ? sp[ii * 1600 + gg] : 0.f;
    }
    __syncthreads();
    const float* wb = wT + cs * 3072 + og * 16;   // 16 ci * 3 kt * 64 o = 3072 per chunk
    #pragma unroll 2
    for (int i = 0; i < 16; ++i) {
      float h0 = hs[i][off0];
      float h1 = hs[i][off0 + 25];
      float h2 = hs[i][off0 + 50];
      const float* wi = wb + i * 192;
      #pragma unroll
      for (int oo = 0; oo < 16; ++oo) {
        acc[oo] += wi[oo] * h0 + wi[64 + oo] * h1 + wi[128 + oo] * h2;
      }
    }
  }

  const float aout = aout_[0];
  const float* xres = x + (b * 64 + og * 16) * 1600 + c;
  float* op = out + (b * 64 + og * 16) * 1600 + c;
  #pragma unroll
  for (int oo = 0; oo < 16; ++oo) {
    float v = (acc[oo] + btcn[og * 16 + oo]) * BN_SCALE_F + xres[oo * 1600];
    op[oo * 1600] = v >= 0.f ? v : aout * v;
  }
}

extern "C" void kernel_launch(void* const* d_in, const int* in_sizes, int n_in,
                              void* d_out, int out_size, void* d_ws, size_t ws_size,
                              hipStream_t stream) {
  const float* x     = (const float*)d_in[0];
  const float* A1    = (const float*)d_in[1];
  const float* A2    = (const float*)d_in[2];
  const float* A3    = (const float*)d_in[3];
  const float* Wp1   = (const float*)d_in[4];
  const float* ap1   = (const float*)d_in[5];
  const float* Wp2   = (const float*)d_in[6];
  const float* ap2   = (const float*)d_in[7];
  const float* Wg2   = (const float*)d_in[8];
  const float* bg2   = (const float*)d_in[9];
  const float* Wt2   = (const float*)d_in[10];
  const float* bt2   = (const float*)d_in[11];
  const float* Wph2  = (const float*)d_in[12];
  const float* bph2  = (const float*)d_in[13];
  const float* wcat2 = (const float*)d_in[14];
  const float* Ck2   = (const float*)d_in[15];
  const float* Wg3   = (const float*)d_in[16];
  const float* bg3   = (const float*)d_in[17];
  const float* Wt3   = (const float*)d_in[18];
  const float* bt3   = (const float*)d_in[19];
  const float* Wph3  = (const float*)d_in[20];
  const float* bph3  = (const float*)d_in[21];
  const float* wcat3 = (const float*)d_in[22];
  const float* Ck3   = (const float*)d_in[23];
  const float* Wtcn  = (const float*)d_in[24];
  const float* btcn  = (const float*)d_in[25];
  const float* aout  = (const float*)d_in[26];
  float* out = (float*)d_out;
  float* ws  = (float*)d_ws;

  float* xcd1 = ws;
  float* Pp   = ws + 6553600;
  float* xcd2 = ws + 13107200;
  float* x2b  = ws + 19660800;
  float* preb = ws + 24641536;
  float* F19  = ws + 29622272;
  float* F15  = ws + 29652672;
  float* uv   = ws + 29676672;
  float* partials = x2b;   // 1,740,800 floats; dead before x2_einsum writes x2b
  float* wT       = x2b;   // 49,152 floats; written after x2b's last reader

  prep_uv<<<1, 64, 0, stream>>>(Wt2, bt2, Wph2, bph2, wcat2,
                                Wt3, bt3, Wph3, bph3, wcat3, uv);
  ldnet1_fused<<<4096, 256, 0, stream>>>(x, A1, xcd1, Pp);

  // both pools in one pass over Pperm
  pool_partial<<<2048, 256, 0, stream>>>(Pp, Wp1, Wp2, ap1, ap2, partials);
  pool_reduce<<<64, 256, 0, stream>>>(partials, F19, F15);

  // branch 2 (R=19)
  x2_einsum<19><<<1024, 256, 0, stream>>>(xcd1, F19, x2b);
  ldnet_g<19><<<4096, 256, 0, stream>>>(x2b, A2, preb);
  restore_k<19><<<4096, 256, 0, stream>>>(xcd1, preb, Wg2, bg2, Ck2,
                                          uv, uv + 64, uv + 256, xcd2);

  // branch 3 (R=15)
  x2_einsum<15><<<1024, 256, 0, stream>>>(xcd1, F15, x2b);
  ldnet_g<15><<<4096, 256, 0, stream>>>(x2b, A3, preb);
  transpose_w<<<192, 256, 0, stream>>>(Wtcn, wT);   // x2b region free after ldnet_g<15>
  restore_k<15><<<4096, 256, 0, stream>>>(xcd1, preb, Wg3, bg3, Ck3,
                                          uv + 128, uv + 192, uv + 258, Pp /* xcd3 */);

  // final conv + bias + BN + residual + PReLU
  conv_fast<<<1600, 256, 0, stream>>>(x, xcd1, xcd2, Pp, wT, btcn, aout, out);
}

// Round 5
// 393.226 us; speedup vs baseline: 3.5387x; 1.6033x over previous
//
#include <hip/hip_runtime.h>
#include <hip/hip_bf16.h>
#include <math.h>

// ---------------------------------------------------------------------------
// LDSTNet forward. B=64, C=64, T=64, N=25, Ci=32. Pools: R1=19, R2=15.
//
// Workspace layout (floats):
//   xcd1   @ 0          : 6,553,600   (B,C,T,25) fp32
//   R1     @ 6,553,600  : 6,553,600   Pperm fp32 (ldnet1->pool), then HbT_B bf16
//                                     [b][1600][128] (ci 0..63=xcd2, 64..127=xcd3)
//   R2     @ 13,107,200 : 6,553,600   HbT_A bf16 [b][1600][128] (0..63=x, 64..127=xcd1)
//   x2buf  @ 19,660,800 : 4,980,736   partials -> x_2/x_3 -> Wb bf16 (49,152)
//   prebuf @ 24,641,536 : 4,980,736   (B,C,T,19) / (B,C,T,15)
//   F19    @ 29,622,272 : 30,400
//   F15    @ 29,652,672 : 24,000
//   uvbuf  @ 29,676,672 : 320
// ---------------------------------------------------------------------------

#define BN_SCALE_F 0.9999950000374997f

typedef __attribute__((ext_vector_type(8))) short short8;
typedef __attribute__((ext_vector_type(4))) float f32x4;

// ---- precompute wu = wcat[:Ci]@Wt, wv = wcat[Ci:]@Wph, cu, cv for both tags
__global__ void prep_uv(const float* __restrict__ Wt2, const float* __restrict__ bt2,
                        const float* __restrict__ Wph2, const float* __restrict__ bph2,
                        const float* __restrict__ wcat2,
                        const float* __restrict__ Wt3, const float* __restrict__ bt3,
                        const float* __restrict__ Wph3, const float* __restrict__ bph3,
                        const float* __restrict__ wcat3,
                        float* __restrict__ uv) {
  int c = threadIdx.x;
  if (c < 64) {
    float s1 = 0.f, s2 = 0.f, s3 = 0.f, s4 = 0.f;
    for (int i = 0; i < 32; ++i) {
      s1 += wcat2[i]      * Wt2[i * 64 + c];
      s2 += wcat2[32 + i] * Wph2[i * 64 + c];
      s3 += wcat3[i]      * Wt3[i * 64 + c];
      s4 += wcat3[32 + i] * Wph3[i * 64 + c];
    }
    uv[c] = s1; uv[64 + c] = s2; uv[128 + c] = s3; uv[192 + c] = s4;
  }
  if (c == 0) {
    float c1 = 0.f, c2 = 0.f, c3 = 0.f, c4 = 0.f;
    for (int i = 0; i < 32; ++i) {
      c1 += wcat2[i] * bt2[i];       c2 += wcat2[32 + i] * bph2[i];
      c3 += wcat3[i] * bt3[i];       c4 += wcat3[32 + i] * bph3[i];
    }
    uv[256] = c1; uv[257] = c2; uv[258] = c3; uv[259] = c4;
  }
}

// ---- ldnet1 fused: FA1 (LDS only), x_cd1 = x@FA1, P = (x@FA1)@FA1 in pool layout.
// Also writes bf16 transposed sidecars HbT_A[b][col][ci]: ci 0..63 = x, 64..127 = xcd1.
__global__ void ldnet1_fused(const float* __restrict__ x, const float* __restrict__ A,
                             float* __restrict__ xcd1, float* __restrict__ Pperm,
                             __hip_bfloat16* __restrict__ HbTA) {
  const int b = blockIdx.x >> 6;
  const int t = blockIdx.x & 63;
  const int tid = threadIdx.x;
  __shared__ float xt[64][25];
  __shared__ float fa[25][25];
  __shared__ float ot[64][25];
  for (int idx = tid; idx < 1600; idx += 256) {
    int c = idx / 25, n = idx % 25;
    xt[c][n] = x[((b * 64 + c) * 64 + t) * 25 + n];
  }
  __syncthreads();
  for (int idx = tid; idx < 625; idx += 256) {
    int n = idx / 25, m = idx % 25;
    float s = 0.f;
    #pragma unroll
    for (int c = 0; c < 64; ++c) s += xt[c][n] * xt[c][m];
    fa[n][m] = s * 0.125f;
  }
  __syncthreads();
  if (tid < 25) {
    int n = tid;
    float mx = -1e30f;
    for (int m = 0; m < 25; ++m) mx = fmaxf(mx, fa[n][m]);
    float sum = 0.f;
    for (int m = 0; m < 25; ++m) sum += __expf(fa[n][m] - mx);
    float inv = 1.f / sum;
    for (int m = 0; m < 25; ++m) fa[n][m] = __expf(fa[n][m] - mx) * inv + A[n * 25 + m];
  }
  __syncthreads();
  for (int idx = tid; idx < 1600; idx += 256) {
    int c = idx / 25, m = idx % 25;
    float s = 0.f;
    #pragma unroll
    for (int n = 0; n < 25; ++n) s += xt[c][n] * fa[n][m];
    ot[c][m] = s;
    xcd1[((b * 64 + c) * 64 + t) * 25 + m] = s;
  }
  __syncthreads();
  for (int idx = tid; idx < 1600; idx += 256) {
    int c = idx / 25, l = idx % 25;
    float s = 0.f;
    #pragma unroll
    for (int n = 0; n < 25; ++n) s += ot[c][n] * fa[n][l];
    Pperm[b * 102400 + c * 1600 + l * 64 + t] = s;
  }
  // bf16 transposed sidecars (coalesced: c fastest -> contiguous 128-elem rows)
  for (int idx = tid; idx < 1600; idx += 256) {
    int n = idx >> 6, c = idx & 63;
    size_t base = (size_t)(b * 1600 + t * 25 + n) * 128;
    HbTA[base + c]      = __float2bfloat16(xt[c][n]);
    HbTA[base + 64 + c] = __float2bfloat16(ot[c][n]);
  }
}

// ---- generic ldnet
template<int M>
__global__ void ldnet_g(const float* __restrict__ in, const float* __restrict__ A,
                        float* __restrict__ outp) {
  const int b = blockIdx.x >> 6;
  const int t = blockIdx.x & 63;
  const int tid = threadIdx.x;
  __shared__ float xt[64][M];
  __shared__ float fa[M][M];
  for (int idx = tid; idx < 64 * M; idx += 256) {
    int c = idx / M, n = idx % M;
    xt[c][n] = in[((b * 64 + c) * 64 + t) * M + n];
  }
  __syncthreads();
  for (int idx = tid; idx < M * M; idx += 256) {
    int n = idx / M, m = idx % M;
    float s = 0.f;
    #pragma unroll
    for (int c = 0; c < 64; ++c) s += xt[c][n] * xt[c][m];
    fa[n][m] = s * 0.125f;
  }
  __syncthreads();
  if (tid < M) {
    int n = tid;
    float mx = -1e30f;
    for (int m = 0; m < M; ++m) mx = fmaxf(mx, fa[n][m]);
    float sum = 0.f;
    for (int m = 0; m < M; ++m) sum += __expf(fa[n][m] - mx);
    float inv = 1.f / sum;
    for (int m = 0; m < M; ++m) fa[n][m] = __expf(fa[n][m] - mx) * inv + A[n * M + m];
  }
  __syncthreads();
  for (int idx = tid; idx < 64 * M; idx += 256) {
    int c = idx / M, m = idx % M;
    float s = 0.f;
    #pragma unroll
    for (int n = 0; n < M; ++n) s += xt[c][n] * fa[n][m];
    outp[((b * 64 + c) * 64 + t) * M + m] = s;
  }
}

// ---- fused pool partials for BOTH branches (single pass over Pperm).
__global__ void pool_partial(const float* __restrict__ Pperm,
                             const float* __restrict__ Wp1, const float* __restrict__ Wp2,
                             const float* __restrict__ ap1_, const float* __restrict__ ap2_,
                             float* __restrict__ partials) {
  const int b = blockIdx.x >> 5;
  const int ch = blockIdx.x & 31;
  const int i0 = ch << 7;
  const int tid = threadIdx.x;
  const float a1 = ap1_[0], a2 = ap2_[0];
  __shared__ float pg1[128][25];
  __shared__ float pg2[128][25];
  __shared__ float wct[128][36];
  for (int idx = tid; idx < 3200; idx += 256) {
    float v = Pperm[b * 102400 + i0 * 25 + idx];
    int ii = idx / 25, j = idx - ii * 25;
    pg1[ii][j] = v >= 0.f ? v : a1 * v;
    pg2[ii][j] = v >= 0.f ? v : a2 * v;
  }
  for (int idx = tid; idx < 19 * 128; idx += 256) {
    int r = idx >> 7, ii = idx & 127;
    wct[ii][r] = Wp1[r * 4096 + i0 + ii];
  }
  for (int idx = tid; idx < 15 * 128; idx += 256) {
    int r = idx >> 7, ii = idx & 127;
    wct[ii][20 + r] = Wp2[r * 4096 + i0 + ii];
  }
  __syncthreads();
  if (tid < 225) {
    const int j = tid / 9;
    const int g = tid - j * 9;
    const bool br1 = (g < 5);
    const int r0 = br1 ? g * 4 : 20 + (g - 5) * 4;
    const float* pgc = br1 ? &pg1[0][0] : &pg2[0][0];
    float acc0 = 0.f, acc1 = 0.f, acc2 = 0.f, acc3 = 0.f;
    #pragma unroll 4
    for (int ii = 0; ii < 128; ++ii) {
      float p = pgc[ii * 25 + j];
      const float4 wv = *(const float4*)&wct[ii][r0];
      acc0 += p * wv.x; acc1 += p * wv.y; acc2 += p * wv.z; acc3 += p * wv.w;
    }
    const int base = (b * 32 + ch) * 850;
    if (br1) {
      const int m = base + j * 19 + r0;
      partials[m] = acc0; partials[m + 1] = acc1; partials[m + 2] = acc2;
      if (g != 4) partials[m + 3] = acc3;
    } else {
      const int m = base + 475 + j * 15 + (r0 - 20);
      partials[m] = acc0; partials[m + 1] = acc1; partials[m + 2] = acc2;
      if (g != 8) partials[m + 3] = acc3;
    }
  }
}

// ---- reduce partials over 32 chunks + per-branch softmax
__global__ void pool_reduce(const float* __restrict__ partials,
                            float* __restrict__ F19, float* __restrict__ F15) {
  const int b = blockIdx.x;
  const int tid = threadIdx.x;
  __shared__ float lg[850];
  for (int m = tid; m < 850; m += 256) {
    float s = 0.f;
    for (int ch = 0; ch < 32; ++ch) s += partials[(b * 32 + ch) * 850 + m];
    lg[m] = s;
  }
  __syncthreads();
  if (tid < 25) {
    const float* row = lg + tid * 19;
    float mx = -1e30f;
    for (int r = 0; r < 19; ++r) mx = fmaxf(mx, row[r]);
    float sum = 0.f;
    for (int r = 0; r < 19; ++r) sum += __expf(row[r] - mx);
    float inv = 1.f / sum;
    for (int r = 0; r < 19; ++r)
      F19[(b * 25 + tid) * 19 + r] = __expf(row[r] - mx) * inv;
  } else if (tid >= 32 && tid < 57) {
    const int j = tid - 32;
    const float* row = lg + 475 + j * 15;
    float mx = -1e30f;
    for (int r = 0; r < 15; ++r) mx = fmaxf(mx, row[r]);
    float sum = 0.f;
    for (int r = 0; r < 15; ++r) sum += __expf(row[r] - mx);
    float inv = 1.f / sum;
    for (int r = 0; r < 15; ++r)
      F15[(b * 25 + j) * 15 + r] = __expf(row[r] - mx) * inv;
  }
}

// ---- x2[b,c,t,r] = sum_n xcd1[b,c,t,n] * F3[b,n,r]
template<int R>
__global__ void x2_einsum(const float* __restrict__ xcd1, const float* __restrict__ F3,
                          float* __restrict__ x2) {
  const int row = blockIdx.x * 256 + threadIdx.x;
  const int b = row >> 12;
  __shared__ float f3[25 * R];
  for (int idx = threadIdx.x; idx < 25 * R; idx += 256) f3[idx] = F3[b * 25 * R + idx];
  __syncthreads();
  float xr[25];
  #pragma unroll
  for (int n = 0; n < 25; ++n) xr[n] = xcd1[row * 25 + n];
  float acc[R];
  #pragma unroll
  for (int r = 0; r < R; ++r) acc[r] = 0.f;
  #pragma unroll
  for (int n = 0; n < 25; ++n) {
    float v = xr[n];
    #pragma unroll
    for (int r = 0; r < R; ++r) acc[r] += v * f3[n * R + r];
  }
  #pragma unroll
  for (int r = 0; r < R; ++r) x2[row * R + r] = acc[r];
}

// ---- restore: g_x + rank-1 attention + apply + BN(eval)+ReLU per (b,t).
// Output written as bf16 into transposed HbT_B[b][col][128] at ci offset cioff.
template<int M>
__global__ void restore_k(const float* __restrict__ xcd1, const float* __restrict__ pre,
                          const float* __restrict__ Wg, const float* __restrict__ bg,
                          const float* __restrict__ Ck, const float* __restrict__ wu,
                          const float* __restrict__ wv, const float* __restrict__ cuv,
                          __hip_bfloat16* __restrict__ outb, int cioff) {
  const int b = blockIdx.x >> 6;
  const int t = blockIdx.x & 63;
  const int tid = threadIdx.x;
  __shared__ float xt[64][25];
  __shared__ float yt[64][M];
  __shared__ float wgt[64][64];   // wgt[c][g] = Wg[g][c]  (transposed: conflict-free)
  __shared__ float gx[M][64];
  __shared__ float att[25][M];
  __shared__ float uu[25];
  __shared__ float vv[M];
  for (int idx = tid; idx < 1600; idx += 256) {
    int c = idx / 25, n = idx % 25;
    xt[c][n] = xcd1[((b * 64 + c) * 64 + t) * 25 + n];
  }
  for (int idx = tid; idx < 64 * M; idx += 256) {
    int c = idx / M, m = idx % M;
    yt[c][m] = pre[((b * 64 + c) * 64 + t) * M + m];
  }
  for (int idx = tid; idx < 4096; idx += 256) {
    int c = idx >> 6, g = idx & 63;
    wgt[c][g] = Wg[g * 64 + c];
  }
  __syncthreads();
  for (int idx = tid; idx < M * 64; idx += 256) {
    int m = idx >> 6, g = idx & 63;
    float s = bg[g];
    #pragma unroll
    for (int c = 0; c < 64; ++c) s += wgt[c][g] * yt[c][m];
    gx[m][g] = s;
  }
  if (tid < 25) {
    float s = cuv[0];
    #pragma unroll
    for (int c = 0; c < 64; ++c) s += wu[c] * xt[c][tid];
    uu[tid] = s;
  }
  if (tid >= 64 && tid < 64 + M) {
    int m = tid - 64;
    float s = cuv[1];
    #pragma unroll
    for (int c = 0; c < 64; ++c) s += wv[c] * yt[c][m];
    vv[m] = s;
  }
  __syncthreads();
  if (tid < 25) {
    int n = tid;
    float f[M];
    float mx = -1e30f;
    #pragma unroll
    for (int m = 0; m < M; ++m) {
      float v = uu[n] + vv[m];
      v = v >= 0.f ? v : 0.2f * v;
      f[m] = v;
      mx = fmaxf(mx, v);
    }
    float sum = 0.f;
    #pragma unroll
    for (int m = 0; m < M; ++m) { f[m] = __expf(f[m] - mx); sum += f[m]; }
    float inv = 1.f / sum;
    #pragma unroll
    for (int m = 0; m < M; ++m) att[n][m] = f[m] * inv + Ck[n * M + m];
  }
  __syncthreads();
  for (int idx = tid; idx < 1600; idx += 256) {
    int n = idx >> 6, g = idx & 63;   // g fastest: gx stride-4B, att broadcast
    float s = 0.f;
    #pragma unroll
    for (int m = 0; m < M; ++m) s += att[n][m] * gx[m][g];
    float v = fmaxf(s * BN_SCALE_F, 0.f);
    outb[(size_t)(b * 1600 + t * 25 + n) * 128 + cioff + g] = __float2bfloat16(v);
  }
}

// ---- conv weights -> bf16, layout Wb[kt][o][ci] (ci contiguous)
__global__ void transpose_w(const float* __restrict__ Wtcn, __hip_bfloat16* __restrict__ Wb) {
  int idx = blockIdx.x * 256 + threadIdx.x;
  if (idx < 49152) {
    int ci = idx & 255;
    int rest = idx >> 8;
    int o = rest & 63, kt = rest >> 6;
    Wb[idx] = __float2bfloat16(Wtcn[(o * 256 + ci) * 3 + kt]);
  }
}

// ---- final conv via MFMA: per block (b, 320-col tile). 4 waves: wave = 80 cols x 64 o.
// M = col (tile 16), N = o (tile 16), K = 256 ci x 3 taps, chunked 32 ci.
// HbT_[A|B][b][col][128] bf16 holds the 4 concat tensors transposed; A-frags read
// directly (col-major rows), B-frags from Wl. Pitch 40 -> 16B aligned, ~2-way banks.
__global__ __launch_bounds__(256, 3) void conv_mfma(
    const __hip_bfloat16* __restrict__ HbTA, const __hip_bfloat16* __restrict__ HbTB,
    const __hip_bfloat16* __restrict__ Wb, const float* __restrict__ x,
    const float* __restrict__ btcn, const float* __restrict__ aout_,
    float* __restrict__ out) {
  const int b = blockIdx.x / 5;
  const int col0 = (blockIdx.x % 5) * 320;
  const int tid = threadIdx.x;
  const int w = tid >> 6, l = tid & 63;
  const int lr = l & 15, lg = l >> 4;

  __shared__ __hip_bfloat16 Hl[384 * 40];       // [stagedcol][ci32] pitch 40
  __shared__ __hip_bfloat16 Wl[3 * 64 * 40];    // [kt][o][ci32] pitch 40

  f32x4 acc[5][4];
  #pragma unroll
  for (int mt = 0; mt < 5; ++mt)
    #pragma unroll
    for (int nt = 0; nt < 4; ++nt) acc[mt][nt] = (f32x4){0.f, 0.f, 0.f, 0.f};

  const int base_a = (w * 80 + lr + 7) * 40 + lg * 8;
  const int base_b = lr * 40 + lg * 8;

  for (int ch = 0; ch < 8; ++ch) {
    const __hip_bfloat16* Ht = (ch < 4) ? HbTA : HbTB;
    const int ci0 = (ch & 3) * 32;   // local channel offset within Ht (128 ci)
    const int wci0 = ch * 32;        // GLOBAL channel offset for weights (256 ci)
    __syncthreads();
    #pragma unroll
    for (int it = 0; it < 6; ++it) {          // H: 384 cols x 4 segs of 8 ci
      int idx = it * 256 + tid;
      int colr = idx >> 2, seg = idx & 3;
      int gcol = col0 - 32 + colr;
      uint4 v = {0u, 0u, 0u, 0u};
      if (gcol >= 0 && gcol < 1600)
        v = *(const uint4*)(Ht + ((size_t)(b * 1600 + gcol) * 128 + ci0 + seg * 8));
      *(uint4*)(&Hl[colr * 40 + seg * 8]) = v;
    }
    #pragma unroll
    for (int it = 0; it < 3; ++it) {          // W: 3 kt x 64 o x 4 segs
      int idx = it * 256 + tid;
      int o = (idx >> 2) & 63, kt = idx >> 8, seg = idx & 3;
      uint4 v = *(const uint4*)(Wb + ((kt * 64 + o) * 256 + wci0 + seg * 8));
      *(uint4*)(&Wl[(kt * 64 + o) * 40 + seg * 8]) = v;
    }
    __syncthreads();
    #pragma unroll
    for (int kt = 0; kt < 3; ++kt) {
      short8 af[5], bf[4];
      const int ab = base_a + kt * 1000;      // +25 cols per tap
      const int bb = base_b + kt * 2560;      // +64 o-rows per tap
      #pragma unroll
      for (int mt = 0; mt < 5; ++mt) af[mt] = *(const short8*)(&Hl[ab + mt * 640]);
      #pragma unroll
      for (int nt = 0; nt < 4; ++nt) bf[nt] = *(const short8*)(&Wl[bb + nt * 640]);
      #pragma unroll
      for (int mt = 0; mt < 5; ++mt)
        #pragma unroll
        for (int nt = 0; nt < 4; ++nt)
          acc[mt][nt] = __builtin_amdgcn_mfma_f32_16x16x32_bf16(af[mt], bf[nt],
                                                                acc[mt][nt], 0, 0, 0);
    }
  }

  const float aout = aout_[0];
  const int colbase = col0 + w * 80 + lg * 4;
  #pragma unroll
  for (int nt = 0; nt < 4; ++nt) {
    const int o = nt * 16 + lr;
    const float bo = btcn[o];
    const float* xr = x + ((size_t)b * 64 + o) * 1600 + colbase;
    float* op = out + ((size_t)b * 64 + o) * 1600 + colbase;
    #pragma unroll
    for (int mt = 0; mt < 5; ++mt) {
      float4 xv = *(const float4*)(xr + mt * 16);
      f32x4 a4 = acc[mt][nt];
      float4 res;
      float v0 = (a4[0] + bo) * BN_SCALE_F + xv.x;
      float v1 = (a4[1] + bo) * BN_SCALE_F + xv.y;
      float v2 = (a4[2] + bo) * BN_SCALE_F + xv.z;
      float v3 = (a4[3] + bo) * BN_SCALE_F + xv.w;
      res.x = v0 >= 0.f ? v0 : aout * v0;
      res.y = v1 >= 0.f ? v1 : aout * v1;
      res.z = v2 >= 0.f ? v2 : aout * v2;
      res.w = v3 >= 0.f ? v3 : aout * v3;
      *(float4*)(op + mt * 16) = res;
    }
  }
}

extern "C" void kernel_launch(void* const* d_in, const int* in_sizes, int n_in,
                              void* d_out, int out_size, void* d_ws, size_t ws_size,
                              hipStream_t stream) {
  const float* x     = (const float*)d_in[0];
  const float* A1    = (const float*)d_in[1];
  const float* A2    = (const float*)d_in[2];
  const float* A3    = (const float*)d_in[3];
  const float* Wp1   = (const float*)d_in[4];
  const float* ap1   = (const float*)d_in[5];
  const float* Wp2   = (const float*)d_in[6];
  const float* ap2   = (const float*)d_in[7];
  const float* Wg2   = (const float*)d_in[8];
  const float* bg2   = (const float*)d_in[9];
  const float* Wt2   = (const float*)d_in[10];
  const float* bt2   = (const float*)d_in[11];
  const float* Wph2  = (const float*)d_in[12];
  const float* bph2  = (const float*)d_in[13];
  const float* wcat2 = (const float*)d_in[14];
  const float* Ck2   = (const float*)d_in[15];
  const float* Wg3   = (const float*)d_in[16];
  const float* bg3   = (const float*)d_in[17];
  const float* Wt3   = (const float*)d_in[18];
  const float* bt3   = (const float*)d_in[19];
  const float* Wph3  = (const float*)d_in[20];
  const float* bph3  = (const float*)d_in[21];
  const float* wcat3 = (const float*)d_in[22];
  const float* Ck3   = (const float*)d_in[23];
  const float* Wtcn  = (const float*)d_in[24];
  const float* btcn  = (const float*)d_in[25];
  const float* aout  = (const float*)d_in[26];
  float* out = (float*)d_out;
  float* ws  = (float*)d_ws;

  float* xcd1 = ws;
  float* Pp   = ws + 6553600;                              // R1: Pperm, later HbT_B
  __hip_bfloat16* HbTB = (__hip_bfloat16*)(ws + 6553600);
  __hip_bfloat16* HbTA = (__hip_bfloat16*)(ws + 13107200); // R2
  float* x2b  = ws + 19660800;
  float* preb = ws + 24641536;
  float* F19  = ws + 29622272;
  float* F15  = ws + 29652672;
  float* uv   = ws + 29676672;
  float* partials = x2b;
  __hip_bfloat16* Wb = (__hip_bfloat16*)x2b;   // after ldnet_g<15> is done with x2b

  prep_uv<<<1, 64, 0, stream>>>(Wt2, bt2, Wph2, bph2, wcat2,
                                Wt3, bt3, Wph3, bph3, wcat3, uv);
  ldnet1_fused<<<4096, 256, 0, stream>>>(x, A1, xcd1, Pp, HbTA);

  // both pools in one pass over Pperm (R1 still Pperm here)
  pool_partial<<<2048, 256, 0, stream>>>(Pp, Wp1, Wp2, ap1, ap2, partials);
  pool_reduce<<<64, 256, 0, stream>>>(partials, F19, F15);

  // branch 2 (R=19); restore writes bf16 xcd2 into HbT_B (R1, Pperm now dead)
  x2_einsum<19><<<1024, 256, 0, stream>>>(xcd1, F19, x2b);
  ldnet_g<19><<<4096, 256, 0, stream>>>(x2b, A2, preb);
  restore_k<19><<<4096, 256, 0, stream>>>(xcd1, preb, Wg2, bg2, Ck2,
                                          uv, uv + 64, uv + 256, HbTB, 0);

  // branch 3 (R=15); restore writes bf16 xcd3 into HbT_B at ci offset 64
  x2_einsum<15><<<1024, 256, 0, stream>>>(xcd1, F15, x2b);
  ldnet_g<15><<<4096, 256, 0, stream>>>(x2b, A3, preb);
  transpose_w<<<192, 256, 0, stream>>>(Wtcn, Wb);   // x2b free after ldnet_g<15>
  restore_k<15><<<4096, 256, 0, stream>>>(xcd1, preb, Wg3, bg3, Ck3,
                                          uv + 128, uv + 192, uv + 258, HbTB, 64);

  // final conv via MFMA + bias + BN + residual + PReLU
  conv_mfma<<<320, 256, 0, stream>>>(HbTA, HbTB, Wb, x, btcn, aout, out);
}

// Round 6
// 392.649 us; speedup vs baseline: 3.5439x; 1.0015x over previous
//
#include <hip/hip_runtime.h>
#include <hip/hip_bf16.h>
#include <math.h>

// ---------------------------------------------------------------------------
// LDSTNet forward. B=64, C=64, T=64, N=25, Ci=32. Pools: R1=19, R2=15.
//
// Workspace layout (floats):
//   xcd1   @ 0          : 6,553,600   (B,C,T,25) fp32
//   R1     @ 6,553,600  : 6,553,600   Pp2 fp32 [b][t][c][n] (ldnet1->pool), then
//                                     HbT_B bf16 [b][1600][128] (0..63=xcd2, 64..127=xcd3)
//   R2     @ 13,107,200 : 6,553,600   HbT_A bf16 [b][1600][128] (0..63=x, 64..127=xcd1)
//   x2buf  @ 19,660,800 : 4,980,736   partials (64x64x850) -> x_2/x_3 -> Wb bf16
//   prebuf @ 24,641,536 : 4,980,736   (B,C,T,19) / (B,C,T,15)
//   F19    @ 29,622,272 : 30,400
//   F15    @ 29,652,672 : 24,000
//   uvbuf  @ 29,676,672 : 320
// ---------------------------------------------------------------------------

#define BN_SCALE_F 0.9999950000374997f

typedef __attribute__((ext_vector_type(8))) short short8;
typedef __attribute__((ext_vector_type(4))) float f32x4;

// ---- precompute wu = wcat[:Ci]@Wt, wv = wcat[Ci:]@Wph, cu, cv for both tags
__global__ void prep_uv(const float* __restrict__ Wt2, const float* __restrict__ bt2,
                        const float* __restrict__ Wph2, const float* __restrict__ bph2,
                        const float* __restrict__ wcat2,
                        const float* __restrict__ Wt3, const float* __restrict__ bt3,
                        const float* __restrict__ Wph3, const float* __restrict__ bph3,
                        const float* __restrict__ wcat3,
                        float* __restrict__ uv) {
  int c = threadIdx.x;
  if (c < 64) {
    float s1 = 0.f, s2 = 0.f, s3 = 0.f, s4 = 0.f;
    for (int i = 0; i < 32; ++i) {
      s1 += wcat2[i]      * Wt2[i * 64 + c];
      s2 += wcat2[32 + i] * Wph2[i * 64 + c];
      s3 += wcat3[i]      * Wt3[i * 64 + c];
      s4 += wcat3[32 + i] * Wph3[i * 64 + c];
    }
    uv[c] = s1; uv[64 + c] = s2; uv[128 + c] = s3; uv[192 + c] = s4;
  }
  if (c == 0) {
    float c1 = 0.f, c2 = 0.f, c3 = 0.f, c4 = 0.f;
    for (int i = 0; i < 32; ++i) {
      c1 += wcat2[i] * bt2[i];       c2 += wcat2[32 + i] * bph2[i];
      c3 += wcat3[i] * bt3[i];       c4 += wcat3[32 + i] * bph3[i];
    }
    uv[256] = c1; uv[257] = c2; uv[258] = c3; uv[259] = c4;
  }
}

// ---- ldnet1 fused: FA1 (LDS only), x_cd1 = x@FA1, P = (x@FA1)@FA1.
// P written in [b][t][c][n] layout -> block (b,t) writes 1600 CONTIGUOUS floats.
// Also writes bf16 transposed sidecars HbT_A[b][col][ci]: ci 0..63 = x, 64..127 = xcd1.
__global__ void ldnet1_fused(const float* __restrict__ x, const float* __restrict__ A,
                             float* __restrict__ xcd1, float* __restrict__ Pp2,
                             __hip_bfloat16* __restrict__ HbTA) {
  const int b = blockIdx.x >> 6;
  const int t = blockIdx.x & 63;
  const int tid = threadIdx.x;
  __shared__ float xt[64][25];
  __shared__ float fa[25][25];
  __shared__ float ot[64][25];
  for (int idx = tid; idx < 1600; idx += 256) {
    int c = idx / 25, n = idx % 25;
    xt[c][n] = x[((b * 64 + c) * 64 + t) * 25 + n];
  }
  __syncthreads();
  for (int idx = tid; idx < 625; idx += 256) {
    int n = idx / 25, m = idx % 25;
    float s = 0.f;
    #pragma unroll
    for (int c = 0; c < 64; ++c) s += xt[c][n] * xt[c][m];
    fa[n][m] = s * 0.125f;
  }
  __syncthreads();
  if (tid < 25) {
    int n = tid;
    float mx = -1e30f;
    for (int m = 0; m < 25; ++m) mx = fmaxf(mx, fa[n][m]);
    float sum = 0.f;
    for (int m = 0; m < 25; ++m) sum += __expf(fa[n][m] - mx);
    float inv = 1.f / sum;
    for (int m = 0; m < 25; ++m) fa[n][m] = __expf(fa[n][m] - mx) * inv + A[n * 25 + m];
  }
  __syncthreads();
  for (int idx = tid; idx < 1600; idx += 256) {
    int c = idx / 25, m = idx % 25;
    float s = 0.f;
    #pragma unroll
    for (int n = 0; n < 25; ++n) s += xt[c][n] * fa[n][m];
    ot[c][m] = s;
    xcd1[((b * 64 + c) * 64 + t) * 25 + m] = s;
  }
  __syncthreads();
  for (int idx = tid; idx < 1600; idx += 256) {
    int c = idx / 25, l = idx % 25;
    float s = 0.f;
    #pragma unroll
    for (int n = 0; n < 25; ++n) s += ot[c][n] * fa[n][l];
    Pp2[b * 102400 + t * 1600 + idx] = s;   // coalesced: idx = c*25+l contiguous
  }
  // bf16 transposed sidecars (coalesced: c fastest -> contiguous 128-elem rows)
  for (int idx = tid; idx < 1600; idx += 256) {
    int n = idx >> 6, c = idx & 63;
    size_t base = (size_t)(b * 1600 + t * 25 + n) * 128;
    HbTA[base + c]      = __float2bfloat16(xt[c][n]);
    HbTA[base + 64 + c] = __float2bfloat16(ot[c][n]);
  }
}

// ---- generic ldnet
template<int M>
__global__ void ldnet_g(const float* __restrict__ in, const float* __restrict__ A,
                        float* __restrict__ outp) {
  const int b = blockIdx.x >> 6;
  const int t = blockIdx.x & 63;
  const int tid = threadIdx.x;
  __shared__ float xt[64][M];
  __shared__ float fa[M][M];
  for (int idx = tid; idx < 64 * M; idx += 256) {
    int c = idx / M, n = idx % M;
    xt[c][n] = in[((b * 64 + c) * 64 + t) * M + n];
  }
  __syncthreads();
  for (int idx = tid; idx < M * M; idx += 256) {
    int n = idx / M, m = idx % M;
    float s = 0.f;
    #pragma unroll
    for (int c = 0; c < 64; ++c) s += xt[c][n] * xt[c][m];
    fa[n][m] = s * 0.125f;
  }
  __syncthreads();
  if (tid < M) {
    int n = tid;
    float mx = -1e30f;
    for (int m = 0; m < M; ++m) mx = fmaxf(mx, fa[n][m]);
    float sum = 0.f;
    for (int m = 0; m < M; ++m) sum += __expf(fa[n][m] - mx);
    float inv = 1.f / sum;
    for (int m = 0; m < M; ++m) fa[n][m] = __expf(fa[n][m] - mx) * inv + A[n * M + m];
  }
  __syncthreads();
  for (int idx = tid; idx < 64 * M; idx += 256) {
    int c = idx / M, m = idx % M;
    float s = 0.f;
    #pragma unroll
    for (int n = 0; n < M; ++n) s += xt[c][n] * fa[n][m];
    outp[((b * 64 + c) * 64 + t) * M + m] = s;
  }
}

// ---- pool partials, block = (b, c-channel). For channel c, flat f in
// [1600c, 1600c+1600) maps to weight rows k = f/25 in [64c, 64c+64).
// Reads Pp2[b][t][c][n]; thread (j, r-quad) walks kl=0..63:
//   off = kl*25 + j -> (t = off&63, n = off>>6), weight wct[kl][r].
__global__ void pool_partial(const float* __restrict__ Pp2,
                             const float* __restrict__ Wp1, const float* __restrict__ Wp2,
                             const float* __restrict__ ap1_, const float* __restrict__ ap2_,
                             float* __restrict__ partials) {
  const int b = blockIdx.x >> 6;
  const int c = blockIdx.x & 63;
  const int tid = threadIdx.x;
  const float a1 = ap1_[0], a2 = ap2_[0];
  __shared__ float pg1[1600];          // [t*25+n], prelu(a1)
  __shared__ float pg2[1600];          // [t*25+n], prelu(a2)
  __shared__ float wct[64][36];        // [kl][r]: 0..18 Wp1, 20..34 Wp2
  for (int idx = tid; idx < 1600; idx += 256) {
    int t = idx / 25, n = idx - t * 25;
    float v = Pp2[b * 102400 + t * 1600 + c * 25 + n];
    pg1[idx] = v >= 0.f ? v : a1 * v;
    pg2[idx] = v >= 0.f ? v : a2 * v;
  }
  for (int idx = tid; idx < 19 * 64; idx += 256) {
    int kl = idx & 63, r = idx >> 6;
    wct[kl][r] = Wp1[r * 4096 + (c << 6) + kl];
  }
  for (int idx = tid; idx < 15 * 64; idx += 256) {
    int kl = idx & 63, r = idx >> 6;
    wct[kl][20 + r] = Wp2[r * 4096 + (c << 6) + kl];
  }
  __syncthreads();
  if (tid < 225) {
    const int j = tid / 9;
    const int g = tid - j * 9;
    const bool br1 = (g < 5);
    const int r0 = br1 ? g * 4 : 20 + (g - 5) * 4;
    const float* pgc = br1 ? pg1 : pg2;
    float acc0 = 0.f, acc1 = 0.f, acc2 = 0.f, acc3 = 0.f;
    #pragma unroll 4
    for (int kl = 0; kl < 64; ++kl) {
      int off = kl * 25 + j;
      float p = pgc[(off & 63) * 25 + (off >> 6)];
      const float4 wv = *(const float4*)&wct[kl][r0];
      acc0 += p * wv.x; acc1 += p * wv.y; acc2 += p * wv.z; acc3 += p * wv.w;
    }
    const int base = (b * 64 + c) * 850;
    if (br1) {
      const int m = base + j * 19 + r0;
      partials[m] = acc0; partials[m + 1] = acc1; partials[m + 2] = acc2;
      if (g != 4) partials[m + 3] = acc3;
    } else {
      const int m = base + 475 + j * 15 + (r0 - 20);
      partials[m] = acc0; partials[m + 1] = acc1; partials[m + 2] = acc2;
      if (g != 8) partials[m + 3] = acc3;
    }
  }
}

// ---- reduce partials over 64 channel-chunks + per-branch softmax
__global__ void pool_reduce(const float* __restrict__ partials,
                            float* __restrict__ F19, float* __restrict__ F15) {
  const int b = blockIdx.x;
  const int tid = threadIdx.x;
  __shared__ float lg[850];
  for (int m = tid; m < 850; m += 256) {
    float s = 0.f;
    for (int ch = 0; ch < 64; ++ch) s += partials[(b * 64 + ch) * 850 + m];
    lg[m] = s;
  }
  __syncthreads();
  if (tid < 25) {
    const float* row = lg + tid * 19;
    float mx = -1e30f;
    for (int r = 0; r < 19; ++r) mx = fmaxf(mx, row[r]);
    float sum = 0.f;
    for (int r = 0; r < 19; ++r) sum += __expf(row[r] - mx);
    float inv = 1.f / sum;
    for (int r = 0; r < 19; ++r)
      F19[(b * 25 + tid) * 19 + r] = __expf(row[r] - mx) * inv;
  } else if (tid >= 32 && tid < 57) {
    const int j = tid - 32;
    const float* row = lg + 475 + j * 15;
    float mx = -1e30f;
    for (int r = 0; r < 15; ++r) mx = fmaxf(mx, row[r]);
    float sum = 0.f;
    for (int r = 0; r < 15; ++r) sum += __expf(row[r] - mx);
    float inv = 1.f / sum;
    for (int r = 0; r < 15; ++r)
      F15[(b * 25 + j) * 15 + r] = __expf(row[r] - mx) * inv;
  }
}

// ---- x2[b,c,t,r] = sum_n xcd1[b,c,t,n] * F3[b,n,r]
template<int R>
__global__ void x2_einsum(const float* __restrict__ xcd1, const float* __restrict__ F3,
                          float* __restrict__ x2) {
  const int row = blockIdx.x * 256 + threadIdx.x;
  const int b = row >> 12;
  __shared__ float f3[25 * R];
  for (int idx = threadIdx.x; idx < 25 * R; idx += 256) f3[idx] = F3[b * 25 * R + idx];
  __syncthreads();
  float xr[25];
  #pragma unroll
  for (int n = 0; n < 25; ++n) xr[n] = xcd1[row * 25 + n];
  float acc[R];
  #pragma unroll
  for (int r = 0; r < R; ++r) acc[r] = 0.f;
  #pragma unroll
  for (int n = 0; n < 25; ++n) {
    float v = xr[n];
    #pragma unroll
    for (int r = 0; r < R; ++r) acc[r] += v * f3[n * R + r];
  }
  #pragma unroll
  for (int r = 0; r < R; ++r) x2[row * R + r] = acc[r];
}

// ---- restore: g_x + rank-1 attention + apply + BN(eval)+ReLU per (b,t).
// Output written as bf16 into transposed HbT_B[b][col][128] at ci offset cioff.
template<int M>
__global__ void restore_k(const float* __restrict__ xcd1, const float* __restrict__ pre,
                          const float* __restrict__ Wg, const float* __restrict__ bg,
                          const float* __restrict__ Ck, const float* __restrict__ wu,
                          const float* __restrict__ wv, const float* __restrict__ cuv,
                          __hip_bfloat16* __restrict__ outb, int cioff) {
  const int b = blockIdx.x >> 6;
  const int t = blockIdx.x & 63;
  const int tid = threadIdx.x;
  __shared__ float xt[64][25];
  __shared__ float yt[64][M];
  __shared__ float wgt[64][64];   // wgt[c][g] = Wg[g][c]  (transposed: conflict-free)
  __shared__ float gx[M][64];
  __shared__ float att[25][M];
  __shared__ float uu[25];
  __shared__ float vv[M];
  for (int idx = tid; idx < 1600; idx += 256) {
    int c = idx / 25, n = idx % 25;
    xt[c][n] = xcd1[((b * 64 + c) * 64 + t) * 25 + n];
  }
  for (int idx = tid; idx < 64 * M; idx += 256) {
    int c = idx / M, m = idx % M;
    yt[c][m] = pre[((b * 64 + c) * 64 + t) * M + m];
  }
  for (int idx = tid; idx < 4096; idx += 256) {
    int c = idx >> 6, g = idx & 63;
    wgt[c][g] = Wg[g * 64 + c];
  }
  __syncthreads();
  for (int idx = tid; idx < M * 64; idx += 256) {
    int m = idx >> 6, g = idx & 63;
    float s = bg[g];
    #pragma unroll
    for (int c = 0; c < 64; ++c) s += wgt[c][g] * yt[c][m];
    gx[m][g] = s;
  }
  if (tid < 25) {
    float s = cuv[0];
    #pragma unroll
    for (int c = 0; c < 64; ++c) s += wu[c] * xt[c][tid];
    uu[tid] = s;
  }
  if (tid >= 64 && tid < 64 + M) {
    int m = tid - 64;
    float s = cuv[1];
    #pragma unroll
    for (int c = 0; c < 64; ++c) s += wv[c] * yt[c][m];
    vv[m] = s;
  }
  __syncthreads();
  if (tid < 25) {
    int n = tid;
    float f[M];
    float mx = -1e30f;
    #pragma unroll
    for (int m = 0; m < M; ++m) {
      float v = uu[n] + vv[m];
      v = v >= 0.f ? v : 0.2f * v;
      f[m] = v;
      mx = fmaxf(mx, v);
    }
    float sum = 0.f;
    #pragma unroll
    for (int m = 0; m < M; ++m) { f[m] = __expf(f[m] - mx); sum += f[m]; }
    float inv = 1.f / sum;
    #pragma unroll
    for (int m = 0; m < M; ++m) att[n][m] = f[m] * inv + Ck[n * M + m];
  }
  __syncthreads();
  for (int idx = tid; idx < 1600; idx += 256) {
    int n = idx >> 6, g = idx & 63;   // g fastest: gx stride-4B, att broadcast
    float s = 0.f;
    #pragma unroll
    for (int m = 0; m < M; ++m) s += att[n][m] * gx[m][g];
    float v = fmaxf(s * BN_SCALE_F, 0.f);
    outb[(size_t)(b * 1600 + t * 25 + n) * 128 + cioff + g] = __float2bfloat16(v);
  }
}

// ---- conv weights -> bf16, layout Wb[kt][o][ci] (ci contiguous)
__global__ void transpose_w(const float* __restrict__ Wtcn, __hip_bfloat16* __restrict__ Wb) {
  int idx = blockIdx.x * 256 + threadIdx.x;
  if (idx < 49152) {
    int ci = idx & 255;
    int rest = idx >> 8;
    int o = rest & 63, kt = rest >> 6;
    Wb[idx] = __float2bfloat16(Wtcn[(o * 256 + ci) * 3 + kt]);
  }
}

// ---- final conv via MFMA: per block (b, 320-col tile). 4 waves: wave = 80 cols x 64 o.
__global__ __launch_bounds__(256, 3) void conv_mfma(
    const __hip_bfloat16* __restrict__ HbTA, const __hip_bfloat16* __restrict__ HbTB,
    const __hip_bfloat16* __restrict__ Wb, const float* __restrict__ x,
    const float* __restrict__ btcn, const float* __restrict__ aout_,
    float* __restrict__ out) {
  const int b = blockIdx.x / 5;
  const int col0 = (blockIdx.x % 5) * 320;
  const int tid = threadIdx.x;
  const int w = tid >> 6, l = tid & 63;
  const int lr = l & 15, lg = l >> 4;

  __shared__ __hip_bfloat16 Hl[384 * 40];       // [stagedcol][ci32] pitch 40
  __shared__ __hip_bfloat16 Wl[3 * 64 * 40];    // [kt][o][ci32] pitch 40

  f32x4 acc[5][4];
  #pragma unroll
  for (int mt = 0; mt < 5; ++mt)
    #pragma unroll
    for (int nt = 0; nt < 4; ++nt) acc[mt][nt] = (f32x4){0.f, 0.f, 0.f, 0.f};

  const int base_a = (w * 80 + lr + 7) * 40 + lg * 8;
  const int base_b = lr * 40 + lg * 8;

  for (int ch = 0; ch < 8; ++ch) {
    const __hip_bfloat16* Ht = (ch < 4) ? HbTA : HbTB;
    const int ci0 = (ch & 3) * 32;   // local channel offset within Ht (128 ci)
    const int wci0 = ch * 32;        // GLOBAL channel offset for weights (256 ci)
    __syncthreads();
    #pragma unroll
    for (int it = 0; it < 6; ++it) {          // H: 384 cols x 4 segs of 8 ci
      int idx = it * 256 + tid;
      int colr = idx >> 2, seg = idx & 3;
      int gcol = col0 - 32 + colr;
      uint4 v = {0u, 0u, 0u, 0u};
      if (gcol >= 0 && gcol < 1600)
        v = *(const uint4*)(Ht + ((size_t)(b * 1600 + gcol) * 128 + ci0 + seg * 8));
      *(uint4*)(&Hl[colr * 40 + seg * 8]) = v;
    }
    #pragma unroll
    for (int it = 0; it < 3; ++it) {          // W: 3 kt x 64 o x 4 segs
      int idx = it * 256 + tid;
      int o = (idx >> 2) & 63, kt = idx >> 8, seg = idx & 3;
      uint4 v = *(const uint4*)(Wb + ((kt * 64 + o) * 256 + wci0 + seg * 8));
      *(uint4*)(&Wl[(kt * 64 + o) * 40 + seg * 8]) = v;
    }
    __syncthreads();
    #pragma unroll
    for (int kt = 0; kt < 3; ++kt) {
      short8 af[5], bf[4];
      const int ab = base_a + kt * 1000;      // +25 cols per tap
      const int bb = base_b + kt * 2560;      // +64 o-rows per tap
      #pragma unroll
      for (int mt = 0; mt < 5; ++mt) af[mt] = *(const short8*)(&Hl[ab + mt * 640]);
      #pragma unroll
      for (int nt = 0; nt < 4; ++nt) bf[nt] = *(const short8*)(&Wl[bb + nt * 640]);
      #pragma unroll
      for (int mt = 0; mt < 5; ++mt)
        #pragma unroll
        for (int nt = 0; nt < 4; ++nt)
          acc[mt][nt] = __builtin_amdgcn_mfma_f32_16x16x32_bf16(af[mt], bf[nt],
                                                                acc[mt][nt], 0, 0, 0);
    }
  }

  const float aout = aout_[0];
  const int colbase = col0 + w * 80 + lg * 4;
  #pragma unroll
  for (int nt = 0; nt < 4; ++nt) {
    const int o = nt * 16 + lr;
    const float bo = btcn[o];
    const float* xr = x + ((size_t)b * 64 + o) * 1600 + colbase;
    float* op = out + ((size_t)b * 64 + o) * 1600 + colbase;
    #pragma unroll
    for (int mt = 0; mt < 5; ++mt) {
      float4 xv = *(const float4*)(xr + mt * 16);
      f32x4 a4 = acc[mt][nt];
      float4 res;
      float v0 = (a4[0] + bo) * BN_SCALE_F + xv.x;
      float v1 = (a4[1] + bo) * BN_SCALE_F + xv.y;
      float v2 = (a4[2] + bo) * BN_SCALE_F + xv.z;
      float v3 = (a4[3] + bo) * BN_SCALE_F + xv.w;
      res.x = v0 >= 0.f ? v0 : aout * v0;
      res.y = v1 >= 0.f ? v1 : aout * v1;
      res.z = v2 >= 0.f ? v2 : aout * v2;
      res.w = v3 >= 0.f ? v3 : aout * v3;
      *(float4*)(op + mt * 16) = res;
    }
  }
}

extern "C" void kernel_launch(void* const* d_in, const int* in_sizes, int n_in,
                              void* d_out, int out_size, void* d_ws, size_t ws_size,
                              hipStream_t stream) {
  const float* x     = (const float*)d_in[0];
  const float* A1    = (const float*)d_in[1];
  const float* A2    = (const float*)d_in[2];
  const float* A3    = (const float*)d_in[3];
  const float* Wp1   = (const float*)d_in[4];
  const float* ap1   = (const float*)d_in[5];
  const float* Wp2   = (const float*)d_in[6];
  const float* ap2   = (const float*)d_in[7];
  const float* Wg2   = (const float*)d_in[8];
  const float* bg2   = (const float*)d_in[9];
  const float* Wt2   = (const float*)d_in[10];
  const float* bt2   = (const float*)d_in[11];
  const float* Wph2  = (const float*)d_in[12];
  const float* bph2  = (const float*)d_in[13];
  const float* wcat2 = (const float*)d_in[14];
  const float* Ck2   = (const float*)d_in[15];
  const float* Wg3   = (const float*)d_in[16];
  const float* bg3   = (const float*)d_in[17];
  const float* Wt3   = (const float*)d_in[18];
  const float* bt3   = (const float*)d_in[19];
  const float* Wph3  = (const float*)d_in[20];
  const float* bph3  = (const float*)d_in[21];
  const float* wcat3 = (const float*)d_in[22];
  const float* Ck3   = (const float*)d_in[23];
  const float* Wtcn  = (const float*)d_in[24];
  const float* btcn  = (const float*)d_in[25];
  const float* aout  = (const float*)d_in[26];
  float* out = (float*)d_out;
  float* ws  = (float*)d_ws;

  float* xcd1 = ws;
  float* Pp   = ws + 6553600;                              // R1: Pp2, later HbT_B
  __hip_bfloat16* HbTB = (__hip_bfloat16*)(ws + 6553600);
  __hip_bfloat16* HbTA = (__hip_bfloat16*)(ws + 13107200); // R2
  float* x2b  = ws + 19660800;
  float* preb = ws + 24641536;
  float* F19  = ws + 29622272;
  float* F15  = ws + 29652672;
  float* uv   = ws + 29676672;
  float* partials = x2b;                        // 64*64*850 = 3,481,600 floats
  __hip_bfloat16* Wb = (__hip_bfloat16*)x2b;    // after ldnet_g<15> is done with x2b

  prep_uv<<<1, 64, 0, stream>>>(Wt2, bt2, Wph2, bph2, wcat2,
                                Wt3, bt3, Wph3, bph3, wcat3, uv);
  ldnet1_fused<<<4096, 256, 0, stream>>>(x, A1, xcd1, Pp, HbTA);

  // both pools in one pass over Pp2 (block per (b, channel))
  pool_partial<<<4096, 256, 0, stream>>>(Pp, Wp1, Wp2, ap1, ap2, partials);
  pool_reduce<<<64, 256, 0, stream>>>(partials, F19, F15);

  // branch 2 (R=19); restore writes bf16 xcd2 into HbT_B (R1, Pp2 now dead)
  x2_einsum<19><<<1024, 256, 0, stream>>>(xcd1, F19, x2b);
  ldnet_g<19><<<4096, 256, 0, stream>>>(x2b, A2, preb);
  restore_k<19><<<4096, 256, 0, stream>>>(xcd1, preb, Wg2, bg2, Ck2,
                                          uv, uv + 64, uv + 256, HbTB, 0);

  // branch 3 (R=15); restore writes bf16 xcd3 into HbT_B at ci offset 64
  x2_einsum<15><<<1024, 256, 0, stream>>>(xcd1, F15, x2b);
  ldnet_g<15><<<4096, 256, 0, stream>>>(x2b, A3, preb);
  transpose_w<<<192, 256, 0, stream>>>(Wtcn, Wb);   // x2b free after ldnet_g<15>
  restore_k<15><<<4096, 256, 0, stream>>>(xcd1, preb, Wg3, bg3, Ck3,
                                          uv + 128, uv + 192, uv + 258, HbTB, 64);

  // final conv via MFMA + bias + BN + residual + PReLU
  conv_mfma<<<320, 256, 0, stream>>>(HbTA, HbTB, Wb, x, btcn, aout, out);
}

// Round 7
// 306.737 us; speedup vs baseline: 4.5365x; 1.2801x over previous
//
#include <hip/hip_runtime.h>
#include <hip/hip_bf16.h>
#include <math.h>

// ---------------------------------------------------------------------------
// LDSTNet forward. B=64, C=64, T=64, N=25, Ci=32. Pools: R1=19, R2=15.
//
// Workspace layout (floats):
//   xcd1   @ 0          : 6,553,600   (B,C,T,25) fp32
//   R1     @ 6,553,600  : 6,553,600   Pp2 fp32 [b][t][c][n] -> Zb/HbTB bf16 [col][128]
//                                     (Zb: ch0..63=Z2, 64..127=Z3; gemm transforms
//                                      in place to HbTB: ch0..63=xcd2, 64..127=xcd3)
//   R2     @ 13,107,200 : 6,553,600   HbT_A bf16 [b][1600][128] (0..63=x, 64..127=xcd1)
//   x2buf  @ 19,660,800 : 4,980,736   partials (64x64x850) -> x_2 -> x_3
//   preb   @ 24,641,536 : 4,980,736   Wb bf16 (49,152) | Wgb bf16 (8,192) | sconst (50)
//   F19    @ 29,622,272 : 30,400
//   F15    @ 29,652,672 : 24,000
//   uvbuf  @ 29,676,672 : 320
// ---------------------------------------------------------------------------

#define BN_SCALE_F 0.9999950000374997f

typedef __attribute__((ext_vector_type(8))) short short8;
typedef __attribute__((ext_vector_type(4))) float f32x4;

// ---- precompute wu/wv/cu/cv for both branches + att row-sum constants
// s_k[n] = 1 + sum_m Ck_k[n,m]  (softmax row-sum is exactly 1)
__global__ void prep_uv(const float* __restrict__ Wt2, const float* __restrict__ bt2,
                        const float* __restrict__ Wph2, const float* __restrict__ bph2,
                        const float* __restrict__ wcat2,
                        const float* __restrict__ Wt3, const float* __restrict__ bt3,
                        const float* __restrict__ Wph3, const float* __restrict__ bph3,
                        const float* __restrict__ wcat3,
                        const float* __restrict__ Ck2, const float* __restrict__ Ck3,
                        float* __restrict__ uv, float* __restrict__ sconst) {
  int c = threadIdx.x;
  if (c < 64) {
    float s1 = 0.f, s2 = 0.f, s3 = 0.f, s4 = 0.f;
    for (int i = 0; i < 32; ++i) {
      s1 += wcat2[i]      * Wt2[i * 64 + c];
      s2 += wcat2[32 + i] * Wph2[i * 64 + c];
      s3 += wcat3[i]      * Wt3[i * 64 + c];
      s4 += wcat3[32 + i] * Wph3[i * 64 + c];
    }
    uv[c] = s1; uv[64 + c] = s2; uv[128 + c] = s3; uv[192 + c] = s4;
  }
  if (c == 0) {
    float c1 = 0.f, c2 = 0.f, c3 = 0.f, c4 = 0.f;
    for (int i = 0; i < 32; ++i) {
      c1 += wcat2[i] * bt2[i];       c2 += wcat2[32 + i] * bph2[i];
      c3 += wcat3[i] * bt3[i];       c4 += wcat3[32 + i] * bph3[i];
    }
    uv[256] = c1; uv[257] = c2; uv[258] = c3; uv[259] = c4;
  }
  if (c < 25) {
    float s2 = 1.f, s3 = 1.f;
    for (int m = 0; m < 19; ++m) s2 += Ck2[c * 19 + m];
    for (int m = 0; m < 15; ++m) s3 += Ck3[c * 15 + m];
    sconst[c] = s2; sconst[25 + c] = s3;
  }
}

// ---- pack Wg2/Wg3 transposed to bf16: Wgb[c][g], g 0..63 = Wg2, 64..127 = Wg3
__global__ void prep_wgb(const float* __restrict__ Wg2, const float* __restrict__ Wg3,
                         __hip_bfloat16* __restrict__ Wgb) {
  int idx = blockIdx.x * 256 + threadIdx.x;
  if (idx < 8192) {
    int c = idx >> 7, g = idx & 127;
    float v = (g < 64) ? Wg2[g * 64 + c] : Wg3[(g - 64) * 64 + c];
    Wgb[idx] = __float2bfloat16(v);
  }
}

// ---- ldnet1 fused: FA1 (LDS only), x_cd1 = x@FA1, P = (x@FA1)@FA1 (coalesced layout),
// bf16 transposed sidecars HbT_A[b][col][ci]: ci 0..63 = x, 64..127 = xcd1.
__global__ void ldnet1_fused(const float* __restrict__ x, const float* __restrict__ A,
                             float* __restrict__ xcd1, float* __restrict__ Pp2,
                             __hip_bfloat16* __restrict__ HbTA) {
  const int b = blockIdx.x >> 6;
  const int t = blockIdx.x & 63;
  const int tid = threadIdx.x;
  __shared__ float xt[64][25];
  __shared__ float fa[25][25];
  __shared__ float ot[64][25];
  for (int idx = tid; idx < 1600; idx += 256) {
    int c = idx / 25, n = idx % 25;
    xt[c][n] = x[((b * 64 + c) * 64 + t) * 25 + n];
  }
  __syncthreads();
  for (int idx = tid; idx < 625; idx += 256) {
    int n = idx / 25, m = idx % 25;
    float s = 0.f;
    #pragma unroll
    for (int c = 0; c < 64; ++c) s += xt[c][n] * xt[c][m];
    fa[n][m] = s * 0.125f;
  }
  __syncthreads();
  if (tid < 25) {
    int n = tid;
    float mx = -1e30f;
    for (int m = 0; m < 25; ++m) mx = fmaxf(mx, fa[n][m]);
    float sum = 0.f;
    for (int m = 0; m < 25; ++m) sum += __expf(fa[n][m] - mx);
    float inv = 1.f / sum;
    for (int m = 0; m < 25; ++m) fa[n][m] = __expf(fa[n][m] - mx) * inv + A[n * 25 + m];
  }
  __syncthreads();
  for (int idx = tid; idx < 1600; idx += 256) {
    int c = idx / 25, m = idx % 25;
    float s = 0.f;
    #pragma unroll
    for (int n = 0; n < 25; ++n) s += xt[c][n] * fa[n][m];
    ot[c][m] = s;
    xcd1[((b * 64 + c) * 64 + t) * 25 + m] = s;
  }
  __syncthreads();
  for (int idx = tid; idx < 1600; idx += 256) {
    int c = idx / 25, l = idx % 25;
    float s = 0.f;
    #pragma unroll
    for (int n = 0; n < 25; ++n) s += ot[c][n] * fa[n][l];
    Pp2[b * 102400 + t * 1600 + idx] = s;   // coalesced: idx = c*25+l contiguous
  }
  for (int idx = tid; idx < 1600; idx += 256) {
    int n = idx >> 6, c = idx & 63;
    size_t base = (size_t)(b * 1600 + t * 25 + n) * 128;
    HbTA[base + c]      = __float2bfloat16(xt[c][n]);
    HbTA[base + 64 + c] = __float2bfloat16(ot[c][n]);
  }
}

// ---- pool partials, block = (b, c-channel); Pp2[b][t][c][n]
__global__ void pool_partial(const float* __restrict__ Pp2,
                             const float* __restrict__ Wp1, const float* __restrict__ Wp2,
                             const float* __restrict__ ap1_, const float* __restrict__ ap2_,
                             float* __restrict__ partials) {
  const int b = blockIdx.x >> 6;
  const int c = blockIdx.x & 63;
  const int tid = threadIdx.x;
  const float a1 = ap1_[0], a2 = ap2_[0];
  __shared__ float pg1[1600];
  __shared__ float pg2[1600];
  __shared__ float wct[64][36];
  for (int idx = tid; idx < 1600; idx += 256) {
    int t = idx / 25, n = idx - t * 25;
    float v = Pp2[b * 102400 + t * 1600 + c * 25 + n];
    pg1[idx] = v >= 0.f ? v : a1 * v;
    pg2[idx] = v >= 0.f ? v : a2 * v;
  }
  for (int idx = tid; idx < 19 * 64; idx += 256) {
    int kl = idx & 63, r = idx >> 6;
    wct[kl][r] = Wp1[r * 4096 + (c << 6) + kl];
  }
  for (int idx = tid; idx < 15 * 64; idx += 256) {
    int kl = idx & 63, r = idx >> 6;
    wct[kl][20 + r] = Wp2[r * 4096 + (c << 6) + kl];
  }
  __syncthreads();
  if (tid < 225) {
    const int j = tid / 9;
    const int g = tid - j * 9;
    const bool br1 = (g < 5);
    const int r0 = br1 ? g * 4 : 20 + (g - 5) * 4;
    const float* pgc = br1 ? pg1 : pg2;
    float acc0 = 0.f, acc1 = 0.f, acc2 = 0.f, acc3 = 0.f;
    #pragma unroll 4
    for (int kl = 0; kl < 64; ++kl) {
      int off = kl * 25 + j;
      float p = pgc[(off & 63) * 25 + (off >> 6)];
      const float4 wv = *(const float4*)&wct[kl][r0];
      acc0 += p * wv.x; acc1 += p * wv.y; acc2 += p * wv.z; acc3 += p * wv.w;
    }
    const int base = (b * 64 + c) * 850;
    if (br1) {
      const int m = base + j * 19 + r0;
      partials[m] = acc0; partials[m + 1] = acc1; partials[m + 2] = acc2;
      if (g != 4) partials[m + 3] = acc3;
    } else {
      const int m = base + 475 + j * 15 + (r0 - 20);
      partials[m] = acc0; partials[m + 1] = acc1; partials[m + 2] = acc2;
      if (g != 8) partials[m + 3] = acc3;
    }
  }
}

// ---- reduce partials over 64 channel-chunks + per-branch softmax
__global__ void pool_reduce(const float* __restrict__ partials,
                            float* __restrict__ F19, float* __restrict__ F15) {
  const int b = blockIdx.x;
  const int tid = threadIdx.x;
  __shared__ float lg[850];
  for (int m = tid; m < 850; m += 256) {
    float s = 0.f;
    for (int ch = 0; ch < 64; ++ch) s += partials[(b * 64 + ch) * 850 + m];
    lg[m] = s;
  }
  __syncthreads();
  if (tid < 25) {
    const float* row = lg + tid * 19;
    float mx = -1e30f;
    for (int r = 0; r < 19; ++r) mx = fmaxf(mx, row[r]);
    float sum = 0.f;
    for (int r = 0; r < 19; ++r) sum += __expf(row[r] - mx);
    float inv = 1.f / sum;
    for (int r = 0; r < 19; ++r)
      F19[(b * 25 + tid) * 19 + r] = __expf(row[r] - mx) * inv;
  } else if (tid >= 32 && tid < 57) {
    const int j = tid - 32;
    const float* row = lg + 475 + j * 15;
    float mx = -1e30f;
    for (int r = 0; r < 15; ++r) mx = fmaxf(mx, row[r]);
    float sum = 0.f;
    for (int r = 0; r < 15; ++r) sum += __expf(row[r] - mx);
    float inv = 1.f / sum;
    for (int r = 0; r < 15; ++r)
      F15[(b * 25 + j) * 15 + r] = __expf(row[r] - mx) * inv;
  }
}

// ---- x2[b,c,t,r] = sum_n xcd1[b,c,t,n] * F3[b,n,r]
template<int R>
__global__ void x2_einsum(const float* __restrict__ xcd1, const float* __restrict__ F3,
                          float* __restrict__ x2) {
  const int row = blockIdx.x * 256 + threadIdx.x;
  const int b = row >> 12;
  __shared__ float f3[25 * R];
  for (int idx = threadIdx.x; idx < 25 * R; idx += 256) f3[idx] = F3[b * 25 * R + idx];
  __syncthreads();
  float xr[25];
  #pragma unroll
  for (int n = 0; n < 25; ++n) xr[n] = xcd1[row * 25 + n];
  float acc[R];
  #pragma unroll
  for (int r = 0; r < R; ++r) acc[r] = 0.f;
  #pragma unroll
  for (int n = 0; n < 25; ++n) {
    float v = xr[n];
    #pragma unroll
    for (int r = 0; r < R; ++r) acc[r] += v * f3[n * R + r];
  }
  #pragma unroll
  for (int r = 0; r < R; ++r) x2[row * R + r] = acc[r];
}

// ---- fused ldnet + attention + Z: per (b,t).
// fa = softmax(x2ᵀx2/8)+A; ot = x2@fa (the "pre" tensor, LDS only);
// uu from xcd1, vv from ot; att = softmax(leaky(uu+vv))+Ck;
// Z[c][n] = sum_m ot[c][m]*att[n][m]  -> Zb[col][cioff+c] bf16.
template<int M>
__global__ void ldnet_restore(const float* __restrict__ in, const float* __restrict__ A,
                              const float* __restrict__ xcd1,
                              const float* __restrict__ wu, const float* __restrict__ wv,
                              const float* __restrict__ cuv, const float* __restrict__ Ck,
                              __hip_bfloat16* __restrict__ Zb, int cioff) {
  const int b = blockIdx.x >> 6;
  const int t = blockIdx.x & 63;
  const int tid = threadIdx.x;
  __shared__ float xt[64][M];
  __shared__ float fa[M][M];
  __shared__ float ot[64][M];
  __shared__ float att[25][M];
  __shared__ float uu[25];
  __shared__ float vv[M];
  __shared__ float upart[25][8];
  for (int idx = tid; idx < 64 * M; idx += 256) {
    int c = idx / M, n = idx % M;
    xt[c][n] = in[((b * 64 + c) * 64 + t) * M + n];
  }
  if (tid < 200) {                       // uu partials from xcd1
    int n = tid >> 3, cg = tid & 7;
    float s = 0.f;
    #pragma unroll
    for (int j = 0; j < 8; ++j) {
      int c = cg * 8 + j;
      s += wu[c] * xcd1[((b * 64 + c) * 64 + t) * 25 + n];
    }
    upart[n][cg] = s;
  }
  __syncthreads();
  for (int idx = tid; idx < M * M; idx += 256) {
    int n = idx / M, m = idx % M;
    float s = 0.f;
    #pragma unroll
    for (int c = 0; c < 64; ++c) s += xt[c][n] * xt[c][m];
    fa[n][m] = s * 0.125f;
  }
  __syncthreads();
  if (tid < M) {
    int n = tid;
    float mx = -1e30f;
    for (int m = 0; m < M; ++m) mx = fmaxf(mx, fa[n][m]);
    float sum = 0.f;
    for (int m = 0; m < M; ++m) sum += __expf(fa[n][m] - mx);
    float inv = 1.f / sum;
    for (int m = 0; m < M; ++m) fa[n][m] = __expf(fa[n][m] - mx) * inv + A[n * M + m];
  }
  if (tid >= 64 && tid < 89) {           // finalize uu
    int n = tid - 64;
    float s = cuv[0];
    #pragma unroll
    for (int j = 0; j < 8; ++j) s += upart[n][j];
    uu[n] = s;
  }
  __syncthreads();
  for (int idx = tid; idx < 64 * M; idx += 256) {
    int c = idx / M, m = idx % M;
    float s = 0.f;
    #pragma unroll
    for (int n = 0; n < M; ++n) s += xt[c][n] * fa[n][m];
    ot[c][m] = s;
  }
  __syncthreads();
  if (tid < M) {
    int m = tid;
    float s = cuv[1];
    #pragma unroll
    for (int c = 0; c < 64; ++c) s += wv[c] * ot[c][m];
    vv[m] = s;
  }
  __syncthreads();
  if (tid < 25) {
    int n = tid;
    float f[M];
    float mx = -1e30f;
    #pragma unroll
    for (int m = 0; m < M; ++m) {
      float v = uu[n] + vv[m];
      v = v >= 0.f ? v : 0.2f * v;
      f[m] = v;
      mx = fmaxf(mx, v);
    }
    float sum = 0.f;
    #pragma unroll
    for (int m = 0; m < M; ++m) { f[m] = __expf(f[m] - mx); sum += f[m]; }
    float inv = 1.f / sum;
    #pragma unroll
    for (int m = 0; m < M; ++m) att[n][m] = f[m] * inv + Ck[n * M + m];
  }
  __syncthreads();
  for (int idx = tid; idx < 1600; idx += 256) {
    int n = idx >> 6, c = idx & 63;
    float s = 0.f;
    #pragma unroll
    for (int m = 0; m < M; ++m) s += ot[c][m] * att[n][m];
    Zb[(size_t)(b * 1600 + t * 25 + n) * 128 + cioff + c] = __float2bfloat16(s);
  }
}

__device__ __forceinline__ void unpack8(float* d, uint4 v) {
  d[0] = __uint_as_float(v.x << 16); d[1] = __uint_as_float(v.x & 0xffff0000u);
  d[2] = __uint_as_float(v.y << 16); d[3] = __uint_as_float(v.y & 0xffff0000u);
  d[4] = __uint_as_float(v.z << 16); d[5] = __uint_as_float(v.z & 0xffff0000u);
  d[6] = __uint_as_float(v.w << 16); d[7] = __uint_as_float(v.w & 0xffff0000u);
}

// ---- restore GEMM (both branches), IN PLACE on ZH rows:
// H[col][g] = relu(BN*(sum_c Wgb[c][g]*Z[col][ch(c,g)] + bg[g]*s[col%25]))
// block = 128 cols x 128 g; thread = 4 cols (stride 32) x 16 g.
__global__ __launch_bounds__(256) void restore_gemm(
    __hip_bfloat16* __restrict__ ZH, const __hip_bfloat16* __restrict__ Wgb,
    const float* __restrict__ bg2, const float* __restrict__ bg3,
    const float* __restrict__ sconst) {
  const int col0 = blockIdx.x * 128;
  const int tid = threadIdx.x;
  __shared__ __hip_bfloat16 Zl[128 * 136];
  __shared__ __hip_bfloat16 Wl[64 * 136];
  __shared__ float bgl[128];
  __shared__ float scl[50];
  const ushort* Zg = (const ushort*)ZH;
  #pragma unroll
  for (int it = 0; it < 8; ++it) {            // stage Z: 128 cols x 16 u4-segs
    int idx = it * 256 + tid;
    int colr = idx >> 4, seg = idx & 15;
    uint4 v = *(const uint4*)(Zg + (size_t)(col0 + colr) * 128 + seg * 8);
    *(uint4*)(&Zl[colr * 136 + seg * 8]) = v;
  }
  #pragma unroll
  for (int it = 0; it < 4; ++it) {            // stage W: 64 c x 16 segs
    int idx = it * 256 + tid;
    int k = idx >> 4, seg = idx & 15;
    uint4 v = *(const uint4*)((const ushort*)Wgb + k * 128 + seg * 8);
    *(uint4*)(&Wl[k * 136 + seg * 8]) = v;
  }
  if (tid < 128) bgl[tid] = tid < 64 ? bg2[tid] : bg3[tid - 64];
  if (tid >= 128 && tid < 178) scl[tid - 128] = sconst[tid - 128];
  __syncthreads();

  const int cq = tid >> 3;                    // 0..31
  const int gq = tid & 7;                     // 0..7
  const int g0 = gq * 16;
  const int chbase = (gq < 4) ? 0 : 64;

  float acc[4][16];
  #pragma unroll
  for (int i = 0; i < 4; ++i)
    #pragma unroll
    for (int j = 0; j < 16; ++j) acc[i][j] = 0.f;

  #pragma unroll 4
  for (int k = 0; k < 64; k += 2) {
    float z0[4], z1[4];
    #pragma unroll
    for (int i = 0; i < 4; ++i) {
      uint32_t zz = *(const uint32_t*)(&Zl[(cq + i * 32) * 136 + chbase + k]);
      z0[i] = __uint_as_float(zz << 16);
      z1[i] = __uint_as_float(zz & 0xffff0000u);
    }
    float w0[16], w1[16];
    unpack8(w0,     *(const uint4*)(&Wl[k * 136 + g0]));
    unpack8(w0 + 8, *(const uint4*)(&Wl[k * 136 + g0 + 8]));
    unpack8(w1,     *(const uint4*)(&Wl[(k + 1) * 136 + g0]));
    unpack8(w1 + 8, *(const uint4*)(&Wl[(k + 1) * 136 + g0 + 8]));
    #pragma unroll
    for (int i = 0; i < 4; ++i)
      #pragma unroll
      for (int j = 0; j < 16; ++j)
        acc[i][j] += z0[i] * w0[j] + z1[i] * w1[j];
  }

  #pragma unroll
  for (int i = 0; i < 4; ++i) {
    const int col = col0 + cq + i * 32;
    const int n = col % 25;
    const float s = (gq < 4) ? scl[n] : scl[25 + n];
    uint32_t ow[8];
    #pragma unroll
    for (int jj = 0; jj < 8; ++jj) {
      float v0 = fmaxf((acc[i][2 * jj]     + bgl[g0 + 2 * jj]     * s) * BN_SCALE_F, 0.f);
      float v1 = fmaxf((acc[i][2 * jj + 1] + bgl[g0 + 2 * jj + 1] * s) * BN_SCALE_F, 0.f);
      __hip_bfloat16 h0 = __float2bfloat16(v0);
      __hip_bfloat16 h1 = __float2bfloat16(v1);
      ow[jj] = (uint32_t)(*(ushort*)&h0) | ((uint32_t)(*(ushort*)&h1) << 16);
    }
    ushort* Hp = (ushort*)ZH + (size_t)col * 128 + g0;
    *(uint4*)Hp       = make_uint4(ow[0], ow[1], ow[2], ow[3]);
    *(uint4*)(Hp + 8) = make_uint4(ow[4], ow[5], ow[6], ow[7]);
  }
}

// ---- conv weights -> bf16, layout Wb[kt][o][ci]
__global__ void transpose_w(const float* __restrict__ Wtcn, __hip_bfloat16* __restrict__ Wb) {
  int idx = blockIdx.x * 256 + threadIdx.x;
  if (idx < 49152) {
    int ci = idx & 255;
    int rest = idx >> 8;
    int o = rest & 63, kt = rest >> 6;
    Wb[idx] = __float2bfloat16(Wtcn[(o * 256 + ci) * 3 + kt]);
  }
}

// ---- final conv via MFMA: per block (b, 320-col tile). 4 waves: wave = 80 cols x 64 o.
__global__ __launch_bounds__(256, 3) void conv_mfma(
    const __hip_bfloat16* __restrict__ HbTA, const __hip_bfloat16* __restrict__ HbTB,
    const __hip_bfloat16* __restrict__ Wb, const float* __restrict__ x,
    const float* __restrict__ btcn, const float* __restrict__ aout_,
    float* __restrict__ out) {
  const int b = blockIdx.x / 5;
  const int col0 = (blockIdx.x % 5) * 320;
  const int tid = threadIdx.x;
  const int w = tid >> 6, l = tid & 63;
  const int lr = l & 15, lg = l >> 4;

  __shared__ __hip_bfloat16 Hl[384 * 40];
  __shared__ __hip_bfloat16 Wl[3 * 64 * 40];

  f32x4 acc[5][4];
  #pragma unroll
  for (int mt = 0; mt < 5; ++mt)
    #pragma unroll
    for (int nt = 0; nt < 4; ++nt) acc[mt][nt] = (f32x4){0.f, 0.f, 0.f, 0.f};

  const int base_a = (w * 80 + lr + 7) * 40 + lg * 8;
  const int base_b = lr * 40 + lg * 8;

  for (int ch = 0; ch < 8; ++ch) {
    const __hip_bfloat16* Ht = (ch < 4) ? HbTA : HbTB;
    const int ci0 = (ch & 3) * 32;
    const int wci0 = ch * 32;
    __syncthreads();
    #pragma unroll
    for (int it = 0; it < 6; ++it) {
      int idx = it * 256 + tid;
      int colr = idx >> 2, seg = idx & 3;
      int gcol = col0 - 32 + colr;
      uint4 v = {0u, 0u, 0u, 0u};
      if (gcol >= 0 && gcol < 1600)
        v = *(const uint4*)(Ht + ((size_t)(b * 1600 + gcol) * 128 + ci0 + seg * 8));
      *(uint4*)(&Hl[colr * 40 + seg * 8]) = v;
    }
    #pragma unroll
    for (int it = 0; it < 3; ++it) {
      int idx = it * 256 + tid;
      int o = (idx >> 2) & 63, kt = idx >> 8, seg = idx & 3;
      uint4 v = *(const uint4*)(Wb + ((kt * 64 + o) * 256 + wci0 + seg * 8));
      *(uint4*)(&Wl[(kt * 64 + o) * 40 + seg * 8]) = v;
    }
    __syncthreads();
    #pragma unroll
    for (int kt = 0; kt < 3; ++kt) {
      short8 af[5], bf[4];
      const int ab = base_a + kt * 1000;
      const int bb = base_b + kt * 2560;
      #pragma unroll
      for (int mt = 0; mt < 5; ++mt) af[mt] = *(const short8*)(&Hl[ab + mt * 640]);
      #pragma unroll
      for (int nt = 0; nt < 4; ++nt) bf[nt] = *(const short8*)(&Wl[bb + nt * 640]);
      #pragma unroll
      for (int mt = 0; mt < 5; ++mt)
        #pragma unroll
        for (int nt = 0; nt < 4; ++nt)
          acc[mt][nt] = __builtin_amdgcn_mfma_f32_16x16x32_bf16(af[mt], bf[nt],
                                                                acc[mt][nt], 0, 0, 0);
    }
  }

  const float aout = aout_[0];
  const int colbase = col0 + w * 80 + lg * 4;
  #pragma unroll
  for (int nt = 0; nt < 4; ++nt) {
    const int o = nt * 16 + lr;
    const float bo = btcn[o];
    const float* xr = x + ((size_t)b * 64 + o) * 1600 + colbase;
    float* op = out + ((size_t)b * 64 + o) * 1600 + colbase;
    #pragma unroll
    for (int mt = 0; mt < 5; ++mt) {
      float4 xv = *(const float4*)(xr + mt * 16);
      f32x4 a4 = acc[mt][nt];
      float4 res;
      float v0 = (a4[0] + bo) * BN_SCALE_F + xv.x;
      float v1 = (a4[1] + bo) * BN_SCALE_F + xv.y;
      float v2 = (a4[2] + bo) * BN_SCALE_F + xv.z;
      float v3 = (a4[3] + bo) * BN_SCALE_F + xv.w;
      res.x = v0 >= 0.f ? v0 : aout * v0;
      res.y = v1 >= 0.f ? v1 : aout * v1;
      res.z = v2 >= 0.f ? v2 : aout * v2;
      res.w = v3 >= 0.f ? v3 : aout * v3;
      *(float4*)(op + mt * 16) = res;
    }
  }
}

extern "C" void kernel_launch(void* const* d_in, const int* in_sizes, int n_in,
                              void* d_out, int out_size, void* d_ws, size_t ws_size,
                              hipStream_t stream) {
  const float* x     = (const float*)d_in[0];
  const float* A1    = (const float*)d_in[1];
  const float* A2    = (const float*)d_in[2];
  const float* A3    = (const float*)d_in[3];
  const float* Wp1   = (const float*)d_in[4];
  const float* ap1   = (const float*)d_in[5];
  const float* Wp2   = (const float*)d_in[6];
  const float* ap2   = (const float*)d_in[7];
  const float* Wg2   = (const float*)d_in[8];
  const float* bg2   = (const float*)d_in[9];
  const float* Wt2   = (const float*)d_in[10];
  const float* bt2   = (const float*)d_in[11];
  const float* Wph2  = (const float*)d_in[12];
  const float* bph2  = (const float*)d_in[13];
  const float* wcat2 = (const float*)d_in[14];
  const float* Ck2   = (const float*)d_in[15];
  const float* Wg3   = (const float*)d_in[16];
  const float* bg3   = (const float*)d_in[17];
  const float* Wt3   = (const float*)d_in[18];
  const float* bt3   = (const float*)d_in[19];
  const float* Wph3  = (const float*)d_in[20];
  const float* bph3  = (const float*)d_in[21];
  const float* wcat3 = (const float*)d_in[22];
  const float* Ck3   = (const float*)d_in[23];
  const float* Wtcn  = (const float*)d_in[24];
  const float* btcn  = (const float*)d_in[25];
  const float* aout  = (const float*)d_in[26];
  float* out = (float*)d_out;
  float* ws  = (float*)d_ws;

  float* xcd1 = ws;
  float* Pp   = ws + 6553600;                               // R1: Pp2 -> Zb/HbTB
  __hip_bfloat16* ZH   = (__hip_bfloat16*)(ws + 6553600);
  __hip_bfloat16* HbTA = (__hip_bfloat16*)(ws + 13107200);  // R2
  float* x2b  = ws + 19660800;
  float* preb = ws + 24641536;                              // Wb | Wgb | sconst
  float* F19  = ws + 29622272;
  float* F15  = ws + 29652672;
  float* uv   = ws + 29676672;
  float* partials = x2b;
  __hip_bfloat16* Wb   = (__hip_bfloat16*)preb;             // 49,152 bf16
  __hip_bfloat16* Wgb  = (__hip_bfloat16*)(preb + 24576);   // 8,192 bf16
  float* sconst        = preb + 28672;                      // 50 fp32

  prep_uv<<<1, 64, 0, stream>>>(Wt2, bt2, Wph2, bph2, wcat2,
                                Wt3, bt3, Wph3, bph3, wcat3,
                                Ck2, Ck3, uv, sconst);
  prep_wgb<<<32, 256, 0, stream>>>(Wg2, Wg3, Wgb);
  transpose_w<<<192, 256, 0, stream>>>(Wtcn, Wb);
  ldnet1_fused<<<4096, 256, 0, stream>>>(x, A1, xcd1, Pp, HbTA);

  // both pools in one pass over Pp2 (block per (b, channel))
  pool_partial<<<4096, 256, 0, stream>>>(Pp, Wp1, Wp2, ap1, ap2, partials);
  pool_reduce<<<64, 256, 0, stream>>>(partials, F19, F15);

  // branch 2 (R=19): fused ldnet+attention writes Z2 into ZH ch 0..63
  x2_einsum<19><<<1024, 256, 0, stream>>>(xcd1, F19, x2b);
  ldnet_restore<19><<<4096, 256, 0, stream>>>(x2b, A2, xcd1,
                                              uv, uv + 64, uv + 256, Ck2, ZH, 0);

  // branch 3 (R=15): Z3 into ZH ch 64..127
  x2_einsum<15><<<1024, 256, 0, stream>>>(xcd1, F15, x2b);
  ldnet_restore<15><<<4096, 256, 0, stream>>>(x2b, A3, xcd1,
                                              uv + 128, uv + 192, uv + 258, Ck3, ZH, 64);

  // shared Wg GEMM, in place: ZH rows become HbTB rows (xcd2|xcd3 bf16)
  restore_gemm<<<800, 256, 0, stream>>>(ZH, Wgb, bg2, bg3, sconst);

  // final conv via MFMA + bias + BN + residual + PReLU
  conv_mfma<<<320, 256, 0, stream>>>(HbTA, ZH, Wb, x, btcn, aout, out);
}

// Round 8
// 284.923 us; speedup vs baseline: 4.8838x; 1.0766x over previous
//
#include <hip/hip_runtime.h>
#include <hip/hip_bf16.h>
#include <math.h>

// ---------------------------------------------------------------------------
// LDSTNet forward. B=64, C=64, T=64, N=25, Ci=32. Pools: R1=19, R2=15.
//
// Workspace layout (floats):
//   xcd1   @ 0          : 6,553,600   (B,C,T,25) fp32
//   R1     @ 6,553,600  : 6,553,600   Pp2 fp32 [b][t][c][n] -> Zb/HbTB bf16 [col][128]
//   R2     @ 13,107,200 : 6,553,600   HbT_A bf16 [b][1600][128] (0..63=x, 64..127=xcd1)
//   x2buf  @ 19,660,800 : 4,980,736   partials (64x64x850) -> x_2 -> x_3
//   preb   @ 24,641,536 : 4,980,736   Wb bf16 | Wgb bf16 | sconst
//   F19    @ 29,622,272 : 30,400
//   F15    @ 29,652,672 : 24,000
//   uvbuf  @ 29,676,672 : 320
// ---------------------------------------------------------------------------

#define BN_SCALE_F 0.9999950000374997f

typedef __attribute__((ext_vector_type(8))) short short8;
typedef __attribute__((ext_vector_type(4))) float f32x4;

// ---- precompute wu/wv/cu/cv for both branches + att row-sum constants
__global__ void prep_uv(const float* __restrict__ Wt2, const float* __restrict__ bt2,
                        const float* __restrict__ Wph2, const float* __restrict__ bph2,
                        const float* __restrict__ wcat2,
                        const float* __restrict__ Wt3, const float* __restrict__ bt3,
                        const float* __restrict__ Wph3, const float* __restrict__ bph3,
                        const float* __restrict__ wcat3,
                        const float* __restrict__ Ck2, const float* __restrict__ Ck3,
                        float* __restrict__ uv, float* __restrict__ sconst) {
  int c = threadIdx.x;
  if (c < 64) {
    float s1 = 0.f, s2 = 0.f, s3 = 0.f, s4 = 0.f;
    for (int i = 0; i < 32; ++i) {
      s1 += wcat2[i]      * Wt2[i * 64 + c];
      s2 += wcat2[32 + i] * Wph2[i * 64 + c];
      s3 += wcat3[i]      * Wt3[i * 64 + c];
      s4 += wcat3[32 + i] * Wph3[i * 64 + c];
    }
    uv[c] = s1; uv[64 + c] = s2; uv[128 + c] = s3; uv[192 + c] = s4;
  }
  if (c == 0) {
    float c1 = 0.f, c2 = 0.f, c3 = 0.f, c4 = 0.f;
    for (int i = 0; i < 32; ++i) {
      c1 += wcat2[i] * bt2[i];       c2 += wcat2[32 + i] * bph2[i];
      c3 += wcat3[i] * bt3[i];       c4 += wcat3[32 + i] * bph3[i];
    }
    uv[256] = c1; uv[257] = c2; uv[258] = c3; uv[259] = c4;
  }
  if (c < 25) {
    float s2 = 1.f, s3 = 1.f;
    for (int m = 0; m < 19; ++m) s2 += Ck2[c * 19 + m];
    for (int m = 0; m < 15; ++m) s3 += Ck3[c * 15 + m];
    sconst[c] = s2; sconst[25 + c] = s3;
  }
}

// ---- pack Wg2/Wg3 transposed to bf16: Wgb[c][g], g 0..63 = Wg2, 64..127 = Wg3
__global__ void prep_wgb(const float* __restrict__ Wg2, const float* __restrict__ Wg3,
                         __hip_bfloat16* __restrict__ Wgb) {
  int idx = blockIdx.x * 256 + threadIdx.x;
  if (idx < 8192) {
    int c = idx >> 7, g = idx & 127;
    float v = (g < 64) ? Wg2[g * 64 + c] : Wg3[(g - 64) * 64 + c];
    Wgb[idx] = __float2bfloat16(v);
  }
}

// ---- ldnet1 via MFMA: one wave per (b,t), 4 waves/block.
// gram(25x25,K=64) -> softmax+A -> out1=X@FA (64x25) -> P=out1@FA.
// MFMA convention (proven in conv_mfma): A-frag lane holds A[i=l&15][k=(l>>4)*8+j],
// B-frag B[j=l&15][k], D[i=(l>>4)*4+r][j=l&15], D = sum_k A[i][k]*B[j][k].
__global__ __launch_bounds__(256) void ldnet1_mfma(
    const float* __restrict__ x, const float* __restrict__ A,
    float* __restrict__ xcd1, float* __restrict__ Pp2,
    __hip_bfloat16* __restrict__ HbTA) {
  const int b = blockIdx.x >> 4;
  const int t0 = (blockIdx.x & 15) << 2;
  const int tid = threadIdx.x;
  const int w = tid >> 6;
  const int l = tid & 63;
  const int t = t0 + w;
  const int lr = l & 15, lg = l >> 4;

  __shared__ __hip_bfloat16 XbS[4][64 * 40];   // rows c, cols n (25..31 zero); reused as otb
  __shared__ float scS[4][64 * 26];            // scores -> out1 f32 -> P f32
  __shared__ __hip_bfloat16 FTS[4][32 * 40];   // FT[m][n] = FA[n][m], zero-padded
  __hip_bfloat16* Xb = XbS[w];
  float* scf = scS[w];
  __hip_bfloat16* FT = FTS[w];

  const float* xp = x + b * 102400 + t * 25;   // + c*1600 + n

  // phase 0: zero FT, stage Xb bf16 (cols 25..31 zero)
  {
    uint32_t* ftz = (uint32_t*)FT;
    for (int i = l; i < 32 * 40 / 2; i += 64) ftz[i] = 0u;
    for (int idx = l; idx < 64 * 32; idx += 64) {
      int c = idx >> 5, n = idx & 31;
      float v = (n < 25) ? xp[c * 1600 + n] : 0.f;
      Xb[c * 40 + n] = __float2bfloat16(v);
    }
  }
  // phase 0b: HbTA x-part (lane = c; gather read L1-warm, coalesced 128B write)
  for (int n = 0; n < 25; ++n) {
    float v = xp[l * 1600 + n];
    HbTA[(size_t)(b * 1600 + t * 25 + n) * 128 + l] = __float2bfloat16(v);
  }

  // phase 1: gram fragments (global gather, bf16) + 8 MFMA -> scores to scf[n*26+m]
  typedef union { short8 v; ushort u[8]; } frag_u;
  frag_u yf[2][2];                             // [i-tile][k-step]
  #pragma unroll
  for (int it = 0; it < 2; ++it) {
    const int n = it * 16 + lr;
    #pragma unroll
    for (int ks = 0; ks < 2; ++ks) {
      #pragma unroll
      for (int j = 0; j < 8; ++j) {
        int c = ks * 32 + lg * 8 + j;
        float v = (n < 25) ? xp[c * 1600 + n] : 0.f;
        __hip_bfloat16 h = __float2bfloat16(v);
        yf[it][ks].u[j] = *(ushort*)&h;
      }
    }
  }
  f32x4 accg[2][2];
  #pragma unroll
  for (int it = 0; it < 2; ++it)
    #pragma unroll
    for (int jt = 0; jt < 2; ++jt) {
      f32x4 a = (f32x4){0.f, 0.f, 0.f, 0.f};
      a = __builtin_amdgcn_mfma_f32_16x16x32_bf16(yf[it][0].v, yf[jt][0].v, a, 0, 0, 0);
      a = __builtin_amdgcn_mfma_f32_16x16x32_bf16(yf[it][1].v, yf[jt][1].v, a, 0, 0, 0);
      accg[it][jt] = a;
    }
  #pragma unroll
  for (int it = 0; it < 2; ++it)
    #pragma unroll
    for (int jt = 0; jt < 2; ++jt)
      #pragma unroll
      for (int r = 0; r < 4; ++r) {
        int i = it * 16 + lg * 4 + r;
        int j = jt * 16 + lr;
        if (i < 25 && j < 25) scf[i * 26 + j] = accg[it][jt][r];
      }
  __syncthreads();

  // phase 2: softmax rows (lanes 0..24) -> FT[m*40+n] = softmax+A transposed, bf16
  if (l < 25) {
    const int n = l;
    float f[25];
    float mx = -1e30f;
    #pragma unroll
    for (int m = 0; m < 25; ++m) { f[m] = scf[n * 26 + m] * 0.125f; mx = fmaxf(mx, f[m]); }
    float sum = 0.f;
    #pragma unroll
    for (int m = 0; m < 25; ++m) { f[m] = __expf(f[m] - mx); sum += f[m]; }
    float inv = 1.f / sum;
    #pragma unroll
    for (int m = 0; m < 25; ++m) {
      float v = f[m] * inv + A[n * 25 + m];
      FT[m * 40 + n] = __float2bfloat16(v);
    }
  }
  __syncthreads();

  // phase 3: out1 = X@FA -> D[i=c][j=m]
  short8 xf[4], ff[2];
  #pragma unroll
  for (int it = 0; it < 4; ++it)
    xf[it] = *(const short8*)(&Xb[(it * 16 + lr) * 40 + lg * 8]);
  #pragma unroll
  for (int jt = 0; jt < 2; ++jt)
    ff[jt] = *(const short8*)(&FT[(jt * 16 + lr) * 40 + lg * 8]);
  f32x4 acco[4][2];
  #pragma unroll
  for (int it = 0; it < 4; ++it)
    #pragma unroll
    for (int jt = 0; jt < 2; ++jt) {
      f32x4 a = (f32x4){0.f, 0.f, 0.f, 0.f};
      acco[it][jt] = __builtin_amdgcn_mfma_f32_16x16x32_bf16(xf[it], ff[jt], a, 0, 0, 0);
    }
  __syncthreads();   // scf(scores) dead, Xb frag-loads done -> safe to overwrite both
  #pragma unroll
  for (int it = 0; it < 4; ++it)
    #pragma unroll
    for (int jt = 0; jt < 2; ++jt)
      #pragma unroll
      for (int r = 0; r < 4; ++r) {
        int c = it * 16 + lg * 4 + r;
        int m = jt * 16 + lr;
        if (m < 25) {
          float v = acco[it][jt][r];
          scf[c * 26 + m] = v;                       // out1 f32
          Xb[c * 40 + m] = __float2bfloat16(v);      // otb (cols 25..31 stay zero)
        }
      }
  __syncthreads();

  // phase 4: write xcd1 f32 + HbTA out1-part
  for (int idx = l; idx < 1600; idx += 64) {
    int c = idx / 25, n = idx - c * 25;
    xcd1[b * 102400 + c * 1600 + t * 25 + n] = scf[c * 26 + n];
  }
  for (int n = 0; n < 25; ++n) {
    float v = scf[l * 26 + n];                       // lane = c
    HbTA[(size_t)(b * 1600 + t * 25 + n) * 128 + 64 + l] = __float2bfloat16(v);
  }

  // phase 5: P = out1@FA -> D[i=c][j=n]
  short8 of[4];
  #pragma unroll
  for (int it = 0; it < 4; ++it)
    of[it] = *(const short8*)(&Xb[(it * 16 + lr) * 40 + lg * 8]);
  f32x4 accp[4][2];
  #pragma unroll
  for (int it = 0; it < 4; ++it)
    #pragma unroll
    for (int jt = 0; jt < 2; ++jt) {
      f32x4 a = (f32x4){0.f, 0.f, 0.f, 0.f};
      accp[it][jt] = __builtin_amdgcn_mfma_f32_16x16x32_bf16(of[it], ff[jt], a, 0, 0, 0);
    }
  __syncthreads();   // phase-4 scf reads done -> safe to overwrite
  #pragma unroll
  for (int it = 0; it < 4; ++it)
    #pragma unroll
    for (int jt = 0; jt < 2; ++jt)
      #pragma unroll
      for (int r = 0; r < 4; ++r) {
        int c = it * 16 + lg * 4 + r;
        int n = jt * 16 + lr;
        if (n < 25) scf[c * 26 + n] = accp[it][jt][r];
      }
  __syncthreads();

  // phase 6: Pp2 coalesced (1600 contiguous floats per (b,t))
  for (int idx = l; idx < 1600; idx += 64) {
    int c = idx / 25, n = idx - c * 25;
    Pp2[b * 102400 + t * 1600 + idx] = scf[c * 26 + n];
  }
}

// ---- pool partials, block = (b, c-channel); Pp2[b][t][c][n]
__global__ void pool_partial(const float* __restrict__ Pp2,
                             const float* __restrict__ Wp1, const float* __restrict__ Wp2,
                             const float* __restrict__ ap1_, const float* __restrict__ ap2_,
                             float* __restrict__ partials) {
  const int b = blockIdx.x >> 6;
  const int c = blockIdx.x & 63;
  const int tid = threadIdx.x;
  const float a1 = ap1_[0], a2 = ap2_[0];
  __shared__ float pg1[1600];
  __shared__ float pg2[1600];
  __shared__ float wct[64][36];
  for (int idx = tid; idx < 1600; idx += 256) {
    int t = idx / 25, n = idx - t * 25;
    float v = Pp2[b * 102400 + t * 1600 + c * 25 + n];
    pg1[idx] = v >= 0.f ? v : a1 * v;
    pg2[idx] = v >= 0.f ? v : a2 * v;
  }
  for (int idx = tid; idx < 19 * 64; idx += 256) {
    int kl = idx & 63, r = idx >> 6;
    wct[kl][r] = Wp1[r * 4096 + (c << 6) + kl];
  }
  for (int idx = tid; idx < 15 * 64; idx += 256) {
    int kl = idx & 63, r = idx >> 6;
    wct[kl][20 + r] = Wp2[r * 4096 + (c << 6) + kl];
  }
  __syncthreads();
  if (tid < 225) {
    const int j = tid / 9;
    const int g = tid - j * 9;
    const bool br1 = (g < 5);
    const int r0 = br1 ? g * 4 : 20 + (g - 5) * 4;
    const float* pgc = br1 ? pg1 : pg2;
    float acc0 = 0.f, acc1 = 0.f, acc2 = 0.f, acc3 = 0.f;
    #pragma unroll 4
    for (int kl = 0; kl < 64; ++kl) {
      int off = kl * 25 + j;
      float p = pgc[(off & 63) * 25 + (off >> 6)];
      const float4 wv = *(const float4*)&wct[kl][r0];
      acc0 += p * wv.x; acc1 += p * wv.y; acc2 += p * wv.z; acc3 += p * wv.w;
    }
    const int base = (b * 64 + c) * 850;
    if (br1) {
      const int m = base + j * 19 + r0;
      partials[m] = acc0; partials[m + 1] = acc1; partials[m + 2] = acc2;
      if (g != 4) partials[m + 3] = acc3;
    } else {
      const int m = base + 475 + j * 15 + (r0 - 20);
      partials[m] = acc0; partials[m + 1] = acc1; partials[m + 2] = acc2;
      if (g != 8) partials[m + 3] = acc3;
    }
  }
}

// ---- reduce partials over 64 channel-chunks + per-branch softmax
__global__ void pool_reduce(const float* __restrict__ partials,
                            float* __restrict__ F19, float* __restrict__ F15) {
  const int b = blockIdx.x;
  const int tid = threadIdx.x;
  __shared__ float lg[850];
  for (int m = tid; m < 850; m += 256) {
    float s = 0.f;
    for (int ch = 0; ch < 64; ++ch) s += partials[(b * 64 + ch) * 850 + m];
    lg[m] = s;
  }
  __syncthreads();
  if (tid < 25) {
    const float* row = lg + tid * 19;
    float mx = -1e30f;
    for (int r = 0; r < 19; ++r) mx = fmaxf(mx, row[r]);
    float sum = 0.f;
    for (int r = 0; r < 19; ++r) sum += __expf(row[r] - mx);
    float inv = 1.f / sum;
    for (int r = 0; r < 19; ++r)
      F19[(b * 25 + tid) * 19 + r] = __expf(row[r] - mx) * inv;
  } else if (tid >= 32 && tid < 57) {
    const int j = tid - 32;
    const float* row = lg + 475 + j * 15;
    float mx = -1e30f;
    for (int r = 0; r < 15; ++r) mx = fmaxf(mx, row[r]);
    float sum = 0.f;
    for (int r = 0; r < 15; ++r) sum += __expf(row[r] - mx);
    float inv = 1.f / sum;
    for (int r = 0; r < 15; ++r)
      F15[(b * 25 + j) * 15 + r] = __expf(row[r] - mx) * inv;
  }
}

// ---- x2[b,c,t,r] = sum_n xcd1[b,c,t,n] * F3[b,n,r]
template<int R>
__global__ void x2_einsum(const float* __restrict__ xcd1, const float* __restrict__ F3,
                          float* __restrict__ x2) {
  const int row = blockIdx.x * 256 + threadIdx.x;
  const int b = row >> 12;
  __shared__ float f3[25 * R];
  for (int idx = threadIdx.x; idx < 25 * R; idx += 256) f3[idx] = F3[b * 25 * R + idx];
  __syncthreads();
  float xr[25];
  #pragma unroll
  for (int n = 0; n < 25; ++n) xr[n] = xcd1[row * 25 + n];
  float acc[R];
  #pragma unroll
  for (int r = 0; r < R; ++r) acc[r] = 0.f;
  #pragma unroll
  for (int n = 0; n < 25; ++n) {
    float v = xr[n];
    #pragma unroll
    for (int r = 0; r < R; ++r) acc[r] += v * f3[n * R + r];
  }
  #pragma unroll
  for (int r = 0; r < R; ++r) x2[row * R + r] = acc[r];
}

// ---- fused ldnet + attention + Z (unchanged from round 7)
template<int M>
__global__ void ldnet_restore(const float* __restrict__ in, const float* __restrict__ A,
                              const float* __restrict__ xcd1,
                              const float* __restrict__ wu, const float* __restrict__ wv,
                              const float* __restrict__ cuv, const float* __restrict__ Ck,
                              __hip_bfloat16* __restrict__ Zb, int cioff) {
  const int b = blockIdx.x >> 6;
  const int t = blockIdx.x & 63;
  const int tid = threadIdx.x;
  __shared__ float xt[64][M];
  __shared__ float fa[M][M];
  __shared__ float ot[64][M];
  __shared__ float att[25][M];
  __shared__ float uu[25];
  __shared__ float vv[M];
  __shared__ float upart[25][8];
  for (int idx = tid; idx < 64 * M; idx += 256) {
    int c = idx / M, n = idx % M;
    xt[c][n] = in[((b * 64 + c) * 64 + t) * M + n];
  }
  if (tid < 200) {
    int n = tid >> 3, cg = tid & 7;
    float s = 0.f;
    #pragma unroll
    for (int j = 0; j < 8; ++j) {
      int c = cg * 8 + j;
      s += wu[c] * xcd1[((b * 64 + c) * 64 + t) * 25 + n];
    }
    upart[n][cg] = s;
  }
  __syncthreads();
  for (int idx = tid; idx < M * M; idx += 256) {
    int n = idx / M, m = idx % M;
    float s = 0.f;
    #pragma unroll
    for (int c = 0; c < 64; ++c) s += xt[c][n] * xt[c][m];
    fa[n][m] = s * 0.125f;
  }
  __syncthreads();
  if (tid < M) {
    int n = tid;
    float mx = -1e30f;
    for (int m = 0; m < M; ++m) mx = fmaxf(mx, fa[n][m]);
    float sum = 0.f;
    for (int m = 0; m < M; ++m) sum += __expf(fa[n][m] - mx);
    float inv = 1.f / sum;
    for (int m = 0; m < M; ++m) fa[n][m] = __expf(fa[n][m] - mx) * inv + A[n * M + m];
  }
  if (tid >= 64 && tid < 89) {
    int n = tid - 64;
    float s = cuv[0];
    #pragma unroll
    for (int j = 0; j < 8; ++j) s += upart[n][j];
    uu[n] = s;
  }
  __syncthreads();
  for (int idx = tid; idx < 64 * M; idx += 256) {
    int c = idx / M, m = idx % M;
    float s = 0.f;
    #pragma unroll
    for (int n = 0; n < M; ++n) s += xt[c][n] * fa[n][m];
    ot[c][m] = s;
  }
  __syncthreads();
  if (tid < M) {
    int m = tid;
    float s = cuv[1];
    #pragma unroll
    for (int c = 0; c < 64; ++c) s += wv[c] * ot[c][m];
    vv[m] = s;
  }
  __syncthreads();
  if (tid < 25) {
    int n = tid;
    float f[M];
    float mx = -1e30f;
    #pragma unroll
    for (int m = 0; m < M; ++m) {
      float v = uu[n] + vv[m];
      v = v >= 0.f ? v : 0.2f * v;
      f[m] = v;
      mx = fmaxf(mx, v);
    }
    float sum = 0.f;
    #pragma unroll
    for (int m = 0; m < M; ++m) { f[m] = __expf(f[m] - mx); sum += f[m]; }
    float inv = 1.f / sum;
    #pragma unroll
    for (int m = 0; m < M; ++m) att[n][m] = f[m] * inv + Ck[n * M + m];
  }
  __syncthreads();
  for (int idx = tid; idx < 1600; idx += 256) {
    int n = idx >> 6, c = idx & 63;
    float s = 0.f;
    #pragma unroll
    for (int m = 0; m < M; ++m) s += ot[c][m] * att[n][m];
    Zb[(size_t)(b * 1600 + t * 25 + n) * 128 + cioff + c] = __float2bfloat16(s);
  }
}

__device__ __forceinline__ void unpack8(float* d, uint4 v) {
  d[0] = __uint_as_float(v.x << 16); d[1] = __uint_as_float(v.x & 0xffff0000u);
  d[2] = __uint_as_float(v.y << 16); d[3] = __uint_as_float(v.y & 0xffff0000u);
  d[4] = __uint_as_float(v.z << 16); d[5] = __uint_as_float(v.z & 0xffff0000u);
  d[6] = __uint_as_float(v.w << 16); d[7] = __uint_as_float(v.w & 0xffff0000u);
}

// ---- restore GEMM (both branches), IN PLACE on ZH rows (unchanged)
__global__ __launch_bounds__(256) void restore_gemm(
    __hip_bfloat16* __restrict__ ZH, const __hip_bfloat16* __restrict__ Wgb,
    const float* __restrict__ bg2, const float* __restrict__ bg3,
    const float* __restrict__ sconst) {
  const int col0 = blockIdx.x * 128;
  const int tid = threadIdx.x;
  __shared__ __hip_bfloat16 Zl[128 * 136];
  __shared__ __hip_bfloat16 Wl[64 * 136];
  __shared__ float bgl[128];
  __shared__ float scl[50];
  const ushort* Zg = (const ushort*)ZH;
  #pragma unroll
  for (int it = 0; it < 8; ++it) {
    int idx = it * 256 + tid;
    int colr = idx >> 4, seg = idx & 15;
    uint4 v = *(const uint4*)(Zg + (size_t)(col0 + colr) * 128 + seg * 8);
    *(uint4*)(&Zl[colr * 136 + seg * 8]) = v;
  }
  #pragma unroll
  for (int it = 0; it < 4; ++it) {
    int idx = it * 256 + tid;
    int k = idx >> 4, seg = idx & 15;
    uint4 v = *(const uint4*)((const ushort*)Wgb + k * 128 + seg * 8);
    *(uint4*)(&Wl[k * 136 + seg * 8]) = v;
  }
  if (tid < 128) bgl[tid] = tid < 64 ? bg2[tid] : bg3[tid - 64];
  if (tid >= 128 && tid < 178) scl[tid - 128] = sconst[tid - 128];
  __syncthreads();

  const int cq = tid >> 3;
  const int gq = tid & 7;
  const int g0 = gq * 16;
  const int chbase = (gq < 4) ? 0 : 64;

  float acc[4][16];
  #pragma unroll
  for (int i = 0; i < 4; ++i)
    #pragma unroll
    for (int j = 0; j < 16; ++j) acc[i][j] = 0.f;

  #pragma unroll 4
  for (int k = 0; k < 64; k += 2) {
    float z0[4], z1[4];
    #pragma unroll
    for (int i = 0; i < 4; ++i) {
      uint32_t zz = *(const uint32_t*)(&Zl[(cq + i * 32) * 136 + chbase + k]);
      z0[i] = __uint_as_float(zz << 16);
      z1[i] = __uint_as_float(zz & 0xffff0000u);
    }
    float w0[16], w1[16];
    unpack8(w0,     *(const uint4*)(&Wl[k * 136 + g0]));
    unpack8(w0 + 8, *(const uint4*)(&Wl[k * 136 + g0 + 8]));
    unpack8(w1,     *(const uint4*)(&Wl[(k + 1) * 136 + g0]));
    unpack8(w1 + 8, *(const uint4*)(&Wl[(k + 1) * 136 + g0 + 8]));
    #pragma unroll
    for (int i = 0; i < 4; ++i)
      #pragma unroll
      for (int j = 0; j < 16; ++j)
        acc[i][j] += z0[i] * w0[j] + z1[i] * w1[j];
  }

  #pragma unroll
  for (int i = 0; i < 4; ++i) {
    const int col = col0 + cq + i * 32;
    const int n = col % 25;
    const float s = (gq < 4) ? scl[n] : scl[25 + n];
    uint32_t ow[8];
    #pragma unroll
    for (int jj = 0; jj < 8; ++jj) {
      float v0 = fmaxf((acc[i][2 * jj]     + bgl[g0 + 2 * jj]     * s) * BN_SCALE_F, 0.f);
      float v1 = fmaxf((acc[i][2 * jj + 1] + bgl[g0 + 2 * jj + 1] * s) * BN_SCALE_F, 0.f);
      __hip_bfloat16 h0 = __float2bfloat16(v0);
      __hip_bfloat16 h1 = __float2bfloat16(v1);
      ow[jj] = (uint32_t)(*(ushort*)&h0) | ((uint32_t)(*(ushort*)&h1) << 16);
    }
    ushort* Hp = (ushort*)ZH + (size_t)col * 128 + g0;
    *(uint4*)Hp       = make_uint4(ow[0], ow[1], ow[2], ow[3]);
    *(uint4*)(Hp + 8) = make_uint4(ow[4], ow[5], ow[6], ow[7]);
  }
}

// ---- conv weights -> bf16, layout Wb[kt][o][ci]
__global__ void transpose_w(const float* __restrict__ Wtcn, __hip_bfloat16* __restrict__ Wb) {
  int idx = blockIdx.x * 256 + threadIdx.x;
  if (idx < 49152) {
    int ci = idx & 255;
    int rest = idx >> 8;
    int o = rest & 63, kt = rest >> 6;
    Wb[idx] = __float2bfloat16(Wtcn[(o * 256 + ci) * 3 + kt]);
  }
}

// ---- final conv via MFMA (unchanged)
__global__ __launch_bounds__(256, 3) void conv_mfma(
    const __hip_bfloat16* __restrict__ HbTA, const __hip_bfloat16* __restrict__ HbTB,
    const __hip_bfloat16* __restrict__ Wb, const float* __restrict__ x,
    const float* __restrict__ btcn, const float* __restrict__ aout_,
    float* __restrict__ out) {
  const int b = blockIdx.x / 5;
  const int col0 = (blockIdx.x % 5) * 320;
  const int tid = threadIdx.x;
  const int w = tid >> 6, l = tid & 63;
  const int lr = l & 15, lg = l >> 4;

  __shared__ __hip_bfloat16 Hl[384 * 40];
  __shared__ __hip_bfloat16 Wl[3 * 64 * 40];

  f32x4 acc[5][4];
  #pragma unroll
  for (int mt = 0; mt < 5; ++mt)
    #pragma unroll
    for (int nt = 0; nt < 4; ++nt) acc[mt][nt] = (f32x4){0.f, 0.f, 0.f, 0.f};

  const int base_a = (w * 80 + lr + 7) * 40 + lg * 8;
  const int base_b = lr * 40 + lg * 8;

  for (int ch = 0; ch < 8; ++ch) {
    const __hip_bfloat16* Ht = (ch < 4) ? HbTA : HbTB;
    const int ci0 = (ch & 3) * 32;
    const int wci0 = ch * 32;
    __syncthreads();
    #pragma unroll
    for (int it = 0; it < 6; ++it) {
      int idx = it * 256 + tid;
      int colr = idx >> 2, seg = idx & 3;
      int gcol = col0 - 32 + colr;
      uint4 v = {0u, 0u, 0u, 0u};
      if (gcol >= 0 && gcol < 1600)
        v = *(const uint4*)(Ht + ((size_t)(b * 1600 + gcol) * 128 + ci0 + seg * 8));
      *(uint4*)(&Hl[colr * 40 + seg * 8]) = v;
    }
    #pragma unroll
    for (int it = 0; it < 3; ++it) {
      int idx = it * 256 + tid;
      int o = (idx >> 2) & 63, kt = idx >> 8, seg = idx & 3;
      uint4 v = *(const uint4*)(Wb + ((kt * 64 + o) * 256 + wci0 + seg * 8));
      *(uint4*)(&Wl[(kt * 64 + o) * 40 + seg * 8]) = v;
    }
    __syncthreads();
    #pragma unroll
    for (int kt = 0; kt < 3; ++kt) {
      short8 af[5], bf[4];
      const int ab = base_a + kt * 1000;
      const int bb = base_b + kt * 2560;
      #pragma unroll
      for (int mt = 0; mt < 5; ++mt) af[mt] = *(const short8*)(&Hl[ab + mt * 640]);
      #pragma unroll
      for (int nt = 0; nt < 4; ++nt) bf[nt] = *(const short8*)(&Wl[bb + nt * 640]);
      #pragma unroll
      for (int mt = 0; mt < 5; ++mt)
        #pragma unroll
        for (int nt = 0; nt < 4; ++nt)
          acc[mt][nt] = __builtin_amdgcn_mfma_f32_16x16x32_bf16(af[mt], bf[nt],
                                                                acc[mt][nt], 0, 0, 0);
    }
  }

  const float aout = aout_[0];
  const int colbase = col0 + w * 80 + lg * 4;
  #pragma unroll
  for (int nt = 0; nt < 4; ++nt) {
    const int o = nt * 16 + lr;
    const float bo = btcn[o];
    const float* xr = x + ((size_t)b * 64 + o) * 1600 + colbase;
    float* op = out + ((size_t)b * 64 + o) * 1600 + colbase;
    #pragma unroll
    for (int mt = 0; mt < 5; ++mt) {
      float4 xv = *(const float4*)(xr + mt * 16);
      f32x4 a4 = acc[mt][nt];
      float4 res;
      float v0 = (a4[0] + bo) * BN_SCALE_F + xv.x;
      float v1 = (a4[1] + bo) * BN_SCALE_F + xv.y;
      float v2 = (a4[2] + bo) * BN_SCALE_F + xv.z;
      float v3 = (a4[3] + bo) * BN_SCALE_F + xv.w;
      res.x = v0 >= 0.f ? v0 : aout * v0;
      res.y = v1 >= 0.f ? v1 : aout * v1;
      res.z = v2 >= 0.f ? v2 : aout * v2;
      res.w = v3 >= 0.f ? v3 : aout * v3;
      *(float4*)(op + mt * 16) = res;
    }
  }
}

extern "C" void kernel_launch(void* const* d_in, const int* in_sizes, int n_in,
                              void* d_out, int out_size, void* d_ws, size_t ws_size,
                              hipStream_t stream) {
  const float* x     = (const float*)d_in[0];
  const float* A1    = (const float*)d_in[1];
  const float* A2    = (const float*)d_in[2];
  const float* A3    = (const float*)d_in[3];
  const float* Wp1   = (const float*)d_in[4];
  const float* ap1   = (const float*)d_in[5];
  const float* Wp2   = (const float*)d_in[6];
  const float* ap2   = (const float*)d_in[7];
  const float* Wg2   = (const float*)d_in[8];
  const float* bg2   = (const float*)d_in[9];
  const float* Wt2   = (const float*)d_in[10];
  const float* bt2   = (const float*)d_in[11];
  const float* Wph2  = (const float*)d_in[12];
  const float* bph2  = (const float*)d_in[13];
  const float* wcat2 = (const float*)d_in[14];
  const float* Ck2   = (const float*)d_in[15];
  const float* Wg3   = (const float*)d_in[16];
  const float* bg3   = (const float*)d_in[17];
  const float* Wt3   = (const float*)d_in[18];
  const float* bt3   = (const float*)d_in[19];
  const float* Wph3  = (const float*)d_in[20];
  const float* bph3  = (const float*)d_in[21];
  const float* wcat3 = (const float*)d_in[22];
  const float* Ck3   = (const float*)d_in[23];
  const float* Wtcn  = (const float*)d_in[24];
  const float* btcn  = (const float*)d_in[25];
  const float* aout  = (const float*)d_in[26];
  float* out = (float*)d_out;
  float* ws  = (float*)d_ws;

  float* xcd1 = ws;
  float* Pp   = ws + 6553600;
  __hip_bfloat16* ZH   = (__hip_bfloat16*)(ws + 6553600);
  __hip_bfloat16* HbTA = (__hip_bfloat16*)(ws + 13107200);
  float* x2b  = ws + 19660800;
  float* preb = ws + 24641536;
  float* F19  = ws + 29622272;
  float* F15  = ws + 29652672;
  float* uv   = ws + 29676672;
  float* partials = x2b;
  __hip_bfloat16* Wb   = (__hip_bfloat16*)preb;
  __hip_bfloat16* Wgb  = (__hip_bfloat16*)(preb + 24576);
  float* sconst        = preb + 28672;

  prep_uv<<<1, 64, 0, stream>>>(Wt2, bt2, Wph2, bph2, wcat2,
                                Wt3, bt3, Wph3, bph3, wcat3,
                                Ck2, Ck3, uv, sconst);
  prep_wgb<<<32, 256, 0, stream>>>(Wg2, Wg3, Wgb);
  transpose_w<<<192, 256, 0, stream>>>(Wtcn, Wb);
  ldnet1_mfma<<<1024, 256, 0, stream>>>(x, A1, xcd1, Pp, HbTA);

  // both pools in one pass over Pp2 (block per (b, channel))
  pool_partial<<<4096, 256, 0, stream>>>(Pp, Wp1, Wp2, ap1, ap2, partials);
  pool_reduce<<<64, 256, 0, stream>>>(partials, F19, F15);

  // branch 2 (R=19): fused ldnet+attention writes Z2 into ZH ch 0..63
  x2_einsum<19><<<1024, 256, 0, stream>>>(xcd1, F19, x2b);
  ldnet_restore<19><<<4096, 256, 0, stream>>>(x2b, A2, xcd1,
                                              uv, uv + 64, uv + 256, Ck2, ZH, 0);

  // branch 3 (R=15): Z3 into ZH ch 64..127
  x2_einsum<15><<<1024, 256, 0, stream>>>(xcd1, F15, x2b);
  ldnet_restore<15><<<4096, 256, 0, stream>>>(x2b, A3, xcd1,
                                              uv + 128, uv + 192, uv + 258, Ck3, ZH, 64);

  // shared Wg GEMM, in place: ZH rows become HbTB rows (xcd2|xcd3 bf16)
  restore_gemm<<<800, 256, 0, stream>>>(ZH, Wgb, bg2, bg3, sconst);

  // final conv via MFMA + bias + BN + residual + PReLU
  conv_mfma<<<320, 256, 0, stream>>>(HbTA, ZH, Wb, x, btcn, aout, out);
}

// Round 9
// 281.552 us; speedup vs baseline: 4.9422x; 1.0120x over previous
//
#include <hip/hip_runtime.h>
#include <hip/hip_bf16.h>
#include <math.h>

// ---------------------------------------------------------------------------
// LDSTNet forward. B=64, C=64, T=64, N=25, Ci=32. Pools: R1=19, R2=15.
//
// Workspace layout (floats):
//   xcd1   @ 0          : 6,553,600   (B,C,T,25) fp32
//   R1     @ 6,553,600  : 6,553,600   Pp2 fp32 [b][t][c][n] -> Zb/HbTB bf16 [col][128]
//   R2     @ 13,107,200 : 6,553,600   HbT_A bf16 [b][1600][128] (0..63=x, 64..127=xcd1)
//   x2buf  @ 19,660,800 : 4,980,736   partials (64x64x850) -> x_2 -> x_3
//   preb   @ 24,641,536 : 4,980,736   Wb | Wgb | sconst | ubuf2 | ubuf3
//   F19    @ 29,622,272 : 30,400
//   F15    @ 29,652,672 : 24,000
//   uvbuf  @ 29,676,672 : 320
// ---------------------------------------------------------------------------

#define BN_SCALE_F 0.9999950000374997f

typedef __attribute__((ext_vector_type(8))) short short8;
typedef __attribute__((ext_vector_type(4))) float f32x4;

// ---- precompute wu/wv/cu/cv for both branches + att row-sum constants
__global__ void prep_uv(const float* __restrict__ Wt2, const float* __restrict__ bt2,
                        const float* __restrict__ Wph2, const float* __restrict__ bph2,
                        const float* __restrict__ wcat2,
                        const float* __restrict__ Wt3, const float* __restrict__ bt3,
                        const float* __restrict__ Wph3, const float* __restrict__ bph3,
                        const float* __restrict__ wcat3,
                        const float* __restrict__ Ck2, const float* __restrict__ Ck3,
                        float* __restrict__ uv, float* __restrict__ sconst) {
  int c = threadIdx.x;
  if (c < 64) {
    float s1 = 0.f, s2 = 0.f, s3 = 0.f, s4 = 0.f;
    for (int i = 0; i < 32; ++i) {
      s1 += wcat2[i]      * Wt2[i * 64 + c];
      s2 += wcat2[32 + i] * Wph2[i * 64 + c];
      s3 += wcat3[i]      * Wt3[i * 64 + c];
      s4 += wcat3[32 + i] * Wph3[i * 64 + c];
    }
    uv[c] = s1; uv[64 + c] = s2; uv[128 + c] = s3; uv[192 + c] = s4;
  }
  if (c == 0) {
    float c1 = 0.f, c2 = 0.f, c3 = 0.f, c4 = 0.f;
    for (int i = 0; i < 32; ++i) {
      c1 += wcat2[i] * bt2[i];       c2 += wcat2[32 + i] * bph2[i];
      c3 += wcat3[i] * bt3[i];       c4 += wcat3[32 + i] * bph3[i];
    }
    uv[256] = c1; uv[257] = c2; uv[258] = c3; uv[259] = c4;
  }
  if (c < 25) {
    float s2 = 1.f, s3 = 1.f;
    for (int m = 0; m < 19; ++m) s2 += Ck2[c * 19 + m];
    for (int m = 0; m < 15; ++m) s3 += Ck3[c * 15 + m];
    sconst[c] = s2; sconst[25 + c] = s3;
  }
}

// ---- pack Wg2/Wg3 transposed to bf16: Wgb[c][g], g 0..63 = Wg2, 64..127 = Wg3
__global__ void prep_wgb(const float* __restrict__ Wg2, const float* __restrict__ Wg3,
                         __hip_bfloat16* __restrict__ Wgb) {
  int idx = blockIdx.x * 256 + threadIdx.x;
  if (idx < 8192) {
    int c = idx >> 7, g = idx & 127;
    float v = (g < 64) ? Wg2[g * 64 + c] : Wg3[(g - 64) * 64 + c];
    Wgb[idx] = __float2bfloat16(v);
  }
}

// ---- ldnet1 via MFMA: one wave per (b,t), 4 waves/block, NO BARRIERS
// (all LDS is wave-private; same-wave DS ordering is in-order + waitcnt).
// Also computes uu2/uu3 (restore attention row terms) from out1 while in LDS.
__global__ __launch_bounds__(256) void ldnet1_mfma(
    const float* __restrict__ x, const float* __restrict__ A,
    const float* __restrict__ uvg,
    float* __restrict__ xcd1, float* __restrict__ Pp2,
    __hip_bfloat16* __restrict__ HbTA,
    float* __restrict__ ubuf2, float* __restrict__ ubuf3) {
  const int b = blockIdx.x >> 4;
  const int t0 = (blockIdx.x & 15) << 2;
  const int tid = threadIdx.x;
  const int w = tid >> 6;
  const int l = tid & 63;
  const int t = t0 + w;
  const int lr = l & 15, lg = l >> 4;

  __shared__ __hip_bfloat16 XbS[4][64 * 40];   // rows c, cols n (25..31 zero); reused as otb
  __shared__ float scS[4][64 * 26];            // scores -> out1 f32 -> P f32
  __shared__ __hip_bfloat16 FTS[4][32 * 40];   // FT[m][n] = FA[n][m], zero-padded
  __hip_bfloat16* Xb = XbS[w];
  float* scf = scS[w];
  __hip_bfloat16* FT = FTS[w];

  const float* xp = x + b * 102400 + t * 25;   // + c*1600 + n

  // phase 0: zero FT, stage Xb bf16 (cols 25..31 zero)
  {
    uint32_t* ftz = (uint32_t*)FT;
    for (int i = l; i < 32 * 40 / 2; i += 64) ftz[i] = 0u;
    for (int idx = l; idx < 64 * 32; idx += 64) {
      int c = idx >> 5, n = idx & 31;
      float v = (n < 25) ? xp[c * 1600 + n] : 0.f;
      Xb[c * 40 + n] = __float2bfloat16(v);
    }
  }
  // phase 0b: HbTA x-part (lane = c)
  for (int n = 0; n < 25; ++n) {
    float v = xp[l * 1600 + n];
    HbTA[(size_t)(b * 1600 + t * 25 + n) * 128 + l] = __float2bfloat16(v);
  }

  // phase 1: gram fragments (global gather, bf16) + 8 MFMA -> scores
  typedef union { short8 v; ushort u[8]; } frag_u;
  frag_u yf[2][2];
  #pragma unroll
  for (int it = 0; it < 2; ++it) {
    const int n = it * 16 + lr;
    #pragma unroll
    for (int ks = 0; ks < 2; ++ks) {
      #pragma unroll
      for (int j = 0; j < 8; ++j) {
        int c = ks * 32 + lg * 8 + j;
        float v = (n < 25) ? xp[c * 1600 + n] : 0.f;
        __hip_bfloat16 h = __float2bfloat16(v);
        yf[it][ks].u[j] = *(ushort*)&h;
      }
    }
  }
  f32x4 accg[2][2];
  #pragma unroll
  for (int it = 0; it < 2; ++it)
    #pragma unroll
    for (int jt = 0; jt < 2; ++jt) {
      f32x4 a = (f32x4){0.f, 0.f, 0.f, 0.f};
      a = __builtin_amdgcn_mfma_f32_16x16x32_bf16(yf[it][0].v, yf[jt][0].v, a, 0, 0, 0);
      a = __builtin_amdgcn_mfma_f32_16x16x32_bf16(yf[it][1].v, yf[jt][1].v, a, 0, 0, 0);
      accg[it][jt] = a;
    }
  #pragma unroll
  for (int it = 0; it < 2; ++it)
    #pragma unroll
    for (int jt = 0; jt < 2; ++jt)
      #pragma unroll
      for (int r = 0; r < 4; ++r) {
        int i = it * 16 + lg * 4 + r;
        int j = jt * 16 + lr;
        if (i < 25 && j < 25) scf[i * 26 + j] = accg[it][jt][r];
      }

  // phase 2: softmax rows (lanes 0..24) -> FT transposed bf16
  if (l < 25) {
    const int n = l;
    float f[25];
    float mx = -1e30f;
    #pragma unroll
    for (int m = 0; m < 25; ++m) { f[m] = scf[n * 26 + m] * 0.125f; mx = fmaxf(mx, f[m]); }
    float sum = 0.f;
    #pragma unroll
    for (int m = 0; m < 25; ++m) { f[m] = __expf(f[m] - mx); sum += f[m]; }
    float inv = 1.f / sum;
    #pragma unroll
    for (int m = 0; m < 25; ++m) {
      float v = f[m] * inv + A[n * 25 + m];
      FT[m * 40 + n] = __float2bfloat16(v);
    }
  }

  // phase 3: out1 = X@FA -> D[i=c][j=m]
  short8 xf[4], ff[2];
  #pragma unroll
  for (int it = 0; it < 4; ++it)
    xf[it] = *(const short8*)(&Xb[(it * 16 + lr) * 40 + lg * 8]);
  #pragma unroll
  for (int jt = 0; jt < 2; ++jt)
    ff[jt] = *(const short8*)(&FT[(jt * 16 + lr) * 40 + lg * 8]);
  f32x4 acco[4][2];
  #pragma unroll
  for (int it = 0; it < 4; ++it)
    #pragma unroll
    for (int jt = 0; jt < 2; ++jt) {
      f32x4 a = (f32x4){0.f, 0.f, 0.f, 0.f};
      acco[it][jt] = __builtin_amdgcn_mfma_f32_16x16x32_bf16(xf[it], ff[jt], a, 0, 0, 0);
    }
  #pragma unroll
  for (int it = 0; it < 4; ++it)
    #pragma unroll
    for (int jt = 0; jt < 2; ++jt)
      #pragma unroll
      for (int r = 0; r < 4; ++r) {
        int c = it * 16 + lg * 4 + r;
        int m = jt * 16 + lr;
        if (m < 25) {
          float v = acco[it][jt][r];
          scf[c * 26 + m] = v;                       // out1 f32
          Xb[c * 40 + m] = __float2bfloat16(v);      // otb
        }
      }

  // phase 4: write xcd1 f32 + HbTA out1-part + uu2/uu3 for restore branches
  for (int idx = l; idx < 1600; idx += 64) {
    int c = idx / 25, n = idx - c * 25;
    xcd1[b * 102400 + c * 1600 + t * 25 + n] = scf[c * 26 + n];
  }
  for (int n = 0; n < 25; ++n) {
    float v = scf[l * 26 + n];
    HbTA[(size_t)(b * 1600 + t * 25 + n) * 128 + 64 + l] = __float2bfloat16(v);
  }
  if (l < 25) {
    float s2 = uvg[256], s3 = uvg[258];
    #pragma unroll 8
    for (int c = 0; c < 64; ++c) {
      float o = scf[c * 26 + l];
      s2 += uvg[c] * o;           // wu2
      s3 += uvg[128 + c] * o;     // wu3
    }
    ubuf2[b * 1600 + t * 25 + l] = s2;
    ubuf3[b * 1600 + t * 25 + l] = s3;
  }

  // phase 5: P = out1@FA -> D[i=c][j=n]
  short8 of[4];
  #pragma unroll
  for (int it = 0; it < 4; ++it)
    of[it] = *(const short8*)(&Xb[(it * 16 + lr) * 40 + lg * 8]);
  f32x4 accp[4][2];
  #pragma unroll
  for (int it = 0; it < 4; ++it)
    #pragma unroll
    for (int jt = 0; jt < 2; ++jt) {
      f32x4 a = (f32x4){0.f, 0.f, 0.f, 0.f};
      accp[it][jt] = __builtin_amdgcn_mfma_f32_16x16x32_bf16(of[it], ff[jt], a, 0, 0, 0);
    }
  #pragma unroll
  for (int it = 0; it < 4; ++it)
    #pragma unroll
    for (int jt = 0; jt < 2; ++jt)
      #pragma unroll
      for (int r = 0; r < 4; ++r) {
        int c = it * 16 + lg * 4 + r;
        int n = jt * 16 + lr;
        if (n < 25) scf[c * 26 + n] = accp[it][jt][r];
      }

  // phase 6: Pp2 coalesced
  for (int idx = l; idx < 1600; idx += 64) {
    int c = idx / 25, n = idx - c * 25;
    Pp2[b * 102400 + t * 1600 + idx] = scf[c * 26 + n];
  }
}

// ---- pool partials, block = (b, c-channel); Pp2[b][t][c][n]
__global__ void pool_partial(const float* __restrict__ Pp2,
                             const float* __restrict__ Wp1, const float* __restrict__ Wp2,
                             const float* __restrict__ ap1_, const float* __restrict__ ap2_,
                             float* __restrict__ partials) {
  const int b = blockIdx.x >> 6;
  const int c = blockIdx.x & 63;
  const int tid = threadIdx.x;
  const float a1 = ap1_[0], a2 = ap2_[0];
  __shared__ float pg1[1600];
  __shared__ float pg2[1600];
  __shared__ float wct[64][36];
  for (int idx = tid; idx < 1600; idx += 256) {
    int t = idx / 25, n = idx - t * 25;
    float v = Pp2[b * 102400 + t * 1600 + c * 25 + n];
    pg1[idx] = v >= 0.f ? v : a1 * v;
    pg2[idx] = v >= 0.f ? v : a2 * v;
  }
  for (int idx = tid; idx < 19 * 64; idx += 256) {
    int kl = idx & 63, r = idx >> 6;
    wct[kl][r] = Wp1[r * 4096 + (c << 6) + kl];
  }
  for (int idx = tid; idx < 15 * 64; idx += 256) {
    int kl = idx & 63, r = idx >> 6;
    wct[kl][20 + r] = Wp2[r * 4096 + (c << 6) + kl];
  }
  __syncthreads();
  if (tid < 225) {
    const int j = tid / 9;
    const int g = tid - j * 9;
    const bool br1 = (g < 5);
    const int r0 = br1 ? g * 4 : 20 + (g - 5) * 4;
    const float* pgc = br1 ? pg1 : pg2;
    float acc0 = 0.f, acc1 = 0.f, acc2 = 0.f, acc3 = 0.f;
    #pragma unroll 4
    for (int kl = 0; kl < 64; ++kl) {
      int off = kl * 25 + j;
      float p = pgc[(off & 63) * 25 + (off >> 6)];
      const float4 wv = *(const float4*)&wct[kl][r0];
      acc0 += p * wv.x; acc1 += p * wv.y; acc2 += p * wv.z; acc3 += p * wv.w;
    }
    const int base = (b * 64 + c) * 850;
    if (br1) {
      const int m = base + j * 19 + r0;
      partials[m] = acc0; partials[m + 1] = acc1; partials[m + 2] = acc2;
      if (g != 4) partials[m + 3] = acc3;
    } else {
      const int m = base + 475 + j * 15 + (r0 - 20);
      partials[m] = acc0; partials[m + 1] = acc1; partials[m + 2] = acc2;
      if (g != 8) partials[m + 3] = acc3;
    }
  }
}

// ---- reduce partials over 64 channel-chunks + per-branch softmax
__global__ void pool_reduce(const float* __restrict__ partials,
                            float* __restrict__ F19, float* __restrict__ F15) {
  const int b = blockIdx.x;
  const int tid = threadIdx.x;
  __shared__ float lg[850];
  for (int m = tid; m < 850; m += 256) {
    float s = 0.f;
    for (int ch = 0; ch < 64; ++ch) s += partials[(b * 64 + ch) * 850 + m];
    lg[m] = s;
  }
  __syncthreads();
  if (tid < 25) {
    const float* row = lg + tid * 19;
    float mx = -1e30f;
    for (int r = 0; r < 19; ++r) mx = fmaxf(mx, row[r]);
    float sum = 0.f;
    for (int r = 0; r < 19; ++r) sum += __expf(row[r] - mx);
    float inv = 1.f / sum;
    for (int r = 0; r < 19; ++r)
      F19[(b * 25 + tid) * 19 + r] = __expf(row[r] - mx) * inv;
  } else if (tid >= 32 && tid < 57) {
    const int j = tid - 32;
    const float* row = lg + 475 + j * 15;
    float mx = -1e30f;
    for (int r = 0; r < 15; ++r) mx = fmaxf(mx, row[r]);
    float sum = 0.f;
    for (int r = 0; r < 15; ++r) sum += __expf(row[r] - mx);
    float inv = 1.f / sum;
    for (int r = 0; r < 15; ++r)
      F15[(b * 25 + j) * 15 + r] = __expf(row[r] - mx) * inv;
  }
}

// ---- x2[b,c,t,r] = sum_n xcd1[b,c,t,n] * F3[b,n,r]
template<int R>
__global__ void x2_einsum(const float* __restrict__ xcd1, const float* __restrict__ F3,
                          float* __restrict__ x2) {
  const int row = blockIdx.x * 256 + threadIdx.x;
  const int b = row >> 12;
  __shared__ float f3[25 * R];
  for (int idx = threadIdx.x; idx < 25 * R; idx += 256) f3[idx] = F3[b * 25 * R + idx];
  __syncthreads();
  float xr[25];
  #pragma unroll
  for (int n = 0; n < 25; ++n) xr[n] = xcd1[row * 25 + n];
  float acc[R];
  #pragma unroll
  for (int r = 0; r < R; ++r) acc[r] = 0.f;
  #pragma unroll
  for (int n = 0; n < 25; ++n) {
    float v = xr[n];
    #pragma unroll
    for (int r = 0; r < R; ++r) acc[r] += v * f3[n * R + r];
  }
  #pragma unroll
  for (int r = 0; r < R; ++r) x2[row * R + r] = acc[r];
}

// ---- fused ldnet+attention+Z via MFMA: one wave per (b,t), NO BARRIERS.
// gram(MxM,K=64 from x2 gather) -> softmax+A -> FT; out1 = X2@FA (K=32 pad);
// vv from otb; att (uses precomputed uu) -> AT; Z = otb@AT^T (K=32 pad) -> ZH.
template<int M>
__global__ __launch_bounds__(256) void ldnet_restore_mfma(
    const float* __restrict__ x2, const float* __restrict__ A,
    const float* __restrict__ uub, const float* __restrict__ wv,
    const float* __restrict__ cuv, const float* __restrict__ Ck,
    __hip_bfloat16* __restrict__ ZH, int cioff) {
  const int b = blockIdx.x >> 4;
  const int t0 = (blockIdx.x & 15) << 2;
  const int tid = threadIdx.x;
  const int w = tid >> 6;
  const int l = tid & 63;
  const int t = t0 + w;
  const int lr = l & 15, lg = l >> 4;

  __shared__ __hip_bfloat16 XbS[4][64 * 40];   // x2-tile bf16 -> otb
  __shared__ float scS[4][64 * 26];            // scores f32 -> Zt bf16 staging
  __shared__ __hip_bfloat16 FTS[4][32 * 40];   // FT[m][n]=FA[n][m]
  __shared__ __hip_bfloat16 ATS[4][32 * 40];   // AT[n][m]=att[n][m]
  __shared__ float vvS[4][32];
  __hip_bfloat16* Xb = XbS[w];
  float* scf = scS[w];
  __hip_bfloat16* FT = FTS[w];
  __hip_bfloat16* AT = ATS[w];
  float* vv = vvS[w];

  const float* xp = x2 + (size_t)(b * 4096 + t) * M;   // + c*(64*M) + n

  // phase 0: zero FT/AT, stage Xb (cols n<M)
  {
    uint32_t* z1 = (uint32_t*)FT;
    uint32_t* z2 = (uint32_t*)AT;
    for (int i = l; i < 32 * 40 / 2; i += 64) { z1[i] = 0u; z2[i] = 0u; }
    for (int idx = l; idx < 64 * 32; idx += 64) {
      int c = idx >> 5, n = idx & 31;
      float v = (n < M) ? xp[c * (64 * M) + n] : 0.f;
      Xb[c * 40 + n] = __float2bfloat16(v);
    }
  }

  // phase 1: gram frags (gather) + 8 MFMA -> scores scf[i*26+j]
  typedef union { short8 v; ushort u[8]; } frag_u;
  frag_u yf[2][2];
  #pragma unroll
  for (int it = 0; it < 2; ++it) {
    const int n = it * 16 + lr;
    #pragma unroll
    for (int ks = 0; ks < 2; ++ks) {
      #pragma unroll
      for (int j = 0; j < 8; ++j) {
        int c = ks * 32 + lg * 8 + j;
        float v = (n < M) ? xp[c * (64 * M) + n] : 0.f;
        __hip_bfloat16 h = __float2bfloat16(v);
        yf[it][ks].u[j] = *(ushort*)&h;
      }
    }
  }
  f32x4 accg[2][2];
  #pragma unroll
  for (int it = 0; it < 2; ++it)
    #pragma unroll
    for (int jt = 0; jt < 2; ++jt) {
      f32x4 a = (f32x4){0.f, 0.f, 0.f, 0.f};
      a = __builtin_amdgcn_mfma_f32_16x16x32_bf16(yf[it][0].v, yf[jt][0].v, a, 0, 0, 0);
      a = __builtin_amdgcn_mfma_f32_16x16x32_bf16(yf[it][1].v, yf[jt][1].v, a, 0, 0, 0);
      accg[it][jt] = a;
    }
  #pragma unroll
  for (int it = 0; it < 2; ++it)
    #pragma unroll
    for (int jt = 0; jt < 2; ++jt)
      #pragma unroll
      for (int r = 0; r < 4; ++r) {
        int i = it * 16 + lg * 4 + r;
        int j = jt * 16 + lr;
        if (i < M && j < M) scf[i * 26 + j] = accg[it][jt][r];
      }

  // phase 2: softmax rows (lanes 0..M-1) -> FT[m*40+n]
  if (l < M) {
    const int n = l;
    float f[M];
    float mx = -1e30f;
    #pragma unroll
    for (int m = 0; m < M; ++m) { f[m] = scf[n * 26 + m] * 0.125f; mx = fmaxf(mx, f[m]); }
    float sum = 0.f;
    #pragma unroll
    for (int m = 0; m < M; ++m) { f[m] = __expf(f[m] - mx); sum += f[m]; }
    float inv = 1.f / sum;
    #pragma unroll
    for (int m = 0; m < M; ++m) {
      float v = f[m] * inv + A[n * M + m];
      FT[m * 40 + n] = __float2bfloat16(v);
    }
  }

  // phase 3: out1 = X2@FA (K=32), otb into Xb
  short8 xf[4], ff[2];
  #pragma unroll
  for (int it = 0; it < 4; ++it)
    xf[it] = *(const short8*)(&Xb[(it * 16 + lr) * 40 + lg * 8]);
  #pragma unroll
  for (int jt = 0; jt < 2; ++jt)
    ff[jt] = *(const short8*)(&FT[(jt * 16 + lr) * 40 + lg * 8]);
  f32x4 acco[4][2];
  #pragma unroll
  for (int it = 0; it < 4; ++it)
    #pragma unroll
    for (int jt = 0; jt < 2; ++jt) {
      f32x4 a = (f32x4){0.f, 0.f, 0.f, 0.f};
      acco[it][jt] = __builtin_amdgcn_mfma_f32_16x16x32_bf16(xf[it], ff[jt], a, 0, 0, 0);
    }
  #pragma unroll
  for (int it = 0; it < 4; ++it)
    #pragma unroll
    for (int jt = 0; jt < 2; ++jt)
      #pragma unroll
      for (int r = 0; r < 4; ++r) {
        int c = it * 16 + lg * 4 + r;
        int m = jt * 16 + lr;
        if (m < M) Xb[c * 40 + m] = __float2bfloat16(acco[it][jt][r]);
      }

  // phase 4: vv[m] = cv + sum_c wv[c]*otb[c][m]  (lanes 0..M-1)
  if (l < M) {
    float s = cuv[1];
    #pragma unroll 8
    for (int c = 0; c < 64; ++c)
      s += wv[c] * __bfloat162float(Xb[c * 40 + l]);
    vv[l] = s;
  }

  // phase 5: att (lanes 0..24): leaky(uu[n]+vv[m]) -> softmax + Ck -> AT[n*40+m]
  if (l < 25) {
    const int n = l;
    const float uu = uub[b * 1600 + t * 25 + n];
    float f[M];
    float mx = -1e30f;
    #pragma unroll
    for (int m = 0; m < M; ++m) {
      float v = uu + vv[m];
      v = v >= 0.f ? v : 0.2f * v;
      f[m] = v;
      mx = fmaxf(mx, v);
    }
    float sum = 0.f;
    #pragma unroll
    for (int m = 0; m < M; ++m) { f[m] = __expf(f[m] - mx); sum += f[m]; }
    float inv = 1.f / sum;
    #pragma unroll
    for (int m = 0; m < M; ++m)
      AT[n * 40 + m] = __float2bfloat16(f[m] * inv + Ck[n * M + m]);
  }

  // phase 6: Z = otb @ AT^T (K=32): D[i=c][j=n] -> Zt (transposed staging)
  short8 of[4], af[2];
  #pragma unroll
  for (int it = 0; it < 4; ++it)
    of[it] = *(const short8*)(&Xb[(it * 16 + lr) * 40 + lg * 8]);
  #pragma unroll
  for (int jt = 0; jt < 2; ++jt)
    af[jt] = *(const short8*)(&AT[(jt * 16 + lr) * 40 + lg * 8]);
  f32x4 accz[4][2];
  #pragma unroll
  for (int it = 0; it < 4; ++it)
    #pragma unroll
    for (int jt = 0; jt < 2; ++jt) {
      f32x4 a = (f32x4){0.f, 0.f, 0.f, 0.f};
      accz[it][jt] = __builtin_amdgcn_mfma_f32_16x16x32_bf16(of[it], af[jt], a, 0, 0, 0);
    }
  __hip_bfloat16* Zt = (__hip_bfloat16*)scf;   // scores dead; 25*66*2 B < 6656 B
  #pragma unroll
  for (int it = 0; it < 4; ++it)
    #pragma unroll
    for (int jt = 0; jt < 2; ++jt)
      #pragma unroll
      for (int r = 0; r < 4; ++r) {
        int c = it * 16 + lg * 4 + r;
        int n = jt * 16 + lr;
        if (n < 25) Zt[n * 66 + c] = __float2bfloat16(accz[it][jt][r]);
      }

  // phase 7: coalesced ZH write (lane = c, 128B per row)
  for (int n = 0; n < 25; ++n)
    ZH[(size_t)(b * 1600 + t * 25 + n) * 128 + cioff + l] = Zt[n * 66 + l];
}

__device__ __forceinline__ void unpack8(float* d, uint4 v) {
  d[0] = __uint_as_float(v.x << 16); d[1] = __uint_as_float(v.x & 0xffff0000u);
  d[2] = __uint_as_float(v.y << 16); d[3] = __uint_as_float(v.y & 0xffff0000u);
  d[4] = __uint_as_float(v.z << 16); d[5] = __uint_as_float(v.z & 0xffff0000u);
  d[6] = __uint_as_float(v.w << 16); d[7] = __uint_as_float(v.w & 0xffff0000u);
}

// ---- restore GEMM (both branches), IN PLACE on ZH rows (unchanged)
__global__ __launch_bounds__(256) void restore_gemm(
    __hip_bfloat16* __restrict__ ZH, const __hip_bfloat16* __restrict__ Wgb,
    const float* __restrict__ bg2, const float* __restrict__ bg3,
    const float* __restrict__ sconst) {
  const int col0 = blockIdx.x * 128;
  const int tid = threadIdx.x;
  __shared__ __hip_bfloat16 Zl[128 * 136];
  __shared__ __hip_bfloat16 Wl[64 * 136];
  __shared__ float bgl[128];
  __shared__ float scl[50];
  const ushort* Zg = (const ushort*)ZH;
  #pragma unroll
  for (int it = 0; it < 8; ++it) {
    int idx = it * 256 + tid;
    int colr = idx >> 4, seg = idx & 15;
    uint4 v = *(const uint4*)(Zg + (size_t)(col0 + colr) * 128 + seg * 8);
    *(uint4*)(&Zl[colr * 136 + seg * 8]) = v;
  }
  #pragma unroll
  for (int it = 0; it < 4; ++it) {
    int idx = it * 256 + tid;
    int k = idx >> 4, seg = idx & 15;
    uint4 v = *(const uint4*)((const ushort*)Wgb + k * 128 + seg * 8);
    *(uint4*)(&Wl[k * 136 + seg * 8]) = v;
  }
  if (tid < 128) bgl[tid] = tid < 64 ? bg2[tid] : bg3[tid - 64];
  if (tid >= 128 && tid < 178) scl[tid - 128] = sconst[tid - 128];
  __syncthreads();

  const int cq = tid >> 3;
  const int gq = tid & 7;
  const int g0 = gq * 16;
  const int chbase = (gq < 4) ? 0 : 64;

  float acc[4][16];
  #pragma unroll
  for (int i = 0; i < 4; ++i)
    #pragma unroll
    for (int j = 0; j < 16; ++j) acc[i][j] = 0.f;

  #pragma unroll 4
  for (int k = 0; k < 64; k += 2) {
    float z0[4], z1[4];
    #pragma unroll
    for (int i = 0; i < 4; ++i) {
      uint32_t zz = *(const uint32_t*)(&Zl[(cq + i * 32) * 136 + chbase + k]);
      z0[i] = __uint_as_float(zz << 16);
      z1[i] = __uint_as_float(zz & 0xffff0000u);
    }
    float w0[16], w1[16];
    unpack8(w0,     *(const uint4*)(&Wl[k * 136 + g0]));
    unpack8(w0 + 8, *(const uint4*)(&Wl[k * 136 + g0 + 8]));
    unpack8(w1,     *(const uint4*)(&Wl[(k + 1) * 136 + g0]));
    unpack8(w1 + 8, *(const uint4*)(&Wl[(k + 1) * 136 + g0 + 8]));
    #pragma unroll
    for (int i = 0; i < 4; ++i)
      #pragma unroll
      for (int j = 0; j < 16; ++j)
        acc[i][j] += z0[i] * w0[j] + z1[i] * w1[j];
  }

  #pragma unroll
  for (int i = 0; i < 4; ++i) {
    const int col = col0 + cq + i * 32;
    const int n = col % 25;
    const float s = (gq < 4) ? scl[n] : scl[25 + n];
    uint32_t ow[8];
    #pragma unroll
    for (int jj = 0; jj < 8; ++jj) {
      float v0 = fmaxf((acc[i][2 * jj]     + bgl[g0 + 2 * jj]     * s) * BN_SCALE_F, 0.f);
      float v1 = fmaxf((acc[i][2 * jj + 1] + bgl[g0 + 2 * jj + 1] * s) * BN_SCALE_F, 0.f);
      __hip_bfloat16 h0 = __float2bfloat16(v0);
      __hip_bfloat16 h1 = __float2bfloat16(v1);
      ow[jj] = (uint32_t)(*(ushort*)&h0) | ((uint32_t)(*(ushort*)&h1) << 16);
    }
    ushort* Hp = (ushort*)ZH + (size_t)col * 128 + g0;
    *(uint4*)Hp       = make_uint4(ow[0], ow[1], ow[2], ow[3]);
    *(uint4*)(Hp + 8) = make_uint4(ow[4], ow[5], ow[6], ow[7]);
  }
}

// ---- conv weights -> bf16, layout Wb[kt][o][ci]
__global__ void transpose_w(const float* __restrict__ Wtcn, __hip_bfloat16* __restrict__ Wb) {
  int idx = blockIdx.x * 256 + threadIdx.x;
  if (idx < 49152) {
    int ci = idx & 255;
    int rest = idx >> 8;
    int o = rest & 63, kt = rest >> 6;
    Wb[idx] = __float2bfloat16(Wtcn[(o * 256 + ci) * 3 + kt]);
  }
}

// ---- final conv via MFMA (unchanged)
__global__ __launch_bounds__(256, 3) void conv_mfma(
    const __hip_bfloat16* __restrict__ HbTA, const __hip_bfloat16* __restrict__ HbTB,
    const __hip_bfloat16* __restrict__ Wb, const float* __restrict__ x,
    const float* __restrict__ btcn, const float* __restrict__ aout_,
    float* __restrict__ out) {
  const int b = blockIdx.x / 5;
  const int col0 = (blockIdx.x % 5) * 320;
  const int tid = threadIdx.x;
  const int w = tid >> 6, l = tid & 63;
  const int lr = l & 15, lg = l >> 4;

  __shared__ __hip_bfloat16 Hl[384 * 40];
  __shared__ __hip_bfloat16 Wl[3 * 64 * 40];

  f32x4 acc[5][4];
  #pragma unroll
  for (int mt = 0; mt < 5; ++mt)
    #pragma unroll
    for (int nt = 0; nt < 4; ++nt) acc[mt][nt] = (f32x4){0.f, 0.f, 0.f, 0.f};

  const int base_a = (w * 80 + lr + 7) * 40 + lg * 8;
  const int base_b = lr * 40 + lg * 8;

  for (int ch = 0; ch < 8; ++ch) {
    const __hip_bfloat16* Ht = (ch < 4) ? HbTA : HbTB;
    const int ci0 = (ch & 3) * 32;
    const int wci0 = ch * 32;
    __syncthreads();
    #pragma unroll
    for (int it = 0; it < 6; ++it) {
      int idx = it * 256 + tid;
      int colr = idx >> 2, seg = idx & 3;
      int gcol = col0 - 32 + colr;
      uint4 v = {0u, 0u, 0u, 0u};
      if (gcol >= 0 && gcol < 1600)
        v = *(const uint4*)(Ht + ((size_t)(b * 1600 + gcol) * 128 + ci0 + seg * 8));
      *(uint4*)(&Hl[colr * 40 + seg * 8]) = v;
    }
    #pragma unroll
    for (int it = 0; it < 3; ++it) {
      int idx = it * 256 + tid;
      int o = (idx >> 2) & 63, kt = idx >> 8, seg = idx & 3;
      uint4 v = *(const uint4*)(Wb + ((kt * 64 + o) * 256 + wci0 + seg * 8));
      *(uint4*)(&Wl[(kt * 64 + o) * 40 + seg * 8]) = v;
    }
    __syncthreads();
    #pragma unroll
    for (int kt = 0; kt < 3; ++kt) {
      short8 af[5], bf[4];
      const int ab = base_a + kt * 1000;
      const int bb = base_b + kt * 2560;
      #pragma unroll
      for (int mt = 0; mt < 5; ++mt) af[mt] = *(const short8*)(&Hl[ab + mt * 640]);
      #pragma unroll
      for (int nt = 0; nt < 4; ++nt) bf[nt] = *(const short8*)(&Wl[bb + nt * 640]);
      #pragma unroll
      for (int mt = 0; mt < 5; ++mt)
        #pragma unroll
        for (int nt = 0; nt < 4; ++nt)
          acc[mt][nt] = __builtin_amdgcn_mfma_f32_16x16x32_bf16(af[mt], bf[nt],
                                                                acc[mt][nt], 0, 0, 0);
    }
  }

  const float aout = aout_[0];
  const int colbase = col0 + w * 80 + lg * 4;
  #pragma unroll
  for (int nt = 0; nt < 4; ++nt) {
    const int o = nt * 16 + lr;
    const float bo = btcn[o];
    const float* xr = x + ((size_t)b * 64 + o) * 1600 + colbase;
    float* op = out + ((size_t)b * 64 + o) * 1600 + colbase;
    #pragma unroll
    for (int mt = 0; mt < 5; ++mt) {
      float4 xv = *(const float4*)(xr + mt * 16);
      f32x4 a4 = acc[mt][nt];
      float4 res;
      float v0 = (a4[0] + bo) * BN_SCALE_F + xv.x;
      float v1 = (a4[1] + bo) * BN_SCALE_F + xv.y;
      float v2 = (a4[2] + bo) * BN_SCALE_F + xv.z;
      float v3 = (a4[3] + bo) * BN_SCALE_F + xv.w;
      res.x = v0 >= 0.f ? v0 : aout * v0;
      res.y = v1 >= 0.f ? v1 : aout * v1;
      res.z = v2 >= 0.f ? v2 : aout * v2;
      res.w = v3 >= 0.f ? v3 : aout * v3;
      *(float4*)(op + mt * 16) = res;
    }
  }
}

extern "C" void kernel_launch(void* const* d_in, const int* in_sizes, int n_in,
                              void* d_out, int out_size, void* d_ws, size_t ws_size,
                              hipStream_t stream) {
  const float* x     = (const float*)d_in[0];
  const float* A1    = (const float*)d_in[1];
  const float* A2    = (const float*)d_in[2];
  const float* A3    = (const float*)d_in[3];
  const float* Wp1   = (const float*)d_in[4];
  const float* ap1   = (const float*)d_in[5];
  const float* Wp2   = (const float*)d_in[6];
  const float* ap2   = (const float*)d_in[7];
  const float* Wg2   = (const float*)d_in[8];
  const float* bg2   = (const float*)d_in[9];
  const float* Wt2   = (const float*)d_in[10];
  const float* bt2   = (const float*)d_in[11];
  const float* Wph2  = (const float*)d_in[12];
  const float* bph2  = (const float*)d_in[13];
  const float* wcat2 = (const float*)d_in[14];
  const float* Ck2   = (const float*)d_in[15];
  const float* Wg3   = (const float*)d_in[16];
  const float* bg3   = (const float*)d_in[17];
  const float* Wt3   = (const float*)d_in[18];
  const float* bt3   = (const float*)d_in[19];
  const float* Wph3  = (const float*)d_in[20];
  const float* bph3  = (const float*)d_in[21];
  const float* wcat3 = (const float*)d_in[22];
  const float* Ck3   = (const float*)d_in[23];
  const float* Wtcn  = (const float*)d_in[24];
  const float* btcn  = (const float*)d_in[25];
  const float* aout  = (const float*)d_in[26];
  float* out = (float*)d_out;
  float* ws  = (float*)d_ws;

  float* xcd1 = ws;
  float* Pp   = ws + 6553600;
  __hip_bfloat16* ZH   = (__hip_bfloat16*)(ws + 6553600);
  __hip_bfloat16* HbTA = (__hip_bfloat16*)(ws + 13107200);
  float* x2b  = ws + 19660800;
  float* preb = ws + 24641536;
  float* F19  = ws + 29622272;
  float* F15  = ws + 29652672;
  float* uv   = ws + 29676672;
  float* partials = x2b;
  __hip_bfloat16* Wb   = (__hip_bfloat16*)preb;             // 49,152 bf16 = 24,576 f
  __hip_bfloat16* Wgb  = (__hip_bfloat16*)(preb + 24576);   // 8,192 bf16 = 4,096 f
  float* sconst        = preb + 28672;                      // 50 f
  float* ubuf2         = preb + 32768;                      // 102,400 f
  float* ubuf3         = preb + 139264;                     // 102,400 f

  prep_uv<<<1, 64, 0, stream>>>(Wt2, bt2, Wph2, bph2, wcat2,
                                Wt3, bt3, Wph3, bph3, wcat3,
                                Ck2, Ck3, uv, sconst);
  prep_wgb<<<32, 256, 0, stream>>>(Wg2, Wg3, Wgb);
  transpose_w<<<192, 256, 0, stream>>>(Wtcn, Wb);
  ldnet1_mfma<<<1024, 256, 0, stream>>>(x, A1, uv, xcd1, Pp, HbTA, ubuf2, ubuf3);

  // both pools in one pass over Pp2 (block per (b, channel))
  pool_partial<<<4096, 256, 0, stream>>>(Pp, Wp1, Wp2, ap1, ap2, partials);
  pool_reduce<<<64, 256, 0, stream>>>(partials, F19, F15);

  // branch 2 (R=19): MFMA ldnet+attention+Z -> ZH ch 0..63
  x2_einsum<19><<<1024, 256, 0, stream>>>(xcd1, F19, x2b);
  ldnet_restore_mfma<19><<<1024, 256, 0, stream>>>(x2b, A2, ubuf2,
                                                   uv + 64, uv + 256, Ck2, ZH, 0);

  // branch 3 (R=15): Z3 -> ZH ch 64..127
  x2_einsum<15><<<1024, 256, 0, stream>>>(xcd1, F15, x2b);
  ldnet_restore_mfma<15><<<1024, 256, 0, stream>>>(x2b, A3, ubuf3,
                                                   uv + 192, uv + 258, Ck3, ZH, 64);

  // shared Wg GEMM, in place: ZH rows become HbTB rows (xcd2|xcd3 bf16)
  restore_gemm<<<800, 256, 0, stream>>>(ZH, Wgb, bg2, bg3, sconst);

  // final conv via MFMA + bias + BN + residual + PReLU
  conv_mfma<<<320, 256, 0, stream>>>(HbTA, ZH, Wb, x, btcn, aout, out);
}

// Round 10
// 272.307 us; speedup vs baseline: 5.1100x; 1.0340x over previous
//
#include <hip/hip_runtime.h>
#include <hip/hip_bf16.h>
#include <math.h>

// ---------------------------------------------------------------------------
// LDSTNet forward. B=64, C=64, T=64, N=25, Ci=32. Pools: R1=19, R2=15.
//
// Workspace layout (floats):
//   xcd1   @ 0          : 6,553,600   (B,C,T,25) fp32 (bf16-rounded values)
//   R1     @ 6,553,600  : 6,553,600   Pp2 bf16 [b][t][1600] -> ZH/HbTB bf16 [col][128]
//   R2     @ 13,107,200 : 6,553,600   HbT_A bf16 [b][1600][128] (0..63=x, 64..127=xcd1)
//   x2buf  @ 19,660,800 : 4,980,736   partials (64x64x850) -> x_2 -> x_3
//   preb   @ 24,641,536 : 4,980,736   Wb | Wgb | sconst | ubuf2 | ubuf3
//   F19    @ 29,622,272 : 30,400
//   F15    @ 29,652,672 : 24,000
//   uvbuf  @ 29,676,672 : 320
// ---------------------------------------------------------------------------

#define BN_SCALE_F 0.9999950000374997f

typedef __attribute__((ext_vector_type(8))) short short8;
typedef __attribute__((ext_vector_type(4))) float f32x4;

// ---- precompute wu/wv/cu/cv for both branches + att row-sum constants
__global__ void prep_uv(const float* __restrict__ Wt2, const float* __restrict__ bt2,
                        const float* __restrict__ Wph2, const float* __restrict__ bph2,
                        const float* __restrict__ wcat2,
                        const float* __restrict__ Wt3, const float* __restrict__ bt3,
                        const float* __restrict__ Wph3, const float* __restrict__ bph3,
                        const float* __restrict__ wcat3,
                        const float* __restrict__ Ck2, const float* __restrict__ Ck3,
                        float* __restrict__ uv, float* __restrict__ sconst) {
  int c = threadIdx.x;
  if (c < 64) {
    float s1 = 0.f, s2 = 0.f, s3 = 0.f, s4 = 0.f;
    for (int i = 0; i < 32; ++i) {
      s1 += wcat2[i]      * Wt2[i * 64 + c];
      s2 += wcat2[32 + i] * Wph2[i * 64 + c];
      s3 += wcat3[i]      * Wt3[i * 64 + c];
      s4 += wcat3[32 + i] * Wph3[i * 64 + c];
    }
    uv[c] = s1; uv[64 + c] = s2; uv[128 + c] = s3; uv[192 + c] = s4;
  }
  if (c == 0) {
    float c1 = 0.f, c2 = 0.f, c3 = 0.f, c4 = 0.f;
    for (int i = 0; i < 32; ++i) {
      c1 += wcat2[i] * bt2[i];       c2 += wcat2[32 + i] * bph2[i];
      c3 += wcat3[i] * bt3[i];       c4 += wcat3[32 + i] * bph3[i];
    }
    uv[256] = c1; uv[257] = c2; uv[258] = c3; uv[259] = c4;
  }
  if (c < 25) {
    float s2 = 1.f, s3 = 1.f;
    for (int m = 0; m < 19; ++m) s2 += Ck2[c * 19 + m];
    for (int m = 0; m < 15; ++m) s3 += Ck3[c * 15 + m];
    sconst[c] = s2; sconst[25 + c] = s3;
  }
}

// ---- pack Wg2/Wg3 transposed to bf16: Wgb[c][g], g 0..63 = Wg2, 64..127 = Wg3
__global__ void prep_wgb(const float* __restrict__ Wg2, const float* __restrict__ Wg3,
                         __hip_bfloat16* __restrict__ Wgb) {
  int idx = blockIdx.x * 256 + threadIdx.x;
  if (idx < 8192) {
    int c = idx >> 7, g = idx & 127;
    float v = (g < 64) ? Wg2[g * 64 + c] : Wg3[(g - 64) * 64 + c];
    Wgb[idx] = __float2bfloat16(v);
  }
}

// ---- ldnet1 via MFMA, v2: one wave per (b,t), 4 waves/block, NO BARRIERS,
// 10.2 KB LDS/wave -> 4 blocks/CU (grid 1024 = fully resident).
// gram (global-gathered frags) -> softmax -> FT;
// Q = out1^T via A=FT-rows-m, B=X-rows-c (global gather); otb scatter + HbTA from regs;
// P = otb@FA (A=otb rows c, B=FT rows l (same frag regs)); P bf16 -> Pp2 coalesced.
__global__ __launch_bounds__(256, 4) void ldnet1_mfma(
    const float* __restrict__ x, const float* __restrict__ A,
    const float* __restrict__ uvg,
    float* __restrict__ xcd1, __hip_bfloat16* __restrict__ Pp2,
    __hip_bfloat16* __restrict__ HbTA,
    float* __restrict__ ubuf2, float* __restrict__ ubuf3) {
  const int b = blockIdx.x >> 4;
  const int t0 = (blockIdx.x & 15) << 2;
  const int tid = threadIdx.x;
  const int w = tid >> 6;
  const int l = tid & 63;
  const int t = t0 + w;
  const int lr = l & 15, lg = l >> 4;

  __shared__ __hip_bfloat16 XbS[4][64 * 40];   // otb, then P (bf16); cols 25..31 zero
  __shared__ __hip_bfloat16 FTS[4][32 * 40];   // FT[m][n] = FA[n][m]
  __shared__ float scS[4][25 * 25];            // gram scores only
  __hip_bfloat16* Xb = XbS[w];
  __hip_bfloat16* FT = FTS[w];
  float* scf = scS[w];

  const float* xp = x + b * 102400 + t * 25;   // + c*1600 + n

  // phase 0: zero Xb + FT (cols/rows beyond 25 must be 0 for padded K)
  {
    uint32_t* z1 = (uint32_t*)Xb;
    for (int i = l; i < 1280; i += 64) z1[i] = 0u;
    uint32_t* z2 = (uint32_t*)FT;
    for (int i = l; i < 640; i += 64) z2[i] = 0u;
  }
  // phase 0b: HbTA x-part (lane = c; column gather, coalesced 128B stores)
  for (int n = 0; n < 25; ++n) {
    float v = xp[l * 1600 + n];
    HbTA[(size_t)(b * 1600 + t * 25 + n) * 128 + l] = __float2bfloat16(v);
  }

  // phase 1: gram frags (X^T rows n, global gather) + 8 MFMA -> scores
  typedef union { short8 v; ushort u[8]; } frag_u;
  frag_u yf[2][2];
  #pragma unroll
  for (int it = 0; it < 2; ++it) {
    const int n = it * 16 + lr;
    #pragma unroll
    for (int ks = 0; ks < 2; ++ks) {
      #pragma unroll
      for (int j = 0; j < 8; ++j) {
        int c = ks * 32 + lg * 8 + j;
        float v = (n < 25) ? xp[c * 1600 + n] : 0.f;
        __hip_bfloat16 h = __float2bfloat16(v);
        yf[it][ks].u[j] = *(ushort*)&h;
      }
    }
  }
  f32x4 accg[2][2];
  #pragma unroll
  for (int it = 0; it < 2; ++it)
    #pragma unroll
    for (int jt = 0; jt < 2; ++jt) {
      f32x4 a = (f32x4){0.f, 0.f, 0.f, 0.f};
      a = __builtin_amdgcn_mfma_f32_16x16x32_bf16(yf[it][0].v, yf[jt][0].v, a, 0, 0, 0);
      a = __builtin_amdgcn_mfma_f32_16x16x32_bf16(yf[it][1].v, yf[jt][1].v, a, 0, 0, 0);
      accg[it][jt] = a;
    }
  #pragma unroll
  for (int it = 0; it < 2; ++it)
    #pragma unroll
    for (int jt = 0; jt < 2; ++jt)
      #pragma unroll
      for (int r = 0; r < 4; ++r) {
        int i = it * 16 + lg * 4 + r;
        int j = jt * 16 + lr;
        if (i < 25 && j < 25) scf[i * 25 + j] = accg[it][jt][r];
      }

  // phase 2: softmax rows (lanes 0..24) -> FT[m*40+n] = FA[n][m]
  if (l < 25) {
    const int n = l;
    float f[25];
    float mx = -1e30f;
    #pragma unroll
    for (int m = 0; m < 25; ++m) { f[m] = scf[n * 25 + m] * 0.125f; mx = fmaxf(mx, f[m]); }
    float sum = 0.f;
    #pragma unroll
    for (int m = 0; m < 25; ++m) { f[m] = __expf(f[m] - mx); sum += f[m]; }
    float inv = 1.f / sum;
    #pragma unroll
    for (int m = 0; m < 25; ++m) {
      float v = f[m] * inv + A[n * 25 + m];
      FT[m * 40 + n] = __float2bfloat16(v);
    }
  }

  // phase 3: Q = out1^T. A = FT rows m (LDS frags), B = X rows c (global gather).
  short8 fa_[2];
  fa_[0] = *(const short8*)(&FT[lr * 40 + lg * 8]);
  fa_[1] = *(const short8*)(&FT[(16 + lr) * 40 + lg * 8]);
  frag_u xb2[4];
  #pragma unroll
  for (int jt = 0; jt < 4; ++jt) {
    const int c = jt * 16 + lr;
    #pragma unroll
    for (int jj = 0; jj < 8; ++jj) {
      int n = lg * 8 + jj;
      float v = (n < 25) ? xp[c * 1600 + n] : 0.f;
      __hip_bfloat16 h = __float2bfloat16(v);
      xb2[jt].u[jj] = *(ushort*)&h;
    }
  }
  f32x4 q_[2][4];
  #pragma unroll
  for (int it = 0; it < 2; ++it)
    #pragma unroll
    for (int jt = 0; jt < 4; ++jt) {
      f32x4 a = (f32x4){0.f, 0.f, 0.f, 0.f};
      q_[it][jt] = __builtin_amdgcn_mfma_f32_16x16x32_bf16(fa_[it], xb2[jt].v, a, 0, 0, 0);
    }
  // scatter otb (Xb rows c, cols m) + HbTA out1-part straight from registers
  #pragma unroll
  for (int it = 0; it < 2; ++it)
    #pragma unroll
    for (int jt = 0; jt < 4; ++jt)
      #pragma unroll
      for (int r = 0; r < 4; ++r) {
        int m = it * 16 + lg * 4 + r;
        int c = jt * 16 + lr;
        if (m < 25) {
          __hip_bfloat16 h = __float2bfloat16(q_[it][jt][r]);
          Xb[c * 40 + m] = h;
          HbTA[(size_t)(b * 1600 + t * 25 + m) * 128 + 64 + c] = h;
        }
      }

  // phase 4a: xcd1 f32 write (values bf16-rounded; coalesced-ish 50B segments)
  for (int idx = l; idx < 1600; idx += 64) {
    int c = idx / 25, n = idx - c * 25;
    xcd1[b * 102400 + c * 1600 + t * 25 + n] = __bfloat162float(Xb[c * 40 + n]);
  }
  // phase 4b: uu2/uu3 from otb (lanes 0..24)
  if (l < 25) {
    float s2 = uvg[256], s3 = uvg[258];
    #pragma unroll 8
    for (int c = 0; c < 64; ++c) {
      float o = __bfloat162float(Xb[c * 40 + l]);
      s2 += uvg[c] * o;
      s3 += uvg[128 + c] * o;
    }
    ubuf2[b * 1600 + t * 25 + l] = s2;
    ubuf3[b * 1600 + t * 25 + l] = s3;
  }

  // phase 5: P = otb @ FA. A = otb rows c (LDS), B = FT rows l (reuse fa_ regs).
  short8 ofr[4];
  #pragma unroll
  for (int it = 0; it < 4; ++it)
    ofr[it] = *(const short8*)(&Xb[(it * 16 + lr) * 40 + lg * 8]);
  f32x4 p_[4][2];
  #pragma unroll
  for (int it = 0; it < 4; ++it)
    #pragma unroll
    for (int jt = 0; jt < 2; ++jt) {
      f32x4 a = (f32x4){0.f, 0.f, 0.f, 0.f};
      p_[it][jt] = __builtin_amdgcn_mfma_f32_16x16x32_bf16(ofr[it], fa_[jt], a, 0, 0, 0);
    }
  // scatter P bf16 into Xb (otb dead after ofr reads + phase-4 reads, in-order DS)
  #pragma unroll
  for (int it = 0; it < 4; ++it)
    #pragma unroll
    for (int jt = 0; jt < 2; ++jt)
      #pragma unroll
      for (int r = 0; r < 4; ++r) {
        int c = it * 16 + lg * 4 + r;
        int n = jt * 16 + lr;
        if (n < 25) Xb[c * 40 + n] = __float2bfloat16(p_[it][jt][r]);
      }

  // phase 6: Pp2 bf16 coalesced (1600 contiguous bf16 per (b,t))
  for (int idx = l; idx < 1600; idx += 64) {
    int c = idx / 25, n = idx - c * 25;
    Pp2[b * 102400 + t * 1600 + idx] = Xb[c * 40 + n];
  }
}

// ---- pool partials, block = (b, c-channel); Pp2 bf16 [b][t][1600]
__global__ void pool_partial(const __hip_bfloat16* __restrict__ Pp2,
                             const float* __restrict__ Wp1, const float* __restrict__ Wp2,
                             const float* __restrict__ ap1_, const float* __restrict__ ap2_,
                             float* __restrict__ partials) {
  const int b = blockIdx.x >> 6;
  const int c = blockIdx.x & 63;
  const int tid = threadIdx.x;
  const float a1 = ap1_[0], a2 = ap2_[0];
  __shared__ float pg1[1600];
  __shared__ float pg2[1600];
  __shared__ float wct[64][36];
  for (int idx = tid; idx < 1600; idx += 256) {
    int t = idx / 25, n = idx - t * 25;
    float v = __bfloat162float(Pp2[b * 102400 + t * 1600 + c * 25 + n]);
    pg1[idx] = v >= 0.f ? v : a1 * v;
    pg2[idx] = v >= 0.f ? v : a2 * v;
  }
  for (int idx = tid; idx < 19 * 64; idx += 256) {
    int kl = idx & 63, r = idx >> 6;
    wct[kl][r] = Wp1[r * 4096 + (c << 6) + kl];
  }
  for (int idx = tid; idx < 15 * 64; idx += 256) {
    int kl = idx & 63, r = idx >> 6;
    wct[kl][20 + r] = Wp2[r * 4096 + (c << 6) + kl];
  }
  __syncthreads();
  if (tid < 225) {
    const int j = tid / 9;
    const int g = tid - j * 9;
    const bool br1 = (g < 5);
    const int r0 = br1 ? g * 4 : 20 + (g - 5) * 4;
    const float* pgc = br1 ? pg1 : pg2;
    float acc0 = 0.f, acc1 = 0.f, acc2 = 0.f, acc3 = 0.f;
    #pragma unroll 4
    for (int kl = 0; kl < 64; ++kl) {
      int off = kl * 25 + j;
      float p = pgc[(off & 63) * 25 + (off >> 6)];
      const float4 wv = *(const float4*)&wct[kl][r0];
      acc0 += p * wv.x; acc1 += p * wv.y; acc2 += p * wv.z; acc3 += p * wv.w;
    }
    const int base = (b * 64 + c) * 850;
    if (br1) {
      const int m = base + j * 19 + r0;
      partials[m] = acc0; partials[m + 1] = acc1; partials[m + 2] = acc2;
      if (g != 4) partials[m + 3] = acc3;
    } else {
      const int m = base + 475 + j * 15 + (r0 - 20);
      partials[m] = acc0; partials[m + 1] = acc1; partials[m + 2] = acc2;
      if (g != 8) partials[m + 3] = acc3;
    }
  }
}

// ---- reduce partials over 64 channel-chunks + per-branch softmax
__global__ void pool_reduce(const float* __restrict__ partials,
                            float* __restrict__ F19, float* __restrict__ F15) {
  const int b = blockIdx.x;
  const int tid = threadIdx.x;
  __shared__ float lg[850];
  for (int m = tid; m < 850; m += 256) {
    float s = 0.f;
    for (int ch = 0; ch < 64; ++ch) s += partials[(b * 64 + ch) * 850 + m];
    lg[m] = s;
  }
  __syncthreads();
  if (tid < 25) {
    const float* row = lg + tid * 19;
    float mx = -1e30f;
    for (int r = 0; r < 19; ++r) mx = fmaxf(mx, row[r]);
    float sum = 0.f;
    for (int r = 0; r < 19; ++r) sum += __expf(row[r] - mx);
    float inv = 1.f / sum;
    for (int r = 0; r < 19; ++r)
      F19[(b * 25 + tid) * 19 + r] = __expf(row[r] - mx) * inv;
  } else if (tid >= 32 && tid < 57) {
    const int j = tid - 32;
    const float* row = lg + 475 + j * 15;
    float mx = -1e30f;
    for (int r = 0; r < 15; ++r) mx = fmaxf(mx, row[r]);
    float sum = 0.f;
    for (int r = 0; r < 15; ++r) sum += __expf(row[r] - mx);
    float inv = 1.f / sum;
    for (int r = 0; r < 15; ++r)
      F15[(b * 25 + j) * 15 + r] = __expf(row[r] - mx) * inv;
  }
}

// ---- x2[b,c,t,r] = sum_n xcd1[b,c,t,n] * F3[b,n,r]
template<int R>
__global__ void x2_einsum(const float* __restrict__ xcd1, const float* __restrict__ F3,
                          float* __restrict__ x2) {
  const int row = blockIdx.x * 256 + threadIdx.x;
  const int b = row >> 12;
  __shared__ float f3[25 * R];
  for (int idx = threadIdx.x; idx < 25 * R; idx += 256) f3[idx] = F3[b * 25 * R + idx];
  __syncthreads();
  float xr[25];
  #pragma unroll
  for (int n = 0; n < 25; ++n) xr[n] = xcd1[row * 25 + n];
  float acc[R];
  #pragma unroll
  for (int r = 0; r < R; ++r) acc[r] = 0.f;
  #pragma unroll
  for (int n = 0; n < 25; ++n) {
    float v = xr[n];
    #pragma unroll
    for (int r = 0; r < R; ++r) acc[r] += v * f3[n * R + r];
  }
  #pragma unroll
  for (int r = 0; r < R; ++r) x2[row * R + r] = acc[r];
}

// ---- fused ldnet+attention+Z via MFMA: one wave per (b,t), NO BARRIERS.
template<int M>
__global__ __launch_bounds__(256) void ldnet_restore_mfma(
    const float* __restrict__ x2, const float* __restrict__ A,
    const float* __restrict__ uub, const float* __restrict__ wv,
    const float* __restrict__ cuv, const float* __restrict__ Ck,
    __hip_bfloat16* __restrict__ ZH, int cioff) {
  const int b = blockIdx.x >> 4;
  const int t0 = (blockIdx.x & 15) << 2;
  const int tid = threadIdx.x;
  const int w = tid >> 6;
  const int l = tid & 63;
  const int t = t0 + w;
  const int lr = l & 15, lg = l >> 4;

  __shared__ __hip_bfloat16 XbS[4][64 * 40];   // x2-tile bf16 -> otb
  __shared__ float scS[4][64 * 26];            // scores f32 -> Zt bf16 staging
  __shared__ __hip_bfloat16 FTS[4][32 * 40];   // FT[m][n]=FA[n][m]
  __shared__ __hip_bfloat16 ATS[4][32 * 40];   // AT[n][m]=att[n][m]
  __shared__ float vvS[4][32];
  __hip_bfloat16* Xb = XbS[w];
  float* scf = scS[w];
  __hip_bfloat16* FT = FTS[w];
  __hip_bfloat16* AT = ATS[w];
  float* vv = vvS[w];

  const float* xp = x2 + (size_t)(b * 4096 + t) * M;   // + c*(64*M) + n

  // phase 0: zero FT/AT, stage Xb (cols n<M)
  {
    uint32_t* z1 = (uint32_t*)FT;
    uint32_t* z2 = (uint32_t*)AT;
    for (int i = l; i < 32 * 40 / 2; i += 64) { z1[i] = 0u; z2[i] = 0u; }
    for (int idx = l; idx < 64 * 32; idx += 64) {
      int c = idx >> 5, n = idx & 31;
      float v = (n < M) ? xp[c * (64 * M) + n] : 0.f;
      Xb[c * 40 + n] = __float2bfloat16(v);
    }
  }

  // phase 1: gram frags (gather) + 8 MFMA -> scores scf[i*26+j]
  typedef union { short8 v; ushort u[8]; } frag_u;
  frag_u yf[2][2];
  #pragma unroll
  for (int it = 0; it < 2; ++it) {
    const int n = it * 16 + lr;
    #pragma unroll
    for (int ks = 0; ks < 2; ++ks) {
      #pragma unroll
      for (int j = 0; j < 8; ++j) {
        int c = ks * 32 + lg * 8 + j;
        float v = (n < M) ? xp[c * (64 * M) + n] : 0.f;
        __hip_bfloat16 h = __float2bfloat16(v);
        yf[it][ks].u[j] = *(ushort*)&h;
      }
    }
  }
  f32x4 accg[2][2];
  #pragma unroll
  for (int it = 0; it < 2; ++it)
    #pragma unroll
    for (int jt = 0; jt < 2; ++jt) {
      f32x4 a = (f32x4){0.f, 0.f, 0.f, 0.f};
      a = __builtin_amdgcn_mfma_f32_16x16x32_bf16(yf[it][0].v, yf[jt][0].v, a, 0, 0, 0);
      a = __builtin_amdgcn_mfma_f32_16x16x32_bf16(yf[it][1].v, yf[jt][1].v, a, 0, 0, 0);
      accg[it][jt] = a;
    }
  #pragma unroll
  for (int it = 0; it < 2; ++it)
    #pragma unroll
    for (int jt = 0; jt < 2; ++jt)
      #pragma unroll
      for (int r = 0; r < 4; ++r) {
        int i = it * 16 + lg * 4 + r;
        int j = jt * 16 + lr;
        if (i < M && j < M) scf[i * 26 + j] = accg[it][jt][r];
      }

  // phase 2: softmax rows (lanes 0..M-1) -> FT[m*40+n]
  if (l < M) {
    const int n = l;
    float f[M];
    float mx = -1e30f;
    #pragma unroll
    for (int m = 0; m < M; ++m) { f[m] = scf[n * 26 + m] * 0.125f; mx = fmaxf(mx, f[m]); }
    float sum = 0.f;
    #pragma unroll
    for (int m = 0; m < M; ++m) { f[m] = __expf(f[m] - mx); sum += f[m]; }
    float inv = 1.f / sum;
    #pragma unroll
    for (int m = 0; m < M; ++m) {
      float v = f[m] * inv + A[n * M + m];
      FT[m * 40 + n] = __float2bfloat16(v);
    }
  }

  // phase 3: out1 = X2@FA (K=32), otb into Xb
  short8 xf[4], ff[2];
  #pragma unroll
  for (int it = 0; it < 4; ++it)
    xf[it] = *(const short8*)(&Xb[(it * 16 + lr) * 40 + lg * 8]);
  #pragma unroll
  for (int jt = 0; jt < 2; ++jt)
    ff[jt] = *(const short8*)(&FT[(jt * 16 + lr) * 40 + lg * 8]);
  f32x4 acco[4][2];
  #pragma unroll
  for (int it = 0; it < 4; ++it)
    #pragma unroll
    for (int jt = 0; jt < 2; ++jt) {
      f32x4 a = (f32x4){0.f, 0.f, 0.f, 0.f};
      acco[it][jt] = __builtin_amdgcn_mfma_f32_16x16x32_bf16(xf[it], ff[jt], a, 0, 0, 0);
    }
  #pragma unroll
  for (int it = 0; it < 4; ++it)
    #pragma unroll
    for (int jt = 0; jt < 2; ++jt)
      #pragma unroll
      for (int r = 0; r < 4; ++r) {
        int c = it * 16 + lg * 4 + r;
        int m = jt * 16 + lr;
        if (m < M) Xb[c * 40 + m] = __float2bfloat16(acco[it][jt][r]);
      }

  // phase 4: vv[m] = cv + sum_c wv[c]*otb[c][m]  (lanes 0..M-1)
  if (l < M) {
    float s = cuv[1];
    #pragma unroll 8
    for (int c = 0; c < 64; ++c)
      s += wv[c] * __bfloat162float(Xb[c * 40 + l]);
    vv[l] = s;
  }

  // phase 5: att (lanes 0..24): leaky(uu[n]+vv[m]) -> softmax + Ck -> AT[n*40+m]
  if (l < 25) {
    const int n = l;
    const float uu = uub[b * 1600 + t * 25 + n];
    float f[M];
    float mx = -1e30f;
    #pragma unroll
    for (int m = 0; m < M; ++m) {
      float v = uu + vv[m];
      v = v >= 0.f ? v : 0.2f * v;
      f[m] = v;
      mx = fmaxf(mx, v);
    }
    float sum = 0.f;
    #pragma unroll
    for (int m = 0; m < M; ++m) { f[m] = __expf(f[m] - mx); sum += f[m]; }
    float inv = 1.f / sum;
    #pragma unroll
    for (int m = 0; m < M; ++m)
      AT[n * 40 + m] = __float2bfloat16(f[m] * inv + Ck[n * M + m]);
  }

  // phase 6: Z = otb @ AT^T (K=32): D[i=c][j=n] -> Zt (transposed staging)
  short8 of[4], af[2];
  #pragma unroll
  for (int it = 0; it < 4; ++it)
    of[it] = *(const short8*)(&Xb[(it * 16 + lr) * 40 + lg * 8]);
  #pragma unroll
  for (int jt = 0; jt < 2; ++jt)
    af[jt] = *(const short8*)(&AT[(jt * 16 + lr) * 40 + lg * 8]);
  f32x4 accz[4][2];
  #pragma unroll
  for (int it = 0; it < 4; ++it)
    #pragma unroll
    for (int jt = 0; jt < 2; ++jt) {
      f32x4 a = (f32x4){0.f, 0.f, 0.f, 0.f};
      accz[it][jt] = __builtin_amdgcn_mfma_f32_16x16x32_bf16(of[it], af[jt], a, 0, 0, 0);
    }
  __hip_bfloat16* Zt = (__hip_bfloat16*)scf;   // scores dead; 25*66*2 B < 6656 B
  #pragma unroll
  for (int it = 0; it < 4; ++it)
    #pragma unroll
    for (int jt = 0; jt < 2; ++jt)
      #pragma unroll
      for (int r = 0; r < 4; ++r) {
        int c = it * 16 + lg * 4 + r;
        int n = jt * 16 + lr;
        if (n < 25) Zt[n * 66 + c] = __float2bfloat16(accz[it][jt][r]);
      }

  // phase 7: coalesced ZH write (lane = c, 128B per row)
  for (int n = 0; n < 25; ++n)
    ZH[(size_t)(b * 1600 + t * 25 + n) * 128 + cioff + l] = Zt[n * 66 + l];
}

__device__ __forceinline__ void unpack8(float* d, uint4 v) {
  d[0] = __uint_as_float(v.x << 16); d[1] = __uint_as_float(v.x & 0xffff0000u);
  d[2] = __uint_as_float(v.y << 16); d[3] = __uint_as_float(v.y & 0xffff0000u);
  d[4] = __uint_as_float(v.z << 16); d[5] = __uint_as_float(v.z & 0xffff0000u);
  d[6] = __uint_as_float(v.w << 16); d[7] = __uint_as_float(v.w & 0xffff0000u);
}

// ---- restore GEMM (both branches), IN PLACE on ZH rows
__global__ __launch_bounds__(256) void restore_gemm(
    __hip_bfloat16* __restrict__ ZH, const __hip_bfloat16* __restrict__ Wgb,
    const float* __restrict__ bg2, const float* __restrict__ bg3,
    const float* __restrict__ sconst) {
  const int col0 = blockIdx.x * 128;
  const int tid = threadIdx.x;
  __shared__ __hip_bfloat16 Zl[128 * 136];
  __shared__ __hip_bfloat16 Wl[64 * 136];
  __shared__ float bgl[128];
  __shared__ float scl[50];
  const ushort* Zg = (const ushort*)ZH;
  #pragma unroll
  for (int it = 0; it < 8; ++it) {
    int idx = it * 256 + tid;
    int colr = idx >> 4, seg = idx & 15;
    uint4 v = *(const uint4*)(Zg + (size_t)(col0 + colr) * 128 + seg * 8);
    *(uint4*)(&Zl[colr * 136 + seg * 8]) = v;
  }
  #pragma unroll
  for (int it = 0; it < 4; ++it) {
    int idx = it * 256 + tid;
    int k = idx >> 4, seg = idx & 15;
    uint4 v = *(const uint4*)((const ushort*)Wgb + k * 128 + seg * 8);
    *(uint4*)(&Wl[k * 136 + seg * 8]) = v;
  }
  if (tid < 128) bgl[tid] = tid < 64 ? bg2[tid] : bg3[tid - 64];
  if (tid >= 128 && tid < 178) scl[tid - 128] = sconst[tid - 128];
  __syncthreads();

  const int cq = tid >> 3;
  const int gq = tid & 7;
  const int g0 = gq * 16;
  const int chbase = (gq < 4) ? 0 : 64;

  float acc[4][16];
  #pragma unroll
  for (int i = 0; i < 4; ++i)
    #pragma unroll
    for (int j = 0; j < 16; ++j) acc[i][j] = 0.f;

  #pragma unroll 4
  for (int k = 0; k < 64; k += 2) {
    float z0[4], z1[4];
    #pragma unroll
    for (int i = 0; i < 4; ++i) {
      uint32_t zz = *(const uint32_t*)(&Zl[(cq + i * 32) * 136 + chbase + k]);
      z0[i] = __uint_as_float(zz << 16);
      z1[i] = __uint_as_float(zz & 0xffff0000u);
    }
    float w0[16], w1[16];
    unpack8(w0,     *(const uint4*)(&Wl[k * 136 + g0]));
    unpack8(w0 + 8, *(const uint4*)(&Wl[k * 136 + g0 + 8]));
    unpack8(w1,     *(const uint4*)(&Wl[(k + 1) * 136 + g0]));
    unpack8(w1 + 8, *(const uint4*)(&Wl[(k + 1) * 136 + g0 + 8]));
    #pragma unroll
    for (int i = 0; i < 4; ++i)
      #pragma unroll
      for (int j = 0; j < 16; ++j)
        acc[i][j] += z0[i] * w0[j] + z1[i] * w1[j];
  }

  #pragma unroll
  for (int i = 0; i < 4; ++i) {
    const int col = col0 + cq + i * 32;
    const int n = col % 25;
    const float s = (gq < 4) ? scl[n] : scl[25 + n];
    uint32_t ow[8];
    #pragma unroll
    for (int jj = 0; jj < 8; ++jj) {
      float v0 = fmaxf((acc[i][2 * jj]     + bgl[g0 + 2 * jj]     * s) * BN_SCALE_F, 0.f);
      float v1 = fmaxf((acc[i][2 * jj + 1] + bgl[g0 + 2 * jj + 1] * s) * BN_SCALE_F, 0.f);
      __hip_bfloat16 h0 = __float2bfloat16(v0);
      __hip_bfloat16 h1 = __float2bfloat16(v1);
      ow[jj] = (uint32_t)(*(ushort*)&h0) | ((uint32_t)(*(ushort*)&h1) << 16);
    }
    ushort* Hp = (ushort*)ZH + (size_t)col * 128 + g0;
    *(uint4*)Hp       = make_uint4(ow[0], ow[1], ow[2], ow[3]);
    *(uint4*)(Hp + 8) = make_uint4(ow[4], ow[5], ow[6], ow[7]);
  }
}

// ---- conv weights -> bf16, layout Wb[kt][o][ci]
__global__ void transpose_w(const float* __restrict__ Wtcn, __hip_bfloat16* __restrict__ Wb) {
  int idx = blockIdx.x * 256 + threadIdx.x;
  if (idx < 49152) {
    int ci = idx & 255;
    int rest = idx >> 8;
    int o = rest & 63, kt = rest >> 6;
    Wb[idx] = __float2bfloat16(Wtcn[(o * 256 + ci) * 3 + kt]);
  }
}

// ---- final conv via MFMA (unchanged)
__global__ __launch_bounds__(256, 3) void conv_mfma(
    const __hip_bfloat16* __restrict__ HbTA, const __hip_bfloat16* __restrict__ HbTB,
    const __hip_bfloat16* __restrict__ Wb, const float* __restrict__ x,
    const float* __restrict__ btcn, const float* __restrict__ aout_,
    float* __restrict__ out) {
  const int b = blockIdx.x / 5;
  const int col0 = (blockIdx.x % 5) * 320;
  const int tid = threadIdx.x;
  const int w = tid >> 6, l = tid & 63;
  const int lr = l & 15, lg = l >> 4;

  __shared__ __hip_bfloat16 Hl[384 * 40];
  __shared__ __hip_bfloat16 Wl[3 * 64 * 40];

  f32x4 acc[5][4];
  #pragma unroll
  for (int mt = 0; mt < 5; ++mt)
    #pragma unroll
    for (int nt = 0; nt < 4; ++nt) acc[mt][nt] = (f32x4){0.f, 0.f, 0.f, 0.f};

  const int base_a = (w * 80 + lr + 7) * 40 + lg * 8;
  const int base_b = lr * 40 + lg * 8;

  for (int ch = 0; ch < 8; ++ch) {
    const __hip_bfloat16* Ht = (ch < 4) ? HbTA : HbTB;
    const int ci0 = (ch & 3) * 32;
    const int wci0 = ch * 32;
    __syncthreads();
    #pragma unroll
    for (int it = 0; it < 6; ++it) {
      int idx = it * 256 + tid;
      int colr = idx >> 2, seg = idx & 3;
      int gcol = col0 - 32 + colr;
      uint4 v = {0u, 0u, 0u, 0u};
      if (gcol >= 0 && gcol < 1600)
        v = *(const uint4*)(Ht + ((size_t)(b * 1600 + gcol) * 128 + ci0 + seg * 8));
      *(uint4*)(&Hl[colr * 40 + seg * 8]) = v;
    }
    #pragma unroll
    for (int it = 0; it < 3; ++it) {
      int idx = it * 256 + tid;
      int o = (idx >> 2) & 63, kt = idx >> 8, seg = idx & 3;
      uint4 v = *(const uint4*)(Wb + ((kt * 64 + o) * 256 + wci0 + seg * 8));
      *(uint4*)(&Wl[(kt * 64 + o) * 40 + seg * 8]) = v;
    }
    __syncthreads();
    #pragma unroll
    for (int kt = 0; kt < 3; ++kt) {
      short8 af[5], bf[4];
      const int ab = base_a + kt * 1000;
      const int bb = base_b + kt * 2560;
      #pragma unroll
      for (int mt = 0; mt < 5; ++mt) af[mt] = *(const short8*)(&Hl[ab + mt * 640]);
      #pragma unroll
      for (int nt = 0; nt < 4; ++nt) bf[nt] = *(const short8*)(&Wl[bb + nt * 640]);
      #pragma unroll
      for (int mt = 0; mt < 5; ++mt)
        #pragma unroll
        for (int nt = 0; nt < 4; ++nt)
          acc[mt][nt] = __builtin_amdgcn_mfma_f32_16x16x32_bf16(af[mt], bf[nt],
                                                                acc[mt][nt], 0, 0, 0);
    }
  }

  const float aout = aout_[0];
  const int colbase = col0 + w * 80 + lg * 4;
  #pragma unroll
  for (int nt = 0; nt < 4; ++nt) {
    const int o = nt * 16 + lr;
    const float bo = btcn[o];
    const float* xr = x + ((size_t)b * 64 + o) * 1600 + colbase;
    float* op = out + ((size_t)b * 64 + o) * 1600 + colbase;
    #pragma unroll
    for (int mt = 0; mt < 5; ++mt) {
      float4 xv = *(const float4*)(xr + mt * 16);
      f32x4 a4 = acc[mt][nt];
      float4 res;
      float v0 = (a4[0] + bo) * BN_SCALE_F + xv.x;
      float v1 = (a4[1] + bo) * BN_SCALE_F + xv.y;
      float v2 = (a4[2] + bo) * BN_SCALE_F + xv.z;
      float v3 = (a4[3] + bo) * BN_SCALE_F + xv.w;
      res.x = v0 >= 0.f ? v0 : aout * v0;
      res.y = v1 >= 0.f ? v1 : aout * v1;
      res.z = v2 >= 0.f ? v2 : aout * v2;
      res.w = v3 >= 0.f ? v3 : aout * v3;
      *(float4*)(op + mt * 16) = res;
    }
  }
}

extern "C" void kernel_launch(void* const* d_in, const int* in_sizes, int n_in,
                              void* d_out, int out_size, void* d_ws, size_t ws_size,
                              hipStream_t stream) {
  const float* x     = (const float*)d_in[0];
  const float* A1    = (const float*)d_in[1];
  const float* A2    = (const float*)d_in[2];
  const float* A3    = (const float*)d_in[3];
  const float* Wp1   = (const float*)d_in[4];
  const float* ap1   = (const float*)d_in[5];
  const float* Wp2   = (const float*)d_in[6];
  const float* ap2   = (const float*)d_in[7];
  const float* Wg2   = (const float*)d_in[8];
  const float* bg2   = (const float*)d_in[9];
  const float* Wt2   = (const float*)d_in[10];
  const float* bt2   = (const float*)d_in[11];
  const float* Wph2  = (const float*)d_in[12];
  const float* bph2  = (const float*)d_in[13];
  const float* wcat2 = (const float*)d_in[14];
  const float* Ck2   = (const float*)d_in[15];
  const float* Wg3   = (const float*)d_in[16];
  const float* bg3   = (const float*)d_in[17];
  const float* Wt3   = (const float*)d_in[18];
  const float* bt3   = (const float*)d_in[19];
  const float* Wph3  = (const float*)d_in[20];
  const float* bph3  = (const float*)d_in[21];
  const float* wcat3 = (const float*)d_in[22];
  const float* Ck3   = (const float*)d_in[23];
  const float* Wtcn  = (const float*)d_in[24];
  const float* btcn  = (const float*)d_in[25];
  const float* aout  = (const float*)d_in[26];
  float* out = (float*)d_out;
  float* ws  = (float*)d_ws;

  float* xcd1 = ws;
  __hip_bfloat16* ZH   = (__hip_bfloat16*)(ws + 6553600);   // also Pp2 bf16 (earlier life)
  __hip_bfloat16* HbTA = (__hip_bfloat16*)(ws + 13107200);
  float* x2b  = ws + 19660800;
  float* preb = ws + 24641536;
  float* F19  = ws + 29622272;
  float* F15  = ws + 29652672;
  float* uv   = ws + 29676672;
  float* partials = x2b;
  __hip_bfloat16* Wb   = (__hip_bfloat16*)preb;             // 49,152 bf16 = 24,576 f
  __hip_bfloat16* Wgb  = (__hip_bfloat16*)(preb + 24576);   // 8,192 bf16 = 4,096 f
  float* sconst        = preb + 28672;                      // 50 f
  float* ubuf2         = preb + 32768;                      // 102,400 f
  float* ubuf3         = preb + 139264;                     // 102,400 f

  prep_uv<<<1, 64, 0, stream>>>(Wt2, bt2, Wph2, bph2, wcat2,
                                Wt3, bt3, Wph3, bph3, wcat3,
                                Ck2, Ck3, uv, sconst);
  prep_wgb<<<32, 256, 0, stream>>>(Wg2, Wg3, Wgb);
  transpose_w<<<192, 256, 0, stream>>>(Wtcn, Wb);
  ldnet1_mfma<<<1024, 256, 0, stream>>>(x, A1, uv, xcd1, ZH /*Pp2 bf16*/, HbTA,
                                        ubuf2, ubuf3);

  // both pools in one pass over Pp2 bf16 (block per (b, channel))
  pool_partial<<<4096, 256, 0, stream>>>(ZH, Wp1, Wp2, ap1, ap2, partials);
  pool_reduce<<<64, 256, 0, stream>>>(partials, F19, F15);

  // branch 2 (R=19): MFMA ldnet+attention+Z -> ZH ch 0..63 (Pp2 now dead)
  x2_einsum<19><<<1024, 256, 0, stream>>>(xcd1, F19, x2b);
  ldnet_restore_mfma<19><<<1024, 256, 0, stream>>>(x2b, A2, ubuf2,
                                                   uv + 64, uv + 256, Ck2, ZH, 0);

  // branch 3 (R=15): Z3 -> ZH ch 64..127
  x2_einsum<15><<<1024, 256, 0, stream>>>(xcd1, F15, x2b);
  ldnet_restore_mfma<15><<<1024, 256, 0, stream>>>(x2b, A3, ubuf3,
                                                   uv + 192, uv + 258, Ck3, ZH, 64);

  // shared Wg GEMM, in place: ZH rows become HbTB rows (xcd2|xcd3 bf16)
  restore_gemm<<<800, 256, 0, stream>>>(ZH, Wgb, bg2, bg3, sconst);

  // final conv via MFMA + bias + BN + residual + PReLU
  conv_mfma<<<320, 256, 0, stream>>>(HbTA, ZH, Wb, x, btcn, aout, out);
}

// Round 11
// 249.400 us; speedup vs baseline: 5.5794x; 1.0918x over previous
//
#include <hip/hip_runtime.h>
#include <hip/hip_bf16.h>
#include <math.h>

// ---------------------------------------------------------------------------
// LDSTNet forward. B=64, C=64, T=64, N=25, Ci=32. Pools: R1=19, R2=15.
//
// Workspace layout (floats):
//   xcd1   @ 0          : 6,553,600   (B,C,T,25) fp32 (bf16-rounded values)
//   R1     @ 6,553,600  : 6,553,600   Pp2 bf16 [b][t][1600] -> ZH/HbTB bf16 [col][128]
//   R2     @ 13,107,200 : 6,553,600   HbT_A bf16 [b][1600][128] (0..63=x, 64..127=xcd1)
//   x2buf  @ 19,660,800 : 4,980,736   partials (64x64x850) -> x_2 -> x_3
//   preb   @ 24,641,536 : 4,980,736   Wb | WgT | sconst | ubuf2 | ubuf3
//   F19    @ 29,622,272 : 30,400
//   F15    @ 29,652,672 : 24,000
//   uvbuf  @ 29,676,672 : 320
// ---------------------------------------------------------------------------

#define BN_SCALE_F 0.9999950000374997f

typedef __attribute__((ext_vector_type(8))) short short8;
typedef __attribute__((ext_vector_type(4))) float f32x4;

// ---- precompute wu/wv/cu/cv for both branches + att row-sum constants
__global__ void prep_uv(const float* __restrict__ Wt2, const float* __restrict__ bt2,
                        const float* __restrict__ Wph2, const float* __restrict__ bph2,
                        const float* __restrict__ wcat2,
                        const float* __restrict__ Wt3, const float* __restrict__ bt3,
                        const float* __restrict__ Wph3, const float* __restrict__ bph3,
                        const float* __restrict__ wcat3,
                        const float* __restrict__ Ck2, const float* __restrict__ Ck3,
                        float* __restrict__ uv, float* __restrict__ sconst) {
  int c = threadIdx.x;
  if (c < 64) {
    float s1 = 0.f, s2 = 0.f, s3 = 0.f, s4 = 0.f;
    for (int i = 0; i < 32; ++i) {
      s1 += wcat2[i]      * Wt2[i * 64 + c];
      s2 += wcat2[32 + i] * Wph2[i * 64 + c];
      s3 += wcat3[i]      * Wt3[i * 64 + c];
      s4 += wcat3[32 + i] * Wph3[i * 64 + c];
    }
    uv[c] = s1; uv[64 + c] = s2; uv[128 + c] = s3; uv[192 + c] = s4;
  }
  if (c == 0) {
    float c1 = 0.f, c2 = 0.f, c3 = 0.f, c4 = 0.f;
    for (int i = 0; i < 32; ++i) {
      c1 += wcat2[i] * bt2[i];       c2 += wcat2[32 + i] * bph2[i];
      c3 += wcat3[i] * bt3[i];       c4 += wcat3[32 + i] * bph3[i];
    }
    uv[256] = c1; uv[257] = c2; uv[258] = c3; uv[259] = c4;
  }
  if (c < 25) {
    float s2 = 1.f, s3 = 1.f;
    for (int m = 0; m < 19; ++m) s2 += Ck2[c * 19 + m];
    for (int m = 0; m < 15; ++m) s3 += Ck3[c * 15 + m];
    sconst[c] = s2; sconst[25 + c] = s3;
  }
}

// ---- pack Wg2/Wg3 row-major bf16: WgT[g][c], g 0..63 = Wg2, 64..127 = Wg3
__global__ void prep_wgt(const float* __restrict__ Wg2, const float* __restrict__ Wg3,
                         __hip_bfloat16* __restrict__ WgT) {
  int idx = blockIdx.x * 256 + threadIdx.x;
  if (idx < 8192) {
    int g = idx >> 6, c = idx & 63;
    float v = (g < 64) ? Wg2[g * 64 + c] : Wg3[(g - 64) * 64 + c];
    WgT[idx] = __float2bfloat16(v);
  }
}

// ---- ldnet1 via MFMA, v2: one wave per (b,t), 4 waves/block, NO BARRIERS.
__global__ __launch_bounds__(256, 4) void ldnet1_mfma(
    const float* __restrict__ x, const float* __restrict__ A,
    const float* __restrict__ uvg,
    float* __restrict__ xcd1, __hip_bfloat16* __restrict__ Pp2,
    __hip_bfloat16* __restrict__ HbTA,
    float* __restrict__ ubuf2, float* __restrict__ ubuf3) {
  const int b = blockIdx.x >> 4;
  const int t0 = (blockIdx.x & 15) << 2;
  const int tid = threadIdx.x;
  const int w = tid >> 6;
  const int l = tid & 63;
  const int t = t0 + w;
  const int lr = l & 15, lg = l >> 4;

  __shared__ __hip_bfloat16 XbS[4][64 * 40];   // otb, then P (bf16); cols 25..31 zero
  __shared__ __hip_bfloat16 FTS[4][32 * 40];   // FT[m][n] = FA[n][m]
  __shared__ float scS[4][25 * 25];            // gram scores only
  __hip_bfloat16* Xb = XbS[w];
  __hip_bfloat16* FT = FTS[w];
  float* scf = scS[w];

  const float* xp = x + b * 102400 + t * 25;   // + c*1600 + n

  // phase 0: zero Xb + FT
  {
    uint32_t* z1 = (uint32_t*)Xb;
    for (int i = l; i < 1280; i += 64) z1[i] = 0u;
    uint32_t* z2 = (uint32_t*)FT;
    for (int i = l; i < 640; i += 64) z2[i] = 0u;
  }
  // phase 0b: HbTA x-part (lane = c)
  for (int n = 0; n < 25; ++n) {
    float v = xp[l * 1600 + n];
    HbTA[(size_t)(b * 1600 + t * 25 + n) * 128 + l] = __float2bfloat16(v);
  }

  // phase 1: gram frags + 8 MFMA -> scores
  typedef union { short8 v; ushort u[8]; } frag_u;
  frag_u yf[2][2];
  #pragma unroll
  for (int it = 0; it < 2; ++it) {
    const int n = it * 16 + lr;
    #pragma unroll
    for (int ks = 0; ks < 2; ++ks) {
      #pragma unroll
      for (int j = 0; j < 8; ++j) {
        int c = ks * 32 + lg * 8 + j;
        float v = (n < 25) ? xp[c * 1600 + n] : 0.f;
        __hip_bfloat16 h = __float2bfloat16(v);
        yf[it][ks].u[j] = *(ushort*)&h;
      }
    }
  }
  f32x4 accg[2][2];
  #pragma unroll
  for (int it = 0; it < 2; ++it)
    #pragma unroll
    for (int jt = 0; jt < 2; ++jt) {
      f32x4 a = (f32x4){0.f, 0.f, 0.f, 0.f};
      a = __builtin_amdgcn_mfma_f32_16x16x32_bf16(yf[it][0].v, yf[jt][0].v, a, 0, 0, 0);
      a = __builtin_amdgcn_mfma_f32_16x16x32_bf16(yf[it][1].v, yf[jt][1].v, a, 0, 0, 0);
      accg[it][jt] = a;
    }
  #pragma unroll
  for (int it = 0; it < 2; ++it)
    #pragma unroll
    for (int jt = 0; jt < 2; ++jt)
      #pragma unroll
      for (int r = 0; r < 4; ++r) {
        int i = it * 16 + lg * 4 + r;
        int j = jt * 16 + lr;
        if (i < 25 && j < 25) scf[i * 25 + j] = accg[it][jt][r];
      }

  // phase 2: softmax rows (lanes 0..24) -> FT[m*40+n] = FA[n][m]
  if (l < 25) {
    const int n = l;
    float f[25];
    float mx = -1e30f;
    #pragma unroll
    for (int m = 0; m < 25; ++m) { f[m] = scf[n * 25 + m] * 0.125f; mx = fmaxf(mx, f[m]); }
    float sum = 0.f;
    #pragma unroll
    for (int m = 0; m < 25; ++m) { f[m] = __expf(f[m] - mx); sum += f[m]; }
    float inv = 1.f / sum;
    #pragma unroll
    for (int m = 0; m < 25; ++m) {
      float v = f[m] * inv + A[n * 25 + m];
      FT[m * 40 + n] = __float2bfloat16(v);
    }
  }

  // phase 3: Q = out1^T. A = FT rows m, B = X rows c (global gather).
  short8 fa_[2];
  fa_[0] = *(const short8*)(&FT[lr * 40 + lg * 8]);
  fa_[1] = *(const short8*)(&FT[(16 + lr) * 40 + lg * 8]);
  frag_u xb2[4];
  #pragma unroll
  for (int jt = 0; jt < 4; ++jt) {
    const int c = jt * 16 + lr;
    #pragma unroll
    for (int jj = 0; jj < 8; ++jj) {
      int n = lg * 8 + jj;
      float v = (n < 25) ? xp[c * 1600 + n] : 0.f;
      __hip_bfloat16 h = __float2bfloat16(v);
      xb2[jt].u[jj] = *(ushort*)&h;
    }
  }
  f32x4 q_[2][4];
  #pragma unroll
  for (int it = 0; it < 2; ++it)
    #pragma unroll
    for (int jt = 0; jt < 4; ++jt) {
      f32x4 a = (f32x4){0.f, 0.f, 0.f, 0.f};
      q_[it][jt] = __builtin_amdgcn_mfma_f32_16x16x32_bf16(fa_[it], xb2[jt].v, a, 0, 0, 0);
    }
  #pragma unroll
  for (int it = 0; it < 2; ++it)
    #pragma unroll
    for (int jt = 0; jt < 4; ++jt)
      #pragma unroll
      for (int r = 0; r < 4; ++r) {
        int m = it * 16 + lg * 4 + r;
        int c = jt * 16 + lr;
        if (m < 25) {
          __hip_bfloat16 h = __float2bfloat16(q_[it][jt][r]);
          Xb[c * 40 + m] = h;
          HbTA[(size_t)(b * 1600 + t * 25 + m) * 128 + 64 + c] = h;
        }
      }

  // phase 4a: xcd1 f32 write
  for (int idx = l; idx < 1600; idx += 64) {
    int c = idx / 25, n = idx - c * 25;
    xcd1[b * 102400 + c * 1600 + t * 25 + n] = __bfloat162float(Xb[c * 40 + n]);
  }
  // phase 4b: uu2/uu3 from otb (lanes 0..24)
  if (l < 25) {
    float s2 = uvg[256], s3 = uvg[258];
    #pragma unroll 8
    for (int c = 0; c < 64; ++c) {
      float o = __bfloat162float(Xb[c * 40 + l]);
      s2 += uvg[c] * o;
      s3 += uvg[128 + c] * o;
    }
    ubuf2[b * 1600 + t * 25 + l] = s2;
    ubuf3[b * 1600 + t * 25 + l] = s3;
  }

  // phase 5: P = otb @ FA
  short8 ofr[4];
  #pragma unroll
  for (int it = 0; it < 4; ++it)
    ofr[it] = *(const short8*)(&Xb[(it * 16 + lr) * 40 + lg * 8]);
  f32x4 p_[4][2];
  #pragma unroll
  for (int it = 0; it < 4; ++it)
    #pragma unroll
    for (int jt = 0; jt < 2; ++jt) {
      f32x4 a = (f32x4){0.f, 0.f, 0.f, 0.f};
      p_[it][jt] = __builtin_amdgcn_mfma_f32_16x16x32_bf16(ofr[it], fa_[jt], a, 0, 0, 0);
    }
  #pragma unroll
  for (int it = 0; it < 4; ++it)
    #pragma unroll
    for (int jt = 0; jt < 2; ++jt)
      #pragma unroll
      for (int r = 0; r < 4; ++r) {
        int c = it * 16 + lg * 4 + r;
        int n = jt * 16 + lr;
        if (n < 25) Xb[c * 40 + n] = __float2bfloat16(p_[it][jt][r]);
      }

  // phase 6: Pp2 bf16 coalesced
  for (int idx = l; idx < 1600; idx += 64) {
    int c = idx / 25, n = idx - c * 25;
    Pp2[b * 102400 + t * 1600 + idx] = Xb[c * 40 + n];
  }
}

// ---- pool partials, block = (b, c-channel); Pp2 bf16 [b][t][1600]
__global__ void pool_partial(const __hip_bfloat16* __restrict__ Pp2,
                             const float* __restrict__ Wp1, const float* __restrict__ Wp2,
                             const float* __restrict__ ap1_, const float* __restrict__ ap2_,
                             float* __restrict__ partials) {
  const int b = blockIdx.x >> 6;
  const int c = blockIdx.x & 63;
  const int tid = threadIdx.x;
  const float a1 = ap1_[0], a2 = ap2_[0];
  __shared__ float pg1[1600];
  __shared__ float pg2[1600];
  __shared__ float wct[64][36];
  for (int idx = tid; idx < 1600; idx += 256) {
    int t = idx / 25, n = idx - t * 25;
    float v = __bfloat162float(Pp2[b * 102400 + t * 1600 + c * 25 + n]);
    pg1[idx] = v >= 0.f ? v : a1 * v;
    pg2[idx] = v >= 0.f ? v : a2 * v;
  }
  for (int idx = tid; idx < 19 * 64; idx += 256) {
    int kl = idx & 63, r = idx >> 6;
    wct[kl][r] = Wp1[r * 4096 + (c << 6) + kl];
  }
  for (int idx = tid; idx < 15 * 64; idx += 256) {
    int kl = idx & 63, r = idx >> 6;
    wct[kl][20 + r] = Wp2[r * 4096 + (c << 6) + kl];
  }
  __syncthreads();
  if (tid < 225) {
    const int j = tid / 9;
    const int g = tid - j * 9;
    const bool br1 = (g < 5);
    const int r0 = br1 ? g * 4 : 20 + (g - 5) * 4;
    const float* pgc = br1 ? pg1 : pg2;
    float acc0 = 0.f, acc1 = 0.f, acc2 = 0.f, acc3 = 0.f;
    #pragma unroll 4
    for (int kl = 0; kl < 64; ++kl) {
      int off = kl * 25 + j;
      float p = pgc[(off & 63) * 25 + (off >> 6)];
      const float4 wv = *(const float4*)&wct[kl][r0];
      acc0 += p * wv.x; acc1 += p * wv.y; acc2 += p * wv.z; acc3 += p * wv.w;
    }
    const int base = (b * 64 + c) * 850;
    if (br1) {
      const int m = base + j * 19 + r0;
      partials[m] = acc0; partials[m + 1] = acc1; partials[m + 2] = acc2;
      if (g != 4) partials[m + 3] = acc3;
    } else {
      const int m = base + 475 + j * 15 + (r0 - 20);
      partials[m] = acc0; partials[m + 1] = acc1; partials[m + 2] = acc2;
      if (g != 8) partials[m + 3] = acc3;
    }
  }
}

// ---- reduce partials over 64 channel-chunks + per-branch softmax
__global__ void pool_reduce(const float* __restrict__ partials,
                            float* __restrict__ F19, float* __restrict__ F15) {
  const int b = blockIdx.x;
  const int tid = threadIdx.x;
  __shared__ float lg[850];
  for (int m = tid; m < 850; m += 256) {
    float s = 0.f;
    for (int ch = 0; ch < 64; ++ch) s += partials[(b * 64 + ch) * 850 + m];
    lg[m] = s;
  }
  __syncthreads();
  if (tid < 25) {
    const float* row = lg + tid * 19;
    float mx = -1e30f;
    for (int r = 0; r < 19; ++r) mx = fmaxf(mx, row[r]);
    float sum = 0.f;
    for (int r = 0; r < 19; ++r) sum += __expf(row[r] - mx);
    float inv = 1.f / sum;
    for (int r = 0; r < 19; ++r)
      F19[(b * 25 + tid) * 19 + r] = __expf(row[r] - mx) * inv;
  } else if (tid >= 32 && tid < 57) {
    const int j = tid - 32;
    const float* row = lg + 475 + j * 15;
    float mx = -1e30f;
    for (int r = 0; r < 15; ++r) mx = fmaxf(mx, row[r]);
    float sum = 0.f;
    for (int r = 0; r < 15; ++r) sum += __expf(row[r] - mx);
    float inv = 1.f / sum;
    for (int r = 0; r < 15; ++r)
      F15[(b * 25 + j) * 15 + r] = __expf(row[r] - mx) * inv;
  }
}

// ---- x2[b,c,t,r] = sum_n xcd1[b,c,t,n] * F3[b,n,r]
template<int R>
__global__ void x2_einsum(const float* __restrict__ xcd1, const float* __restrict__ F3,
                          float* __restrict__ x2) {
  const int row = blockIdx.x * 256 + threadIdx.x;
  const int b = row >> 12;
  __shared__ float f3[25 * R];
  for (int idx = threadIdx.x; idx < 25 * R; idx += 256) f3[idx] = F3[b * 25 * R + idx];
  __syncthreads();
  float xr[25];
  #pragma unroll
  for (int n = 0; n < 25; ++n) xr[n] = xcd1[row * 25 + n];
  float acc[R];
  #pragma unroll
  for (int r = 0; r < R; ++r) acc[r] = 0.f;
  #pragma unroll
  for (int n = 0; n < 25; ++n) {
    float v = xr[n];
    #pragma unroll
    for (int r = 0; r < R; ++r) acc[r] += v * f3[n * R + r];
  }
  #pragma unroll
  for (int r = 0; r < R; ++r) x2[row * R + r] = acc[r];
}

// ---- fused ldnet+attention+Z via MFMA: one wave per (b,t), NO BARRIERS.
template<int M>
__global__ __launch_bounds__(256) void ldnet_restore_mfma(
    const float* __restrict__ x2, const float* __restrict__ A,
    const float* __restrict__ uub, const float* __restrict__ wv,
    const float* __restrict__ cuv, const float* __restrict__ Ck,
    __hip_bfloat16* __restrict__ ZH, int cioff) {
  const int b = blockIdx.x >> 4;
  const int t0 = (blockIdx.x & 15) << 2;
  const int tid = threadIdx.x;
  const int w = tid >> 6;
  const int l = tid & 63;
  const int t = t0 + w;
  const int lr = l & 15, lg = l >> 4;

  __shared__ __hip_bfloat16 XbS[4][64 * 40];   // x2-tile bf16 -> otb
  __shared__ float scS[4][64 * 26];            // scores f32 -> Zt bf16 staging
  __shared__ __hip_bfloat16 FTS[4][32 * 40];   // FT[m][n]=FA[n][m]
  __shared__ __hip_bfloat16 ATS[4][32 * 40];   // AT[n][m]=att[n][m]
  __shared__ float vvS[4][32];
  __hip_bfloat16* Xb = XbS[w];
  float* scf = scS[w];
  __hip_bfloat16* FT = FTS[w];
  __hip_bfloat16* AT = ATS[w];
  float* vv = vvS[w];

  const float* xp = x2 + (size_t)(b * 4096 + t) * M;   // + c*(64*M) + n

  // phase 0: zero FT/AT, stage Xb (cols n<M)
  {
    uint32_t* z1 = (uint32_t*)FT;
    uint32_t* z2 = (uint32_t*)AT;
    for (int i = l; i < 32 * 40 / 2; i += 64) { z1[i] = 0u; z2[i] = 0u; }
    for (int idx = l; idx < 64 * 32; idx += 64) {
      int c = idx >> 5, n = idx & 31;
      float v = (n < M) ? xp[c * (64 * M) + n] : 0.f;
      Xb[c * 40 + n] = __float2bfloat16(v);
    }
  }

  // phase 1: gram frags (gather) + 8 MFMA -> scores scf[i*26+j]
  typedef union { short8 v; ushort u[8]; } frag_u;
  frag_u yf[2][2];
  #pragma unroll
  for (int it = 0; it < 2; ++it) {
    const int n = it * 16 + lr;
    #pragma unroll
    for (int ks = 0; ks < 2; ++ks) {
      #pragma unroll
      for (int j = 0; j < 8; ++j) {
        int c = ks * 32 + lg * 8 + j;
        float v = (n < M) ? xp[c * (64 * M) + n] : 0.f;
        __hip_bfloat16 h = __float2bfloat16(v);
        yf[it][ks].u[j] = *(ushort*)&h;
      }
    }
  }
  f32x4 accg[2][2];
  #pragma unroll
  for (int it = 0; it < 2; ++it)
    #pragma unroll
    for (int jt = 0; jt < 2; ++jt) {
      f32x4 a = (f32x4){0.f, 0.f, 0.f, 0.f};
      a = __builtin_amdgcn_mfma_f32_16x16x32_bf16(yf[it][0].v, yf[jt][0].v, a, 0, 0, 0);
      a = __builtin_amdgcn_mfma_f32_16x16x32_bf16(yf[it][1].v, yf[jt][1].v, a, 0, 0, 0);
      accg[it][jt] = a;
    }
  #pragma unroll
  for (int it = 0; it < 2; ++it)
    #pragma unroll
    for (int jt = 0; jt < 2; ++jt)
      #pragma unroll
      for (int r = 0; r < 4; ++r) {
        int i = it * 16 + lg * 4 + r;
        int j = jt * 16 + lr;
        if (i < M && j < M) scf[i * 26 + j] = accg[it][jt][r];
      }

  // phase 2: softmax rows (lanes 0..M-1) -> FT[m*40+n]
  if (l < M) {
    const int n = l;
    float f[M];
    float mx = -1e30f;
    #pragma unroll
    for (int m = 0; m < M; ++m) { f[m] = scf[n * 26 + m] * 0.125f; mx = fmaxf(mx, f[m]); }
    float sum = 0.f;
    #pragma unroll
    for (int m = 0; m < M; ++m) { f[m] = __expf(f[m] - mx); sum += f[m]; }
    float inv = 1.f / sum;
    #pragma unroll
    for (int m = 0; m < M; ++m) {
      float v = f[m] * inv + A[n * M + m];
      FT[m * 40 + n] = __float2bfloat16(v);
    }
  }

  // phase 3: out1 = X2@FA (K=32), otb into Xb
  short8 xf[4], ff[2];
  #pragma unroll
  for (int it = 0; it < 4; ++it)
    xf[it] = *(const short8*)(&Xb[(it * 16 + lr) * 40 + lg * 8]);
  #pragma unroll
  for (int jt = 0; jt < 2; ++jt)
    ff[jt] = *(const short8*)(&FT[(jt * 16 + lr) * 40 + lg * 8]);
  f32x4 acco[4][2];
  #pragma unroll
  for (int it = 0; it < 4; ++it)
    #pragma unroll
    for (int jt = 0; jt < 2; ++jt) {
      f32x4 a = (f32x4){0.f, 0.f, 0.f, 0.f};
      acco[it][jt] = __builtin_amdgcn_mfma_f32_16x16x32_bf16(xf[it], ff[jt], a, 0, 0, 0);
    }
  #pragma unroll
  for (int it = 0; it < 4; ++it)
    #pragma unroll
    for (int jt = 0; jt < 2; ++jt)
      #pragma unroll
      for (int r = 0; r < 4; ++r) {
        int c = it * 16 + lg * 4 + r;
        int m = jt * 16 + lr;
        if (m < M) Xb[c * 40 + m] = __float2bfloat16(acco[it][jt][r]);
      }

  // phase 4: vv[m] = cv + sum_c wv[c]*otb[c][m]  (lanes 0..M-1)
  if (l < M) {
    float s = cuv[1];
    #pragma unroll 8
    for (int c = 0; c < 64; ++c)
      s += wv[c] * __bfloat162float(Xb[c * 40 + l]);
    vv[l] = s;
  }

  // phase 5: att (lanes 0..24) -> AT[n*40+m]
  if (l < 25) {
    const int n = l;
    const float uu = uub[b * 1600 + t * 25 + n];
    float f[M];
    float mx = -1e30f;
    #pragma unroll
    for (int m = 0; m < M; ++m) {
      float v = uu + vv[m];
      v = v >= 0.f ? v : 0.2f * v;
      f[m] = v;
      mx = fmaxf(mx, v);
    }
    float sum = 0.f;
    #pragma unroll
    for (int m = 0; m < M; ++m) { f[m] = __expf(f[m] - mx); sum += f[m]; }
    float inv = 1.f / sum;
    #pragma unroll
    for (int m = 0; m < M; ++m)
      AT[n * 40 + m] = __float2bfloat16(f[m] * inv + Ck[n * M + m]);
  }

  // phase 6: Z = otb @ AT^T (K=32): D[i=c][j=n] -> Zt (transposed staging)
  short8 of[4], af[2];
  #pragma unroll
  for (int it = 0; it < 4; ++it)
    of[it] = *(const short8*)(&Xb[(it * 16 + lr) * 40 + lg * 8]);
  #pragma unroll
  for (int jt = 0; jt < 2; ++jt)
    af[jt] = *(const short8*)(&AT[(jt * 16 + lr) * 40 + lg * 8]);
  f32x4 accz[4][2];
  #pragma unroll
  for (int it = 0; it < 4; ++it)
    #pragma unroll
    for (int jt = 0; jt < 2; ++jt) {
      f32x4 a = (f32x4){0.f, 0.f, 0.f, 0.f};
      accz[it][jt] = __builtin_amdgcn_mfma_f32_16x16x32_bf16(of[it], af[jt], a, 0, 0, 0);
    }
  __hip_bfloat16* Zt = (__hip_bfloat16*)scf;
  #pragma unroll
  for (int it = 0; it < 4; ++it)
    #pragma unroll
    for (int jt = 0; jt < 2; ++jt)
      #pragma unroll
      for (int r = 0; r < 4; ++r) {
        int c = it * 16 + lg * 4 + r;
        int n = jt * 16 + lr;
        if (n < 25) Zt[n * 66 + c] = __float2bfloat16(accz[it][jt][r]);
      }

  // phase 7: coalesced ZH write (lane = c, 128B per row)
  for (int n = 0; n < 25; ++n)
    ZH[(size_t)(b * 1600 + t * 25 + n) * 128 + cioff + l] = Zt[n * 66 + l];
}

// ---- restore GEMM via MFMA, wave-private 32-col slices, IN PLACE, no LDS/barriers.
// H[col][g] = relu(BN*(sum_c WgT[g][c]*Z[col][br*64+c] + bg[g]*s[br][col%25]))
// wave: M=32 cols (2 tiles), N=128 g (8 tiles, br = nt>>2), K=64 (2 frags).
__global__ __launch_bounds__(256) void restore_gemm_mfma(
    __hip_bfloat16* __restrict__ ZH, const __hip_bfloat16* __restrict__ WgT,
    const float* __restrict__ bg2, const float* __restrict__ bg3,
    const float* __restrict__ sconst) {
  const int tid = threadIdx.x;
  const int wv = tid >> 6, l = tid & 63;
  const int lr = l & 15, lg = l >> 4;
  const size_t col0 = ((size_t)blockIdx.x * 4 + wv) * 32;
  const ushort* Zg = (const ushort*)ZH;
  const ushort* Wu = (const ushort*)WgT;

  // A-frags: [mt][br][ks]; lane holds Z[col0+mt*16+lr][br*64+ks*32+lg*8 ..+8]
  short8 afr[2][2][2];
  #pragma unroll
  for (int mt = 0; mt < 2; ++mt)
    #pragma unroll
    for (int br = 0; br < 2; ++br)
      #pragma unroll
      for (int ks = 0; ks < 2; ++ks)
        afr[mt][br][ks] = *(const short8*)(
            Zg + (col0 + mt * 16 + lr) * 128 + br * 64 + ks * 32 + lg * 8);

  f32x4 acc[2][8];
  #pragma unroll
  for (int nt = 0; nt < 8; ++nt) {
    const int br = nt >> 2;
    const int g = nt * 16 + lr;
    short8 b0 = *(const short8*)(Wu + g * 64 + lg * 8);
    short8 b1 = *(const short8*)(Wu + g * 64 + 32 + lg * 8);
    #pragma unroll
    for (int mt = 0; mt < 2; ++mt) {
      f32x4 a = (f32x4){0.f, 0.f, 0.f, 0.f};
      a = __builtin_amdgcn_mfma_f32_16x16x32_bf16(afr[mt][br][0], b0, a, 0, 0, 0);
      a = __builtin_amdgcn_mfma_f32_16x16x32_bf16(afr[mt][br][1], b1, a, 0, 0, 0);
      acc[mt][nt] = a;
    }
  }

  // epilogue: bias*s[n] + BN + ReLU + bf16, in-place scatter (32B per 16-lane group)
  #pragma unroll
  for (int mt = 0; mt < 2; ++mt)
    #pragma unroll
    for (int r = 0; r < 4; ++r) {
      const size_t col = col0 + mt * 16 + lg * 4 + r;
      const int n = (int)(col % 25);
      const float s2v = sconst[n], s3v = sconst[25 + n];
      ushort* zp = (ushort*)ZH + col * 128;
      #pragma unroll
      for (int nt = 0; nt < 8; ++nt) {
        const int g = nt * 16 + lr;
        const float bo = (nt < 4) ? bg2[g] : bg3[g - 64];
        const float s = (nt < 4) ? s2v : s3v;
        float v = fmaxf((acc[mt][nt][r] + bo * s) * BN_SCALE_F, 0.f);
        __hip_bfloat16 h = __float2bfloat16(v);
        zp[g] = *(ushort*)&h;
      }
    }
}

// ---- conv weights -> bf16, layout Wb[kt][o][ci]
__global__ void transpose_w(const float* __restrict__ Wtcn, __hip_bfloat16* __restrict__ Wb) {
  int idx = blockIdx.x * 256 + threadIdx.x;
  if (idx < 49152) {
    int ci = idx & 255;
    int rest = idx >> 8;
    int o = rest & 63, kt = rest >> 6;
    Wb[idx] = __float2bfloat16(Wtcn[(o * 256 + ci) * 3 + kt]);
  }
}

// ---- final conv via MFMA (unchanged)
__global__ __launch_bounds__(256, 3) void conv_mfma(
    const __hip_bfloat16* __restrict__ HbTA, const __hip_bfloat16* __restrict__ HbTB,
    const __hip_bfloat16* __restrict__ Wb, const float* __restrict__ x,
    const float* __restrict__ btcn, const float* __restrict__ aout_,
    float* __restrict__ out) {
  const int b = blockIdx.x / 5;
  const int col0 = (blockIdx.x % 5) * 320;
  const int tid = threadIdx.x;
  const int w = tid >> 6, l = tid & 63;
  const int lr = l & 15, lg = l >> 4;

  __shared__ __hip_bfloat16 Hl[384 * 40];
  __shared__ __hip_bfloat16 Wl[3 * 64 * 40];

  f32x4 acc[5][4];
  #pragma unroll
  for (int mt = 0; mt < 5; ++mt)
    #pragma unroll
    for (int nt = 0; nt < 4; ++nt) acc[mt][nt] = (f32x4){0.f, 0.f, 0.f, 0.f};

  const int base_a = (w * 80 + lr + 7) * 40 + lg * 8;
  const int base_b = lr * 40 + lg * 8;

  for (int ch = 0; ch < 8; ++ch) {
    const __hip_bfloat16* Ht = (ch < 4) ? HbTA : HbTB;
    const int ci0 = (ch & 3) * 32;
    const int wci0 = ch * 32;
    __syncthreads();
    #pragma unroll
    for (int it = 0; it < 6; ++it) {
      int idx = it * 256 + tid;
      int colr = idx >> 2, seg = idx & 3;
      int gcol = col0 - 32 + colr;
      uint4 v = {0u, 0u, 0u, 0u};
      if (gcol >= 0 && gcol < 1600)
        v = *(const uint4*)(Ht + ((size_t)(b * 1600 + gcol) * 128 + ci0 + seg * 8));
      *(uint4*)(&Hl[colr * 40 + seg * 8]) = v;
    }
    #pragma unroll
    for (int it = 0; it < 3; ++it) {
      int idx = it * 256 + tid;
      int o = (idx >> 2) & 63, kt = idx >> 8, seg = idx & 3;
      uint4 v = *(const uint4*)(Wb + ((kt * 64 + o) * 256 + wci0 + seg * 8));
      *(uint4*)(&Wl[(kt * 64 + o) * 40 + seg * 8]) = v;
    }
    __syncthreads();
    #pragma unroll
    for (int kt = 0; kt < 3; ++kt) {
      short8 af[5], bf[4];
      const int ab = base_a + kt * 1000;
      const int bb = base_b + kt * 2560;
      #pragma unroll
      for (int mt = 0; mt < 5; ++mt) af[mt] = *(const short8*)(&Hl[ab + mt * 640]);
      #pragma unroll
      for (int nt = 0; nt < 4; ++nt) bf[nt] = *(const short8*)(&Wl[bb + nt * 640]);
      #pragma unroll
      for (int mt = 0; mt < 5; ++mt)
        #pragma unroll
        for (int nt = 0; nt < 4; ++nt)
          acc[mt][nt] = __builtin_amdgcn_mfma_f32_16x16x32_bf16(af[mt], bf[nt],
                                                                acc[mt][nt], 0, 0, 0);
    }
  }

  const float aout = aout_[0];
  const int colbase = col0 + w * 80 + lg * 4;
  #pragma unroll
  for (int nt = 0; nt < 4; ++nt) {
    const int o = nt * 16 + lr;
    const float bo = btcn[o];
    const float* xr = x + ((size_t)b * 64 + o) * 1600 + colbase;
    float* op = out + ((size_t)b * 64 + o) * 1600 + colbase;
    #pragma unroll
    for (int mt = 0; mt < 5; ++mt) {
      float4 xv = *(const float4*)(xr + mt * 16);
      f32x4 a4 = acc[mt][nt];
      float4 res;
      float v0 = (a4[0] + bo) * BN_SCALE_F + xv.x;
      float v1 = (a4[1] + bo) * BN_SCALE_F + xv.y;
      float v2 = (a4[2] + bo) * BN_SCALE_F + xv.z;
      float v3 = (a4[3] + bo) * BN_SCALE_F + xv.w;
      res.x = v0 >= 0.f ? v0 : aout * v0;
      res.y = v1 >= 0.f ? v1 : aout * v1;
      res.z = v2 >= 0.f ? v2 : aout * v2;
      res.w = v3 >= 0.f ? v3 : aout * v3;
      *(float4*)(op + mt * 16) = res;
    }
  }
}

extern "C" void kernel_launch(void* const* d_in, const int* in_sizes, int n_in,
                              void* d_out, int out_size, void* d_ws, size_t ws_size,
                              hipStream_t stream) {
  const float* x     = (const float*)d_in[0];
  const float* A1    = (const float*)d_in[1];
  const float* A2    = (const float*)d_in[2];
  const float* A3    = (const float*)d_in[3];
  const float* Wp1   = (const float*)d_in[4];
  const float* ap1   = (const float*)d_in[5];
  const float* Wp2   = (const float*)d_in[6];
  const float* ap2   = (const float*)d_in[7];
  const float* Wg2   = (const float*)d_in[8];
  const float* bg2   = (const float*)d_in[9];
  const float* Wt2   = (const float*)d_in[10];
  const float* bt2   = (const float*)d_in[11];
  const float* Wph2  = (const float*)d_in[12];
  const float* bph2  = (const float*)d_in[13];
  const float* wcat2 = (const float*)d_in[14];
  const float* Ck2   = (const float*)d_in[15];
  const float* Wg3   = (const float*)d_in[16];
  const float* bg3   = (const float*)d_in[17];
  const float* Wt3   = (const float*)d_in[18];
  const float* bt3   = (const float*)d_in[19];
  const float* Wph3  = (const float*)d_in[20];
  const float* bph3  = (const float*)d_in[21];
  const float* wcat3 = (const float*)d_in[22];
  const float* Ck3   = (const float*)d_in[23];
  const float* Wtcn  = (const float*)d_in[24];
  const float* btcn  = (const float*)d_in[25];
  const float* aout  = (const float*)d_in[26];
  float* out = (float*)d_out;
  float* ws  = (float*)d_ws;

  float* xcd1 = ws;
  __hip_bfloat16* ZH   = (__hip_bfloat16*)(ws + 6553600);   // also Pp2 bf16 (earlier life)
  __hip_bfloat16* HbTA = (__hip_bfloat16*)(ws + 13107200);
  float* x2b  = ws + 19660800;
  float* preb = ws + 24641536;
  float* F19  = ws + 29622272;
  float* F15  = ws + 29652672;
  float* uv   = ws + 29676672;
  float* partials = x2b;
  __hip_bfloat16* Wb   = (__hip_bfloat16*)preb;             // 49,152 bf16 = 24,576 f
  __hip_bfloat16* WgT  = (__hip_bfloat16*)(preb + 24576);   // 8,192 bf16 = 4,096 f
  float* sconst        = preb + 28672;                      // 50 f
  float* ubuf2         = preb + 32768;                      // 102,400 f
  float* ubuf3         = preb + 139264;                     // 102,400 f

  prep_uv<<<1, 64, 0, stream>>>(Wt2, bt2, Wph2, bph2, wcat2,
                                Wt3, bt3, Wph3, bph3, wcat3,
                                Ck2, Ck3, uv, sconst);
  prep_wgt<<<32, 256, 0, stream>>>(Wg2, Wg3, WgT);
  transpose_w<<<192, 256, 0, stream>>>(Wtcn, Wb);
  ldnet1_mfma<<<1024, 256, 0, stream>>>(x, A1, uv, xcd1, ZH /*Pp2 bf16*/, HbTA,
                                        ubuf2, ubuf3);

  // both pools in one pass over Pp2 bf16 (block per (b, channel))
  pool_partial<<<4096, 256, 0, stream>>>(ZH, Wp1, Wp2, ap1, ap2, partials);
  pool_reduce<<<64, 256, 0, stream>>>(partials, F19, F15);

  // branch 2 (R=19): MFMA ldnet+attention+Z -> ZH ch 0..63 (Pp2 now dead)
  x2_einsum<19><<<1024, 256, 0, stream>>>(xcd1, F19, x2b);
  ldnet_restore_mfma<19><<<1024, 256, 0, stream>>>(x2b, A2, ubuf2,
                                                   uv + 64, uv + 256, Ck2, ZH, 0);

  // branch 3 (R=15): Z3 -> ZH ch 64..127
  x2_einsum<15><<<1024, 256, 0, stream>>>(xcd1, F15, x2b);
  ldnet_restore_mfma<15><<<1024, 256, 0, stream>>>(x2b, A3, ubuf3,
                                                   uv + 192, uv + 258, Ck3, ZH, 64);

  // shared Wg GEMM via MFMA, in place: ZH rows become HbTB rows (xcd2|xcd3 bf16)
  restore_gemm_mfma<<<800, 256, 0, stream>>>(ZH, WgT, bg2, bg3, sconst);

  // final conv via MFMA + bias + BN + residual + PReLU
  conv_mfma<<<320, 256, 0, stream>>>(HbTA, ZH, Wb, x, btcn, aout, out);
}

// Round 13
// 184.313 us; speedup vs baseline: 7.5497x; 1.3531x over previous
//
#include <hip/hip_runtime.h>
#include <hip/hip_bf16.h>
#include <math.h>

// ---------------------------------------------------------------------------
// LDSTNet forward. B=64, C=64, T=64, N=25, Ci=32. Pools: R1=19, R2=15.
//
// Workspace layout (floats):
//   (free)  @ 0          : 6,553,600
//   R1      @ 6,553,600  : 6,553,600  Pp2 bf16 [b][t][1600] -> ZH/HbTB bf16 [col][128]
//   R2      @ 13,107,200 : 6,553,600  HbT_A bf16 [b][1600][128] (0..63=x, 64..127=out1)
//   x2buf   @ 19,660,800 : 4,980,736  partials (64x64x850)
//   preb    @ 24,641,536 : 4,980,736  Wb | WgT | sconst | ubuf2 | ubuf3
//   F19     @ 29,622,272 : 30,400
//   F15     @ 29,652,672 : 24,000
//   uvbuf   @ 29,676,672 : 320
// ---------------------------------------------------------------------------

#define BN_SCALE_F 0.9999950000374997f

typedef __attribute__((ext_vector_type(8))) short short8;
typedef __attribute__((ext_vector_type(4))) float f32x4;

// ---- precompute wu/wv/cu/cv for both branches + att row-sum constants
__global__ void prep_uv(const float* __restrict__ Wt2, const float* __restrict__ bt2,
                        const float* __restrict__ Wph2, const float* __restrict__ bph2,
                        const float* __restrict__ wcat2,
                        const float* __restrict__ Wt3, const float* __restrict__ bt3,
                        const float* __restrict__ Wph3, const float* __restrict__ bph3,
                        const float* __restrict__ wcat3,
                        const float* __restrict__ Ck2, const float* __restrict__ Ck3,
                        float* __restrict__ uv, float* __restrict__ sconst) {
  int c = threadIdx.x;
  if (c < 64) {
    float s1 = 0.f, s2 = 0.f, s3 = 0.f, s4 = 0.f;
    for (int i = 0; i < 32; ++i) {
      s1 += wcat2[i]      * Wt2[i * 64 + c];
      s2 += wcat2[32 + i] * Wph2[i * 64 + c];
      s3 += wcat3[i]      * Wt3[i * 64 + c];
      s4 += wcat3[32 + i] * Wph3[i * 64 + c];
    }
    uv[c] = s1; uv[64 + c] = s2; uv[128 + c] = s3; uv[192 + c] = s4;
  }
  if (c == 0) {
    float c1 = 0.f, c2 = 0.f, c3 = 0.f, c4 = 0.f;
    for (int i = 0; i < 32; ++i) {
      c1 += wcat2[i] * bt2[i];       c2 += wcat2[32 + i] * bph2[i];
      c3 += wcat3[i] * bt3[i];       c4 += wcat3[32 + i] * bph3[i];
    }
    uv[256] = c1; uv[257] = c2; uv[258] = c3; uv[259] = c4;
  }
  if (c < 25) {
    float s2 = 1.f, s3 = 1.f;
    for (int m = 0; m < 19; ++m) s2 += Ck2[c * 19 + m];
    for (int m = 0; m < 15; ++m) s3 += Ck3[c * 15 + m];
    sconst[c] = s2; sconst[25 + c] = s3;
  }
}

// ---- pack Wg2/Wg3 row-major bf16: WgT[g][c], g 0..63 = Wg2, 64..127 = Wg3
__global__ void prep_wgt(const float* __restrict__ Wg2, const float* __restrict__ Wg3,
                         __hip_bfloat16* __restrict__ WgT) {
  int idx = blockIdx.x * 256 + threadIdx.x;
  if (idx < 8192) {
    int g = idx >> 6, c = idx & 63;
    float v = (g < 64) ? Wg2[g * 64 + c] : Wg3[(g - 64) * 64 + c];
    WgT[idx] = __float2bfloat16(v);
  }
}

// ---- ldnet1 via MFMA: one wave per (b,t), 4 waves/block, NO BARRIERS.
__global__ __launch_bounds__(256, 4) void ldnet1_mfma(
    const float* __restrict__ x, const float* __restrict__ A,
    const float* __restrict__ uvg,
    __hip_bfloat16* __restrict__ Pp2,
    __hip_bfloat16* __restrict__ HbTA,
    float* __restrict__ ubuf2, float* __restrict__ ubuf3) {
  const int b = blockIdx.x >> 4;
  const int t0 = (blockIdx.x & 15) << 2;
  const int tid = threadIdx.x;
  const int w = tid >> 6;
  const int l = tid & 63;
  const int t = t0 + w;
  const int lr = l & 15, lg = l >> 4;

  __shared__ __hip_bfloat16 XbS[4][64 * 40];   // otb, then P (bf16); cols 25..31 zero
  __shared__ __hip_bfloat16 FTS[4][32 * 40];   // FT[m][n] = FA[n][m]
  __shared__ float scS[4][25 * 25];            // gram scores only
  __hip_bfloat16* Xb = XbS[w];
  __hip_bfloat16* FT = FTS[w];
  float* scf = scS[w];

  const float* xp = x + b * 102400 + t * 25;   // + c*1600 + n

  // phase 0: zero Xb + FT
  {
    uint32_t* z1 = (uint32_t*)Xb;
    for (int i = l; i < 1280; i += 64) z1[i] = 0u;
    uint32_t* z2 = (uint32_t*)FT;
    for (int i = l; i < 640; i += 64) z2[i] = 0u;
  }
  // phase 0b: HbTA x-part (lane = c)
  for (int n = 0; n < 25; ++n) {
    float v = xp[l * 1600 + n];
    HbTA[(size_t)(b * 1600 + t * 25 + n) * 128 + l] = __float2bfloat16(v);
  }

  // phase 1: gram frags + 8 MFMA -> scores
  typedef union { short8 v; ushort u[8]; } frag_u;
  frag_u yf[2][2];
  #pragma unroll
  for (int it = 0; it < 2; ++it) {
    const int n = it * 16 + lr;
    #pragma unroll
    for (int ks = 0; ks < 2; ++ks) {
      #pragma unroll
      for (int j = 0; j < 8; ++j) {
        int c = ks * 32 + lg * 8 + j;
        float v = (n < 25) ? xp[c * 1600 + n] : 0.f;
        __hip_bfloat16 h = __float2bfloat16(v);
        yf[it][ks].u[j] = *(ushort*)&h;
      }
    }
  }
  f32x4 accg[2][2];
  #pragma unroll
  for (int it = 0; it < 2; ++it)
    #pragma unroll
    for (int jt = 0; jt < 2; ++jt) {
      f32x4 a = (f32x4){0.f, 0.f, 0.f, 0.f};
      a = __builtin_amdgcn_mfma_f32_16x16x32_bf16(yf[it][0].v, yf[jt][0].v, a, 0, 0, 0);
      a = __builtin_amdgcn_mfma_f32_16x16x32_bf16(yf[it][1].v, yf[jt][1].v, a, 0, 0, 0);
      accg[it][jt] = a;
    }
  #pragma unroll
  for (int it = 0; it < 2; ++it)
    #pragma unroll
    for (int jt = 0; jt < 2; ++jt)
      #pragma unroll
      for (int r = 0; r < 4; ++r) {
        int i = it * 16 + lg * 4 + r;
        int j = jt * 16 + lr;
        if (i < 25 && j < 25) scf[i * 25 + j] = accg[it][jt][r];
      }

  // phase 2: softmax rows (lanes 0..24) -> FT[m*40+n] = FA[n][m]
  if (l < 25) {
    const int n = l;
    float f[25];
    float mx = -1e30f;
    #pragma unroll
    for (int m = 0; m < 25; ++m) { f[m] = scf[n * 25 + m] * 0.125f; mx = fmaxf(mx, f[m]); }
    float sum = 0.f;
    #pragma unroll
    for (int m = 0; m < 25; ++m) { f[m] = __expf(f[m] - mx); sum += f[m]; }
    float inv = 1.f / sum;
    #pragma unroll
    for (int m = 0; m < 25; ++m) {
      float v = f[m] * inv + A[n * 25 + m];
      FT[m * 40 + n] = __float2bfloat16(v);
    }
  }

  // phase 3: Q = out1^T. A = FT rows m, B = X rows c (global gather).
  short8 fa_[2];
  fa_[0] = *(const short8*)(&FT[lr * 40 + lg * 8]);
  fa_[1] = *(const short8*)(&FT[(16 + lr) * 40 + lg * 8]);
  frag_u xb2[4];
  #pragma unroll
  for (int jt = 0; jt < 4; ++jt) {
    const int c = jt * 16 + lr;
    #pragma unroll
    for (int jj = 0; jj < 8; ++jj) {
      int n = lg * 8 + jj;
      float v = (n < 25) ? xp[c * 1600 + n] : 0.f;
      __hip_bfloat16 h = __float2bfloat16(v);
      xb2[jt].u[jj] = *(ushort*)&h;
    }
  }
  f32x4 q_[2][4];
  #pragma unroll
  for (int it = 0; it < 2; ++it)
    #pragma unroll
    for (int jt = 0; jt < 4; ++jt) {
      f32x4 a = (f32x4){0.f, 0.f, 0.f, 0.f};
      q_[it][jt] = __builtin_amdgcn_mfma_f32_16x16x32_bf16(fa_[it], xb2[jt].v, a, 0, 0, 0);
    }
  #pragma unroll
  for (int it = 0; it < 2; ++it)
    #pragma unroll
    for (int jt = 0; jt < 4; ++jt)
      #pragma unroll
      for (int r = 0; r < 4; ++r) {
        int m = it * 16 + lg * 4 + r;
        int c = jt * 16 + lr;
        if (m < 25) {
          __hip_bfloat16 h = __float2bfloat16(q_[it][jt][r]);
          Xb[c * 40 + m] = h;
          HbTA[(size_t)(b * 1600 + t * 25 + m) * 128 + 64 + c] = h;
        }
      }

  // phase 4: uu2/uu3 from otb (lanes 0..24)
  if (l < 25) {
    float s2 = uvg[256], s3 = uvg[258];
    #pragma unroll 8
    for (int c = 0; c < 64; ++c) {
      float o = __bfloat162float(Xb[c * 40 + l]);
      s2 += uvg[c] * o;
      s3 += uvg[128 + c] * o;
    }
    ubuf2[b * 1600 + t * 25 + l] = s2;
    ubuf3[b * 1600 + t * 25 + l] = s3;
  }

  // phase 5: P = otb @ FA
  short8 ofr[4];
  #pragma unroll
  for (int it = 0; it < 4; ++it)
    ofr[it] = *(const short8*)(&Xb[(it * 16 + lr) * 40 + lg * 8]);
  f32x4 p_[4][2];
  #pragma unroll
  for (int it = 0; it < 4; ++it)
    #pragma unroll
    for (int jt = 0; jt < 2; ++jt) {
      f32x4 a = (f32x4){0.f, 0.f, 0.f, 0.f};
      p_[it][jt] = __builtin_amdgcn_mfma_f32_16x16x32_bf16(ofr[it], fa_[jt], a, 0, 0, 0);
    }
  #pragma unroll
  for (int it = 0; it < 4; ++it)
    #pragma unroll
    for (int jt = 0; jt < 2; ++jt)
      #pragma unroll
      for (int r = 0; r < 4; ++r) {
        int c = it * 16 + lg * 4 + r;
        int n = jt * 16 + lr;
        if (n < 25) Xb[c * 40 + n] = __float2bfloat16(p_[it][jt][r]);
      }

  // phase 6: Pp2 bf16 coalesced
  for (int idx = l; idx < 1600; idx += 64) {
    int c = idx / 25, n = idx - c * 25;
    Pp2[b * 102400 + t * 1600 + idx] = Xb[c * 40 + n];
  }
}

// ---- pool partials, block = (b, c-channel); Pp2 bf16 [b][t][1600]
__global__ void pool_partial(const __hip_bfloat16* __restrict__ Pp2,
                             const float* __restrict__ Wp1, const float* __restrict__ Wp2,
                             const float* __restrict__ ap1_, const float* __restrict__ ap2_,
                             float* __restrict__ partials) {
  const int b = blockIdx.x >> 6;
  const int c = blockIdx.x & 63;
  const int tid = threadIdx.x;
  const float a1 = ap1_[0], a2 = ap2_[0];
  __shared__ float pg1[1600];
  __shared__ float pg2[1600];
  __shared__ float wct[64][36];
  for (int idx = tid; idx < 1600; idx += 256) {
    int t = idx / 25, n = idx - t * 25;
    float v = __bfloat162float(Pp2[b * 102400 + t * 1600 + c * 25 + n]);
    pg1[idx] = v >= 0.f ? v : a1 * v;
    pg2[idx] = v >= 0.f ? v : a2 * v;
  }
  for (int idx = tid; idx < 19 * 64; idx += 256) {
    int kl = idx & 63, r = idx >> 6;
    wct[kl][r] = Wp1[r * 4096 + (c << 6) + kl];
  }
  for (int idx = tid; idx < 15 * 64; idx += 256) {
    int kl = idx & 63, r = idx >> 6;
    wct[kl][20 + r] = Wp2[r * 4096 + (c << 6) + kl];
  }
  __syncthreads();
  if (tid < 225) {
    const int j = tid / 9;
    const int g = tid - j * 9;
    const bool br1 = (g < 5);
    const int r0 = br1 ? g * 4 : 20 + (g - 5) * 4;
    const float* pgc = br1 ? pg1 : pg2;
    float acc0 = 0.f, acc1 = 0.f, acc2 = 0.f, acc3 = 0.f;
    #pragma unroll 4
    for (int kl = 0; kl < 64; ++kl) {
      int off = kl * 25 + j;
      float p = pgc[(off & 63) * 25 + (off >> 6)];
      const float4 wv = *(const float4*)&wct[kl][r0];
      acc0 += p * wv.x; acc1 += p * wv.y; acc2 += p * wv.z; acc3 += p * wv.w;
    }
    const int base = (b * 64 + c) * 850;
    if (br1) {
      const int m = base + j * 19 + r0;
      partials[m] = acc0; partials[m + 1] = acc1; partials[m + 2] = acc2;
      if (g != 4) partials[m + 3] = acc3;
    } else {
      const int m = base + 475 + j * 15 + (r0 - 20);
      partials[m] = acc0; partials[m + 1] = acc1; partials[m + 2] = acc2;
      if (g != 8) partials[m + 3] = acc3;
    }
  }
}

// ---- reduce partials over 64 channel-chunks + per-branch softmax
__global__ void pool_reduce(const float* __restrict__ partials,
                            float* __restrict__ F19, float* __restrict__ F15) {
  const int b = blockIdx.x;
  const int tid = threadIdx.x;
  __shared__ float lg[850];
  for (int m = tid; m < 850; m += 256) {
    float s = 0.f;
    for (int ch = 0; ch < 64; ++ch) s += partials[(b * 64 + ch) * 850 + m];
    lg[m] = s;
  }
  __syncthreads();
  if (tid < 25) {
    const float* row = lg + tid * 19;
    float mx = -1e30f;
    for (int r = 0; r < 19; ++r) mx = fmaxf(mx, row[r]);
    float sum = 0.f;
    for (int r = 0; r < 19; ++r) sum += __expf(row[r] - mx);
    float inv = 1.f / sum;
    for (int r = 0; r < 19; ++r)
      F19[(b * 25 + tid) * 19 + r] = __expf(row[r] - mx) * inv;
  } else if (tid >= 32 && tid < 57) {
    const int j = tid - 32;
    const float* row = lg + 475 + j * 15;
    float mx = -1e30f;
    for (int r = 0; r < 15; ++r) mx = fmaxf(mx, row[r]);
    float sum = 0.f;
    for (int r = 0; r < 15; ++r) sum += __expf(row[r] - mx);
    float inv = 1.f / sum;
    for (int r = 0; r < 15; ++r)
      F15[(b * 25 + j) * 15 + r] = __expf(row[r] - mx) * inv;
  }
}

// ---- fused x2 + ldnet + attention + Z via MFMA: one wave per (b,t), NO BARRIERS.
// Conservative buffering: FB (F3), FT (FA^T), AT (att^T) are SEPARATE zeroed
// buffers, each written once. out1 A-frags gathered from global HbTA (gated).
// Xb lifecycle: X2 -> ot -> Zt overlay (single-purpose at each phase).
template<int M>
__global__ __launch_bounds__(256) void ldnet_restore_mfma(
    const __hip_bfloat16* __restrict__ HbTA, const float* __restrict__ F3g,
    const float* __restrict__ A,
    const float* __restrict__ uub, const float* __restrict__ wv,
    const float* __restrict__ cuv, const float* __restrict__ Ck,
    __hip_bfloat16* __restrict__ ZH, int cioff) {
  const int b = blockIdx.x >> 4;
  const int t0 = (blockIdx.x & 15) << 2;
  const int tid = threadIdx.x;
  const int w = tid >> 6;
  const int l = tid & 63;
  const int t = t0 + w;
  const int lr = l & 15, lg = l >> 4;

  __shared__ __hip_bfloat16 XbS[4][64 * 40];   // X2 -> ot -> Zt overlay
  __shared__ __hip_bfloat16 FBS[4][32 * 40];   // FB[r][n] = F3[n][r]
  __shared__ __hip_bfloat16 FTS[4][32 * 40];   // FT[m][n] = FA[n][m]
  __shared__ __hip_bfloat16 ATS[4][32 * 40];   // AT[n][m] = att[n][m]
  __shared__ float scS[4][512];                // gram scores (stride 26)
  __shared__ float vvS[4][32];
  __hip_bfloat16* Xb = XbS[w];
  __hip_bfloat16* FB = FBS[w];
  __hip_bfloat16* FT = FTS[w];
  __hip_bfloat16* AT = ATS[w];
  float* scf = scS[w];
  float* vv = vvS[w];

  typedef union { short8 v; ushort u[8]; } frag_u;
  const ushort* Hu = (const ushort*)HbTA;

  // phase 0: zero everything
  {
    uint32_t* z0 = (uint32_t*)Xb;
    for (int i = l; i < 1280; i += 64) z0[i] = 0u;
    uint32_t* z1 = (uint32_t*)FB;
    uint32_t* z2 = (uint32_t*)FT;
    uint32_t* z3 = (uint32_t*)AT;
    for (int i = l; i < 640; i += 64) { z1[i] = 0u; z2[i] = 0u; z3[i] = 0u; }
  }
  // phase 0a: FB[r*40+n] = bf16(F3[b][n][r])
  for (int idx = l; idx < M * 25; idx += 64) {
    int r = idx / 25, n = idx - r * 25;
    FB[r * 40 + n] = __float2bfloat16(F3g[(b * 25 + n) * M + r]);
  }

  // phase 1: X2 = out1 @ F3. A-frags from global HbTA (gated), B from FB.
  frag_u af0[4];
  #pragma unroll
  for (int it = 0; it < 4; ++it) {
    const int c = it * 16 + lr;
    #pragma unroll
    for (int jj = 0; jj < 8; ++jj) {
      int n = lg * 8 + jj;
      af0[it].u[jj] = (n < 25)
          ? Hu[(size_t)(b * 1600 + t * 25 + n) * 128 + 64 + c] : (ushort)0;
    }
  }
  short8 bf0[2];
  bf0[0] = *(const short8*)(&FB[lr * 40 + lg * 8]);
  bf0[1] = *(const short8*)(&FB[(16 + lr) * 40 + lg * 8]);
  f32x4 x2a[4][2];
  #pragma unroll
  for (int it = 0; it < 4; ++it)
    #pragma unroll
    for (int jt = 0; jt < 2; ++jt) {
      f32x4 a = (f32x4){0.f, 0.f, 0.f, 0.f};
      x2a[it][jt] = __builtin_amdgcn_mfma_f32_16x16x32_bf16(af0[it].v, bf0[jt], a, 0, 0, 0);
    }
  #pragma unroll
  for (int it = 0; it < 4; ++it)
    #pragma unroll
    for (int jt = 0; jt < 2; ++jt)
      #pragma unroll
      for (int rr = 0; rr < 4; ++rr) {
        int c = it * 16 + lg * 4 + rr;
        int r = jt * 16 + lr;
        float v = (r < M) ? x2a[it][jt][rr] : 0.f;
        Xb[c * 40 + r] = __float2bfloat16(v);
      }

  // phase 2: gram(X2) frags from LDS + 8 MFMA -> scores scf[i*26+j]
  frag_u yf[2][2];
  #pragma unroll
  for (int it = 0; it < 2; ++it) {
    const int n = it * 16 + lr;
    #pragma unroll
    for (int ks = 0; ks < 2; ++ks)
      #pragma unroll
      for (int j = 0; j < 8; ++j)
        yf[it][ks].u[j] = *(const ushort*)&Xb[(ks * 32 + lg * 8 + j) * 40 + n];
  }
  f32x4 accg[2][2];
  #pragma unroll
  for (int it = 0; it < 2; ++it)
    #pragma unroll
    for (int jt = 0; jt < 2; ++jt) {
      f32x4 a = (f32x4){0.f, 0.f, 0.f, 0.f};
      a = __builtin_amdgcn_mfma_f32_16x16x32_bf16(yf[it][0].v, yf[jt][0].v, a, 0, 0, 0);
      a = __builtin_amdgcn_mfma_f32_16x16x32_bf16(yf[it][1].v, yf[jt][1].v, a, 0, 0, 0);
      accg[it][jt] = a;
    }
  #pragma unroll
  for (int it = 0; it < 2; ++it)
    #pragma unroll
    for (int jt = 0; jt < 2; ++jt)
      #pragma unroll
      for (int r = 0; r < 4; ++r) {
        int i = it * 16 + lg * 4 + r;
        int j = jt * 16 + lr;
        if (i < M && j < M) scf[i * 26 + j] = accg[it][jt][r];
      }

  // phase 3: softmax rows (lanes 0..M-1) -> FT[m*40+n]
  if (l < M) {
    const int n = l;
    float f[M];
    float mx = -1e30f;
    #pragma unroll
    for (int m = 0; m < M; ++m) { f[m] = scf[n * 26 + m] * 0.125f; mx = fmaxf(mx, f[m]); }
    float sum = 0.f;
    #pragma unroll
    for (int m = 0; m < M; ++m) { f[m] = __expf(f[m] - mx); sum += f[m]; }
    float inv = 1.f / sum;
    #pragma unroll
    for (int m = 0; m < M; ++m) {
      float v = f[m] * inv + A[n * M + m];
      FT[m * 40 + n] = __float2bfloat16(v);
    }
  }

  // phase 4: ot = X2 @ FA (K=32), scatter into Xb (cols >= M -> 0)
  short8 xf[4], ff[2];
  #pragma unroll
  for (int it = 0; it < 4; ++it)
    xf[it] = *(const short8*)(&Xb[(it * 16 + lr) * 40 + lg * 8]);
  #pragma unroll
  for (int jt = 0; jt < 2; ++jt)
    ff[jt] = *(const short8*)(&FT[(jt * 16 + lr) * 40 + lg * 8]);
  f32x4 acco[4][2];
  #pragma unroll
  for (int it = 0; it < 4; ++it)
    #pragma unroll
    for (int jt = 0; jt < 2; ++jt) {
      f32x4 a = (f32x4){0.f, 0.f, 0.f, 0.f};
      acco[it][jt] = __builtin_amdgcn_mfma_f32_16x16x32_bf16(xf[it], ff[jt], a, 0, 0, 0);
    }
  #pragma unroll
  for (int it = 0; it < 4; ++it)
    #pragma unroll
    for (int jt = 0; jt < 2; ++jt)
      #pragma unroll
      for (int r = 0; r < 4; ++r) {
        int c = it * 16 + lg * 4 + r;
        int m = jt * 16 + lr;
        float v = (m < M) ? acco[it][jt][r] : 0.f;
        Xb[c * 40 + m] = __float2bfloat16(v);
      }

  // phase 5: vv[m] = cv + sum_c wv[c]*ot[c][m]  (lanes 0..M-1)
  if (l < M) {
    float s = cuv[1];
    #pragma unroll 8
    for (int c = 0; c < 64; ++c)
      s += wv[c] * __bfloat162float(Xb[c * 40 + l]);
    vv[l] = s;
  }

  // phase 6: att (lanes 0..24) -> AT[n*40+m]
  if (l < 25) {
    const int n = l;
    const float uu = uub[b * 1600 + t * 25 + n];
    float f[M];
    float mx = -1e30f;
    #pragma unroll
    for (int m = 0; m < M; ++m) {
      float v = uu + vv[m];
      v = v >= 0.f ? v : 0.2f * v;
      f[m] = v;
      mx = fmaxf(mx, v);
    }
    float sum = 0.f;
    #pragma unroll
    for (int m = 0; m < M; ++m) { f[m] = __expf(f[m] - mx); sum += f[m]; }
    float inv = 1.f / sum;
    #pragma unroll
    for (int m = 0; m < M; ++m)
      AT[n * 40 + m] = __float2bfloat16(f[m] * inv + Ck[n * M + m]);
  }

  // phase 7: Z = ot @ att^T (K=32): D[i=c][j=n] -> Zt (staged in dead Xb)
  short8 of[4], af[2];
  #pragma unroll
  for (int it = 0; it < 4; ++it)
    of[it] = *(const short8*)(&Xb[(it * 16 + lr) * 40 + lg * 8]);
  #pragma unroll
  for (int jt = 0; jt < 2; ++jt)
    af[jt] = *(const short8*)(&AT[(jt * 16 + lr) * 40 + lg * 8]);
  f32x4 accz[4][2];
  #pragma unroll
  for (int it = 0; it < 4; ++it)
    #pragma unroll
    for (int jt = 0; jt < 2; ++jt) {
      f32x4 a = (f32x4){0.f, 0.f, 0.f, 0.f};
      accz[it][jt] = __builtin_amdgcn_mfma_f32_16x16x32_bf16(of[it], af[jt], a, 0, 0, 0);
    }
  __hip_bfloat16* Zt = Xb;   // Xb dead after `of` reads (accz depends on of)
  #pragma unroll
  for (int it = 0; it < 4; ++it)
    #pragma unroll
    for (int jt = 0; jt < 2; ++jt)
      #pragma unroll
      for (int r = 0; r < 4; ++r) {
        int c = it * 16 + lg * 4 + r;
        int n = jt * 16 + lr;
        if (n < 25) Zt[n * 66 + c] = __float2bfloat16(accz[it][jt][r]);
      }

  // phase 8: coalesced ZH write (lane = c, 128B per row)
  for (int n = 0; n < 25; ++n)
    ZH[(size_t)(b * 1600 + t * 25 + n) * 128 + cioff + l] = Zt[n * 66 + l];
}

// ---- restore GEMM via MFMA, wave-private 32-col slices, IN PLACE, no LDS/barriers.
__global__ __launch_bounds__(256) void restore_gemm_mfma(
    __hip_bfloat16* __restrict__ ZH, const __hip_bfloat16* __restrict__ WgT,
    const float* __restrict__ bg2, const float* __restrict__ bg3,
    const float* __restrict__ sconst) {
  const int tid = threadIdx.x;
  const int wv = tid >> 6, l = tid & 63;
  const int lr = l & 15, lg = l >> 4;
  const size_t col0 = ((size_t)blockIdx.x * 4 + wv) * 32;
  const ushort* Zg = (const ushort*)ZH;
  const ushort* Wu = (const ushort*)WgT;

  short8 afr[2][2][2];
  #pragma unroll
  for (int mt = 0; mt < 2; ++mt)
    #pragma unroll
    for (int br = 0; br < 2; ++br)
      #pragma unroll
      for (int ks = 0; ks < 2; ++ks)
        afr[mt][br][ks] = *(const short8*)(
            Zg + (col0 + mt * 16 + lr) * 128 + br * 64 + ks * 32 + lg * 8);

  f32x4 acc[2][8];
  #pragma unroll
  for (int nt = 0; nt < 8; ++nt) {
    const int br = nt >> 2;
    const int g = nt * 16 + lr;
    short8 b0 = *(const short8*)(Wu + g * 64 + lg * 8);
    short8 b1 = *(const short8*)(Wu + g * 64 + 32 + lg * 8);
    #pragma unroll
    for (int mt = 0; mt < 2; ++mt) {
      f32x4 a = (f32x4){0.f, 0.f, 0.f, 0.f};
      a = __builtin_amdgcn_mfma_f32_16x16x32_bf16(afr[mt][br][0], b0, a, 0, 0, 0);
      a = __builtin_amdgcn_mfma_f32_16x16x32_bf16(afr[mt][br][1], b1, a, 0, 0, 0);
      acc[mt][nt] = a;
    }
  }

  #pragma unroll
  for (int mt = 0; mt < 2; ++mt)
    #pragma unroll
    for (int r = 0; r < 4; ++r) {
      const size_t col = col0 + mt * 16 + lg * 4 + r;
      const int n = (int)(col % 25);
      const float s2v = sconst[n], s3v = sconst[25 + n];
      ushort* zp = (ushort*)ZH + col * 128;
      #pragma unroll
      for (int nt = 0; nt < 8; ++nt) {
        const int g = nt * 16 + lr;
        const float bo = (nt < 4) ? bg2[g] : bg3[g - 64];
        const float s = (nt < 4) ? s2v : s3v;
        float v = fmaxf((acc[mt][nt][r] + bo * s) * BN_SCALE_F, 0.f);
        __hip_bfloat16 h = __float2bfloat16(v);
        zp[g] = *(ushort*)&h;
      }
    }
}

// ---- conv weights -> bf16, layout Wb[kt][o][ci]
__global__ void transpose_w(const float* __restrict__ Wtcn, __hip_bfloat16* __restrict__ Wb) {
  int idx = blockIdx.x * 256 + threadIdx.x;
  if (idx < 49152) {
    int ci = idx & 255;
    int rest = idx >> 8;
    int o = rest & 63, kt = rest >> 6;
    Wb[idx] = __float2bfloat16(Wtcn[(o * 256 + ci) * 3 + kt]);
  }
}

// ---- final conv via MFMA (unchanged)
__global__ __launch_bounds__(256, 3) void conv_mfma(
    const __hip_bfloat16* __restrict__ HbTA, const __hip_bfloat16* __restrict__ HbTB,
    const __hip_bfloat16* __restrict__ Wb, const float* __restrict__ x,
    const float* __restrict__ btcn, const float* __restrict__ aout_,
    float* __restrict__ out) {
  const int b = blockIdx.x / 5;
  const int col0 = (blockIdx.x % 5) * 320;
  const int tid = threadIdx.x;
  const int w = tid >> 6, l = tid & 63;
  const int lr = l & 15, lg = l >> 4;

  __shared__ __hip_bfloat16 Hl[384 * 40];
  __shared__ __hip_bfloat16 Wl[3 * 64 * 40];

  f32x4 acc[5][4];
  #pragma unroll
  for (int mt = 0; mt < 5; ++mt)
    #pragma unroll
    for (int nt = 0; nt < 4; ++nt) acc[mt][nt] = (f32x4){0.f, 0.f, 0.f, 0.f};

  const int base_a = (w * 80 + lr + 7) * 40 + lg * 8;
  const int base_b = lr * 40 + lg * 8;

  for (int ch = 0; ch < 8; ++ch) {
    const __hip_bfloat16* Ht = (ch < 4) ? HbTA : HbTB;
    const int ci0 = (ch & 3) * 32;
    const int wci0 = ch * 32;
    __syncthreads();
    #pragma unroll
    for (int it = 0; it < 6; ++it) {
      int idx = it * 256 + tid;
      int colr = idx >> 2, seg = idx & 3;
      int gcol = col0 - 32 + colr;
      uint4 v = {0u, 0u, 0u, 0u};
      if (gcol >= 0 && gcol < 1600)
        v = *(const uint4*)(Ht + ((size_t)(b * 1600 + gcol) * 128 + ci0 + seg * 8));
      *(uint4*)(&Hl[colr * 40 + seg * 8]) = v;
    }
    #pragma unroll
    for (int it = 0; it < 3; ++it) {
      int idx = it * 256 + tid;
      int o = (idx >> 2) & 63, kt = idx >> 8, seg = idx & 3;
      uint4 v = *(const uint4*)(Wb + ((kt * 64 + o) * 256 + wci0 + seg * 8));
      *(uint4*)(&Wl[(kt * 64 + o) * 40 + seg * 8]) = v;
    }
    __syncthreads();
    #pragma unroll
    for (int kt = 0; kt < 3; ++kt) {
      short8 af[5], bf[4];
      const int ab = base_a + kt * 1000;
      const int bb = base_b + kt * 2560;
      #pragma unroll
      for (int mt = 0; mt < 5; ++mt) af[mt] = *(const short8*)(&Hl[ab + mt * 640]);
      #pragma unroll
      for (int nt = 0; nt < 4; ++nt) bf[nt] = *(const short8*)(&Wl[bb + nt * 640]);
      #pragma unroll
      for (int mt = 0; mt < 5; ++mt)
        #pragma unroll
        for (int nt = 0; nt < 4; ++nt)
          acc[mt][nt] = __builtin_amdgcn_mfma_f32_16x16x32_bf16(af[mt], bf[nt],
                                                                acc[mt][nt], 0, 0, 0);
    }
  }

  const float aout = aout_[0];
  const int colbase = col0 + w * 80 + lg * 4;
  #pragma unroll
  for (int nt = 0; nt < 4; ++nt) {
    const int o = nt * 16 + lr;
    const float bo = btcn[o];
    const float* xr = x + ((size_t)b * 64 + o) * 1600 + colbase;
    float* op = out + ((size_t)b * 64 + o) * 1600 + colbase;
    #pragma unroll
    for (int mt = 0; mt < 5; ++mt) {
      float4 xv = *(const float4*)(xr + mt * 16);
      f32x4 a4 = acc[mt][nt];
      float4 res;
      float v0 = (a4[0] + bo) * BN_SCALE_F + xv.x;
      float v1 = (a4[1] + bo) * BN_SCALE_F + xv.y;
      float v2 = (a4[2] + bo) * BN_SCALE_F + xv.z;
      float v3 = (a4[3] + bo) * BN_SCALE_F + xv.w;
      res.x = v0 >= 0.f ? v0 : aout * v0;
      res.y = v1 >= 0.f ? v1 : aout * v1;
      res.z = v2 >= 0.f ? v2 : aout * v2;
      res.w = v3 >= 0.f ? v3 : aout * v3;
      *(float4*)(op + mt * 16) = res;
    }
  }
}

extern "C" void kernel_launch(void* const* d_in, const int* in_sizes, int n_in,
                              void* d_out, int out_size, void* d_ws, size_t ws_size,
                              hipStream_t stream) {
  const float* x     = (const float*)d_in[0];
  const float* A1    = (const float*)d_in[1];
  const float* A2    = (const float*)d_in[2];
  const float* A3    = (const float*)d_in[3];
  const float* Wp1   = (const float*)d_in[4];
  const float* ap1   = (const float*)d_in[5];
  const float* Wp2   = (const float*)d_in[6];
  const float* ap2   = (const float*)d_in[7];
  const float* Wg2   = (const float*)d_in[8];
  const float* bg2   = (const float*)d_in[9];
  const float* Wt2   = (const float*)d_in[10];
  const float* bt2   = (const float*)d_in[11];
  const float* Wph2  = (const float*)d_in[12];
  const float* bph2  = (const float*)d_in[13];
  const float* wcat2 = (const float*)d_in[14];
  const float* Ck2   = (const float*)d_in[15];
  const float* Wg3   = (const float*)d_in[16];
  const float* bg3   = (const float*)d_in[17];
  const float* Wt3   = (const float*)d_in[18];
  const float* bt3   = (const float*)d_in[19];
  const float* Wph3  = (const float*)d_in[20];
  const float* bph3  = (const float*)d_in[21];
  const float* wcat3 = (const float*)d_in[22];
  const float* Ck3   = (const float*)d_in[23];
  const float* Wtcn  = (const float*)d_in[24];
  const float* btcn  = (const float*)d_in[25];
  const float* aout  = (const float*)d_in[26];
  float* out = (float*)d_out;
  float* ws  = (float*)d_ws;

  __hip_bfloat16* ZH   = (__hip_bfloat16*)(ws + 6553600);   // Pp2 bf16 earlier life
  __hip_bfloat16* HbTA = (__hip_bfloat16*)(ws + 13107200);
  float* x2b  = ws + 19660800;
  float* preb = ws + 24641536;
  float* F19  = ws + 29622272;
  float* F15  = ws + 29652672;
  float* uv   = ws + 29676672;
  float* partials = x2b;
  __hip_bfloat16* Wb   = (__hip_bfloat16*)preb;             // 49,152 bf16
  __hip_bfloat16* WgT  = (__hip_bfloat16*)(preb + 24576);   // 8,192 bf16
  float* sconst        = preb + 28672;                      // 50 f
  float* ubuf2         = preb + 32768;                      // 102,400 f
  float* ubuf3         = preb + 139264;                     // 102,400 f

  prep_uv<<<1, 64, 0, stream>>>(Wt2, bt2, Wph2, bph2, wcat2,
                                Wt3, bt3, Wph3, bph3, wcat3,
                                Ck2, Ck3, uv, sconst);
  prep_wgt<<<32, 256, 0, stream>>>(Wg2, Wg3, WgT);
  transpose_w<<<192, 256, 0, stream>>>(Wtcn, Wb);
  ldnet1_mfma<<<1024, 256, 0, stream>>>(x, A1, uv, ZH /*Pp2*/, HbTA, ubuf2, ubuf3);

  // both pools in one pass over Pp2 bf16 (block per (b, channel))
  pool_partial<<<4096, 256, 0, stream>>>(ZH, Wp1, Wp2, ap1, ap2, partials);
  pool_reduce<<<64, 256, 0, stream>>>(partials, F19, F15);

  // branch 2 (R=19): fused x2+ldnet+attention+Z -> ZH ch 0..63 (Pp2 dead after pools)
  ldnet_restore_mfma<19><<<1024, 256, 0, stream>>>(HbTA, F19, A2, ubuf2,
                                                   uv + 64, uv + 256, Ck2, ZH, 0);

  // branch 3 (R=15): Z3 -> ZH ch 64..127
  ldnet_restore_mfma<15><<<1024, 256, 0, stream>>>(HbTA, F15, A3, ubuf3,
                                                   uv + 192, uv + 258, Ck3, ZH, 64);

  // shared Wg GEMM via MFMA, in place: ZH rows become HbTB rows (xcd2|xcd3 bf16)
  restore_gemm_mfma<<<800, 256, 0, stream>>>(ZH, WgT, bg2, bg3, sconst);

  // final conv via MFMA + bias + BN + residual + PReLU
  conv_mfma<<<320, 256, 0, stream>>>(HbTA, ZH, Wb, x, btcn, aout, out);
}

// Round 14
// 167.248 us; speedup vs baseline: 8.3200x; 1.1020x over previous
//
#include <hip/hip_runtime.h>
#include <hip/hip_bf16.h>
#include <math.h>

// ---------------------------------------------------------------------------
// LDSTNet forward. B=64, C=64, T=64, N=25, Ci=32. Pools: R1=19, R2=15.
//
// Workspace layout (floats):
//   (free)  @ 0          : 6,553,600
//   R1      @ 6,553,600  : 6,553,600  Pp2 bf16 [b][t][1600] -> ZH/HbTB bf16 [col][128]
//   R2      @ 13,107,200 : 6,553,600  HbT_A bf16 [b][1600][128] (0..63=x, 64..127=out1)
//   x2buf   @ 19,660,800 : 4,980,736  partials (64x64x850)
//   preb    @ 24,641,536 : 4,980,736  Wb | WgT | sconst | ubuf2 | ubuf3
//   F19     @ 29,622,272 : 30,400
//   F15     @ 29,652,672 : 24,000
//   uvbuf   @ 29,676,672 : 320
// ---------------------------------------------------------------------------

#define BN_SCALE_F 0.9999950000374997f

typedef __attribute__((ext_vector_type(8))) short short8;
typedef __attribute__((ext_vector_type(4))) float f32x4;

// ---- precompute wu/wv/cu/cv for both branches + att row-sum constants
__global__ void prep_uv(const float* __restrict__ Wt2, const float* __restrict__ bt2,
                        const float* __restrict__ Wph2, const float* __restrict__ bph2,
                        const float* __restrict__ wcat2,
                        const float* __restrict__ Wt3, const float* __restrict__ bt3,
                        const float* __restrict__ Wph3, const float* __restrict__ bph3,
                        const float* __restrict__ wcat3,
                        const float* __restrict__ Ck2, const float* __restrict__ Ck3,
                        float* __restrict__ uv, float* __restrict__ sconst) {
  int c = threadIdx.x;
  if (c < 64) {
    float s1 = 0.f, s2 = 0.f, s3 = 0.f, s4 = 0.f;
    for (int i = 0; i < 32; ++i) {
      s1 += wcat2[i]      * Wt2[i * 64 + c];
      s2 += wcat2[32 + i] * Wph2[i * 64 + c];
      s3 += wcat3[i]      * Wt3[i * 64 + c];
      s4 += wcat3[32 + i] * Wph3[i * 64 + c];
    }
    uv[c] = s1; uv[64 + c] = s2; uv[128 + c] = s3; uv[192 + c] = s4;
  }
  if (c == 0) {
    float c1 = 0.f, c2 = 0.f, c3 = 0.f, c4 = 0.f;
    for (int i = 0; i < 32; ++i) {
      c1 += wcat2[i] * bt2[i];       c2 += wcat2[32 + i] * bph2[i];
      c3 += wcat3[i] * bt3[i];       c4 += wcat3[32 + i] * bph3[i];
    }
    uv[256] = c1; uv[257] = c2; uv[258] = c3; uv[259] = c4;
  }
  if (c < 25) {
    float s2 = 1.f, s3 = 1.f;
    for (int m = 0; m < 19; ++m) s2 += Ck2[c * 19 + m];
    for (int m = 0; m < 15; ++m) s3 += Ck3[c * 15 + m];
    sconst[c] = s2; sconst[25 + c] = s3;
  }
}

// ---- pack Wg2/Wg3 row-major bf16: WgT[g][c], g 0..63 = Wg2, 64..127 = Wg3
__global__ void prep_wgt(const float* __restrict__ Wg2, const float* __restrict__ Wg3,
                         __hip_bfloat16* __restrict__ WgT) {
  int idx = blockIdx.x * 256 + threadIdx.x;
  if (idx < 8192) {
    int g = idx >> 6, c = idx & 63;
    float v = (g < 64) ? Wg2[g * 64 + c] : Wg3[(g - 64) * 64 + c];
    WgT[idx] = __float2bfloat16(v);
  }
}

// ---- ldnet1 via MFMA: one wave per (b,t), 4 waves/block, NO BARRIERS.
// x-tile staged ONCE to LDS (bf16, zero-padded), serving all three consumers.
// Xb lifecycle: x-tile -> otb -> P (single-overwrite, in-order DS).
__global__ __launch_bounds__(256, 4) void ldnet1_mfma(
    const float* __restrict__ x, const float* __restrict__ A,
    const float* __restrict__ uvg,
    __hip_bfloat16* __restrict__ Pp2,
    __hip_bfloat16* __restrict__ HbTA,
    float* __restrict__ ubuf2, float* __restrict__ ubuf3) {
  const int b = blockIdx.x >> 4;
  const int t0 = (blockIdx.x & 15) << 2;
  const int tid = threadIdx.x;
  const int w = tid >> 6;
  const int l = tid & 63;
  const int t = t0 + w;
  const int lr = l & 15, lg = l >> 4;

  __shared__ __hip_bfloat16 XbS[4][64 * 40];   // x-tile -> otb -> P; cols 25..39 zero
  __shared__ __hip_bfloat16 FTS[4][32 * 40];   // FT[m][n] = FA[n][m]
  __shared__ float scS[4][25 * 25];            // gram scores only
  __hip_bfloat16* Xb = XbS[w];
  __hip_bfloat16* FT = FTS[w];
  float* scf = scS[w];

  const float* xp = x + b * 102400 + t * 25;   // + c*1600 + n
  typedef union { short8 v; ushort u[8]; } frag_u;

  // phase 0: zero Xb + FT, then stage x-tile bf16 into Xb (cols 25..39 stay 0)
  {
    uint32_t* z1 = (uint32_t*)Xb;
    for (int i = l; i < 1280; i += 64) z1[i] = 0u;
    uint32_t* z2 = (uint32_t*)FT;
    for (int i = l; i < 640; i += 64) z2[i] = 0u;
  }
  for (int idx = l; idx < 1600; idx += 64) {
    int c = idx / 25, n = idx - c * 25;
    Xb[c * 40 + n] = __float2bfloat16(xp[c * 1600 + n]);
  }

  // phase 0b: HbTA x-part from LDS (lane = c; coalesced 128B global stores)
  for (int n = 0; n < 25; ++n)
    HbTA[(size_t)(b * 1600 + t * 25 + n) * 128 + l] = Xb[l * 40 + n];

  // phase 1: gram frags from LDS + 8 MFMA -> scores (pad cols are zero: no gates)
  frag_u yf[2][2];
  #pragma unroll
  for (int it = 0; it < 2; ++it) {
    const int n = it * 16 + lr;
    #pragma unroll
    for (int ks = 0; ks < 2; ++ks)
      #pragma unroll
      for (int j = 0; j < 8; ++j)
        yf[it][ks].u[j] = *(const ushort*)&Xb[(ks * 32 + lg * 8 + j) * 40 + n];
  }
  f32x4 accg[2][2];
  #pragma unroll
  for (int it = 0; it < 2; ++it)
    #pragma unroll
    for (int jt = 0; jt < 2; ++jt) {
      f32x4 a = (f32x4){0.f, 0.f, 0.f, 0.f};
      a = __builtin_amdgcn_mfma_f32_16x16x32_bf16(yf[it][0].v, yf[jt][0].v, a, 0, 0, 0);
      a = __builtin_amdgcn_mfma_f32_16x16x32_bf16(yf[it][1].v, yf[jt][1].v, a, 0, 0, 0);
      accg[it][jt] = a;
    }
  #pragma unroll
  for (int it = 0; it < 2; ++it)
    #pragma unroll
    for (int jt = 0; jt < 2; ++jt)
      #pragma unroll
      for (int r = 0; r < 4; ++r) {
        int i = it * 16 + lg * 4 + r;
        int j = jt * 16 + lr;
        if (i < 25 && j < 25) scf[i * 25 + j] = accg[it][jt][r];
      }

  // phase 2: softmax rows (lanes 0..24) -> FT[m*40+n] = FA[n][m]
  if (l < 25) {
    const int n = l;
    float f[25];
    float mx = -1e30f;
    #pragma unroll
    for (int m = 0; m < 25; ++m) { f[m] = scf[n * 25 + m] * 0.125f; mx = fmaxf(mx, f[m]); }
    float sum = 0.f;
    #pragma unroll
    for (int m = 0; m < 25; ++m) { f[m] = __expf(f[m] - mx); sum += f[m]; }
    float inv = 1.f / sum;
    #pragma unroll
    for (int m = 0; m < 25; ++m) {
      float v = f[m] * inv + A[n * 25 + m];
      FT[m * 40 + n] = __float2bfloat16(v);
    }
  }

  // phase 3: Q = out1^T. A = FT rows m, B = X rows c (short8 from LDS).
  short8 fa_[2];
  fa_[0] = *(const short8*)(&FT[lr * 40 + lg * 8]);
  fa_[1] = *(const short8*)(&FT[(16 + lr) * 40 + lg * 8]);
  short8 xb2v[4];
  #pragma unroll
  for (int jt = 0; jt < 4; ++jt)
    xb2v[jt] = *(const short8*)(&Xb[(jt * 16 + lr) * 40 + lg * 8]);
  f32x4 q_[2][4];
  #pragma unroll
  for (int it = 0; it < 2; ++it)
    #pragma unroll
    for (int jt = 0; jt < 4; ++jt) {
      f32x4 a = (f32x4){0.f, 0.f, 0.f, 0.f};
      q_[it][jt] = __builtin_amdgcn_mfma_f32_16x16x32_bf16(fa_[it], xb2v[jt], a, 0, 0, 0);
    }
  // scatter otb (Xb rows c, cols m) + HbTA out1-part straight from registers
  #pragma unroll
  for (int it = 0; it < 2; ++it)
    #pragma unroll
    for (int jt = 0; jt < 4; ++jt)
      #pragma unroll
      for (int r = 0; r < 4; ++r) {
        int m = it * 16 + lg * 4 + r;
        int c = jt * 16 + lr;
        if (m < 25) {
          __hip_bfloat16 h = __float2bfloat16(q_[it][jt][r]);
          Xb[c * 40 + m] = h;
          HbTA[(size_t)(b * 1600 + t * 25 + m) * 128 + 64 + c] = h;
        }
      }

  // phase 4: uu2/uu3 from otb (lanes 0..24)
  if (l < 25) {
    float s2 = uvg[256], s3 = uvg[258];
    #pragma unroll 8
    for (int c = 0; c < 64; ++c) {
      float o = __bfloat162float(Xb[c * 40 + l]);
      s2 += uvg[c] * o;
      s3 += uvg[128 + c] * o;
    }
    ubuf2[b * 1600 + t * 25 + l] = s2;
    ubuf3[b * 1600 + t * 25 + l] = s3;
  }

  // phase 5: P = otb @ FA
  short8 ofr[4];
  #pragma unroll
  for (int it = 0; it < 4; ++it)
    ofr[it] = *(const short8*)(&Xb[(it * 16 + lr) * 40 + lg * 8]);
  f32x4 p_[4][2];
  #pragma unroll
  for (int it = 0; it < 4; ++it)
    #pragma unroll
    for (int jt = 0; jt < 2; ++jt) {
      f32x4 a = (f32x4){0.f, 0.f, 0.f, 0.f};
      p_[it][jt] = __builtin_amdgcn_mfma_f32_16x16x32_bf16(ofr[it], fa_[jt], a, 0, 0, 0);
    }
  #pragma unroll
  for (int it = 0; it < 4; ++it)
    #pragma unroll
    for (int jt = 0; jt < 2; ++jt)
      #pragma unroll
      for (int r = 0; r < 4; ++r) {
        int c = it * 16 + lg * 4 + r;
        int n = jt * 16 + lr;
        if (n < 25) Xb[c * 40 + n] = __float2bfloat16(p_[it][jt][r]);
      }

  // phase 6: Pp2 bf16 coalesced
  for (int idx = l; idx < 1600; idx += 64) {
    int c = idx / 25, n = idx - c * 25;
    Pp2[b * 102400 + t * 1600 + idx] = Xb[c * 40 + n];
  }
}

// ---- pool partials, block = (b, c-channel); Pp2 bf16 [b][t][1600]
__global__ void pool_partial(const __hip_bfloat16* __restrict__ Pp2,
                             const float* __restrict__ Wp1, const float* __restrict__ Wp2,
                             const float* __restrict__ ap1_, const float* __restrict__ ap2_,
                             float* __restrict__ partials) {
  const int b = blockIdx.x >> 6;
  const int c = blockIdx.x & 63;
  const int tid = threadIdx.x;
  const float a1 = ap1_[0], a2 = ap2_[0];
  __shared__ float pg1[1600];
  __shared__ float pg2[1600];
  __shared__ float wct[64][36];
  for (int idx = tid; idx < 1600; idx += 256) {
    int t = idx / 25, n = idx - t * 25;
    float v = __bfloat162float(Pp2[b * 102400 + t * 1600 + c * 25 + n]);
    pg1[idx] = v >= 0.f ? v : a1 * v;
    pg2[idx] = v >= 0.f ? v : a2 * v;
  }
  for (int idx = tid; idx < 19 * 64; idx += 256) {
    int kl = idx & 63, r = idx >> 6;
    wct[kl][r] = Wp1[r * 4096 + (c << 6) + kl];
  }
  for (int idx = tid; idx < 15 * 64; idx += 256) {
    int kl = idx & 63, r = idx >> 6;
    wct[kl][20 + r] = Wp2[r * 4096 + (c << 6) + kl];
  }
  __syncthreads();
  if (tid < 225) {
    const int j = tid / 9;
    const int g = tid - j * 9;
    const bool br1 = (g < 5);
    const int r0 = br1 ? g * 4 : 20 + (g - 5) * 4;
    const float* pgc = br1 ? pg1 : pg2;
    float acc0 = 0.f, acc1 = 0.f, acc2 = 0.f, acc3 = 0.f;
    #pragma unroll 4
    for (int kl = 0; kl < 64; ++kl) {
      int off = kl * 25 + j;
      float p = pgc[(off & 63) * 25 + (off >> 6)];
      const float4 wv = *(const float4*)&wct[kl][r0];
      acc0 += p * wv.x; acc1 += p * wv.y; acc2 += p * wv.z; acc3 += p * wv.w;
    }
    const int base = (b * 64 + c) * 850;
    if (br1) {
      const int m = base + j * 19 + r0;
      partials[m] = acc0; partials[m + 1] = acc1; partials[m + 2] = acc2;
      if (g != 4) partials[m + 3] = acc3;
    } else {
      const int m = base + 475 + j * 15 + (r0 - 20);
      partials[m] = acc0; partials[m + 1] = acc1; partials[m + 2] = acc2;
      if (g != 8) partials[m + 3] = acc3;
    }
  }
}

// ---- reduce partials over 64 channel-chunks + per-branch softmax
__global__ void pool_reduce(const float* __restrict__ partials,
                            float* __restrict__ F19, float* __restrict__ F15) {
  const int b = blockIdx.x;
  const int tid = threadIdx.x;
  __shared__ float lg[850];
  for (int m = tid; m < 850; m += 256) {
    float s = 0.f;
    for (int ch = 0; ch < 64; ++ch) s += partials[(b * 64 + ch) * 850 + m];
    lg[m] = s;
  }
  __syncthreads();
  if (tid < 25) {
    const float* row = lg + tid * 19;
    float mx = -1e30f;
    for (int r = 0; r < 19; ++r) mx = fmaxf(mx, row[r]);
    float sum = 0.f;
    for (int r = 0; r < 19; ++r) sum += __expf(row[r] - mx);
    float inv = 1.f / sum;
    for (int r = 0; r < 19; ++r)
      F19[(b * 25 + tid) * 19 + r] = __expf(row[r] - mx) * inv;
  } else if (tid >= 32 && tid < 57) {
    const int j = tid - 32;
    const float* row = lg + 475 + j * 15;
    float mx = -1e30f;
    for (int r = 0; r < 15; ++r) mx = fmaxf(mx, row[r]);
    float sum = 0.f;
    for (int r = 0; r < 15; ++r) sum += __expf(row[r] - mx);
    float inv = 1.f / sum;
    for (int r = 0; r < 15; ++r)
      F15[(b * 25 + j) * 15 + r] = __expf(row[r] - mx) * inv;
  }
}

// ---- fused x2 + ldnet + attention + Z via MFMA: one wave per (b,t), NO BARRIERS.
template<int M>
__global__ __launch_bounds__(256) void ldnet_restore_mfma(
    const __hip_bfloat16* __restrict__ HbTA, const float* __restrict__ F3g,
    const float* __restrict__ A,
    const float* __restrict__ uub, const float* __restrict__ wv,
    const float* __restrict__ cuv, const float* __restrict__ Ck,
    __hip_bfloat16* __restrict__ ZH, int cioff) {
  const int b = blockIdx.x >> 4;
  const int t0 = (blockIdx.x & 15) << 2;
  const int tid = threadIdx.x;
  const int w = tid >> 6;
  const int l = tid & 63;
  const int t = t0 + w;
  const int lr = l & 15, lg = l >> 4;

  __shared__ __hip_bfloat16 XbS[4][64 * 40];   // X2 -> ot -> Zt overlay
  __shared__ __hip_bfloat16 FBS[4][32 * 40];   // FB[r][n] = F3[n][r]
  __shared__ __hip_bfloat16 FTS[4][32 * 40];   // FT[m][n] = FA[n][m]
  __shared__ __hip_bfloat16 ATS[4][32 * 40];   // AT[n][m] = att[n][m]
  __shared__ float scS[4][512];                // gram scores (stride 26)
  __shared__ float vvS[4][32];
  __hip_bfloat16* Xb = XbS[w];
  __hip_bfloat16* FB = FBS[w];
  __hip_bfloat16* FT = FTS[w];
  __hip_bfloat16* AT = ATS[w];
  float* scf = scS[w];
  float* vv = vvS[w];

  typedef union { short8 v; ushort u[8]; } frag_u;
  const ushort* Hu = (const ushort*)HbTA;

  // phase 0: zero everything
  {
    uint32_t* z0 = (uint32_t*)Xb;
    for (int i = l; i < 1280; i += 64) z0[i] = 0u;
    uint32_t* z1 = (uint32_t*)FB;
    uint32_t* z2 = (uint32_t*)FT;
    uint32_t* z3 = (uint32_t*)AT;
    for (int i = l; i < 640; i += 64) { z1[i] = 0u; z2[i] = 0u; z3[i] = 0u; }
  }
  // phase 0a: FB[r*40+n] = bf16(F3[b][n][r])
  for (int idx = l; idx < M * 25; idx += 64) {
    int r = idx / 25, n = idx - r * 25;
    FB[r * 40 + n] = __float2bfloat16(F3g[(b * 25 + n) * M + r]);
  }

  // phase 1: X2 = out1 @ F3. A-frags from global HbTA (gated), B from FB.
  frag_u af0[4];
  #pragma unroll
  for (int it = 0; it < 4; ++it) {
    const int c = it * 16 + lr;
    #pragma unroll
    for (int jj = 0; jj < 8; ++jj) {
      int n = lg * 8 + jj;
      af0[it].u[jj] = (n < 25)
          ? Hu[(size_t)(b * 1600 + t * 25 + n) * 128 + 64 + c] : (ushort)0;
    }
  }
  short8 bf0[2];
  bf0[0] = *(const short8*)(&FB[lr * 40 + lg * 8]);
  bf0[1] = *(const short8*)(&FB[(16 + lr) * 40 + lg * 8]);
  f32x4 x2a[4][2];
  #pragma unroll
  for (int it = 0; it < 4; ++it)
    #pragma unroll
    for (int jt = 0; jt < 2; ++jt) {
      f32x4 a = (f32x4){0.f, 0.f, 0.f, 0.f};
      x2a[it][jt] = __builtin_amdgcn_mfma_f32_16x16x32_bf16(af0[it].v, bf0[jt], a, 0, 0, 0);
    }
  #pragma unroll
  for (int it = 0; it < 4; ++it)
    #pragma unroll
    for (int jt = 0; jt < 2; ++jt)
      #pragma unroll
      for (int rr = 0; rr < 4; ++rr) {
        int c = it * 16 + lg * 4 + rr;
        int r = jt * 16 + lr;
        float v = (r < M) ? x2a[it][jt][rr] : 0.f;
        Xb[c * 40 + r] = __float2bfloat16(v);
      }

  // phase 2: gram(X2) frags from LDS + 8 MFMA -> scores scf[i*26+j]
  frag_u yf[2][2];
  #pragma unroll
  for (int it = 0; it < 2; ++it) {
    const int n = it * 16 + lr;
    #pragma unroll
    for (int ks = 0; ks < 2; ++ks)
      #pragma unroll
      for (int j = 0; j < 8; ++j)
        yf[it][ks].u[j] = *(const ushort*)&Xb[(ks * 32 + lg * 8 + j) * 40 + n];
  }
  f32x4 accg[2][2];
  #pragma unroll
  for (int it = 0; it < 2; ++it)
    #pragma unroll
    for (int jt = 0; jt < 2; ++jt) {
      f32x4 a = (f32x4){0.f, 0.f, 0.f, 0.f};
      a = __builtin_amdgcn_mfma_f32_16x16x32_bf16(yf[it][0].v, yf[jt][0].v, a, 0, 0, 0);
      a = __builtin_amdgcn_mfma_f32_16x16x32_bf16(yf[it][1].v, yf[jt][1].v, a, 0, 0, 0);
      accg[it][jt] = a;
    }
  #pragma unroll
  for (int it = 0; it < 2; ++it)
    #pragma unroll
    for (int jt = 0; jt < 2; ++jt)
      #pragma unroll
      for (int r = 0; r < 4; ++r) {
        int i = it * 16 + lg * 4 + r;
        int j = jt * 16 + lr;
        if (i < M && j < M) scf[i * 26 + j] = accg[it][jt][r];
      }

  // phase 3: softmax rows (lanes 0..M-1) -> FT[m*40+n]
  if (l < M) {
    const int n = l;
    float f[M];
    float mx = -1e30f;
    #pragma unroll
    for (int m = 0; m < M; ++m) { f[m] = scf[n * 26 + m] * 0.125f; mx = fmaxf(mx, f[m]); }
    float sum = 0.f;
    #pragma unroll
    for (int m = 0; m < M; ++m) { f[m] = __expf(f[m] - mx); sum += f[m]; }
    float inv = 1.f / sum;
    #pragma unroll
    for (int m = 0; m < M; ++m) {
      float v = f[m] * inv + A[n * M + m];
      FT[m * 40 + n] = __float2bfloat16(v);
    }
  }

  // phase 4: ot = X2 @ FA (K=32), scatter into Xb (cols >= M -> 0)
  short8 xf[4], ff[2];
  #pragma unroll
  for (int it = 0; it < 4; ++it)
    xf[it] = *(const short8*)(&Xb[(it * 16 + lr) * 40 + lg * 8]);
  #pragma unroll
  for (int jt = 0; jt < 2; ++jt)
    ff[jt] = *(const short8*)(&FT[(jt * 16 + lr) * 40 + lg * 8]);
  f32x4 acco[4][2];
  #pragma unroll
  for (int it = 0; it < 4; ++it)
    #pragma unroll
    for (int jt = 0; jt < 2; ++jt) {
      f32x4 a = (f32x4){0.f, 0.f, 0.f, 0.f};
      acco[it][jt] = __builtin_amdgcn_mfma_f32_16x16x32_bf16(xf[it], ff[jt], a, 0, 0, 0);
    }
  #pragma unroll
  for (int it = 0; it < 4; ++it)
    #pragma unroll
    for (int jt = 0; jt < 2; ++jt)
      #pragma unroll
      for (int r = 0; r < 4; ++r) {
        int c = it * 16 + lg * 4 + r;
        int m = jt * 16 + lr;
        float v = (m < M) ? acco[it][jt][r] : 0.f;
        Xb[c * 40 + m] = __float2bfloat16(v);
      }

  // phase 5: vv[m] = cv + sum_c wv[c]*ot[c][m]  (lanes 0..M-1)
  if (l < M) {
    float s = cuv[1];
    #pragma unroll 8
    for (int c = 0; c < 64; ++c)
      s += wv[c] * __bfloat162float(Xb[c * 40 + l]);
    vv[l] = s;
  }

  // phase 6: att (lanes 0..24) -> AT[n*40+m]
  if (l < 25) {
    const int n = l;
    const float uu = uub[b * 1600 + t * 25 + n];
    float f[M];
    float mx = -1e30f;
    #pragma unroll
    for (int m = 0; m < M; ++m) {
      float v = uu + vv[m];
      v = v >= 0.f ? v : 0.2f * v;
      f[m] = v;
      mx = fmaxf(mx, v);
    }
    float sum = 0.f;
    #pragma unroll
    for (int m = 0; m < M; ++m) { f[m] = __expf(f[m] - mx); sum += f[m]; }
    float inv = 1.f / sum;
    #pragma unroll
    for (int m = 0; m < M; ++m)
      AT[n * 40 + m] = __float2bfloat16(f[m] * inv + Ck[n * M + m]);
  }

  // phase 7: Z = ot @ att^T (K=32): D[i=c][j=n] -> Zt (staged in dead Xb)
  short8 of[4], af[2];
  #pragma unroll
  for (int it = 0; it < 4; ++it)
    of[it] = *(const short8*)(&Xb[(it * 16 + lr) * 40 + lg * 8]);
  #pragma unroll
  for (int jt = 0; jt < 2; ++jt)
    af[jt] = *(const short8*)(&AT[(jt * 16 + lr) * 40 + lg * 8]);
  f32x4 accz[4][2];
  #pragma unroll
  for (int it = 0; it < 4; ++it)
    #pragma unroll
    for (int jt = 0; jt < 2; ++jt) {
      f32x4 a = (f32x4){0.f, 0.f, 0.f, 0.f};
      accz[it][jt] = __builtin_amdgcn_mfma_f32_16x16x32_bf16(of[it], af[jt], a, 0, 0, 0);
    }
  __hip_bfloat16* Zt = Xb;   // Xb dead after `of` reads (accz depends on of)
  #pragma unroll
  for (int it = 0; it < 4; ++it)
    #pragma unroll
    for (int jt = 0; jt < 2; ++jt)
      #pragma unroll
      for (int r = 0; r < 4; ++r) {
        int c = it * 16 + lg * 4 + r;
        int n = jt * 16 + lr;
        if (n < 25) Zt[n * 66 + c] = __float2bfloat16(accz[it][jt][r]);
      }

  // phase 8: coalesced ZH write (lane = c, 128B per row)
  for (int n = 0; n < 25; ++n)
    ZH[(size_t)(b * 1600 + t * 25 + n) * 128 + cioff + l] = Zt[n * 66 + l];
}

// ---- restore GEMM via MFMA, wave-private 32-col slices, IN PLACE, no LDS/barriers.
__global__ __launch_bounds__(256) void restore_gemm_mfma(
    __hip_bfloat16* __restrict__ ZH, const __hip_bfloat16* __restrict__ WgT,
    const float* __restrict__ bg2, const float* __restrict__ bg3,
    const float* __restrict__ sconst) {
  const int tid = threadIdx.x;
  const int wv = tid >> 6, l = tid & 63;
  const int lr = l & 15, lg = l >> 4;
  const size_t col0 = ((size_t)blockIdx.x * 4 + wv) * 32;
  const ushort* Zg = (const ushort*)ZH;
  const ushort* Wu = (const ushort*)WgT;

  short8 afr[2][2][2];
  #pragma unroll
  for (int mt = 0; mt < 2; ++mt)
    #pragma unroll
    for (int br = 0; br < 2; ++br)
      #pragma unroll
      for (int ks = 0; ks < 2; ++ks)
        afr[mt][br][ks] = *(const short8*)(
            Zg + (col0 + mt * 16 + lr) * 128 + br * 64 + ks * 32 + lg * 8);

  f32x4 acc[2][8];
  #pragma unroll
  for (int nt = 0; nt < 8; ++nt) {
    const int br = nt >> 2;
    const int g = nt * 16 + lr;
    short8 b0 = *(const short8*)(Wu + g * 64 + lg * 8);
    short8 b1 = *(const short8*)(Wu + g * 64 + 32 + lg * 8);
    #pragma unroll
    for (int mt = 0; mt < 2; ++mt) {
      f32x4 a = (f32x4){0.f, 0.f, 0.f, 0.f};
      a = __builtin_amdgcn_mfma_f32_16x16x32_bf16(afr[mt][br][0], b0, a, 0, 0, 0);
      a = __builtin_amdgcn_mfma_f32_16x16x32_bf16(afr[mt][br][1], b1, a, 0, 0, 0);
      acc[mt][nt] = a;
    }
  }

  #pragma unroll
  for (int mt = 0; mt < 2; ++mt)
    #pragma unroll
    for (int r = 0; r < 4; ++r) {
      const size_t col = col0 + mt * 16 + lg * 4 + r;
      const int n = (int)(col % 25);
      const float s2v = sconst[n], s3v = sconst[25 + n];
      ushort* zp = (ushort*)ZH + col * 128;
      #pragma unroll
      for (int nt = 0; nt < 8; ++nt) {
        const int g = nt * 16 + lr;
        const float bo = (nt < 4) ? bg2[g] : bg3[g - 64];
        const float s = (nt < 4) ? s2v : s3v;
        float v = fmaxf((acc[mt][nt][r] + bo * s) * BN_SCALE_F, 0.f);
        __hip_bfloat16 h = __float2bfloat16(v);
        zp[g] = *(ushort*)&h;
      }
    }
}

// ---- conv weights -> bf16, layout Wb[kt][o][ci]
__global__ void transpose_w(const float* __restrict__ Wtcn, __hip_bfloat16* __restrict__ Wb) {
  int idx = blockIdx.x * 256 + threadIdx.x;
  if (idx < 49152) {
    int ci = idx & 255;
    int rest = idx >> 8;
    int o = rest & 63, kt = rest >> 6;
    Wb[idx] = __float2bfloat16(Wtcn[(o * 256 + ci) * 3 + kt]);
  }
}

// ---- final conv via MFMA (unchanged)
__global__ __launch_bounds__(256, 3) void conv_mfma(
    const __hip_bfloat16* __restrict__ HbTA, const __hip_bfloat16* __restrict__ HbTB,
    const __hip_bfloat16* __restrict__ Wb, const float* __restrict__ x,
    const float* __restrict__ btcn, const float* __restrict__ aout_,
    float* __restrict__ out) {
  const int b = blockIdx.x / 5;
  const int col0 = (blockIdx.x % 5) * 320;
  const int tid = threadIdx.x;
  const int w = tid >> 6, l = tid & 63;
  const int lr = l & 15, lg = l >> 4;

  __shared__ __hip_bfloat16 Hl[384 * 40];
  __shared__ __hip_bfloat16 Wl[3 * 64 * 40];

  f32x4 acc[5][4];
  #pragma unroll
  for (int mt = 0; mt < 5; ++mt)
    #pragma unroll
    for (int nt = 0; nt < 4; ++nt) acc[mt][nt] = (f32x4){0.f, 0.f, 0.f, 0.f};

  const int base_a = (w * 80 + lr + 7) * 40 + lg * 8;
  const int base_b = lr * 40 + lg * 8;

  for (int ch = 0; ch < 8; ++ch) {
    const __hip_bfloat16* Ht = (ch < 4) ? HbTA : HbTB;
    const int ci0 = (ch & 3) * 32;
    const int wci0 = ch * 32;
    __syncthreads();
    #pragma unroll
    for (int it = 0; it < 6; ++it) {
      int idx = it * 256 + tid;
      int colr = idx >> 2, seg = idx & 3;
      int gcol = col0 - 32 + colr;
      uint4 v = {0u, 0u, 0u, 0u};
      if (gcol >= 0 && gcol < 1600)
        v = *(const uint4*)(Ht + ((size_t)(b * 1600 + gcol) * 128 + ci0 + seg * 8));
      *(uint4*)(&Hl[colr * 40 + seg * 8]) = v;
    }
    #pragma unroll
    for (int it = 0; it < 3; ++it) {
      int idx = it * 256 + tid;
      int o = (idx >> 2) & 63, kt = idx >> 8, seg = idx & 3;
      uint4 v = *(const uint4*)(Wb + ((kt * 64 + o) * 256 + wci0 + seg * 8));
      *(uint4*)(&Wl[(kt * 64 + o) * 40 + seg * 8]) = v;
    }
    __syncthreads();
    #pragma unroll
    for (int kt = 0; kt < 3; ++kt) {
      short8 af[5], bf[4];
      const int ab = base_a + kt * 1000;
      const int bb = base_b + kt * 2560;
      #pragma unroll
      for (int mt = 0; mt < 5; ++mt) af[mt] = *(const short8*)(&Hl[ab + mt * 640]);
      #pragma unroll
      for (int nt = 0; nt < 4; ++nt) bf[nt] = *(const short8*)(&Wl[bb + nt * 640]);
      #pragma unroll
      for (int mt = 0; mt < 5; ++mt)
        #pragma unroll
        for (int nt = 0; nt < 4; ++nt)
          acc[mt][nt] = __builtin_amdgcn_mfma_f32_16x16x32_bf16(af[mt], bf[nt],
                                                                acc[mt][nt], 0, 0, 0);
    }
  }

  const float aout = aout_[0];
  const int colbase = col0 + w * 80 + lg * 4;
  #pragma unroll
  for (int nt = 0; nt < 4; ++nt) {
    const int o = nt * 16 + lr;
    const float bo = btcn[o];
    const float* xr = x + ((size_t)b * 64 + o) * 1600 + colbase;
    float* op = out + ((size_t)b * 64 + o) * 1600 + colbase;
    #pragma unroll
    for (int mt = 0; mt < 5; ++mt) {
      float4 xv = *(const float4*)(xr + mt * 16);
      f32x4 a4 = acc[mt][nt];
      float4 res;
      float v0 = (a4[0] + bo) * BN_SCALE_F + xv.x;
      float v1 = (a4[1] + bo) * BN_SCALE_F + xv.y;
      float v2 = (a4[2] + bo) * BN_SCALE_F + xv.z;
      float v3 = (a4[3] + bo) * BN_SCALE_F + xv.w;
      res.x = v0 >= 0.f ? v0 : aout * v0;
      res.y = v1 >= 0.f ? v1 : aout * v1;
      res.z = v2 >= 0.f ? v2 : aout * v2;
      res.w = v3 >= 0.f ? v3 : aout * v3;
      *(float4*)(op + mt * 16) = res;
    }
  }
}

extern "C" void kernel_launch(void* const* d_in, const int* in_sizes, int n_in,
                              void* d_out, int out_size, void* d_ws, size_t ws_size,
                              hipStream_t stream) {
  const float* x     = (const float*)d_in[0];
  const float* A1    = (const float*)d_in[1];
  const float* A2    = (const float*)d_in[2];
  const float* A3    = (const float*)d_in[3];
  const float* Wp1   = (const float*)d_in[4];
  const float* ap1   = (const float*)d_in[5];
  const float* Wp2   = (const float*)d_in[6];
  const float* ap2   = (const float*)d_in[7];
  const float* Wg2   = (const float*)d_in[8];
  const float* bg2   = (const float*)d_in[9];
  const float* Wt2   = (const float*)d_in[10];
  const float* bt2   = (const float*)d_in[11];
  const float* Wph2  = (const float*)d_in[12];
  const float* bph2  = (const float*)d_in[13];
  const float* wcat2 = (const float*)d_in[14];
  const float* Ck2   = (const float*)d_in[15];
  const float* Wg3   = (const float*)d_in[16];
  const float* bg3   = (const float*)d_in[17];
  const float* Wt3   = (const float*)d_in[18];
  const float* bt3   = (const float*)d_in[19];
  const float* Wph3  = (const float*)d_in[20];
  const float* bph3  = (const float*)d_in[21];
  const float* wcat3 = (const float*)d_in[22];
  const float* Ck3   = (const float*)d_in[23];
  const float* Wtcn  = (const float*)d_in[24];
  const float* btcn  = (const float*)d_in[25];
  const float* aout  = (const float*)d_in[26];
  float* out = (float*)d_out;
  float* ws  = (float*)d_ws;

  __hip_bfloat16* ZH   = (__hip_bfloat16*)(ws + 6553600);   // Pp2 bf16 earlier life
  __hip_bfloat16* HbTA = (__hip_bfloat16*)(ws + 13107200);
  float* x2b  = ws + 19660800;
  float* preb = ws + 24641536;
  float* F19  = ws + 29622272;
  float* F15  = ws + 29652672;
  float* uv   = ws + 29676672;
  float* partials = x2b;
  __hip_bfloat16* Wb   = (__hip_bfloat16*)preb;             // 49,152 bf16
  __hip_bfloat16* WgT  = (__hip_bfloat16*)(preb + 24576);   // 8,192 bf16
  float* sconst        = preb + 28672;                      // 50 f
  float* ubuf2         = preb + 32768;                      // 102,400 f
  float* ubuf3         = preb + 139264;                     // 102,400 f

  prep_uv<<<1, 64, 0, stream>>>(Wt2, bt2, Wph2, bph2, wcat2,
                                Wt3, bt3, Wph3, bph3, wcat3,
                                Ck2, Ck3, uv, sconst);
  prep_wgt<<<32, 256, 0, stream>>>(Wg2, Wg3, WgT);
  transpose_w<<<192, 256, 0, stream>>>(Wtcn, Wb);
  ldnet1_mfma<<<1024, 256, 0, stream>>>(x, A1, uv, ZH /*Pp2*/, HbTA, ubuf2, ubuf3);

  // both pools in one pass over Pp2 bf16 (block per (b, channel))
  pool_partial<<<4096, 256, 0, stream>>>(ZH, Wp1, Wp2, ap1, ap2, partials);
  pool_reduce<<<64, 256, 0, stream>>>(partials, F19, F15);

  // branch 2 (R=19): fused x2+ldnet+attention+Z -> ZH ch 0..63 (Pp2 dead after pools)
  ldnet_restore_mfma<19><<<1024, 256, 0, stream>>>(HbTA, F19, A2, ubuf2,
                                                   uv + 64, uv + 256, Ck2, ZH, 0);

  // branch 3 (R=15): Z3 -> ZH ch 64..127
  ldnet_restore_mfma<15><<<1024, 256, 0, stream>>>(HbTA, F15, A3, ubuf3,
                                                   uv + 192, uv + 258, Ck3, ZH, 64);

  // shared Wg GEMM via MFMA, in place: ZH rows become HbTB rows (xcd2|xcd3 bf16)
  restore_gemm_mfma<<<800, 256, 0, stream>>>(ZH, WgT, bg2, bg3, sconst);

  // final conv via MFMA + bias + BN + residual + PReLU
  conv_mfma<<<320, 256, 0, stream>>>(HbTA, ZH, Wb, x, btcn, aout, out);
}

// Round 15
// 164.238 us; speedup vs baseline: 8.4725x; 1.0183x over previous
//
#include <hip/hip_runtime.h>
#include <hip/hip_bf16.h>
#include <math.h>

// ---------------------------------------------------------------------------
// LDSTNet forward. B=64, C=64, T=64, N=25, Ci=32. Pools: R1=19, R2=15.
//
// Workspace layout (floats):
//   (free)  @ 0          : 6,553,600
//   R1      @ 6,553,600  : 6,553,600  Pp2 bf16 [b][t][1600] -> ZH/HbTB bf16 [col][128]
//   R2      @ 13,107,200 : 6,553,600  HbT_A bf16 [b][1600][128] (0..63=x, 64..127=out1)
//   x2buf   @ 19,660,800 : 4,980,736  partials (64x64x850)
//   preb    @ 24,641,536 : 4,980,736  Wb | WgT | sconst | ubuf2 | ubuf3
//   F19     @ 29,622,272 : 30,400
//   F15     @ 29,652,672 : 24,000
//   uvbuf   @ 29,676,672 : 320
// ---------------------------------------------------------------------------

#define BN_SCALE_F 0.9999950000374997f

typedef __attribute__((ext_vector_type(8))) short short8;
typedef __attribute__((ext_vector_type(4))) float f32x4;

// ---- precompute wu/wv/cu/cv for both branches + att row-sum constants
__global__ void prep_uv(const float* __restrict__ Wt2, const float* __restrict__ bt2,
                        const float* __restrict__ Wph2, const float* __restrict__ bph2,
                        const float* __restrict__ wcat2,
                        const float* __restrict__ Wt3, const float* __restrict__ bt3,
                        const float* __restrict__ Wph3, const float* __restrict__ bph3,
                        const float* __restrict__ wcat3,
                        const float* __restrict__ Ck2, const float* __restrict__ Ck3,
                        float* __restrict__ uv, float* __restrict__ sconst) {
  int c = threadIdx.x;
  if (c < 64) {
    float s1 = 0.f, s2 = 0.f, s3 = 0.f, s4 = 0.f;
    for (int i = 0; i < 32; ++i) {
      s1 += wcat2[i]      * Wt2[i * 64 + c];
      s2 += wcat2[32 + i] * Wph2[i * 64 + c];
      s3 += wcat3[i]      * Wt3[i * 64 + c];
      s4 += wcat3[32 + i] * Wph3[i * 64 + c];
    }
    uv[c] = s1; uv[64 + c] = s2; uv[128 + c] = s3; uv[192 + c] = s4;
  }
  if (c == 0) {
    float c1 = 0.f, c2 = 0.f, c3 = 0.f, c4 = 0.f;
    for (int i = 0; i < 32; ++i) {
      c1 += wcat2[i] * bt2[i];       c2 += wcat2[32 + i] * bph2[i];
      c3 += wcat3[i] * bt3[i];       c4 += wcat3[32 + i] * bph3[i];
    }
    uv[256] = c1; uv[257] = c2; uv[258] = c3; uv[259] = c4;
  }
  if (c < 25) {
    float s2 = 1.f, s3 = 1.f;
    for (int m = 0; m < 19; ++m) s2 += Ck2[c * 19 + m];
    for (int m = 0; m < 15; ++m) s3 += Ck3[c * 15 + m];
    sconst[c] = s2; sconst[25 + c] = s3;
  }
}

// ---- pack Wg2/Wg3 row-major bf16: WgT[g][c], g 0..63 = Wg2, 64..127 = Wg3
__global__ void prep_wgt(const float* __restrict__ Wg2, const float* __restrict__ Wg3,
                         __hip_bfloat16* __restrict__ WgT) {
  int idx = blockIdx.x * 256 + threadIdx.x;
  if (idx < 8192) {
    int g = idx >> 6, c = idx & 63;
    float v = (g < 64) ? Wg2[g * 64 + c] : Wg3[(g - 64) * 64 + c];
    WgT[idx] = __float2bfloat16(v);
  }
}

// ---- ldnet1 via MFMA: one wave per (b,t), 4 waves/block, NO BARRIERS.
__global__ __launch_bounds__(256, 4) void ldnet1_mfma(
    const float* __restrict__ x, const float* __restrict__ A,
    const float* __restrict__ uvg,
    __hip_bfloat16* __restrict__ Pp2,
    __hip_bfloat16* __restrict__ HbTA,
    float* __restrict__ ubuf2, float* __restrict__ ubuf3) {
  const int b = blockIdx.x >> 4;
  const int t0 = (blockIdx.x & 15) << 2;
  const int tid = threadIdx.x;
  const int w = tid >> 6;
  const int l = tid & 63;
  const int t = t0 + w;
  const int lr = l & 15, lg = l >> 4;

  __shared__ __hip_bfloat16 XbS[4][64 * 40];   // x-tile -> otb -> P; cols 25..39 zero
  __shared__ __hip_bfloat16 FTS[4][32 * 40];   // FT[m][n] = FA[n][m]
  __shared__ float scS[4][25 * 25];            // gram scores only
  __hip_bfloat16* Xb = XbS[w];
  __hip_bfloat16* FT = FTS[w];
  float* scf = scS[w];

  const float* xp = x + b * 102400 + t * 25;   // + c*1600 + n
  typedef union { short8 v; ushort u[8]; } frag_u;

  // phase 0: zero Xb + FT, then stage x-tile bf16 into Xb
  {
    uint32_t* z1 = (uint32_t*)Xb;
    for (int i = l; i < 1280; i += 64) z1[i] = 0u;
    uint32_t* z2 = (uint32_t*)FT;
    for (int i = l; i < 640; i += 64) z2[i] = 0u;
  }
  for (int idx = l; idx < 1600; idx += 64) {
    int c = idx / 25, n = idx - c * 25;
    Xb[c * 40 + n] = __float2bfloat16(xp[c * 1600 + n]);
  }

  // phase 0b: HbTA x-part from LDS (lane = c)
  for (int n = 0; n < 25; ++n)
    HbTA[(size_t)(b * 1600 + t * 25 + n) * 128 + l] = Xb[l * 40 + n];

  // phase 1: gram frags from LDS + 8 MFMA -> scores
  frag_u yf[2][2];
  #pragma unroll
  for (int it = 0; it < 2; ++it) {
    const int n = it * 16 + lr;
    #pragma unroll
    for (int ks = 0; ks < 2; ++ks)
      #pragma unroll
      for (int j = 0; j < 8; ++j)
        yf[it][ks].u[j] = *(const ushort*)&Xb[(ks * 32 + lg * 8 + j) * 40 + n];
  }
  f32x4 accg[2][2];
  #pragma unroll
  for (int it = 0; it < 2; ++it)
    #pragma unroll
    for (int jt = 0; jt < 2; ++jt) {
      f32x4 a = (f32x4){0.f, 0.f, 0.f, 0.f};
      a = __builtin_amdgcn_mfma_f32_16x16x32_bf16(yf[it][0].v, yf[jt][0].v, a, 0, 0, 0);
      a = __builtin_amdgcn_mfma_f32_16x16x32_bf16(yf[it][1].v, yf[jt][1].v, a, 0, 0, 0);
      accg[it][jt] = a;
    }
  #pragma unroll
  for (int it = 0; it < 2; ++it)
    #pragma unroll
    for (int jt = 0; jt < 2; ++jt)
      #pragma unroll
      for (int r = 0; r < 4; ++r) {
        int i = it * 16 + lg * 4 + r;
        int j = jt * 16 + lr;
        if (i < 25 && j < 25) scf[i * 25 + j] = accg[it][jt][r];
      }

  // phase 2: softmax rows (lanes 0..24) -> FT[m*40+n] = FA[n][m]
  if (l < 25) {
    const int n = l;
    float f[25];
    float mx = -1e30f;
    #pragma unroll
    for (int m = 0; m < 25; ++m) { f[m] = scf[n * 25 + m] * 0.125f; mx = fmaxf(mx, f[m]); }
    float sum = 0.f;
    #pragma unroll
    for (int m = 0; m < 25; ++m) { f[m] = __expf(f[m] - mx); sum += f[m]; }
    float inv = 1.f / sum;
    #pragma unroll
    for (int m = 0; m < 25; ++m) {
      float v = f[m] * inv + A[n * 25 + m];
      FT[m * 40 + n] = __float2bfloat16(v);
    }
  }

  // phase 3: Q = out1^T. A = FT rows m, B = X rows c (short8 from LDS).
  short8 fa_[2];
  fa_[0] = *(const short8*)(&FT[lr * 40 + lg * 8]);
  fa_[1] = *(const short8*)(&FT[(16 + lr) * 40 + lg * 8]);
  short8 xb2v[4];
  #pragma unroll
  for (int jt = 0; jt < 4; ++jt)
    xb2v[jt] = *(const short8*)(&Xb[(jt * 16 + lr) * 40 + lg * 8]);
  f32x4 q_[2][4];
  #pragma unroll
  for (int it = 0; it < 2; ++it)
    #pragma unroll
    for (int jt = 0; jt < 4; ++jt) {
      f32x4 a = (f32x4){0.f, 0.f, 0.f, 0.f};
      q_[it][jt] = __builtin_amdgcn_mfma_f32_16x16x32_bf16(fa_[it], xb2v[jt], a, 0, 0, 0);
    }
  #pragma unroll
  for (int it = 0; it < 2; ++it)
    #pragma unroll
    for (int jt = 0; jt < 4; ++jt)
      #pragma unroll
      for (int r = 0; r < 4; ++r) {
        int m = it * 16 + lg * 4 + r;
        int c = jt * 16 + lr;
        if (m < 25) {
          __hip_bfloat16 h = __float2bfloat16(q_[it][jt][r]);
          Xb[c * 40 + m] = h;
          HbTA[(size_t)(b * 1600 + t * 25 + m) * 128 + 64 + c] = h;
        }
      }

  // phase 4: uu2/uu3 from otb (lanes 0..24)
  if (l < 25) {
    float s2 = uvg[256], s3 = uvg[258];
    #pragma unroll 8
    for (int c = 0; c < 64; ++c) {
      float o = __bfloat162float(Xb[c * 40 + l]);
      s2 += uvg[c] * o;
      s3 += uvg[128 + c] * o;
    }
    ubuf2[b * 1600 + t * 25 + l] = s2;
    ubuf3[b * 1600 + t * 25 + l] = s3;
  }

  // phase 5: P = otb @ FA
  short8 ofr[4];
  #pragma unroll
  for (int it = 0; it < 4; ++it)
    ofr[it] = *(const short8*)(&Xb[(it * 16 + lr) * 40 + lg * 8]);
  f32x4 p_[4][2];
  #pragma unroll
  for (int it = 0; it < 4; ++it)
    #pragma unroll
    for (int jt = 0; jt < 2; ++jt) {
      f32x4 a = (f32x4){0.f, 0.f, 0.f, 0.f};
      p_[it][jt] = __builtin_amdgcn_mfma_f32_16x16x32_bf16(ofr[it], fa_[jt], a, 0, 0, 0);
    }
  #pragma unroll
  for (int it = 0; it < 4; ++it)
    #pragma unroll
    for (int jt = 0; jt < 2; ++jt)
      #pragma unroll
      for (int r = 0; r < 4; ++r) {
        int c = it * 16 + lg * 4 + r;
        int n = jt * 16 + lr;
        if (n < 25) Xb[c * 40 + n] = __float2bfloat16(p_[it][jt][r]);
      }

  // phase 6: Pp2 bf16 coalesced
  for (int idx = l; idx < 1600; idx += 64) {
    int c = idx / 25, n = idx - c * 25;
    Pp2[b * 102400 + t * 1600 + idx] = Xb[c * 40 + n];
  }
}

// ---- pool partials, block = (b, c-channel); Pp2 bf16 [b][t][1600]
__global__ void pool_partial(const __hip_bfloat16* __restrict__ Pp2,
                             const float* __restrict__ Wp1, const float* __restrict__ Wp2,
                             const float* __restrict__ ap1_, const float* __restrict__ ap2_,
                             float* __restrict__ partials) {
  const int b = blockIdx.x >> 6;
  const int c = blockIdx.x & 63;
  const int tid = threadIdx.x;
  const float a1 = ap1_[0], a2 = ap2_[0];
  __shared__ float pg1[1600];
  __shared__ float pg2[1600];
  __shared__ float wct[64][36];
  for (int idx = tid; idx < 1600; idx += 256) {
    int t = idx / 25, n = idx - t * 25;
    float v = __bfloat162float(Pp2[b * 102400 + t * 1600 + c * 25 + n]);
    pg1[idx] = v >= 0.f ? v : a1 * v;
    pg2[idx] = v >= 0.f ? v : a2 * v;
  }
  for (int idx = tid; idx < 19 * 64; idx += 256) {
    int kl = idx & 63, r = idx >> 6;
    wct[kl][r] = Wp1[r * 4096 + (c << 6) + kl];
  }
  for (int idx = tid; idx < 15 * 64; idx += 256) {
    int kl = idx & 63, r = idx >> 6;
    wct[kl][20 + r] = Wp2[r * 4096 + (c << 6) + kl];
  }
  __syncthreads();
  if (tid < 225) {
    const int j = tid / 9;
    const int g = tid - j * 9;
    const bool br1 = (g < 5);
    const int r0 = br1 ? g * 4 : 20 + (g - 5) * 4;
    const float* pgc = br1 ? pg1 : pg2;
    float acc0 = 0.f, acc1 = 0.f, acc2 = 0.f, acc3 = 0.f;
    #pragma unroll 4
    for (int kl = 0; kl < 64; ++kl) {
      int off = kl * 25 + j;
      float p = pgc[(off & 63) * 25 + (off >> 6)];
      const float4 wv = *(const float4*)&wct[kl][r0];
      acc0 += p * wv.x; acc1 += p * wv.y; acc2 += p * wv.z; acc3 += p * wv.w;
    }
    const int base = (b * 64 + c) * 850;
    if (br1) {
      const int m = base + j * 19 + r0;
      partials[m] = acc0; partials[m + 1] = acc1; partials[m + 2] = acc2;
      if (g != 4) partials[m + 3] = acc3;
    } else {
      const int m = base + 475 + j * 15 + (r0 - 20);
      partials[m] = acc0; partials[m + 1] = acc1; partials[m + 2] = acc2;
      if (g != 8) partials[m + 3] = acc3;
    }
  }
}

// ---- reduce partials over 64 channel-chunks + per-branch softmax
__global__ void pool_reduce(const float* __restrict__ partials,
                            float* __restrict__ F19, float* __restrict__ F15) {
  const int b = blockIdx.x;
  const int tid = threadIdx.x;
  __shared__ float lg[850];
  for (int m = tid; m < 850; m += 256) {
    float s = 0.f;
    for (int ch = 0; ch < 64; ++ch) s += partials[(b * 64 + ch) * 850 + m];
    lg[m] = s;
  }
  __syncthreads();
  if (tid < 25) {
    const float* row = lg + tid * 19;
    float mx = -1e30f;
    for (int r = 0; r < 19; ++r) mx = fmaxf(mx, row[r]);
    float sum = 0.f;
    for (int r = 0; r < 19; ++r) sum += __expf(row[r] - mx);
    float inv = 1.f / sum;
    for (int r = 0; r < 19; ++r)
      F19[(b * 25 + tid) * 19 + r] = __expf(row[r] - mx) * inv;
  } else if (tid >= 32 && tid < 57) {
    const int j = tid - 32;
    const float* row = lg + 475 + j * 15;
    float mx = -1e30f;
    for (int r = 0; r < 15; ++r) mx = fmaxf(mx, row[r]);
    float sum = 0.f;
    for (int r = 0; r < 15; ++r) sum += __expf(row[r] - mx);
    float inv = 1.f / sum;
    for (int r = 0; r < 15; ++r)
      F15[(b * 25 + j) * 15 + r] = __expf(row[r] - mx) * inv;
  }
}

// ---- fused x2 + ldnet + attention + Z via MFMA: one wave per (b,t), NO BARRIERS.
template<int M>
__global__ __launch_bounds__(256) void ldnet_restore_mfma(
    const __hip_bfloat16* __restrict__ HbTA, const float* __restrict__ F3g,
    const float* __restrict__ A,
    const float* __restrict__ uub, const float* __restrict__ wv,
    const float* __restrict__ cuv, const float* __restrict__ Ck,
    __hip_bfloat16* __restrict__ ZH, int cioff) {
  const int b = blockIdx.x >> 4;
  const int t0 = (blockIdx.x & 15) << 2;
  const int tid = threadIdx.x;
  const int w = tid >> 6;
  const int l = tid & 63;
  const int t = t0 + w;
  const int lr = l & 15, lg = l >> 4;

  __shared__ __hip_bfloat16 XbS[4][64 * 40];   // X2 -> ot -> Zt overlay
  __shared__ __hip_bfloat16 FBS[4][32 * 40];   // FB[r][n] = F3[n][r]
  __shared__ __hip_bfloat16 FTS[4][32 * 40];   // FT[m][n] = FA[n][m]
  __shared__ __hip_bfloat16 ATS[4][32 * 40];   // AT[n][m] = att[n][m]
  __shared__ float scS[4][512];                // gram scores (stride 26)
  __shared__ float vvS[4][32];
  __hip_bfloat16* Xb = XbS[w];
  __hip_bfloat16* FB = FBS[w];
  __hip_bfloat16* FT = FTS[w];
  __hip_bfloat16* AT = ATS[w];
  float* scf = scS[w];
  float* vv = vvS[w];

  typedef union { short8 v; ushort u[8]; } frag_u;
  const ushort* Hu = (const ushort*)HbTA;

  // phase 0: zero everything
  {
    uint32_t* z0 = (uint32_t*)Xb;
    for (int i = l; i < 1280; i += 64) z0[i] = 0u;
    uint32_t* z1 = (uint32_t*)FB;
    uint32_t* z2 = (uint32_t*)FT;
    uint32_t* z3 = (uint32_t*)AT;
    for (int i = l; i < 640; i += 64) { z1[i] = 0u; z2[i] = 0u; z3[i] = 0u; }
  }
  // phase 0a: FB[r*40+n] = bf16(F3[b][n][r])
  for (int idx = l; idx < M * 25; idx += 64) {
    int r = idx / 25, n = idx - r * 25;
    FB[r * 40 + n] = __float2bfloat16(F3g[(b * 25 + n) * M + r]);
  }

  // phase 1: X2 = out1 @ F3. A-frags from global HbTA (gated), B from FB.
  frag_u af0[4];
  #pragma unroll
  for (int it = 0; it < 4; ++it) {
    const int c = it * 16 + lr;
    #pragma unroll
    for (int jj = 0; jj < 8; ++jj) {
      int n = lg * 8 + jj;
      af0[it].u[jj] = (n < 25)
          ? Hu[(size_t)(b * 1600 + t * 25 + n) * 128 + 64 + c] : (ushort)0;
    }
  }
  short8 bf0[2];
  bf0[0] = *(const short8*)(&FB[lr * 40 + lg * 8]);
  bf0[1] = *(const short8*)(&FB[(16 + lr) * 40 + lg * 8]);
  f32x4 x2a[4][2];
  #pragma unroll
  for (int it = 0; it < 4; ++it)
    #pragma unroll
    for (int jt = 0; jt < 2; ++jt) {
      f32x4 a = (f32x4){0.f, 0.f, 0.f, 0.f};
      x2a[it][jt] = __builtin_amdgcn_mfma_f32_16x16x32_bf16(af0[it].v, bf0[jt], a, 0, 0, 0);
    }
  #pragma unroll
  for (int it = 0; it < 4; ++it)
    #pragma unroll
    for (int jt = 0; jt < 2; ++jt)
      #pragma unroll
      for (int rr = 0; rr < 4; ++rr) {
        int c = it * 16 + lg * 4 + rr;
        int r = jt * 16 + lr;
        float v = (r < M) ? x2a[it][jt][rr] : 0.f;
        Xb[c * 40 + r] = __float2bfloat16(v);
      }

  // phase 2: gram(X2) frags from LDS + 8 MFMA -> scores scf[i*26+j]
  frag_u yf[2][2];
  #pragma unroll
  for (int it = 0; it < 2; ++it) {
    const int n = it * 16 + lr;
    #pragma unroll
    for (int ks = 0; ks < 2; ++ks)
      #pragma unroll
      for (int j = 0; j < 8; ++j)
        yf[it][ks].u[j] = *(const ushort*)&Xb[(ks * 32 + lg * 8 + j) * 40 + n];
  }
  f32x4 accg[2][2];
  #pragma unroll
  for (int it = 0; it < 2; ++it)
    #pragma unroll
    for (int jt = 0; jt < 2; ++jt) {
      f32x4 a = (f32x4){0.f, 0.f, 0.f, 0.f};
      a = __builtin_amdgcn_mfma_f32_16x16x32_bf16(yf[it][0].v, yf[jt][0].v, a, 0, 0, 0);
      a = __builtin_amdgcn_mfma_f32_16x16x32_bf16(yf[it][1].v, yf[jt][1].v, a, 0, 0, 0);
      accg[it][jt] = a;
    }
  #pragma unroll
  for (int it = 0; it < 2; ++it)
    #pragma unroll
    for (int jt = 0; jt < 2; ++jt)
      #pragma unroll
      for (int r = 0; r < 4; ++r) {
        int i = it * 16 + lg * 4 + r;
        int j = jt * 16 + lr;
        if (i < M && j < M) scf[i * 26 + j] = accg[it][jt][r];
      }

  // phase 3: softmax rows (lanes 0..M-1) -> FT[m*40+n]
  if (l < M) {
    const int n = l;
    float f[M];
    float mx = -1e30f;
    #pragma unroll
    for (int m = 0; m < M; ++m) { f[m] = scf[n * 26 + m] * 0.125f; mx = fmaxf(mx, f[m]); }
    float sum = 0.f;
    #pragma unroll
    for (int m = 0; m < M; ++m) { f[m] = __expf(f[m] - mx); sum += f[m]; }
    float inv = 1.f / sum;
    #pragma unroll
    for (int m = 0; m < M; ++m) {
      float v = f[m] * inv + A[n * M + m];
      FT[m * 40 + n] = __float2bfloat16(v);
    }
  }

  // phase 4: ot = X2 @ FA (K=32), scatter into Xb (cols >= M -> 0)
  short8 xf[4], ff[2];
  #pragma unroll
  for (int it = 0; it < 4; ++it)
    xf[it] = *(const short8*)(&Xb[(it * 16 + lr) * 40 + lg * 8]);
  #pragma unroll
  for (int jt = 0; jt < 2; ++jt)
    ff[jt] = *(const short8*)(&FT[(jt * 16 + lr) * 40 + lg * 8]);
  f32x4 acco[4][2];
  #pragma unroll
  for (int it = 0; it < 4; ++it)
    #pragma unroll
    for (int jt = 0; jt < 2; ++jt) {
      f32x4 a = (f32x4){0.f, 0.f, 0.f, 0.f};
      acco[it][jt] = __builtin_amdgcn_mfma_f32_16x16x32_bf16(xf[it], ff[jt], a, 0, 0, 0);
    }
  #pragma unroll
  for (int it = 0; it < 4; ++it)
    #pragma unroll
    for (int jt = 0; jt < 2; ++jt)
      #pragma unroll
      for (int r = 0; r < 4; ++r) {
        int c = it * 16 + lg * 4 + r;
        int m = jt * 16 + lr;
        float v = (m < M) ? acco[it][jt][r] : 0.f;
        Xb[c * 40 + m] = __float2bfloat16(v);
      }

  // phase 5: vv[m] = cv + sum_c wv[c]*ot[c][m]  (lanes 0..M-1)
  if (l < M) {
    float s = cuv[1];
    #pragma unroll 8
    for (int c = 0; c < 64; ++c)
      s += wv[c] * __bfloat162float(Xb[c * 40 + l]);
    vv[l] = s;
  }

  // phase 6: att (lanes 0..24) -> AT[n*40+m]
  if (l < 25) {
    const int n = l;
    const float uu = uub[b * 1600 + t * 25 + n];
    float f[M];
    float mx = -1e30f;
    #pragma unroll
    for (int m = 0; m < M; ++m) {
      float v = uu + vv[m];
      v = v >= 0.f ? v : 0.2f * v;
      f[m] = v;
      mx = fmaxf(mx, v);
    }
    float sum = 0.f;
    #pragma unroll
    for (int m = 0; m < M; ++m) { f[m] = __expf(f[m] - mx); sum += f[m]; }
    float inv = 1.f / sum;
    #pragma unroll
    for (int m = 0; m < M; ++m)
      AT[n * 40 + m] = __float2bfloat16(f[m] * inv + Ck[n * M + m]);
  }

  // phase 7: Z = ot @ att^T (K=32): D[i=c][j=n] -> Zt (staged in dead Xb)
  short8 of[4], af[2];
  #pragma unroll
  for (int it = 0; it < 4; ++it)
    of[it] = *(const short8*)(&Xb[(it * 16 + lr) * 40 + lg * 8]);
  #pragma unroll
  for (int jt = 0; jt < 2; ++jt)
    af[jt] = *(const short8*)(&AT[(jt * 16 + lr) * 40 + lg * 8]);
  f32x4 accz[4][2];
  #pragma unroll
  for (int it = 0; it < 4; ++it)
    #pragma unroll
    for (int jt = 0; jt < 2; ++jt) {
      f32x4 a = (f32x4){0.f, 0.f, 0.f, 0.f};
      accz[it][jt] = __builtin_amdgcn_mfma_f32_16x16x32_bf16(of[it], af[jt], a, 0, 0, 0);
    }
  __hip_bfloat16* Zt = Xb;   // Xb dead after `of` reads (accz depends on of)
  #pragma unroll
  for (int it = 0; it < 4; ++it)
    #pragma unroll
    for (int jt = 0; jt < 2; ++jt)
      #pragma unroll
      for (int r = 0; r < 4; ++r) {
        int c = it * 16 + lg * 4 + r;
        int n = jt * 16 + lr;
        if (n < 25) Zt[n * 66 + c] = __float2bfloat16(accz[it][jt][r]);
      }

  // phase 8: coalesced ZH write (lane = c, 128B per row)
  for (int n = 0; n < 25; ++n)
    ZH[(size_t)(b * 1600 + t * 25 + n) * 128 + cioff + l] = Zt[n * 66 + l];
}

// ---- restore GEMM via MFMA, wave-private 32-col slices, IN PLACE, no LDS/barriers.
__global__ __launch_bounds__(256) void restore_gemm_mfma(
    __hip_bfloat16* __restrict__ ZH, const __hip_bfloat16* __restrict__ WgT,
    const float* __restrict__ bg2, const float* __restrict__ bg3,
    const float* __restrict__ sconst) {
  const int tid = threadIdx.x;
  const int wv = tid >> 6, l = tid & 63;
  const int lr = l & 15, lg = l >> 4;
  const size_t col0 = ((size_t)blockIdx.x * 4 + wv) * 32;
  const ushort* Zg = (const ushort*)ZH;
  const ushort* Wu = (const ushort*)WgT;

  short8 afr[2][2][2];
  #pragma unroll
  for (int mt = 0; mt < 2; ++mt)
    #pragma unroll
    for (int br = 0; br < 2; ++br)
      #pragma unroll
      for (int ks = 0; ks < 2; ++ks)
        afr[mt][br][ks] = *(const short8*)(
            Zg + (col0 + mt * 16 + lr) * 128 + br * 64 + ks * 32 + lg * 8);

  f32x4 acc[2][8];
  #pragma unroll
  for (int nt = 0; nt < 8; ++nt) {
    const int br = nt >> 2;
    const int g = nt * 16 + lr;
    short8 b0 = *(const short8*)(Wu + g * 64 + lg * 8);
    short8 b1 = *(const short8*)(Wu + g * 64 + 32 + lg * 8);
    #pragma unroll
    for (int mt = 0; mt < 2; ++mt) {
      f32x4 a = (f32x4){0.f, 0.f, 0.f, 0.f};
      a = __builtin_amdgcn_mfma_f32_16x16x32_bf16(afr[mt][br][0], b0, a, 0, 0, 0);
      a = __builtin_amdgcn_mfma_f32_16x16x32_bf16(afr[mt][br][1], b1, a, 0, 0, 0);
      acc[mt][nt] = a;
    }
  }

  #pragma unroll
  for (int mt = 0; mt < 2; ++mt)
    #pragma unroll
    for (int r = 0; r < 4; ++r) {
      const size_t col = col0 + mt * 16 + lg * 4 + r;
      const int n = (int)(col % 25);
      const float s2v = sconst[n], s3v = sconst[25 + n];
      ushort* zp = (ushort*)ZH + col * 128;
      #pragma unroll
      for (int nt = 0; nt < 8; ++nt) {
        const int g = nt * 16 + lr;
        const float bo = (nt < 4) ? bg2[g] : bg3[g - 64];
        const float s = (nt < 4) ? s2v : s3v;
        float v = fmaxf((acc[mt][nt][r] + bo * s) * BN_SCALE_F, 0.f);
        __hip_bfloat16 h = __float2bfloat16(v);
        zp[g] = *(ushort*)&h;
      }
    }
}

// ---- conv weights -> bf16, layout Wb[kt][o][ci]
__global__ void transpose_w(const float* __restrict__ Wtcn, __hip_bfloat16* __restrict__ Wb) {
  int idx = blockIdx.x * 256 + threadIdx.x;
  if (idx < 49152) {
    int ci = idx & 255;
    int rest = idx >> 8;
    int o = rest & 63, kt = rest >> 6;
    Wb[idx] = __float2bfloat16(Wtcn[(o * 256 + ci) * 3 + kt]);
  }
}

// ---- final conv via MFMA, 8 waves/block (512 thr): wave = 80 cols x 32 o.
// wcol = wave&3 (80-col group), who = wave>>2 (o-half). Same math as 4-wave version.
__global__ __launch_bounds__(512) void conv_mfma(
    const __hip_bfloat16* __restrict__ HbTA, const __hip_bfloat16* __restrict__ HbTB,
    const __hip_bfloat16* __restrict__ Wb, const float* __restrict__ x,
    const float* __restrict__ btcn, const float* __restrict__ aout_,
    float* __restrict__ out) {
  const int b = blockIdx.x / 5;
  const int col0 = (blockIdx.x % 5) * 320;
  const int tid = threadIdx.x;
  const int wave = tid >> 6, l = tid & 63;
  const int wcol = wave & 3, who = wave >> 2;
  const int lr = l & 15, lg = l >> 4;

  __shared__ __hip_bfloat16 Hl[384 * 40];
  __shared__ __hip_bfloat16 Wl[3 * 64 * 40];

  f32x4 acc[5][2];
  #pragma unroll
  for (int mt = 0; mt < 5; ++mt)
    #pragma unroll
    for (int nt = 0; nt < 2; ++nt) acc[mt][nt] = (f32x4){0.f, 0.f, 0.f, 0.f};

  const int base_a = (wcol * 80 + lr + 7) * 40 + lg * 8;
  const int base_b = (who * 32 + lr) * 40 + lg * 8;

  for (int ch = 0; ch < 8; ++ch) {
    const __hip_bfloat16* Ht = (ch < 4) ? HbTA : HbTB;
    const int ci0 = (ch & 3) * 32;
    const int wci0 = ch * 32;
    __syncthreads();
    #pragma unroll
    for (int it = 0; it < 3; ++it) {          // H: 384 cols x 4 segs, 512 thr
      int idx = it * 512 + tid;
      int colr = idx >> 2, seg = idx & 3;
      int gcol = col0 - 32 + colr;
      uint4 v = {0u, 0u, 0u, 0u};
      if (gcol >= 0 && gcol < 1600)
        v = *(const uint4*)(Ht + ((size_t)(b * 1600 + gcol) * 128 + ci0 + seg * 8));
      *(uint4*)(&Hl[colr * 40 + seg * 8]) = v;
    }
    for (int idx = tid; idx < 768; idx += 512) {  // W: 3 kt x 64 o x 4 segs
      int o = (idx >> 2) & 63, kt = idx >> 8, seg = idx & 3;
      uint4 v = *(const uint4*)(Wb + ((kt * 64 + o) * 256 + wci0 + seg * 8));
      *(uint4*)(&Wl[(kt * 64 + o) * 40 + seg * 8]) = v;
    }
    __syncthreads();
    #pragma unroll
    for (int kt = 0; kt < 3; ++kt) {
      short8 af[5], bf[2];
      const int ab = base_a + kt * 1000;      // +25 cols per tap
      const int bb = base_b + kt * 2560;      // +64 o-rows per tap
      #pragma unroll
      for (int mt = 0; mt < 5; ++mt) af[mt] = *(const short8*)(&Hl[ab + mt * 640]);
      #pragma unroll
      for (int nt = 0; nt < 2; ++nt) bf[nt] = *(const short8*)(&Wl[bb + nt * 640]);
      #pragma unroll
      for (int mt = 0; mt < 5; ++mt)
        #pragma unroll
        for (int nt = 0; nt < 2; ++nt)
          acc[mt][nt] = __builtin_amdgcn_mfma_f32_16x16x32_bf16(af[mt], bf[nt],
                                                                acc[mt][nt], 0, 0, 0);
    }
  }

  const float aout = aout_[0];
  const int colbase = col0 + wcol * 80 + lg * 4;
  #pragma unroll
  for (int nt = 0; nt < 2; ++nt) {
    const int o = who * 32 + nt * 16 + lr;
    const float bo = btcn[o];
    const float* xr = x + ((size_t)b * 64 + o) * 1600 + colbase;
    float* op = out + ((size_t)b * 64 + o) * 1600 + colbase;
    #pragma unroll
    for (int mt = 0; mt < 5; ++mt) {
      float4 xv = *(const float4*)(xr + mt * 16);
      f32x4 a4 = acc[mt][nt];
      float4 res;
      float v0 = (a4[0] + bo) * BN_SCALE_F + xv.x;
      float v1 = (a4[1] + bo) * BN_SCALE_F + xv.y;
      float v2 = (a4[2] + bo) * BN_SCALE_F + xv.z;
      float v3 = (a4[3] + bo) * BN_SCALE_F + xv.w;
      res.x = v0 >= 0.f ? v0 : aout * v0;
      res.y = v1 >= 0.f ? v1 : aout * v1;
      res.z = v2 >= 0.f ? v2 : aout * v2;
      res.w = v3 >= 0.f ? v3 : aout * v3;
      *(float4*)(op + mt * 16) = res;
    }
  }
}

extern "C" void kernel_launch(void* const* d_in, const int* in_sizes, int n_in,
                              void* d_out, int out_size, void* d_ws, size_t ws_size,
                              hipStream_t stream) {
  const float* x     = (const float*)d_in[0];
  const float* A1    = (const float*)d_in[1];
  const float* A2    = (const float*)d_in[2];
  const float* A3    = (const float*)d_in[3];
  const float* Wp1   = (const float*)d_in[4];
  const float* ap1   = (const float*)d_in[5];
  const float* Wp2   = (const float*)d_in[6];
  const float* ap2   = (const float*)d_in[7];
  const float* Wg2   = (const float*)d_in[8];
  const float* bg2   = (const float*)d_in[9];
  const float* Wt2   = (const float*)d_in[10];
  const float* bt2   = (const float*)d_in[11];
  const float* Wph2  = (const float*)d_in[12];
  const float* bph2  = (const float*)d_in[13];
  const float* wcat2 = (const float*)d_in[14];
  const float* Ck2   = (const float*)d_in[15];
  const float* Wg3   = (const float*)d_in[16];
  const float* bg3   = (const float*)d_in[17];
  const float* Wt3   = (const float*)d_in[18];
  const float* bt3   = (const float*)d_in[19];
  const float* Wph3  = (const float*)d_in[20];
  const float* bph3  = (const float*)d_in[21];
  const float* wcat3 = (const float*)d_in[22];
  const float* Ck3   = (const float*)d_in[23];
  const float* Wtcn  = (const float*)d_in[24];
  const float* btcn  = (const float*)d_in[25];
  const float* aout  = (const float*)d_in[26];
  float* out = (float*)d_out;
  float* ws  = (float*)d_ws;

  __hip_bfloat16* ZH   = (__hip_bfloat16*)(ws + 6553600);   // Pp2 bf16 earlier life
  __hip_bfloat16* HbTA = (__hip_bfloat16*)(ws + 13107200);
  float* x2b  = ws + 19660800;
  float* preb = ws + 24641536;
  float* F19  = ws + 29622272;
  float* F15  = ws + 29652672;
  float* uv   = ws + 29676672;
  float* partials = x2b;
  __hip_bfloat16* Wb   = (__hip_bfloat16*)preb;             // 49,152 bf16
  __hip_bfloat16* WgT  = (__hip_bfloat16*)(preb + 24576);   // 8,192 bf16
  float* sconst        = preb + 28672;                      // 50 f
  float* ubuf2         = preb + 32768;                      // 102,400 f
  float* ubuf3         = preb + 139264;                     // 102,400 f

  prep_uv<<<1, 64, 0, stream>>>(Wt2, bt2, Wph2, bph2, wcat2,
                                Wt3, bt3, Wph3, bph3, wcat3,
                                Ck2, Ck3, uv, sconst);
  prep_wgt<<<32, 256, 0, stream>>>(Wg2, Wg3, WgT);
  transpose_w<<<192, 256, 0, stream>>>(Wtcn, Wb);
  ldnet1_mfma<<<1024, 256, 0, stream>>>(x, A1, uv, ZH /*Pp2*/, HbTA, ubuf2, ubuf3);

  // both pools in one pass over Pp2 bf16 (block per (b, channel))
  pool_partial<<<4096, 256, 0, stream>>>(ZH, Wp1, Wp2, ap1, ap2, partials);
  pool_reduce<<<64, 256, 0, stream>>>(partials, F19, F15);

  // branch 2 (R=19): fused x2+ldnet+attention+Z -> ZH ch 0..63 (Pp2 dead after pools)
  ldnet_restore_mfma<19><<<1024, 256, 0, stream>>>(HbTA, F19, A2, ubuf2,
                                                   uv + 64, uv + 256, Ck2, ZH, 0);

  // branch 3 (R=15): Z3 -> ZH ch 64..127
  ldnet_restore_mfma<15><<<1024, 256, 0, stream>>>(HbTA, F15, A3, ubuf3,
                                                   uv + 192, uv + 258, Ck3, ZH, 64);

  // shared Wg GEMM via MFMA, in place: ZH rows become HbTB rows (xcd2|xcd3 bf16)
  restore_gemm_mfma<<<800, 256, 0, stream>>>(ZH, WgT, bg2, bg3, sconst);

  // final conv via MFMA + bias + BN + residual + PReLU (8-wave blocks)
  conv_mfma<<<320, 512, 0, stream>>>(HbTA, ZH, Wb, x, btcn, aout, out);
}

// Round 16
// 163.590 us; speedup vs baseline: 8.5060x; 1.0040x over previous
//
#include <hip/hip_runtime.h>
#include <hip/hip_bf16.h>
#include <math.h>

// ---------------------------------------------------------------------------
// LDSTNet forward. B=64, C=64, T=64, N=25, Ci=32. Pools: R1=19, R2=15.
//
// Workspace layout (floats):
//   (free)  @ 0          : 6,553,600
//   R1      @ 6,553,600  : 6,553,600  Pp2 bf16 [b][t][1600] -> ZH/HbTB bf16 [col][128]
//   R2      @ 13,107,200 : 6,553,600  HbT_A bf16 [b][1600][128] (0..63=x, 64..127=out1)
//   x2buf   @ 19,660,800 : 4,980,736  partials (64x64x850)
//   preb    @ 24,641,536 : 4,980,736  Wb | WgT | sconst | ubuf2 | ubuf3
//   F19     @ 29,622,272 : 30,400
//   F15     @ 29,652,672 : 24,000
//   uvbuf   @ 29,676,672 : 320
// ---------------------------------------------------------------------------

#define BN_SCALE_F 0.9999950000374997f

typedef __attribute__((ext_vector_type(8))) short short8;
typedef __attribute__((ext_vector_type(4))) float f32x4;

// ---- merged prep: block 0 = uv/sconst; blocks 1..32 = WgT; blocks 33..224 = Wb
__global__ void prep_all(const float* __restrict__ Wt2, const float* __restrict__ bt2,
                         const float* __restrict__ Wph2, const float* __restrict__ bph2,
                         const float* __restrict__ wcat2,
                         const float* __restrict__ Wt3, const float* __restrict__ bt3,
                         const float* __restrict__ Wph3, const float* __restrict__ bph3,
                         const float* __restrict__ wcat3,
                         const float* __restrict__ Ck2, const float* __restrict__ Ck3,
                         const float* __restrict__ Wg2, const float* __restrict__ Wg3,
                         const float* __restrict__ Wtcn,
                         float* __restrict__ uv, float* __restrict__ sconst,
                         __hip_bfloat16* __restrict__ WgT,
                         __hip_bfloat16* __restrict__ Wb) {
  const int bid = blockIdx.x;
  const int tid = threadIdx.x;
  if (bid == 0) {
    int c = tid;
    if (c < 64) {
      float s1 = 0.f, s2 = 0.f, s3 = 0.f, s4 = 0.f;
      for (int i = 0; i < 32; ++i) {
        s1 += wcat2[i]      * Wt2[i * 64 + c];
        s2 += wcat2[32 + i] * Wph2[i * 64 + c];
        s3 += wcat3[i]      * Wt3[i * 64 + c];
        s4 += wcat3[32 + i] * Wph3[i * 64 + c];
      }
      uv[c] = s1; uv[64 + c] = s2; uv[128 + c] = s3; uv[192 + c] = s4;
    }
    if (c == 0) {
      float c1 = 0.f, c2 = 0.f, c3 = 0.f, c4 = 0.f;
      for (int i = 0; i < 32; ++i) {
        c1 += wcat2[i] * bt2[i];       c2 += wcat2[32 + i] * bph2[i];
        c3 += wcat3[i] * bt3[i];       c4 += wcat3[32 + i] * bph3[i];
      }
      uv[256] = c1; uv[257] = c2; uv[258] = c3; uv[259] = c4;
    }
    if (c >= 64 && c < 89) {
      int n = c - 64;
      float s2 = 1.f, s3 = 1.f;
      for (int m = 0; m < 19; ++m) s2 += Ck2[n * 19 + m];
      for (int m = 0; m < 15; ++m) s3 += Ck3[n * 15 + m];
      sconst[n] = s2; sconst[25 + n] = s3;
    }
  } else if (bid < 33) {
    int idx = (bid - 1) * 256 + tid;
    int g = idx >> 6, c = idx & 63;
    float v = (g < 64) ? Wg2[g * 64 + c] : Wg3[(g - 64) * 64 + c];
    WgT[idx] = __float2bfloat16(v);
  } else {
    int idx = (bid - 33) * 256 + tid;
    int ci = idx & 255;
    int rest = idx >> 8;
    int o = rest & 63, kt = rest >> 6;
    Wb[idx] = __float2bfloat16(Wtcn[(o * 256 + ci) * 3 + kt]);
  }
}

// ---- ldnet1 via MFMA: one wave per (b,t), 4 waves/block, NO BARRIERS.
__global__ __launch_bounds__(256, 4) void ldnet1_mfma(
    const float* __restrict__ x, const float* __restrict__ A,
    const float* __restrict__ uvg,
    __hip_bfloat16* __restrict__ Pp2,
    __hip_bfloat16* __restrict__ HbTA,
    float* __restrict__ ubuf2, float* __restrict__ ubuf3) {
  const int b = blockIdx.x >> 4;
  const int t0 = (blockIdx.x & 15) << 2;
  const int tid = threadIdx.x;
  const int w = tid >> 6;
  const int l = tid & 63;
  const int t = t0 + w;
  const int lr = l & 15, lg = l >> 4;

  __shared__ __hip_bfloat16 XbS[4][64 * 40];   // x-tile -> otb -> P; cols 25..31 zero
  __shared__ __hip_bfloat16 FTS[4][32 * 40];   // FT[m][n] = FA[n][m]
  __shared__ float scS[4][25 * 25];            // gram scores only
  __hip_bfloat16* Xb = XbS[w];
  __hip_bfloat16* FT = FTS[w];
  float* scf = scS[w];

  const float* xp = x + b * 102400 + t * 25;   // + c*1600 + n
  typedef union { short8 v; ushort u[8]; } frag_u;

  // phase 0: zero FT; stage x-tile bf16 into Xb cols 0..31 (25..31 = 0).
  // Xb cols 32..39 are never read anywhere in this kernel.
  {
    uint32_t* z2 = (uint32_t*)FT;
    for (int i = l; i < 640; i += 64) z2[i] = 0u;
  }
  for (int idx = l; idx < 2048; idx += 64) {
    int c = idx >> 5, n = idx & 31;
    float v = (n < 25) ? xp[c * 1600 + n] : 0.f;
    Xb[c * 40 + n] = __float2bfloat16(v);
  }

  // phase 0b: HbTA x-part from LDS (lane = c)
  for (int n = 0; n < 25; ++n)
    HbTA[(size_t)(b * 1600 + t * 25 + n) * 128 + l] = Xb[l * 40 + n];

  // phase 1: gram frags from LDS + 8 MFMA -> scores
  frag_u yf[2][2];
  #pragma unroll
  for (int it = 0; it < 2; ++it) {
    const int n = it * 16 + lr;
    #pragma unroll
    for (int ks = 0; ks < 2; ++ks)
      #pragma unroll
      for (int j = 0; j < 8; ++j)
        yf[it][ks].u[j] = *(const ushort*)&Xb[(ks * 32 + lg * 8 + j) * 40 + n];
  }
  f32x4 accg[2][2];
  #pragma unroll
  for (int it = 0; it < 2; ++it)
    #pragma unroll
    for (int jt = 0; jt < 2; ++jt) {
      f32x4 a = (f32x4){0.f, 0.f, 0.f, 0.f};
      a = __builtin_amdgcn_mfma_f32_16x16x32_bf16(yf[it][0].v, yf[jt][0].v, a, 0, 0, 0);
      a = __builtin_amdgcn_mfma_f32_16x16x32_bf16(yf[it][1].v, yf[jt][1].v, a, 0, 0, 0);
      accg[it][jt] = a;
    }
  #pragma unroll
  for (int it = 0; it < 2; ++it)
    #pragma unroll
    for (int jt = 0; jt < 2; ++jt)
      #pragma unroll
      for (int r = 0; r < 4; ++r) {
        int i = it * 16 + lg * 4 + r;
        int j = jt * 16 + lr;
        if (i < 25 && j < 25) scf[i * 25 + j] = accg[it][jt][r];
      }

  // phase 2: softmax rows (lanes 0..24) -> FT[m*40+n] = FA[n][m]
  if (l < 25) {
    const int n = l;
    float f[25];
    float mx = -1e30f;
    #pragma unroll
    for (int m = 0; m < 25; ++m) { f[m] = scf[n * 25 + m] * 0.125f; mx = fmaxf(mx, f[m]); }
    float sum = 0.f;
    #pragma unroll
    for (int m = 0; m < 25; ++m) { f[m] = __expf(f[m] - mx); sum += f[m]; }
    float inv = 1.f / sum;
    #pragma unroll
    for (int m = 0; m < 25; ++m) {
      float v = f[m] * inv + A[n * 25 + m];
      FT[m * 40 + n] = __float2bfloat16(v);
    }
  }

  // phase 3: Q = out1^T. A = FT rows m, B = X rows c (short8 from LDS).
  short8 fa_[2];
  fa_[0] = *(const short8*)(&FT[lr * 40 + lg * 8]);
  fa_[1] = *(const short8*)(&FT[(16 + lr) * 40 + lg * 8]);
  short8 xb2v[4];
  #pragma unroll
  for (int jt = 0; jt < 4; ++jt)
    xb2v[jt] = *(const short8*)(&Xb[(jt * 16 + lr) * 40 + lg * 8]);
  f32x4 q_[2][4];
  #pragma unroll
  for (int it = 0; it < 2; ++it)
    #pragma unroll
    for (int jt = 0; jt < 4; ++jt) {
      f32x4 a = (f32x4){0.f, 0.f, 0.f, 0.f};
      q_[it][jt] = __builtin_amdgcn_mfma_f32_16x16x32_bf16(fa_[it], xb2v[jt], a, 0, 0, 0);
    }
  #pragma unroll
  for (int it = 0; it < 2; ++it)
    #pragma unroll
    for (int jt = 0; jt < 4; ++jt)
      #pragma unroll
      for (int r = 0; r < 4; ++r) {
        int m = it * 16 + lg * 4 + r;
        int c = jt * 16 + lr;
        if (m < 25) {
          __hip_bfloat16 h = __float2bfloat16(q_[it][jt][r]);
          Xb[c * 40 + m] = h;
          HbTA[(size_t)(b * 1600 + t * 25 + m) * 128 + 64 + c] = h;
        }
      }

  // phase 4: uu2/uu3 from otb (lanes 0..24)
  if (l < 25) {
    float s2 = uvg[256], s3 = uvg[258];
    #pragma unroll 8
    for (int c = 0; c < 64; ++c) {
      float o = __bfloat162float(Xb[c * 40 + l]);
      s2 += uvg[c] * o;
      s3 += uvg[128 + c] * o;
    }
    ubuf2[b * 1600 + t * 25 + l] = s2;
    ubuf3[b * 1600 + t * 25 + l] = s3;
  }

  // phase 5: P = otb @ FA
  short8 ofr[4];
  #pragma unroll
  for (int it = 0; it < 4; ++it)
    ofr[it] = *(const short8*)(&Xb[(it * 16 + lr) * 40 + lg * 8]);
  f32x4 p_[4][2];
  #pragma unroll
  for (int it = 0; it < 4; ++it)
    #pragma unroll
    for (int jt = 0; jt < 2; ++jt) {
      f32x4 a = (f32x4){0.f, 0.f, 0.f, 0.f};
      p_[it][jt] = __builtin_amdgcn_mfma_f32_16x16x32_bf16(ofr[it], fa_[jt], a, 0, 0, 0);
    }
  #pragma unroll
  for (int it = 0; it < 4; ++it)
    #pragma unroll
    for (int jt = 0; jt < 2; ++jt)
      #pragma unroll
      for (int r = 0; r < 4; ++r) {
        int c = it * 16 + lg * 4 + r;
        int n = jt * 16 + lr;
        if (n < 25) Xb[c * 40 + n] = __float2bfloat16(p_[it][jt][r]);
      }

  // phase 6: Pp2 bf16 coalesced
  for (int idx = l; idx < 1600; idx += 64) {
    int c = idx / 25, n = idx - c * 25;
    Pp2[b * 102400 + t * 1600 + idx] = Xb[c * 40 + n];
  }
}

// ---- pool partials, block = (b, c-channel); Pp2 bf16 [b][t][1600]
__global__ void pool_partial(const __hip_bfloat16* __restrict__ Pp2,
                             const float* __restrict__ Wp1, const float* __restrict__ Wp2,
                             const float* __restrict__ ap1_, const float* __restrict__ ap2_,
                             float* __restrict__ partials) {
  const int b = blockIdx.x >> 6;
  const int c = blockIdx.x & 63;
  const int tid = threadIdx.x;
  const float a1 = ap1_[0], a2 = ap2_[0];
  __shared__ float pg1[1600];
  __shared__ float pg2[1600];
  __shared__ float wct[64][36];
  for (int idx = tid; idx < 1600; idx += 256) {
    int t = idx / 25, n = idx - t * 25;
    float v = __bfloat162float(Pp2[b * 102400 + t * 1600 + c * 25 + n]);
    pg1[idx] = v >= 0.f ? v : a1 * v;
    pg2[idx] = v >= 0.f ? v : a2 * v;
  }
  for (int idx = tid; idx < 19 * 64; idx += 256) {
    int kl = idx & 63, r = idx >> 6;
    wct[kl][r] = Wp1[r * 4096 + (c << 6) + kl];
  }
  for (int idx = tid; idx < 15 * 64; idx += 256) {
    int kl = idx & 63, r = idx >> 6;
    wct[kl][20 + r] = Wp2[r * 4096 + (c << 6) + kl];
  }
  __syncthreads();
  if (tid < 225) {
    const int j = tid / 9;
    const int g = tid - j * 9;
    const bool br1 = (g < 5);
    const int r0 = br1 ? g * 4 : 20 + (g - 5) * 4;
    const float* pgc = br1 ? pg1 : pg2;
    float acc0 = 0.f, acc1 = 0.f, acc2 = 0.f, acc3 = 0.f;
    #pragma unroll 4
    for (int kl = 0; kl < 64; ++kl) {
      int off = kl * 25 + j;
      float p = pgc[(off & 63) * 25 + (off >> 6)];
      const float4 wv = *(const float4*)&wct[kl][r0];
      acc0 += p * wv.x; acc1 += p * wv.y; acc2 += p * wv.z; acc3 += p * wv.w;
    }
    const int base = (b * 64 + c) * 850;
    if (br1) {
      const int m = base + j * 19 + r0;
      partials[m] = acc0; partials[m + 1] = acc1; partials[m + 2] = acc2;
      if (g != 4) partials[m + 3] = acc3;
    } else {
      const int m = base + 475 + j * 15 + (r0 - 20);
      partials[m] = acc0; partials[m + 1] = acc1; partials[m + 2] = acc2;
      if (g != 8) partials[m + 3] = acc3;
    }
  }
}

// ---- reduce partials over 64 channel-chunks + per-branch softmax
__global__ void pool_reduce(const float* __restrict__ partials,
                            float* __restrict__ F19, float* __restrict__ F15) {
  const int b = blockIdx.x;
  const int tid = threadIdx.x;
  __shared__ float lg[850];
  for (int m = tid; m < 850; m += 256) {
    float s = 0.f;
    for (int ch = 0; ch < 64; ++ch) s += partials[(b * 64 + ch) * 850 + m];
    lg[m] = s;
  }
  __syncthreads();
  if (tid < 25) {
    const float* row = lg + tid * 19;
    float mx = -1e30f;
    for (int r = 0; r < 19; ++r) mx = fmaxf(mx, row[r]);
    float sum = 0.f;
    for (int r = 0; r < 19; ++r) sum += __expf(row[r] - mx);
    float inv = 1.f / sum;
    for (int r = 0; r < 19; ++r)
      F19[(b * 25 + tid) * 19 + r] = __expf(row[r] - mx) * inv;
  } else if (tid >= 32 && tid < 57) {
    const int j = tid - 32;
    const float* row = lg + 475 + j * 15;
    float mx = -1e30f;
    for (int r = 0; r < 15; ++r) mx = fmaxf(mx, row[r]);
    float sum = 0.f;
    for (int r = 0; r < 15; ++r) sum += __expf(row[r] - mx);
    float inv = 1.f / sum;
    for (int r = 0; r < 15; ++r)
      F15[(b * 25 + j) * 15 + r] = __expf(row[r] - mx) * inv;
  }
}

// ---- fused x2 + ldnet + attention + Z via MFMA: one wave per (b,t), NO BARRIERS.
// Xb is NOT pre-zeroed: phase-1 scatter fully initializes rows 0..63 x cols 0..31
// (gated r<M -> 0); cols 32..39 are never read.
template<int M>
__global__ __launch_bounds__(256) void ldnet_restore_mfma(
    const __hip_bfloat16* __restrict__ HbTA, const float* __restrict__ F3g,
    const float* __restrict__ A,
    const float* __restrict__ uub, const float* __restrict__ wv,
    const float* __restrict__ cuv, const float* __restrict__ Ck,
    __hip_bfloat16* __restrict__ ZH, int cioff) {
  const int b = blockIdx.x >> 4;
  const int t0 = (blockIdx.x & 15) << 2;
  const int tid = threadIdx.x;
  const int w = tid >> 6;
  const int l = tid & 63;
  const int t = t0 + w;
  const int lr = l & 15, lg = l >> 4;

  __shared__ __hip_bfloat16 XbS[4][64 * 40];   // X2 -> ot -> Zt overlay
  __shared__ __hip_bfloat16 FBS[4][32 * 40];   // FB[r][n] = F3[n][r]
  __shared__ __hip_bfloat16 FTS[4][32 * 40];   // FT[m][n] = FA[n][m]
  __shared__ __hip_bfloat16 ATS[4][32 * 40];   // AT[n][m] = att[n][m]
  __shared__ float scS[4][512];                // gram scores (stride 26)
  __shared__ float vvS[4][32];
  __hip_bfloat16* Xb = XbS[w];
  __hip_bfloat16* FB = FBS[w];
  __hip_bfloat16* FT = FTS[w];
  __hip_bfloat16* AT = ATS[w];
  float* scf = scS[w];
  float* vv = vvS[w];

  typedef union { short8 v; ushort u[8]; } frag_u;
  const ushort* Hu = (const ushort*)HbTA;

  // phase 0: zero FB/FT/AT (B-operand pads must be 0)
  {
    uint32_t* z1 = (uint32_t*)FB;
    uint32_t* z2 = (uint32_t*)FT;
    uint32_t* z3 = (uint32_t*)AT;
    for (int i = l; i < 640; i += 64) { z1[i] = 0u; z2[i] = 0u; z3[i] = 0u; }
  }
  // phase 0a: FB[r*40+n] = bf16(F3[b][n][r])
  for (int idx = l; idx < M * 25; idx += 64) {
    int r = idx / 25, n = idx - r * 25;
    FB[r * 40 + n] = __float2bfloat16(F3g[(b * 25 + n) * M + r]);
  }

  // phase 1: X2 = out1 @ F3. A-frags from global HbTA (gated), B from FB.
  frag_u af0[4];
  #pragma unroll
  for (int it = 0; it < 4; ++it) {
    const int c = it * 16 + lr;
    #pragma unroll
    for (int jj = 0; jj < 8; ++jj) {
      int n = lg * 8 + jj;
      af0[it].u[jj] = (n < 25)
          ? Hu[(size_t)(b * 1600 + t * 25 + n) * 128 + 64 + c] : (ushort)0;
    }
  }
  short8 bf0[2];
  bf0[0] = *(const short8*)(&FB[lr * 40 + lg * 8]);
  bf0[1] = *(const short8*)(&FB[(16 + lr) * 40 + lg * 8]);
  f32x4 x2a[4][2];
  #pragma unroll
  for (int it = 0; it < 4; ++it)
    #pragma unroll
    for (int jt = 0; jt < 2; ++jt) {
      f32x4 a = (f32x4){0.f, 0.f, 0.f, 0.f};
      x2a[it][jt] = __builtin_amdgcn_mfma_f32_16x16x32_bf16(af0[it].v, bf0[jt], a, 0, 0, 0);
    }
  #pragma unroll
  for (int it = 0; it < 4; ++it)
    #pragma unroll
    for (int jt = 0; jt < 2; ++jt)
      #pragma unroll
      for (int rr = 0; rr < 4; ++rr) {
        int c = it * 16 + lg * 4 + rr;
        int r = jt * 16 + lr;
        float v = (r < M) ? x2a[it][jt][rr] : 0.f;
        Xb[c * 40 + r] = __float2bfloat16(v);
      }

  // phase 2: gram(X2) frags from LDS + 8 MFMA -> scores scf[i*26+j]
  frag_u yf[2][2];
  #pragma unroll
  for (int it = 0; it < 2; ++it) {
    const int n = it * 16 + lr;
    #pragma unroll
    for (int ks = 0; ks < 2; ++ks)
      #pragma unroll
      for (int j = 0; j < 8; ++j)
        yf[it][ks].u[j] = *(const ushort*)&Xb[(ks * 32 + lg * 8 + j) * 40 + n];
  }
  f32x4 accg[2][2];
  #pragma unroll
  for (int it = 0; it < 2; ++it)
    #pragma unroll
    for (int jt = 0; jt < 2; ++jt) {
      f32x4 a = (f32x4){0.f, 0.f, 0.f, 0.f};
      a = __builtin_amdgcn_mfma_f32_16x16x32_bf16(yf[it][0].v, yf[jt][0].v, a, 0, 0, 0);
      a = __builtin_amdgcn_mfma_f32_16x16x32_bf16(yf[it][1].v, yf[jt][1].v, a, 0, 0, 0);
      accg[it][jt] = a;
    }
  #pragma unroll
  for (int it = 0; it < 2; ++it)
    #pragma unroll
    for (int jt = 0; jt < 2; ++jt)
      #pragma unroll
      for (int r = 0; r < 4; ++r) {
        int i = it * 16 + lg * 4 + r;
        int j = jt * 16 + lr;
        if (i < M && j < M) scf[i * 26 + j] = accg[it][jt][r];
      }

  // phase 3: softmax rows (lanes 0..M-1) -> FT[m*40+n]
  if (l < M) {
    const int n = l;
    float f[M];
    float mx = -1e30f;
    #pragma unroll
    for (int m = 0; m < M; ++m) { f[m] = scf[n * 26 + m] * 0.125f; mx = fmaxf(mx, f[m]); }
    float sum = 0.f;
    #pragma unroll
    for (int m = 0; m < M; ++m) { f[m] = __expf(f[m] - mx); sum += f[m]; }
    float inv = 1.f / sum;
    #pragma unroll
    for (int m = 0; m < M; ++m) {
      float v = f[m] * inv + A[n * M + m];
      FT[m * 40 + n] = __float2bfloat16(v);
    }
  }

  // phase 4: ot = X2 @ FA (K=32), scatter into Xb (cols >= M -> 0)
  short8 xf[4], ff[2];
  #pragma unroll
  for (int it = 0; it < 4; ++it)
    xf[it] = *(const short8*)(&Xb[(it * 16 + lr) * 40 + lg * 8]);
  #pragma unroll
  for (int jt = 0; jt < 2; ++jt)
    ff[jt] = *(const short8*)(&FT[(jt * 16 + lr) * 40 + lg * 8]);
  f32x4 acco[4][2];
  #pragma unroll
  for (int it = 0; it < 4; ++it)
    #pragma unroll
    for (int jt = 0; jt < 2; ++jt) {
      f32x4 a = (f32x4){0.f, 0.f, 0.f, 0.f};
      acco[it][jt] = __builtin_amdgcn_mfma_f32_16x16x32_bf16(xf[it], ff[jt], a, 0, 0, 0);
    }
  #pragma unroll
  for (int it = 0; it < 4; ++it)
    #pragma unroll
    for (int jt = 0; jt < 2; ++jt)
      #pragma unroll
      for (int r = 0; r < 4; ++r) {
        int c = it * 16 + lg * 4 + r;
        int m = jt * 16 + lr;
        float v = (m < M) ? acco[it][jt][r] : 0.f;
        Xb[c * 40 + m] = __float2bfloat16(v);
      }

  // phase 5: vv[m] = cv + sum_c wv[c]*ot[c][m]  (lanes 0..M-1)
  if (l < M) {
    float s = cuv[1];
    #pragma unroll 8
    for (int c = 0; c < 64; ++c)
      s += wv[c] * __bfloat162float(Xb[c * 40 + l]);
    vv[l] = s;
  }

  // phase 6: att (lanes 0..24) -> AT[n*40+m]
  if (l < 25) {
    const int n = l;
    const float uu = uub[b * 1600 + t * 25 + n];
    float f[M];
    float mx = -1e30f;
    #pragma unroll
    for (int m = 0; m < M; ++m) {
      float v = uu + vv[m];
      v = v >= 0.f ? v : 0.2f * v;
      f[m] = v;
      mx = fmaxf(mx, v);
    }
    float sum = 0.f;
    #pragma unroll
    for (int m = 0; m < M; ++m) { f[m] = __expf(f[m] - mx); sum += f[m]; }
    float inv = 1.f / sum;
    #pragma unroll
    for (int m = 0; m < M; ++m)
      AT[n * 40 + m] = __float2bfloat16(f[m] * inv + Ck[n * M + m]);
  }

  // phase 7: Z = ot @ att^T (K=32): D[i=c][j=n] -> Zt (staged in dead Xb)
  short8 of[4], af[2];
  #pragma unroll
  for (int it = 0; it < 4; ++it)
    of[it] = *(const short8*)(&Xb[(it * 16 + lr) * 40 + lg * 8]);
  #pragma unroll
  for (int jt = 0; jt < 2; ++jt)
    af[jt] = *(const short8*)(&AT[(jt * 16 + lr) * 40 + lg * 8]);
  f32x4 accz[4][2];
  #pragma unroll
  for (int it = 0; it < 4; ++it)
    #pragma unroll
    for (int jt = 0; jt < 2; ++jt) {
      f32x4 a = (f32x4){0.f, 0.f, 0.f, 0.f};
      accz[it][jt] = __builtin_amdgcn_mfma_f32_16x16x32_bf16(of[it], af[jt], a, 0, 0, 0);
    }
  __hip_bfloat16* Zt = Xb;   // Xb dead after `of` reads (accz depends on of)
  #pragma unroll
  for (int it = 0; it < 4; ++it)
    #pragma unroll
    for (int jt = 0; jt < 2; ++jt)
      #pragma unroll
      for (int r = 0; r < 4; ++r) {
        int c = it * 16 + lg * 4 + r;
        int n = jt * 16 + lr;
        if (n < 25) Zt[n * 66 + c] = __float2bfloat16(accz[it][jt][r]);
      }

  // phase 8: coalesced ZH write (lane = c, 128B per row)
  for (int n = 0; n < 25; ++n)
    ZH[(size_t)(b * 1600 + t * 25 + n) * 128 + cioff + l] = Zt[n * 66 + l];
}

// ---- restore GEMM via MFMA, wave-private 32-col slices, IN PLACE, no LDS/barriers.
__global__ __launch_bounds__(256) void restore_gemm_mfma(
    __hip_bfloat16* __restrict__ ZH, const __hip_bfloat16* __restrict__ WgT,
    const float* __restrict__ bg2, const float* __restrict__ bg3,
    const float* __restrict__ sconst) {
  const int tid = threadIdx.x;
  const int wv = tid >> 6, l = tid & 63;
  const int lr = l & 15, lg = l >> 4;
  const size_t col0 = ((size_t)blockIdx.x * 4 + wv) * 32;
  const ushort* Zg = (const ushort*)ZH;
  const ushort* Wu = (const ushort*)WgT;

  short8 afr[2][2][2];
  #pragma unroll
  for (int mt = 0; mt < 2; ++mt)
    #pragma unroll
    for (int br = 0; br < 2; ++br)
      #pragma unroll
      for (int ks = 0; ks < 2; ++ks)
        afr[mt][br][ks] = *(const short8*)(
            Zg + (col0 + mt * 16 + lr) * 128 + br * 64 + ks * 32 + lg * 8);

  f32x4 acc[2][8];
  #pragma unroll
  for (int nt = 0; nt < 8; ++nt) {
    const int br = nt >> 2;
    const int g = nt * 16 + lr;
    short8 b0 = *(const short8*)(Wu + g * 64 + lg * 8);
    short8 b1 = *(const short8*)(Wu + g * 64 + 32 + lg * 8);
    #pragma unroll
    for (int mt = 0; mt < 2; ++mt) {
      f32x4 a = (f32x4){0.f, 0.f, 0.f, 0.f};
      a = __builtin_amdgcn_mfma_f32_16x16x32_bf16(afr[mt][br][0], b0, a, 0, 0, 0);
      a = __builtin_amdgcn_mfma_f32_16x16x32_bf16(afr[mt][br][1], b1, a, 0, 0, 0);
      acc[mt][nt] = a;
    }
  }

  #pragma unroll
  for (int mt = 0; mt < 2; ++mt)
    #pragma unroll
    for (int r = 0; r < 4; ++r) {
      const size_t col = col0 + mt * 16 + lg * 4 + r;
      const int n = (int)(col % 25);
      const float s2v = sconst[n], s3v = sconst[25 + n];
      ushort* zp = (ushort*)ZH + col * 128;
      #pragma unroll
      for (int nt = 0; nt < 8; ++nt) {
        const int g = nt * 16 + lr;
        const float bo = (nt < 4) ? bg2[g] : bg3[g - 64];
        const float s = (nt < 4) ? s2v : s3v;
        float v = fmaxf((acc[mt][nt][r] + bo * s) * BN_SCALE_F, 0.f);
        __hip_bfloat16 h = __float2bfloat16(v);
        zp[g] = *(ushort*)&h;
      }
    }
}

// ---- final conv via MFMA, 8 waves/block (512 thr): wave = 80 cols x 32 o.
__global__ __launch_bounds__(512) void conv_mfma(
    const __hip_bfloat16* __restrict__ HbTA, const __hip_bfloat16* __restrict__ HbTB,
    const __hip_bfloat16* __restrict__ Wb, const float* __restrict__ x,
    const float* __restrict__ btcn, const float* __restrict__ aout_,
    float* __restrict__ out) {
  const int b = blockIdx.x / 5;
  const int col0 = (blockIdx.x % 5) * 320;
  const int tid = threadIdx.x;
  const int wave = tid >> 6, l = tid & 63;
  const int wcol = wave & 3, who = wave >> 2;
  const int lr = l & 15, lg = l >> 4;

  __shared__ __hip_bfloat16 Hl[384 * 40];
  __shared__ __hip_bfloat16 Wl[3 * 64 * 40];

  f32x4 acc[5][2];
  #pragma unroll
  for (int mt = 0; mt < 5; ++mt)
    #pragma unroll
    for (int nt = 0; nt < 2; ++nt) acc[mt][nt] = (f32x4){0.f, 0.f, 0.f, 0.f};

  const int base_a = (wcol * 80 + lr + 7) * 40 + lg * 8;
  const int base_b = (who * 32 + lr) * 40 + lg * 8;

  for (int ch = 0; ch < 8; ++ch) {
    const __hip_bfloat16* Ht = (ch < 4) ? HbTA : HbTB;
    const int ci0 = (ch & 3) * 32;
    const int wci0 = ch * 32;
    __syncthreads();
    #pragma unroll
    for (int it = 0; it < 3; ++it) {
      int idx = it * 512 + tid;
      int colr = idx >> 2, seg = idx & 3;
      int gcol = col0 - 32 + colr;
      uint4 v = {0u, 0u, 0u, 0u};
      if (gcol >= 0 && gcol < 1600)
        v = *(const uint4*)(Ht + ((size_t)(b * 1600 + gcol) * 128 + ci0 + seg * 8));
      *(uint4*)(&Hl[colr * 40 + seg * 8]) = v;
    }
    for (int idx = tid; idx < 768; idx += 512) {
      int o = (idx >> 2) & 63, kt = idx >> 8, seg = idx & 3;
      uint4 v = *(const uint4*)(Wb + ((kt * 64 + o) * 256 + wci0 + seg * 8));
      *(uint4*)(&Wl[(kt * 64 + o) * 40 + seg * 8]) = v;
    }
    __syncthreads();
    #pragma unroll
    for (int kt = 0; kt < 3; ++kt) {
      short8 af[5], bf[2];
      const int ab = base_a + kt * 1000;
      const int bb = base_b + kt * 2560;
      #pragma unroll
      for (int mt = 0; mt < 5; ++mt) af[mt] = *(const short8*)(&Hl[ab + mt * 640]);
      #pragma unroll
      for (int nt = 0; nt < 2; ++nt) bf[nt] = *(const short8*)(&Wl[bb + nt * 640]);
      #pragma unroll
      for (int mt = 0; mt < 5; ++mt)
        #pragma unroll
        for (int nt = 0; nt < 2; ++nt)
          acc[mt][nt] = __builtin_amdgcn_mfma_f32_16x16x32_bf16(af[mt], bf[nt],
                                                                acc[mt][nt], 0, 0, 0);
    }
  }

  const float aout = aout_[0];
  const int colbase = col0 + wcol * 80 + lg * 4;
  #pragma unroll
  for (int nt = 0; nt < 2; ++nt) {
    const int o = who * 32 + nt * 16 + lr;
    const float bo = btcn[o];
    const float* xr = x + ((size_t)b * 64 + o) * 1600 + colbase;
    float* op = out + ((size_t)b * 64 + o) * 1600 + colbase;
    #pragma unroll
    for (int mt = 0; mt < 5; ++mt) {
      float4 xv = *(const float4*)(xr + mt * 16);
      f32x4 a4 = acc[mt][nt];
      float4 res;
      float v0 = (a4[0] + bo) * BN_SCALE_F + xv.x;
      float v1 = (a4[1] + bo) * BN_SCALE_F + xv.y;
      float v2 = (a4[2] + bo) * BN_SCALE_F + xv.z;
      float v3 = (a4[3] + bo) * BN_SCALE_F + xv.w;
      res.x = v0 >= 0.f ? v0 : aout * v0;
      res.y = v1 >= 0.f ? v1 : aout * v1;
      res.z = v2 >= 0.f ? v2 : aout * v2;
      res.w = v3 >= 0.f ? v3 : aout * v3;
      *(float4*)(op + mt * 16) = res;
    }
  }
}

extern "C" void kernel_launch(void* const* d_in, const int* in_sizes, int n_in,
                              void* d_out, int out_size, void* d_ws, size_t ws_size,
                              hipStream_t stream) {
  const float* x     = (const float*)d_in[0];
  const float* A1    = (const float*)d_in[1];
  const float* A2    = (const float*)d_in[2];
  const float* A3    = (const float*)d_in[3];
  const float* Wp1   = (const float*)d_in[4];
  const float* ap1   = (const float*)d_in[5];
  const float* Wp2   = (const float*)d_in[6];
  const float* ap2   = (const float*)d_in[7];
  const float* Wg2   = (const float*)d_in[8];
  const float* bg2   = (const float*)d_in[9];
  const float* Wt2   = (const float*)d_in[10];
  const float* bt2   = (const float*)d_in[11];
  const float* Wph2  = (const float*)d_in[12];
  const float* bph2  = (const float*)d_in[13];
  const float* wcat2 = (const float*)d_in[14];
  const float* Ck2   = (const float*)d_in[15];
  const float* Wg3   = (const float*)d_in[16];
  const float* bg3   = (const float*)d_in[17];
  const float* Wt3   = (const float*)d_in[18];
  const float* bt3   = (const float*)d_in[19];
  const float* Wph3  = (const float*)d_in[20];
  const float* bph3  = (const float*)d_in[21];
  const float* wcat3 = (const float*)d_in[22];
  const float* Ck3   = (const float*)d_in[23];
  const float* Wtcn  = (const float*)d_in[24];
  const float* btcn  = (const float*)d_in[25];
  const float* aout  = (const float*)d_in[26];
  float* out = (float*)d_out;
  float* ws  = (float*)d_ws;

  __hip_bfloat16* ZH   = (__hip_bfloat16*)(ws + 6553600);   // Pp2 bf16 earlier life
  __hip_bfloat16* HbTA = (__hip_bfloat16*)(ws + 13107200);
  float* x2b  = ws + 19660800;
  float* preb = ws + 24641536;
  float* F19  = ws + 29622272;
  float* F15  = ws + 29652672;
  float* uv   = ws + 29676672;
  float* partials = x2b;
  __hip_bfloat16* Wb   = (__hip_bfloat16*)preb;             // 49,152 bf16
  __hip_bfloat16* WgT  = (__hip_bfloat16*)(preb + 24576);   // 8,192 bf16
  float* sconst        = preb + 28672;                      // 50 f
  float* ubuf2         = preb + 32768;                      // 102,400 f
  float* ubuf3         = preb + 139264;                     // 102,400 f

  prep_all<<<225, 256, 0, stream>>>(Wt2, bt2, Wph2, bph2, wcat2,
                                    Wt3, bt3, Wph3, bph3, wcat3,
                                    Ck2, Ck3, Wg2, Wg3, Wtcn,
                                    uv, sconst, WgT, Wb);
  ldnet1_mfma<<<1024, 256, 0, stream>>>(x, A1, uv, ZH /*Pp2*/, HbTA, ubuf2, ubuf3);

  // both pools in one pass over Pp2 bf16 (block per (b, channel))
  pool_partial<<<4096, 256, 0, stream>>>(ZH, Wp1, Wp2, ap1, ap2, partials);
  pool_reduce<<<64, 256, 0, stream>>>(partials, F19, F15);

  // branch 2 (R=19): fused x2+ldnet+attention+Z -> ZH ch 0..63 (Pp2 dead after pools)
  ldnet_restore_mfma<19><<<1024, 256, 0, stream>>>(HbTA, F19, A2, ubuf2,
                                                   uv + 64, uv + 256, Ck2, ZH, 0);

  // branch 3 (R=15): Z3 -> ZH ch 64..127
  ldnet_restore_mfma<15><<<1024, 256, 0, stream>>>(HbTA, F15, A3, ubuf3,
                                                   uv + 192, uv + 258, Ck3, ZH, 64);

  // shared Wg GEMM via MFMA, in place: ZH rows become HbTB rows (xcd2|xcd3 bf16)
  restore_gemm_mfma<<<800, 256, 0, stream>>>(ZH, WgT, bg2, bg3, sconst);

  // final conv via MFMA + bias + BN + residual + PReLU (8-wave blocks)
  conv_mfma<<<320, 512, 0, stream>>>(HbTA, ZH, Wb, x, btcn, aout, out);
}

// Round 17
// 154.955 us; speedup vs baseline: 8.9800x; 1.0557x over previous
//
#include <hip/hip_runtime.h>
#include <hip/hip_bf16.h>
#include <math.h>

// ---------------------------------------------------------------------------
// LDSTNet forward. B=64, C=64, T=64, N=25, Ci=32. Pools: R1=19, R2=15.
//
// Workspace layout (floats):
//   (free)  @ 0          : 6,553,600
//   R1      @ 6,553,600  : 6,553,600  Pp2 bf16 [b][t][1600] -> ZH/HbTB bf16 [col][128]
//   R2      @ 13,107,200 : 6,553,600  HbT_A bf16 [b][1600][128] (0..63=x, 64..127=out1)
//   x2buf   @ 19,660,800 : 4,980,736  partials (64x64x850)
//   preb    @ 24,641,536 : 4,980,736  Wb | WgT | sconst | ubuf2 | ubuf3
//   F19     @ 29,622,272 : 30,400
//   F15     @ 29,652,672 : 24,000
//   uvbuf   @ 29,676,672 : 320
// ---------------------------------------------------------------------------

#define BN_SCALE_F 0.9999950000374997f

typedef __attribute__((ext_vector_type(8))) short short8;
typedef __attribute__((ext_vector_type(4))) float f32x4;

// ---- merged prep: block 0 = uv/sconst; blocks 1..32 = WgT; blocks 33..224 = Wb
__global__ void prep_all(const float* __restrict__ Wt2, const float* __restrict__ bt2,
                         const float* __restrict__ Wph2, const float* __restrict__ bph2,
                         const float* __restrict__ wcat2,
                         const float* __restrict__ Wt3, const float* __restrict__ bt3,
                         const float* __restrict__ Wph3, const float* __restrict__ bph3,
                         const float* __restrict__ wcat3,
                         const float* __restrict__ Ck2, const float* __restrict__ Ck3,
                         const float* __restrict__ Wg2, const float* __restrict__ Wg3,
                         const float* __restrict__ Wtcn,
                         float* __restrict__ uv, float* __restrict__ sconst,
                         __hip_bfloat16* __restrict__ WgT,
                         __hip_bfloat16* __restrict__ Wb) {
  const int bid = blockIdx.x;
  const int tid = threadIdx.x;
  if (bid == 0) {
    int c = tid;
    if (c < 64) {
      float s1 = 0.f, s2 = 0.f, s3 = 0.f, s4 = 0.f;
      for (int i = 0; i < 32; ++i) {
        s1 += wcat2[i]      * Wt2[i * 64 + c];
        s2 += wcat2[32 + i] * Wph2[i * 64 + c];
        s3 += wcat3[i]      * Wt3[i * 64 + c];
        s4 += wcat3[32 + i] * Wph3[i * 64 + c];
      }
      uv[c] = s1; uv[64 + c] = s2; uv[128 + c] = s3; uv[192 + c] = s4;
    }
    if (c == 0) {
      float c1 = 0.f, c2 = 0.f, c3 = 0.f, c4 = 0.f;
      for (int i = 0; i < 32; ++i) {
        c1 += wcat2[i] * bt2[i];       c2 += wcat2[32 + i] * bph2[i];
        c3 += wcat3[i] * bt3[i];       c4 += wcat3[32 + i] * bph3[i];
      }
      uv[256] = c1; uv[257] = c2; uv[258] = c3; uv[259] = c4;
    }
    if (c >= 64 && c < 89) {
      int n = c - 64;
      float s2 = 1.f, s3 = 1.f;
      for (int m = 0; m < 19; ++m) s2 += Ck2[n * 19 + m];
      for (int m = 0; m < 15; ++m) s3 += Ck3[n * 15 + m];
      sconst[n] = s2; sconst[25 + n] = s3;
    }
  } else if (bid < 33) {
    int idx = (bid - 1) * 256 + tid;
    int g = idx >> 6, c = idx & 63;
    float v = (g < 64) ? Wg2[g * 64 + c] : Wg3[(g - 64) * 64 + c];
    WgT[idx] = __float2bfloat16(v);
  } else {
    int idx = (bid - 33) * 256 + tid;
    int ci = idx & 255;
    int rest = idx >> 8;
    int o = rest & 63, kt = rest >> 6;
    Wb[idx] = __float2bfloat16(Wtcn[(o * 256 + ci) * 3 + kt]);
  }
}

// ---- ldnet1 via MFMA: one wave per (b,t), 4 waves/block, NO BARRIERS.
__global__ __launch_bounds__(256, 4) void ldnet1_mfma(
    const float* __restrict__ x, const float* __restrict__ A,
    const float* __restrict__ uvg,
    __hip_bfloat16* __restrict__ Pp2,
    __hip_bfloat16* __restrict__ HbTA,
    float* __restrict__ ubuf2, float* __restrict__ ubuf3) {
  const int b = blockIdx.x >> 4;
  const int t0 = (blockIdx.x & 15) << 2;
  const int tid = threadIdx.x;
  const int w = tid >> 6;
  const int l = tid & 63;
  const int t = t0 + w;
  const int lr = l & 15, lg = l >> 4;

  __shared__ __hip_bfloat16 XbS[4][64 * 40];   // x-tile -> otb -> P; cols 25..31 zero
  __shared__ __hip_bfloat16 FTS[4][32 * 40];   // FT[m][n] = FA[n][m]
  __shared__ float scS[4][25 * 25];            // gram scores only
  __hip_bfloat16* Xb = XbS[w];
  __hip_bfloat16* FT = FTS[w];
  float* scf = scS[w];

  const float* xp = x + b * 102400 + t * 25;   // + c*1600 + n
  typedef union { short8 v; ushort u[8]; } frag_u;

  // phase 0: zero FT; stage x-tile bf16 into Xb cols 0..31 (25..31 = 0).
  {
    uint32_t* z2 = (uint32_t*)FT;
    for (int i = l; i < 640; i += 64) z2[i] = 0u;
  }
  for (int idx = l; idx < 2048; idx += 64) {
    int c = idx >> 5, n = idx & 31;
    float v = (n < 25) ? xp[c * 1600 + n] : 0.f;
    Xb[c * 40 + n] = __float2bfloat16(v);
  }

  // phase 0b: HbTA x-part from LDS (lane = c)
  for (int n = 0; n < 25; ++n)
    HbTA[(size_t)(b * 1600 + t * 25 + n) * 128 + l] = Xb[l * 40 + n];

  // phase 1: gram frags from LDS + 8 MFMA -> scores
  frag_u yf[2][2];
  #pragma unroll
  for (int it = 0; it < 2; ++it) {
    const int n = it * 16 + lr;
    #pragma unroll
    for (int ks = 0; ks < 2; ++ks)
      #pragma unroll
      for (int j = 0; j < 8; ++j)
        yf[it][ks].u[j] = *(const ushort*)&Xb[(ks * 32 + lg * 8 + j) * 40 + n];
  }
  f32x4 accg[2][2];
  #pragma unroll
  for (int it = 0; it < 2; ++it)
    #pragma unroll
    for (int jt = 0; jt < 2; ++jt) {
      f32x4 a = (f32x4){0.f, 0.f, 0.f, 0.f};
      a = __builtin_amdgcn_mfma_f32_16x16x32_bf16(yf[it][0].v, yf[jt][0].v, a, 0, 0, 0);
      a = __builtin_amdgcn_mfma_f32_16x16x32_bf16(yf[it][1].v, yf[jt][1].v, a, 0, 0, 0);
      accg[it][jt] = a;
    }
  #pragma unroll
  for (int it = 0; it < 2; ++it)
    #pragma unroll
    for (int jt = 0; jt < 2; ++jt)
      #pragma unroll
      for (int r = 0; r < 4; ++r) {
        int i = it * 16 + lg * 4 + r;
        int j = jt * 16 + lr;
        if (i < 25 && j < 25) scf[i * 25 + j] = accg[it][jt][r];
      }

  // phase 2: softmax rows (lanes 0..24) -> FT[m*40+n] = FA[n][m]
  if (l < 25) {
    const int n = l;
    float f[25];
    float mx = -1e30f;
    #pragma unroll
    for (int m = 0; m < 25; ++m) { f[m] = scf[n * 25 + m] * 0.125f; mx = fmaxf(mx, f[m]); }
    float sum = 0.f;
    #pragma unroll
    for (int m = 0; m < 25; ++m) { f[m] = __expf(f[m] - mx); sum += f[m]; }
    float inv = 1.f / sum;
    #pragma unroll
    for (int m = 0; m < 25; ++m) {
      float v = f[m] * inv + A[n * 25 + m];
      FT[m * 40 + n] = __float2bfloat16(v);
    }
  }

  // phase 3: Q = out1^T. A = FT rows m, B = X rows c (short8 from LDS).
  short8 fa_[2];
  fa_[0] = *(const short8*)(&FT[lr * 40 + lg * 8]);
  fa_[1] = *(const short8*)(&FT[(16 + lr) * 40 + lg * 8]);
  short8 xb2v[4];
  #pragma unroll
  for (int jt = 0; jt < 4; ++jt)
    xb2v[jt] = *(const short8*)(&Xb[(jt * 16 + lr) * 40 + lg * 8]);
  f32x4 q_[2][4];
  #pragma unroll
  for (int it = 0; it < 2; ++it)
    #pragma unroll
    for (int jt = 0; jt < 4; ++jt) {
      f32x4 a = (f32x4){0.f, 0.f, 0.f, 0.f};
      q_[it][jt] = __builtin_amdgcn_mfma_f32_16x16x32_bf16(fa_[it], xb2v[jt], a, 0, 0, 0);
    }
  #pragma unroll
  for (int it = 0; it < 2; ++it)
    #pragma unroll
    for (int jt = 0; jt < 4; ++jt)
      #pragma unroll
      for (int r = 0; r < 4; ++r) {
        int m = it * 16 + lg * 4 + r;
        int c = jt * 16 + lr;
        if (m < 25) {
          __hip_bfloat16 h = __float2bfloat16(q_[it][jt][r]);
          Xb[c * 40 + m] = h;
          HbTA[(size_t)(b * 1600 + t * 25 + m) * 128 + 64 + c] = h;
        }
      }

  // phase 4: uu2/uu3 from otb (lanes 0..24)
  if (l < 25) {
    float s2 = uvg[256], s3 = uvg[258];
    #pragma unroll 8
    for (int c = 0; c < 64; ++c) {
      float o = __bfloat162float(Xb[c * 40 + l]);
      s2 += uvg[c] * o;
      s3 += uvg[128 + c] * o;
    }
    ubuf2[b * 1600 + t * 25 + l] = s2;
    ubuf3[b * 1600 + t * 25 + l] = s3;
  }

  // phase 5: P = otb @ FA
  short8 ofr[4];
  #pragma unroll
  for (int it = 0; it < 4; ++it)
    ofr[it] = *(const short8*)(&Xb[(it * 16 + lr) * 40 + lg * 8]);
  f32x4 p_[4][2];
  #pragma unroll
  for (int it = 0; it < 4; ++it)
    #pragma unroll
    for (int jt = 0; jt < 2; ++jt) {
      f32x4 a = (f32x4){0.f, 0.f, 0.f, 0.f};
      p_[it][jt] = __builtin_amdgcn_mfma_f32_16x16x32_bf16(ofr[it], fa_[jt], a, 0, 0, 0);
    }
  #pragma unroll
  for (int it = 0; it < 4; ++it)
    #pragma unroll
    for (int jt = 0; jt < 2; ++jt)
      #pragma unroll
      for (int r = 0; r < 4; ++r) {
        int c = it * 16 + lg * 4 + r;
        int n = jt * 16 + lr;
        if (n < 25) Xb[c * 40 + n] = __float2bfloat16(p_[it][jt][r]);
      }

  // phase 6: Pp2 bf16 coalesced
  for (int idx = l; idx < 1600; idx += 64) {
    int c = idx / 25, n = idx - c * 25;
    Pp2[b * 102400 + t * 1600 + idx] = Xb[c * 40 + n];
  }
}

// ---- pool partials, block = (b, c-channel); Pp2 bf16 [b][t][1600]
__global__ void pool_partial(const __hip_bfloat16* __restrict__ Pp2,
                             const float* __restrict__ Wp1, const float* __restrict__ Wp2,
                             const float* __restrict__ ap1_, const float* __restrict__ ap2_,
                             float* __restrict__ partials) {
  const int b = blockIdx.x >> 6;
  const int c = blockIdx.x & 63;
  const int tid = threadIdx.x;
  const float a1 = ap1_[0], a2 = ap2_[0];
  __shared__ float pg1[1600];
  __shared__ float pg2[1600];
  __shared__ float wct[64][36];
  for (int idx = tid; idx < 1600; idx += 256) {
    int t = idx / 25, n = idx - t * 25;
    float v = __bfloat162float(Pp2[b * 102400 + t * 1600 + c * 25 + n]);
    pg1[idx] = v >= 0.f ? v : a1 * v;
    pg2[idx] = v >= 0.f ? v : a2 * v;
  }
  for (int idx = tid; idx < 19 * 64; idx += 256) {
    int kl = idx & 63, r = idx >> 6;
    wct[kl][r] = Wp1[r * 4096 + (c << 6) + kl];
  }
  for (int idx = tid; idx < 15 * 64; idx += 256) {
    int kl = idx & 63, r = idx >> 6;
    wct[kl][20 + r] = Wp2[r * 4096 + (c << 6) + kl];
  }
  __syncthreads();
  if (tid < 225) {
    const int j = tid / 9;
    const int g = tid - j * 9;
    const bool br1 = (g < 5);
    const int r0 = br1 ? g * 4 : 20 + (g - 5) * 4;
    const float* pgc = br1 ? pg1 : pg2;
    float acc0 = 0.f, acc1 = 0.f, acc2 = 0.f, acc3 = 0.f;
    #pragma unroll 4
    for (int kl = 0; kl < 64; ++kl) {
      int off = kl * 25 + j;
      float p = pgc[(off & 63) * 25 + (off >> 6)];
      const float4 wv = *(const float4*)&wct[kl][r0];
      acc0 += p * wv.x; acc1 += p * wv.y; acc2 += p * wv.z; acc3 += p * wv.w;
    }
    const int base = (b * 64 + c) * 850;
    if (br1) {
      const int m = base + j * 19 + r0;
      partials[m] = acc0; partials[m + 1] = acc1; partials[m + 2] = acc2;
      if (g != 4) partials[m + 3] = acc3;
    } else {
      const int m = base + 475 + j * 15 + (r0 - 20);
      partials[m] = acc0; partials[m + 1] = acc1; partials[m + 2] = acc2;
      if (g != 8) partials[m + 3] = acc3;
    }
  }
}

// ---- reduce partials over 64 channel-chunks + per-branch softmax
__global__ void pool_reduce(const float* __restrict__ partials,
                            float* __restrict__ F19, float* __restrict__ F15) {
  const int b = blockIdx.x;
  const int tid = threadIdx.x;
  __shared__ float lg[850];
  for (int m = tid; m < 850; m += 256) {
    float s = 0.f;
    for (int ch = 0; ch < 64; ++ch) s += partials[(b * 64 + ch) * 850 + m];
    lg[m] = s;
  }
  __syncthreads();
  if (tid < 25) {
    const float* row = lg + tid * 19;
    float mx = -1e30f;
    for (int r = 0; r < 19; ++r) mx = fmaxf(mx, row[r]);
    float sum = 0.f;
    for (int r = 0; r < 19; ++r) sum += __expf(row[r] - mx);
    float inv = 1.f / sum;
    for (int r = 0; r < 19; ++r)
      F19[(b * 25 + tid) * 19 + r] = __expf(row[r] - mx) * inv;
  } else if (tid >= 32 && tid < 57) {
    const int j = tid - 32;
    const float* row = lg + 475 + j * 15;
    float mx = -1e30f;
    for (int r = 0; r < 15; ++r) mx = fmaxf(mx, row[r]);
    float sum = 0.f;
    for (int r = 0; r < 15; ++r) sum += __expf(row[r] - mx);
    float inv = 1.f / sum;
    for (int r = 0; r < 15; ++r)
      F15[(b * 25 + j) * 15 + r] = __expf(row[r] - mx) * inv;
  }
}

// ---- fused x2 + ldnet + attention + Z body (one wave per (b,t), NO BARRIERS).
// scf overlays FB (FB's last read precedes first scf write; wave-private, in-order DS).
template<int M>
__device__ __forceinline__ void restore_body(
    int bid, const __hip_bfloat16* __restrict__ HbTA, const float* __restrict__ F3g,
    const float* __restrict__ A,
    const float* __restrict__ uub, const float* __restrict__ wv,
    const float* __restrict__ cuv, const float* __restrict__ Ck,
    __hip_bfloat16* __restrict__ ZH, int cioff,
    __hip_bfloat16* Xb, __hip_bfloat16* FB, __hip_bfloat16* FT,
    __hip_bfloat16* AT, float* vv) {
  const int b = bid >> 4;
  const int t0 = (bid & 15) << 2;
  const int tid = threadIdx.x;
  const int w = tid >> 6;
  const int l = tid & 63;
  const int t = t0 + w;
  const int lr = l & 15, lg = l >> 4;
  float* scf = (float*)FB;   // overlay: FB read (phase 1 regs) precedes scf write (phase 2)

  typedef union { short8 v; ushort u[8]; } frag_u;
  const ushort* Hu = (const ushort*)HbTA;

  // phase 0: zero FB/FT/AT (B-operand pads must be 0)
  {
    uint32_t* z1 = (uint32_t*)FB;
    uint32_t* z2 = (uint32_t*)FT;
    uint32_t* z3 = (uint32_t*)AT;
    for (int i = l; i < 640; i += 64) { z1[i] = 0u; z2[i] = 0u; z3[i] = 0u; }
  }
  // phase 0a: FB[r*40+n] = bf16(F3[b][n][r])
  for (int idx = l; idx < M * 25; idx += 64) {
    int r = idx / 25, n = idx - r * 25;
    FB[r * 40 + n] = __float2bfloat16(F3g[(b * 25 + n) * M + r]);
  }

  // phase 1: X2 = out1 @ F3. A-frags from global HbTA (gated), B from FB.
  frag_u af0[4];
  #pragma unroll
  for (int it = 0; it < 4; ++it) {
    const int c = it * 16 + lr;
    #pragma unroll
    for (int jj = 0; jj < 8; ++jj) {
      int n = lg * 8 + jj;
      af0[it].u[jj] = (n < 25)
          ? Hu[(size_t)(b * 1600 + t * 25 + n) * 128 + 64 + c] : (ushort)0;
    }
  }
  short8 bf0[2];
  bf0[0] = *(const short8*)(&FB[lr * 40 + lg * 8]);
  bf0[1] = *(const short8*)(&FB[(16 + lr) * 40 + lg * 8]);
  f32x4 x2a[4][2];
  #pragma unroll
  for (int it = 0; it < 4; ++it)
    #pragma unroll
    for (int jt = 0; jt < 2; ++jt) {
      f32x4 a = (f32x4){0.f, 0.f, 0.f, 0.f};
      x2a[it][jt] = __builtin_amdgcn_mfma_f32_16x16x32_bf16(af0[it].v, bf0[jt], a, 0, 0, 0);
    }
  #pragma unroll
  for (int it = 0; it < 4; ++it)
    #pragma unroll
    for (int jt = 0; jt < 2; ++jt)
      #pragma unroll
      for (int rr = 0; rr < 4; ++rr) {
        int c = it * 16 + lg * 4 + rr;
        int r = jt * 16 + lr;
        float v = (r < M) ? x2a[it][jt][rr] : 0.f;
        Xb[c * 40 + r] = __float2bfloat16(v);
      }

  // phase 2: gram(X2) frags from LDS + 8 MFMA -> scores scf[i*26+j]
  frag_u yf[2][2];
  #pragma unroll
  for (int it = 0; it < 2; ++it) {
    const int n = it * 16 + lr;
    #pragma unroll
    for (int ks = 0; ks < 2; ++ks)
      #pragma unroll
      for (int j = 0; j < 8; ++j)
        yf[it][ks].u[j] = *(const ushort*)&Xb[(ks * 32 + lg * 8 + j) * 40 + n];
  }
  f32x4 accg[2][2];
  #pragma unroll
  for (int it = 0; it < 2; ++it)
    #pragma unroll
    for (int jt = 0; jt < 2; ++jt) {
      f32x4 a = (f32x4){0.f, 0.f, 0.f, 0.f};
      a = __builtin_amdgcn_mfma_f32_16x16x32_bf16(yf[it][0].v, yf[jt][0].v, a, 0, 0, 0);
      a = __builtin_amdgcn_mfma_f32_16x16x32_bf16(yf[it][1].v, yf[jt][1].v, a, 0, 0, 0);
      accg[it][jt] = a;
    }
  #pragma unroll
  for (int it = 0; it < 2; ++it)
    #pragma unroll
    for (int jt = 0; jt < 2; ++jt)
      #pragma unroll
      for (int r = 0; r < 4; ++r) {
        int i = it * 16 + lg * 4 + r;
        int j = jt * 16 + lr;
        if (i < M && j < M) scf[i * 26 + j] = accg[it][jt][r];
      }

  // phase 3: softmax rows (lanes 0..M-1) -> FT[m*40+n]
  if (l < M) {
    const int n = l;
    float f[M];
    float mx = -1e30f;
    #pragma unroll
    for (int m = 0; m < M; ++m) { f[m] = scf[n * 26 + m] * 0.125f; mx = fmaxf(mx, f[m]); }
    float sum = 0.f;
    #pragma unroll
    for (int m = 0; m < M; ++m) { f[m] = __expf(f[m] - mx); sum += f[m]; }
    float inv = 1.f / sum;
    #pragma unroll
    for (int m = 0; m < M; ++m) {
      float v = f[m] * inv + A[n * M + m];
      FT[m * 40 + n] = __float2bfloat16(v);
    }
  }

  // phase 4: ot = X2 @ FA (K=32), scatter into Xb (cols >= M -> 0)
  short8 xf[4], ff[2];
  #pragma unroll
  for (int it = 0; it < 4; ++it)
    xf[it] = *(const short8*)(&Xb[(it * 16 + lr) * 40 + lg * 8]);
  #pragma unroll
  for (int jt = 0; jt < 2; ++jt)
    ff[jt] = *(const short8*)(&FT[(jt * 16 + lr) * 40 + lg * 8]);
  f32x4 acco[4][2];
  #pragma unroll
  for (int it = 0; it < 4; ++it)
    #pragma unroll
    for (int jt = 0; jt < 2; ++jt) {
      f32x4 a = (f32x4){0.f, 0.f, 0.f, 0.f};
      acco[it][jt] = __builtin_amdgcn_mfma_f32_16x16x32_bf16(xf[it], ff[jt], a, 0, 0, 0);
    }
  #pragma unroll
  for (int it = 0; it < 4; ++it)
    #pragma unroll
    for (int jt = 0; jt < 2; ++jt)
      #pragma unroll
      for (int r = 0; r < 4; ++r) {
        int c = it * 16 + lg * 4 + r;
        int m = jt * 16 + lr;
        float v = (m < M) ? acco[it][jt][r] : 0.f;
        Xb[c * 40 + m] = __float2bfloat16(v);
      }

  // phase 5: vv[m] = cv + sum_c wv[c]*ot[c][m]  (lanes 0..M-1)
  if (l < M) {
    float s = cuv[1];
    #pragma unroll 8
    for (int c = 0; c < 64; ++c)
      s += wv[c] * __bfloat162float(Xb[c * 40 + l]);
    vv[l] = s;
  }

  // phase 6: att (lanes 0..24) -> AT[n*40+m]
  if (l < 25) {
    const int n = l;
    const float uu = uub[b * 1600 + t * 25 + n];
    float f[M];
    float mx = -1e30f;
    #pragma unroll
    for (int m = 0; m < M; ++m) {
      float v = uu + vv[m];
      v = v >= 0.f ? v : 0.2f * v;
      f[m] = v;
      mx = fmaxf(mx, v);
    }
    float sum = 0.f;
    #pragma unroll
    for (int m = 0; m < M; ++m) { f[m] = __expf(f[m] - mx); sum += f[m]; }
    float inv = 1.f / sum;
    #pragma unroll
    for (int m = 0; m < M; ++m)
      AT[n * 40 + m] = __float2bfloat16(f[m] * inv + Ck[n * M + m]);
  }

  // phase 7: Z = ot @ att^T (K=32): D[i=c][j=n] -> Zt (staged in dead Xb)
  short8 of[4], af[2];
  #pragma unroll
  for (int it = 0; it < 4; ++it)
    of[it] = *(const short8*)(&Xb[(it * 16 + lr) * 40 + lg * 8]);
  #pragma unroll
  for (int jt = 0; jt < 2; ++jt)
    af[jt] = *(const short8*)(&AT[(jt * 16 + lr) * 40 + lg * 8]);
  f32x4 accz[4][2];
  #pragma unroll
  for (int it = 0; it < 4; ++it)
    #pragma unroll
    for (int jt = 0; jt < 2; ++jt) {
      f32x4 a = (f32x4){0.f, 0.f, 0.f, 0.f};
      accz[it][jt] = __builtin_amdgcn_mfma_f32_16x16x32_bf16(of[it], af[jt], a, 0, 0, 0);
    }
  __hip_bfloat16* Zt = Xb;   // Xb dead after `of` reads (accz depends on of)
  #pragma unroll
  for (int it = 0; it < 4; ++it)
    #pragma unroll
    for (int jt = 0; jt < 2; ++jt)
      #pragma unroll
      for (int r = 0; r < 4; ++r) {
        int c = it * 16 + lg * 4 + r;
        int n = jt * 16 + lr;
        if (n < 25) Zt[n * 66 + c] = __float2bfloat16(accz[it][jt][r]);
      }

  // phase 8: coalesced ZH write (lane = c, 128B per row)
  for (int n = 0; n < 25; ++n)
    ZH[(size_t)(b * 1600 + t * 25 + n) * 128 + cioff + l] = Zt[n * 66 + l];
}

// ---- merged restore: blocks 0..1023 = branch 2 (M=19), 1024..2047 = branch 3 (M=15)
__global__ __launch_bounds__(256, 3) void restore_both(
    const __hip_bfloat16* __restrict__ HbTA,
    const float* __restrict__ F19, const float* __restrict__ F15,
    const float* __restrict__ A2, const float* __restrict__ A3,
    const float* __restrict__ ubuf2, const float* __restrict__ ubuf3,
    const float* __restrict__ uv,
    const float* __restrict__ Ck2, const float* __restrict__ Ck3,
    __hip_bfloat16* __restrict__ ZH) {
  __shared__ __hip_bfloat16 XbS[4][64 * 40];
  __shared__ __hip_bfloat16 FBS[4][32 * 40];   // scf overlays this
  __shared__ __hip_bfloat16 FTS[4][32 * 40];
  __shared__ __hip_bfloat16 ATS[4][32 * 40];
  __shared__ float vvS[4][32];
  const int w = threadIdx.x >> 6;
  if (blockIdx.x < 1024) {
    restore_body<19>(blockIdx.x, HbTA, F19, A2, ubuf2, uv + 64, uv + 256, Ck2,
                     ZH, 0, XbS[w], FBS[w], FTS[w], ATS[w], vvS[w]);
  } else {
    restore_body<15>(blockIdx.x - 1024, HbTA, F15, A3, ubuf3, uv + 192, uv + 258, Ck3,
                     ZH, 64, XbS[w], FBS[w], FTS[w], ATS[w], vvS[w]);
  }
}

// ---- restore GEMM via MFMA, wave-private 32-col slices, IN PLACE, no LDS/barriers.
__global__ __launch_bounds__(256) void restore_gemm_mfma(
    __hip_bfloat16* __restrict__ ZH, const __hip_bfloat16* __restrict__ WgT,
    const float* __restrict__ bg2, const float* __restrict__ bg3,
    const float* __restrict__ sconst) {
  const int tid = threadIdx.x;
  const int wv = tid >> 6, l = tid & 63;
  const int lr = l & 15, lg = l >> 4;
  const size_t col0 = ((size_t)blockIdx.x * 4 + wv) * 32;
  const ushort* Zg = (const ushort*)ZH;
  const ushort* Wu = (const ushort*)WgT;

  short8 afr[2][2][2];
  #pragma unroll
  for (int mt = 0; mt < 2; ++mt)
    #pragma unroll
    for (int br = 0; br < 2; ++br)
      #pragma unroll
      for (int ks = 0; ks < 2; ++ks)
        afr[mt][br][ks] = *(const short8*)(
            Zg + (col0 + mt * 16 + lr) * 128 + br * 64 + ks * 32 + lg * 8);

  f32x4 acc[2][8];
  #pragma unroll
  for (int nt = 0; nt < 8; ++nt) {
    const int br = nt >> 2;
    const int g = nt * 16 + lr;
    short8 b0 = *(const short8*)(Wu + g * 64 + lg * 8);
    short8 b1 = *(const short8*)(Wu + g * 64 + 32 + lg * 8);
    #pragma unroll
    for (int mt = 0; mt < 2; ++mt) {
      f32x4 a = (f32x4){0.f, 0.f, 0.f, 0.f};
      a = __builtin_amdgcn_mfma_f32_16x16x32_bf16(afr[mt][br][0], b0, a, 0, 0, 0);
      a = __builtin_amdgcn_mfma_f32_16x16x32_bf16(afr[mt][br][1], b1, a, 0, 0, 0);
      acc[mt][nt] = a;
    }
  }

  #pragma unroll
  for (int mt = 0; mt < 2; ++mt)
    #pragma unroll
    for (int r = 0; r < 4; ++r) {
      const size_t col = col0 + mt * 16 + lg * 4 + r;
      const int n = (int)(col % 25);
      const float s2v = sconst[n], s3v = sconst[25 + n];
      ushort* zp = (ushort*)ZH + col * 128;
      #pragma unroll
      for (int nt = 0; nt < 8; ++nt) {
        const int g = nt * 16 + lr;
        const float bo = (nt < 4) ? bg2[g] : bg3[g - 64];
        const float s = (nt < 4) ? s2v : s3v;
        float v = fmaxf((acc[mt][nt][r] + bo * s) * BN_SCALE_F, 0.f);
        __hip_bfloat16 h = __float2bfloat16(v);
        zp[g] = *(ushort*)&h;
      }
    }
}

// ---- final conv via MFMA, 8 waves/block (512 thr): wave = 80 cols x 32 o.
__global__ __launch_bounds__(512) void conv_mfma(
    const __hip_bfloat16* __restrict__ HbTA, const __hip_bfloat16* __restrict__ HbTB,
    const __hip_bfloat16* __restrict__ Wb, const float* __restrict__ x,
    const float* __restrict__ btcn, const float* __restrict__ aout_,
    float* __restrict__ out) {
  const int b = blockIdx.x / 5;
  const int col0 = (blockIdx.x % 5) * 320;
  const int tid = threadIdx.x;
  const int wave = tid >> 6, l = tid & 63;
  const int wcol = wave & 3, who = wave >> 2;
  const int lr = l & 15, lg = l >> 4;

  __shared__ __hip_bfloat16 Hl[384 * 40];
  __shared__ __hip_bfloat16 Wl[3 * 64 * 40];

  f32x4 acc[5][2];
  #pragma unroll
  for (int mt = 0; mt < 5; ++mt)
    #pragma unroll
    for (int nt = 0; nt < 2; ++nt) acc[mt][nt] = (f32x4){0.f, 0.f, 0.f, 0.f};

  const int base_a = (wcol * 80 + lr + 7) * 40 + lg * 8;
  const int base_b = (who * 32 + lr) * 40 + lg * 8;

  for (int ch = 0; ch < 8; ++ch) {
    const __hip_bfloat16* Ht = (ch < 4) ? HbTA : HbTB;
    const int ci0 = (ch & 3) * 32;
    const int wci0 = ch * 32;
    __syncthreads();
    #pragma unroll
    for (int it = 0; it < 3; ++it) {
      int idx = it * 512 + tid;
      int colr = idx >> 2, seg = idx & 3;
      int gcol = col0 - 32 + colr;
      uint4 v = {0u, 0u, 0u, 0u};
      if (gcol >= 0 && gcol < 1600)
        v = *(const uint4*)(Ht + ((size_t)(b * 1600 + gcol) * 128 + ci0 + seg * 8));
      *(uint4*)(&Hl[colr * 40 + seg * 8]) = v;
    }
    for (int idx = tid; idx < 768; idx += 512) {
      int o = (idx >> 2) & 63, kt = idx >> 8, seg = idx & 3;
      uint4 v = *(const uint4*)(Wb + ((kt * 64 + o) * 256 + wci0 + seg * 8));
      *(uint4*)(&Wl[(kt * 64 + o) * 40 + seg * 8]) = v;
    }
    __syncthreads();
    #pragma unroll
    for (int kt = 0; kt < 3; ++kt) {
      short8 af[5], bf[2];
      const int ab = base_a + kt * 1000;
      const int bb = base_b + kt * 2560;
      #pragma unroll
      for (int mt = 0; mt < 5; ++mt) af[mt] = *(const short8*)(&Hl[ab + mt * 640]);
      #pragma unroll
      for (int nt = 0; nt < 2; ++nt) bf[nt] = *(const short8*)(&Wl[bb + nt * 640]);
      #pragma unroll
      for (int mt = 0; mt < 5; ++mt)
        #pragma unroll
        for (int nt = 0; nt < 2; ++nt)
          acc[mt][nt] = __builtin_amdgcn_mfma_f32_16x16x32_bf16(af[mt], bf[nt],
                                                                acc[mt][nt], 0, 0, 0);
    }
  }

  const float aout = aout_[0];
  const int colbase = col0 + wcol * 80 + lg * 4;
  #pragma unroll
  for (int nt = 0; nt < 2; ++nt) {
    const int o = who * 32 + nt * 16 + lr;
    const float bo = btcn[o];
    const float* xr = x + ((size_t)b * 64 + o) * 1600 + colbase;
    float* op = out + ((size_t)b * 64 + o) * 1600 + colbase;
    #pragma unroll
    for (int mt = 0; mt < 5; ++mt) {
      float4 xv = *(const float4*)(xr + mt * 16);
      f32x4 a4 = acc[mt][nt];
      float4 res;
      float v0 = (a4[0] + bo) * BN_SCALE_F + xv.x;
      float v1 = (a4[1] + bo) * BN_SCALE_F + xv.y;
      float v2 = (a4[2] + bo) * BN_SCALE_F + xv.z;
      float v3 = (a4[3] + bo) * BN_SCALE_F + xv.w;
      res.x = v0 >= 0.f ? v0 : aout * v0;
      res.y = v1 >= 0.f ? v1 : aout * v1;
      res.z = v2 >= 0.f ? v2 : aout * v2;
      res.w = v3 >= 0.f ? v3 : aout * v3;
      *(float4*)(op + mt * 16) = res;
    }
  }
}

extern "C" void kernel_launch(void* const* d_in, const int* in_sizes, int n_in,
                              void* d_out, int out_size, void* d_ws, size_t ws_size,
                              hipStream_t stream) {
  const float* x     = (const float*)d_in[0];
  const float* A1    = (const float*)d_in[1];
  const float* A2    = (const float*)d_in[2];
  const float* A3    = (const float*)d_in[3];
  const float* Wp1   = (const float*)d_in[4];
  const float* ap1   = (const float*)d_in[5];
  const float* Wp2   = (const float*)d_in[6];
  const float* ap2   = (const float*)d_in[7];
  const float* Wg2   = (const float*)d_in[8];
  const float* bg2   = (const float*)d_in[9];
  const float* Wt2   = (const float*)d_in[10];
  const float* bt2   = (const float*)d_in[11];
  const float* Wph2  = (const float*)d_in[12];
  const float* bph2  = (const float*)d_in[13];
  const float* wcat2 = (const float*)d_in[14];
  const float* Ck2   = (const float*)d_in[15];
  const float* Wg3   = (const float*)d_in[16];
  const float* bg3   = (const float*)d_in[17];
  const float* Wt3   = (const float*)d_in[18];
  const float* bt3   = (const float*)d_in[19];
  const float* Wph3  = (const float*)d_in[20];
  const float* bph3  = (const float*)d_in[21];
  const float* wcat3 = (const float*)d_in[22];
  const float* Ck3   = (const float*)d_in[23];
  const float* Wtcn  = (const float*)d_in[24];
  const float* btcn  = (const float*)d_in[25];
  const float* aout  = (const float*)d_in[26];
  float* out = (float*)d_out;
  float* ws  = (float*)d_ws;

  __hip_bfloat16* ZH   = (__hip_bfloat16*)(ws + 6553600);   // Pp2 bf16 earlier life
  __hip_bfloat16* HbTA = (__hip_bfloat16*)(ws + 13107200);
  float* x2b  = ws + 19660800;
  float* preb = ws + 24641536;
  float* F19  = ws + 29622272;
  float* F15  = ws + 29652672;
  float* uv   = ws + 29676672;
  float* partials = x2b;
  __hip_bfloat16* Wb   = (__hip_bfloat16*)preb;             // 49,152 bf16
  __hip_bfloat16* WgT  = (__hip_bfloat16*)(preb + 24576);   // 8,192 bf16
  float* sconst        = preb + 28672;                      // 50 f
  float* ubuf2         = preb + 32768;                      // 102,400 f
  float* ubuf3         = preb + 139264;                     // 102,400 f

  prep_all<<<225, 256, 0, stream>>>(Wt2, bt2, Wph2, bph2, wcat2,
                                    Wt3, bt3, Wph3, bph3, wcat3,
                                    Ck2, Ck3, Wg2, Wg3, Wtcn,
                                    uv, sconst, WgT, Wb);
  ldnet1_mfma<<<1024, 256, 0, stream>>>(x, A1, uv, ZH /*Pp2*/, HbTA, ubuf2, ubuf3);

  // both pools in one pass over Pp2 bf16 (block per (b, channel))
  pool_partial<<<4096, 256, 0, stream>>>(ZH, Wp1, Wp2, ap1, ap2, partials);
  pool_reduce<<<64, 256, 0, stream>>>(partials, F19, F15);

  // both restore branches in ONE launch (disjoint ZH halves; Pp2 dead after pools)
  restore_both<<<2048, 256, 0, stream>>>(HbTA, F19, F15, A2, A3,
                                         ubuf2, ubuf3, uv, Ck2, Ck3, ZH);

  // shared Wg GEMM via MFMA, in place: ZH rows become HbTB rows (xcd2|xcd3 bf16)
  restore_gemm_mfma<<<800, 256, 0, stream>>>(ZH, WgT, bg2, bg3, sconst);

  // final conv via MFMA + bias + BN + residual + PReLU (8-wave blocks)
  conv_mfma<<<320, 512, 0, stream>>>(HbTA, ZH, Wb, x, btcn, aout, out);
}